// Round 6
// baseline (23009.753 us; speedup 1.0000x reference)
//
#include <hip/hip_runtime.h>
#include <hip/hip_bf16.h>
#include <math.h>

#define PAD_ID 0
#define UNK_ID 1
#define START_ID 2
#define END_ID 3

constexpr int B = 16, S = 512, T = 128, V = 32000, E = 128, H = 256, D = 512;
constexpr int C3 = 1536;        // 3*D
constexpr int VO = 31997;       // V-3
constexpr int JS = 32000;       // padded col count for outT2
constexpr int NBLK_DEC = 128;   // decoder persistent blocks (u-slice = 4)
constexpr int NBLK_ENC = 64;    // encoder persistent blocks (2 dir x 32 u-slices of 8)

typedef short short8 __attribute__((ext_vector_type(8)));
typedef float f32x4 __attribute__((ext_vector_type(4)));

__device__ __forceinline__ float sigm(float x) { return 1.0f / (1.0f + __expf(-x)); }
__device__ __forceinline__ short bf16s(float x) {
    __hip_bfloat16 h = __float2bfloat16(x);
    return *reinterpret_cast<short*>(&h);
}
__device__ __forceinline__ float bflo(unsigned int u) { return __uint_as_float(u << 16); }
__device__ __forceinline__ float bfhi(unsigned int u) { return __uint_as_float(u & 0xffff0000u); }

// ---------------- flag-tree grid barrier: per-block flag line (parallel release-stores),
// master wave gathers, single `go` broadcast. No RMW serialization.
// bar layout: flags[nblk*16] ints (64B/block), then go at bar[nblk*16].
__device__ __forceinline__ void flagbar(int* bar, int nblk, int ep) {
    __syncthreads();
    int tid = threadIdx.x;
    int* go = bar + nblk * 16;
    if (blockIdx.x == 0) {
        if (tid == 0) {
            __threadfence();
            __hip_atomic_store(bar, ep, __ATOMIC_RELEASE, __HIP_MEMORY_SCOPE_AGENT);
        }
        if (tid < 64) {
            for (int i = tid; i < nblk; i += 64) {
                while (__hip_atomic_load(bar + i * 16, __ATOMIC_ACQUIRE, __HIP_MEMORY_SCOPE_AGENT) < ep)
                    __builtin_amdgcn_s_sleep(1);
            }
        }
        __syncthreads();
        if (tid == 0)
            __hip_atomic_store(go, ep, __ATOMIC_RELEASE, __HIP_MEMORY_SCOPE_AGENT);
    } else {
        if (tid == 0) {
            __threadfence();
            __hip_atomic_store(bar + blockIdx.x * 16, ep, __ATOMIC_RELEASE, __HIP_MEMORY_SCOPE_AGENT);
            while (__hip_atomic_load(go, __ATOMIC_ACQUIRE, __HIP_MEMORY_SCOPE_AGENT) < ep)
                __builtin_amdgcn_s_sleep(1);
            __threadfence();
        }
        __syncthreads();
    }
}

// ---------------- weight packing: W[4H][K] -> P[k][u] = float4 of 4 gates (f32, for gate kernels)
__global__ void pack4_kernel(const float* __restrict__ W, float4* __restrict__ P, int Hn, int K) {
    int i = blockIdx.x * blockDim.x + threadIdx.x;
    if (i >= K * Hn) return;
    int k = i / Hn, u = i - k * Hn;
    float4 v;
    v.x = W[(size_t)(0 * Hn + u) * K + k];
    v.y = W[(size_t)(1 * Hn + u) * K + k];
    v.z = W[(size_t)(2 * Hn + u) * K + k];
    v.w = W[(size_t)(3 * Hn + u) * K + k];
    P[(size_t)k * Hn + u] = v;
}

// ---------------- encoder Whh pack: W[4H][H] -> P[u][g][k] bf16 (i = u*1024 + g*256 + k)
__global__ void packencT_k(const float* __restrict__ W, ushort* __restrict__ P) {
    int i = blockIdx.x * blockDim.x + threadIdx.x;
    if (i >= 4 * H * H) return;
    int k = i & 255, g = (i >> 8) & 3, u = i >> 10;
    P[i] = (ushort)bf16s(W[(size_t)(g * H + u) * H + k]);
}

// ---------------- decoder weight pack: W[4D][D] -> P[u][g][k] bf16 (i = ((u*4+g)*512)+k)
__global__ void packdec_k(const float* __restrict__ W, ushort* __restrict__ P) {
    int i = blockIdx.x * blockDim.x + threadIdx.x;
    if (i >= D * D * 4) return;
    int k = i & 511, g = (i >> 9) & 3, u = i >> 11;
    P[i] = (ushort)bf16s(W[(size_t)(g * D + u) * D + k]);
}

// ---------------- encoder layer-0 gate preactivations for both directions
__global__ void enc0_gates(const int* __restrict__ ids, const float* __restrict__ emb,
                           const float4* __restrict__ Pf, const float* __restrict__ bf_,
                           const float4* __restrict__ Pb, const float* __restrict__ bb_,
                           float* __restrict__ Gf, float* __restrict__ Gb) {
    int n = blockIdx.x;
    int s = n / B, b = n - s * B;
    int u = threadIdx.x;
    __shared__ float xr[E];
    int tok = ids[b * S + s];
    if (tok >= V) tok = UNK_ID;
    if (u < E) xr[u] = emb[(size_t)tok * E + u];
    __syncthreads();
    float a0 = bf_[0 * H + u], a1 = bf_[1 * H + u], a2 = bf_[2 * H + u], a3 = bf_[3 * H + u];
#pragma unroll 4
    for (int k = 0; k < E; k++) {
        float xv = xr[k]; float4 w = Pf[k * H + u];
        a0 += xv * w.x; a1 += xv * w.y; a2 += xv * w.z; a3 += xv * w.w;
    }
    float* g = Gf + (size_t)n * 4 * H;
    g[0 * H + u] = a0; g[1 * H + u] = a1; g[2 * H + u] = a2; g[3 * H + u] = a3;
    a0 = bb_[0 * H + u]; a1 = bb_[1 * H + u]; a2 = bb_[2 * H + u]; a3 = bb_[3 * H + u];
#pragma unroll 4
    for (int k = 0; k < E; k++) {
        float xv = xr[k]; float4 w = Pb[k * H + u];
        a0 += xv * w.x; a1 += xv * w.y; a2 += xv * w.z; a3 += xv * w.w;
    }
    g = Gb + (size_t)n * 4 * H;
    g[0 * H + u] = a0; g[1 * H + u] = a1; g[2 * H + u] = a2; g[3 * H + u] = a3;
}

// ---------------- encoder layer-1 gate preactivations (input = concat(h0f,h0b))
__global__ void enc1_gates(const float* __restrict__ h0f, const float* __restrict__ h0b,
                           const float4* __restrict__ Pf, const float* __restrict__ bf_,
                           const float4* __restrict__ Pb, const float* __restrict__ bb_,
                           float* __restrict__ Gf, float* __restrict__ Gb) {
    int n = blockIdx.x;      // s*B+b
    int u = threadIdx.x;     // 256
    __shared__ float xr[D];
    xr[u] = h0f[(size_t)n * H + u];
    xr[H + u] = h0b[(size_t)n * H + u];
    __syncthreads();
    float a0 = bf_[0 * H + u], a1 = bf_[1 * H + u], a2 = bf_[2 * H + u], a3 = bf_[3 * H + u];
#pragma unroll 4
    for (int k = 0; k < D; k++) {
        float xv = xr[k]; float4 w = Pf[k * H + u];
        a0 += xv * w.x; a1 += xv * w.y; a2 += xv * w.z; a3 += xv * w.w;
    }
    float* g = Gf + (size_t)n * 4 * H;
    g[0 * H + u] = a0; g[1 * H + u] = a1; g[2 * H + u] = a2; g[3 * H + u] = a3;
    a0 = bb_[0 * H + u]; a1 = bb_[1 * H + u]; a2 = bb_[2 * H + u]; a3 = bb_[3 * H + u];
#pragma unroll 4
    for (int k = 0; k < D; k++) {
        float xv = xr[k]; float4 w = Pb[k * H + u];
        a0 += xv * w.x; a1 += xv * w.y; a2 += xv * w.z; a3 += xv * w.w;
    }
    g = Gb + (size_t)n * 4 * H;
    g[0 * H + u] = a0; g[1 * H + u] = a1; g[2 * H + u] = a2; g[3 * H + u] = a3;
}

// ---------------- encoder persistent scan, one layer, both dirs.
// grid 64 = dir*32 + ub (u-slice 8). 256 threads = (uh 4)(g 4)(b 16); cell threads = 128.
__global__ void __launch_bounds__(256) enc_pscan(
        const float* __restrict__ Gf, const float* __restrict__ Gb,
        const ushort* __restrict__ Pf, const ushort* __restrict__ Pb,   // [u][g][k] bf16
        float* __restrict__ hof, float* __restrict__ hob,
        float* __restrict__ hfin /* [B][2H] */,
        float* __restrict__ hg /* [2buf][2dir][B][H] f32 */, int* __restrict__ bar) {
    __shared__ __align__(16) float Wl[32 * 258];   // [u_loc*4+g][256 + 2 pad]
    __shared__ float hh[256 * 17];                 // [k][b] padded
    __shared__ float gs[512];                      // [u_loc][b][g]
    int blk = blockIdx.x;
    int dirb = blk >> 5, ub = blk & 31;
    const float* G = dirb ? Gb : Gf;
    const ushort* P = dirb ? Pb : Pf;
    float* ho = dirb ? hob : hof;
    int tid = threadIdx.x;
    int b = tid & 15, g = (tid >> 4) & 3, uh = tid >> 6;

    // stage + unpack weight slice (8 u x 4 g x 256 k) to f32 LDS
    const uint* wsrc = (const uint*)(P + (size_t)ub * 8192);
    for (int i = tid; i < 4096; i += 256) {
        int r = i >> 7, c = i & 127;
        uint wv = wsrc[i];
        Wl[r * 258 + 2 * c] = bflo(wv);
        Wl[r * 258 + 2 * c + 1] = bfhi(wv);
    }
    if (tid < 128) {
        int u_loc = tid >> 4, bb = tid & 15;
        hg[dirb * (B * H) + bb * H + ub * 8 + u_loc] = 0.f;
    }
    float c_st = 0.f;
    int ep = 1;
    flagbar(bar, NBLK_ENC, ep);

    int u0 = uh * 2, u1 = u0 + 1;
    const float* w0 = Wl + (u0 * 4 + g) * 258;
    const float* w1 = Wl + (u1 * 4 + g) * 258;
    for (int step = 0; step < S; step++) {
        int s = dirb ? (S - 1 - step) : step;
        int cur = step & 1;
        const float* hgd = hg + cur * (2 * B * H) + dirb * (B * H);   // [b][k]
#pragma unroll
        for (int j = 0; j < 16; j++) {
            int flat = j * 256 + tid;
            int bb = flat >> 8, kk = flat & 255;
            hh[kk * 17 + bb] = hgd[flat];
        }
        __syncthreads();
        float acc0 = 0.f, acc1 = 0.f;
#pragma unroll 8
        for (int k = 0; k < 256; k++) {
            float hv = hh[k * 17 + b];
            acc0 += w0[k] * hv;
            acc1 += w1[k] * hv;
        }
        gs[u0 * 64 + b * 4 + g] = acc0;
        gs[u1 * 64 + b * 4 + g] = acc1;
        __syncthreads();
        if (tid < 128) {
            int u_loc = tid >> 4, bb = tid & 15;
            int uu = ub * 8 + u_loc;
            const float* base = gs + u_loc * 64 + bb * 4;
            const float* gG = G + ((size_t)(s * B + bb)) * 1024 + uu;
            float g0 = gG[0]   + base[0];
            float g1 = gG[256] + base[1];
            float g2 = gG[512] + base[2];
            float g3 = gG[768] + base[3];
            float ig = sigm(g0), fg = sigm(g1), gt = tanhf(g2), og = sigm(g3);
            c_st = fg * c_st + ig * gt;
            float hn = og * tanhf(c_st);
            hg[(cur ^ 1) * (2 * B * H) + dirb * (B * H) + bb * H + uu] = hn;
            ho[((size_t)(s * B + bb)) * H + uu] = hn;
            if (step == S - 1) hfin[bb * (2 * H) + dirb * H + uu] = hn;
        }
        flagbar(bar, NBLK_ENC, ++ep);
    }
}

// ---------------- decoder layer-0 input gates (teacher tokens). grid T*B (n=t*B+b), 512 thr.
__global__ void dec0_gates(const int* __restrict__ tgt, const float* __restrict__ emb,
                           const float4* __restrict__ P, const float* __restrict__ bias,
                           float* __restrict__ G) {
    int n = blockIdx.x;
    int t = n / B, b = n - t * B;
    int u = threadIdx.x;
    __shared__ float xr[E];
    int tok;
    if (t == 0) tok = START_ID;
    else { tok = tgt[b * T + (t - 1)]; if (tok >= V) tok = UNK_ID; }
    if (u < E) xr[u] = emb[(size_t)tok * E + u];
    __syncthreads();
    float a0 = bias[0 * D + u], a1 = bias[1 * D + u], a2 = bias[2 * D + u], a3 = bias[3 * D + u];
#pragma unroll 4
    for (int k = 0; k < E; k++) {
        float xv = xr[k]; float4 w = P[k * D + u];
        a0 += xv * w.x; a1 += xv * w.y; a2 += xv * w.z; a3 += xv * w.w;
    }
    float* g = G + (size_t)n * 4 * D;
    g[0 * D + u] = a0; g[1 * D + u] = a1; g[2 * D + u] = a2; g[3 * D + u] = a3;
}

// ---------------- decoder persistent 2-layer scan.
// grid 128 blocks (u-slice 4), 512 threads = (u_loc 4, g 4, kq 2, b 16).
// ONE grid barrier per step (after phase A); post-B barrier proven redundant.
__global__ void __launch_bounds__(512) dec_scan2(
        const float* __restrict__ G0, const ushort* __restrict__ pb0,
        const ushort* __restrict__ pb1i, const ushort* __restrict__ pb1h,
        const float* __restrict__ b1, const float* __restrict__ hinit,
        float* __restrict__ h0g /* [2][B][D] */, float* __restrict__ h1g /* [2][B][D] */,
        float* __restrict__ h1out, int* __restrict__ bar) {
    __shared__ __align__(16) ushort W0s[16 * 528];
    __shared__ __align__(16) ushort W1is[16 * 528];
    __shared__ __align__(16) ushort W1hs[16 * 528];
    __shared__ float red[4][4][2][16];
    int tid = threadIdx.x;
    int u0 = blockIdx.x * 4;
    int u_loc = tid >> 7, g = (tid >> 5) & 3, kq = (tid >> 4) & 1, b = tid & 15;

    {
        const uint4* s0 = (const uint4*)(pb0 + (size_t)u0 * 2048);
        const uint4* s1 = (const uint4*)(pb1i + (size_t)u0 * 2048);
        const uint4* s2 = (const uint4*)(pb1h + (size_t)u0 * 2048);
        uint4* d0 = (uint4*)W0s; uint4* d1 = (uint4*)W1is; uint4* d2 = (uint4*)W1hs;
        for (int i = tid; i < 1024; i += 512) {
            int r = i >> 6, c = i & 63;
            d0[r * 66 + c] = s0[i]; d1[r * 66 + c] = s1[i]; d2[r * 66 + c] = s2[i];
        }
    }
    float c0v = 0.f, c1v = 0.f;
    if (tid < 64) {
        int ul = tid >> 4, bb = tid & 15;
        h0g[bb * 512 + u0 + ul] = hinit[bb * 512 + u0 + ul];
        h1g[bb * 512 + u0 + ul] = hinit[B * D + bb * 512 + u0 + ul];
    }
    int ep = 1;
    flagbar(bar, NBLK_DEC, ep);

    int cur = 0;
    for (int t = 0; t < T; t++) {
        float* h0c = h0g + cur * (B * D);
        float* h0n = h0g + (cur ^ 1) * (B * D);
        float* h1c = h1g + cur * (B * D);
        float* h1n = h1g + (cur ^ 1) * (B * D);
        // ---- phase A: layer-0 gate partial
        {
            const uint2* w = (const uint2*)(W0s + (u_loc * 4 + g) * 528) + kq * 64;
            const float* hp = h0c + b * 512 + kq * 256;
            float acc = 0.f;
#pragma unroll 4
            for (int i = 0; i < 64; i++) {
                uint2 wv = w[i];
                float4 hv = *(const float4*)(hp + i * 4);
                acc += bflo(wv.x) * hv.x + bfhi(wv.x) * hv.y + bflo(wv.y) * hv.z + bfhi(wv.y) * hv.w;
            }
            red[u_loc][g][kq][b] = acc;
        }
        __syncthreads();
        if (tid < 64) {
            int ul = tid >> 4, bb = tid & 15;
            const float* gg = G0 + ((size_t)(t * B + bb)) * 2048 + (u0 + ul);
            float g0 = gg[0]    + red[ul][0][0][bb] + red[ul][0][1][bb];
            float g1 = gg[512]  + red[ul][1][0][bb] + red[ul][1][1][bb];
            float g2 = gg[1024] + red[ul][2][0][bb] + red[ul][2][1][bb];
            float g3 = gg[1536] + red[ul][3][0][bb] + red[ul][3][1][bb];
            float ig = sigm(g0), fg = sigm(g1), gt = tanhf(g2), og = sigm(g3);
            c0v = fg * c0v + ig * gt;
            h0n[bb * 512 + u0 + ul] = og * tanhf(c0v);
        }
        flagbar(bar, NBLK_DEC, ++ep);   // all blocks' h0[t] visible
        // ---- phase B: layer-1 gates = b1 + W1i*h0[t] + W1h*h1[t-1]
        {
            const uint2* wA = (const uint2*)(W1is + (u_loc * 4 + g) * 528) + kq * 64;
            const uint2* wB = (const uint2*)(W1hs + (u_loc * 4 + g) * 528) + kq * 64;
            const float* hA = h0n + b * 512 + kq * 256;
            const float* hB = h1c + b * 512 + kq * 256;
            float acc = 0.f;
#pragma unroll 4
            for (int i = 0; i < 64; i++) {
                uint2 wv = wA[i];
                float4 hv = *(const float4*)(hA + i * 4);
                acc += bflo(wv.x) * hv.x + bfhi(wv.x) * hv.y + bflo(wv.y) * hv.z + bfhi(wv.y) * hv.w;
                uint2 wv2 = wB[i];
                float4 hv2 = *(const float4*)(hB + i * 4);
                acc += bflo(wv2.x) * hv2.x + bfhi(wv2.x) * hv2.y + bflo(wv2.y) * hv2.z + bfhi(wv2.y) * hv2.w;
            }
            red[u_loc][g][kq][b] = acc;
        }
        __syncthreads();
        if (tid < 64) {
            int ul = tid >> 4, bb = tid & 15;
            int uu = u0 + ul;
            float g0 = b1[uu]        + red[ul][0][0][bb] + red[ul][0][1][bb];
            float g1 = b1[512 + uu]  + red[ul][1][0][bb] + red[ul][1][1][bb];
            float g2 = b1[1024 + uu] + red[ul][2][0][bb] + red[ul][2][1][bb];
            float g3 = b1[1536 + uu] + red[ul][3][0][bb] + red[ul][3][1][bb];
            float ig = sigm(g0), fg = sigm(g1), gt = tanhf(g2), og = sigm(g3);
            c1v = fg * c1v + ig * gt;
            float h1n_v = og * tanhf(c1v);
            h1n[bb * 512 + uu] = h1n_v;
            h1out[((size_t)(t * B + bb)) * 512 + uu] = h1n_v;
        }
        __syncthreads();   // protect `red` reuse by next phase A (no grid barrier needed)
        cur ^= 1;
    }
}

// ---------------- transpose enc hidden to [b][k(512)][s] for coalesced score dots
__global__ void build_encht(const float* __restrict__ h1f, const float* __restrict__ h1b,
                            float* __restrict__ et) {
    int blk = blockIdx.x;                 // b*256 + kt*16 + st
    int b = blk >> 8, rem = blk & 255;
    int kt = rem >> 4, st = rem & 15;
    int c = threadIdx.x & 31, r = threadIdx.x >> 5;   // r in 0..7
    __shared__ float tile[32][33];
#pragma unroll
    for (int i = 0; i < 4; i++) {
        int sl = r + i * 8;               // s_local
        int s = st * 32 + sl;
        int k = kt * 32 + c;              // lane-contiguous over k
        float v = (k < H) ? h1f[((size_t)(s * B + b)) * H + k]
                          : h1b[((size_t)(s * B + b)) * H + (k - H)];
        tile[c][sl] = v;                  // tile[k_local][s_local]
    }
    __syncthreads();
#pragma unroll
    for (int i = 0; i < 4; i++) {
        int kl = r + i * 8;
        et[(size_t)b * D * S + (size_t)(kt * 32 + kl) * S + st * 32 + c] = tile[kl][c];
    }
}

// ---------------- q projections. grid T*B (n=t*B+b), 512 threads
__global__ void qproj(const float* __restrict__ h1d, const float* __restrict__ Wenc,
                      const float* __restrict__ Wdec, float* __restrict__ qe, float* __restrict__ qd) {
    int n = blockIdx.x;
    int o = threadIdx.x;
    __shared__ float hr[D];
    hr[o] = h1d[(size_t)n * D + o];
    __syncthreads();
    float ae = 0.f, ad = 0.f;
#pragma unroll 4
    for (int k = 0; k < D; k++) {
        float hk = hr[k];
        ae += hk * Wenc[k * D + o];
        ad += hk * Wdec[k * D + o];
    }
    qe[(size_t)n * D + o] = ae;
    qd[(size_t)n * D + o] = ad;
}

// ---------------- e = exp(min(score,30)). grid B*T (bt=b*T+t), 512 threads (s)
__global__ void escore(const float* __restrict__ qe, const float* __restrict__ et,
                       float* __restrict__ ew) {
    int bt = blockIdx.x;
    int b = bt / T, t = bt - b * T;
    int sx = threadIdx.x;
    __shared__ float q[D];
    q[sx] = qe[((size_t)(t * B + b)) * D + sx];
    __syncthreads();
    float acc = 0.f;
    const float* eb = et + (size_t)b * D * S + sx;
#pragma unroll 4
    for (int k = 0; k < D; k++) { acc += q[k] * eb[0]; eb += S; }
    acc = fminf(acc, 30.0f);
    ew[(size_t)bt * S + sx] = __expf(acc);
}

// ---------------- temporal normalization (prefix over t, in place)
__global__ void temporal_k(float* __restrict__ ew) {
    int i = blockIdx.x * blockDim.x + threadIdx.x;
    if (i >= B * S) return;
    int b = i / S, sx = i - b * S;
    float cum = 0.f;
    for (int t = 0; t < T; t++) {
        size_t idx = ((size_t)(b * T + t)) * S + sx;
        float v = ew[idx];
        ew[idx] = v / (t == 0 ? 1.0f : (cum + 1e-8f));
        cum += v;
    }
}

// ---------------- attention softmax over s + enc context + copy prob. grid B*T, 512 thr
__global__ void attnctx(const float* __restrict__ ew, const int* __restrict__ ids,
                        const int* __restrict__ tgt,
                        const float* __restrict__ h1f, const float* __restrict__ h1b,
                        float* __restrict__ ectx, float* __restrict__ copyp) {
    int bt = blockIdx.x;
    int b = bt / T, t = bt - b * T;
    int tid = threadIdx.x;
    __shared__ float aw[S];
    __shared__ float red[512];
    float v = ew[(size_t)bt * S + tid];
    int tok = ids[b * S + tid];
    bool pad = (tok == PAD_ID);
    float vm = pad ? -INFINITY : v;
    red[tid] = vm; __syncthreads();
    for (int w = 256; w > 0; w >>= 1) { if (tid < w) red[tid] = fmaxf(red[tid], red[tid + w]); __syncthreads(); }
    float m = red[0]; __syncthreads();
    float ex = pad ? 0.f : __expf(vm - m);
    red[tid] = ex; __syncthreads();
    for (int w = 256; w > 0; w >>= 1) { if (tid < w) red[tid] += red[tid + w]; __syncthreads(); }
    float Z = red[0]; __syncthreads();
    float a = ex / Z;
    aw[tid] = a;
    int nt = tgt[b * T + t];
    red[tid] = (tok == nt) ? a : 0.f; __syncthreads();
    for (int w = 256; w > 0; w >>= 1) { if (tid < w) red[tid] += red[tid + w]; __syncthreads(); }
    if (tid == 0) copyp[bt] = red[0];
    __syncthreads();
    int d = tid;
    const float* hp = (d < H) ? (h1f + (size_t)b * H + d) : (h1b + (size_t)b * H + (d - H));
    float acc = 0.f;
#pragma unroll 4
    for (int s2 = 0; s2 < S; s2++) { acc += aw[s2] * hp[0]; hp += B * H; }
    ectx[(size_t)bt * D + d] = acc;
}

// ---------------- intra-decoder attention. grid B*T, 128 threads
__global__ void decattn(const float* __restrict__ qd, const float* __restrict__ h1d,
                        float* __restrict__ dctx) {
    int bt = blockIdx.x;
    int b = bt / T, t = bt - b * T;
    int tid = threadIdx.x;
    __shared__ float q[D];
    __shared__ float wl[T];
    __shared__ float red[128];
    for (int i = tid; i < D; i += 128) q[i] = qd[((size_t)(t * B + b)) * D + i];
    __syncthreads();
    float sc = -INFINITY;
    if (tid < t) {
        const float* hu = h1d + ((size_t)(tid * B + b)) * D;
        float a = 0.f;
#pragma unroll 4
        for (int k = 0; k < D; k++) a += q[k] * hu[k];
        sc = a;
    }
    red[tid] = sc; __syncthreads();
    for (int w = 64; w > 0; w >>= 1) { if (tid < w) red[tid] = fmaxf(red[tid], red[tid + w]); __syncthreads(); }
    float m = red[0]; __syncthreads();
    float ex = (tid < t) ? __expf(sc - m) : 0.f;
    red[tid] = ex; __syncthreads();
    for (int w = 64; w > 0; w >>= 1) { if (tid < w) red[tid] += red[tid + w]; __syncthreads(); }
    float Z = red[0]; __syncthreads();
    wl[tid] = (t > 0) ? (ex / Z) : 0.f;
    __syncthreads();
    for (int d = tid; d < D; d += 128) {
        float acc = 0.f;
        for (int u = 0; u < t; u++) acc += wl[u] * h1d[((size_t)(u * B + b)) * D + d];
        dctx[(size_t)bt * D + d] = acc;
    }
}

// ---------------- concat + p_gen. grid B*T, 512 threads
__global__ void concat_k(const float* __restrict__ h1d, const float* __restrict__ ectx,
                         const float* __restrict__ dctx, const float* __restrict__ sW,
                         const float* __restrict__ sb, float* __restrict__ cc,
                         float* __restrict__ pgen) {
    int bt = blockIdx.x;
    int b = bt / T, t = bt - b * T;
    int d = threadIdx.x;
    __shared__ float red[512];
    float v0 = h1d[((size_t)(t * B + b)) * D + d];
    float v1 = ectx[(size_t)bt * D + d];
    float v2 = dctx[(size_t)bt * D + d];
    float* c = cc + (size_t)bt * C3;
    c[d] = v0; c[D + d] = v1; c[2 * D + d] = v2;
    red[d] = v0 * sW[d] + v1 * sW[D + d] + v2 * sW[2 * D + d];
    __syncthreads();
    for (int w = 256; w > 0; w >>= 1) { if (d < w) red[d] += red[d + w]; __syncthreads(); }
    if (d == 0) pgen[bt] = 1.f / (1.f + __expf(-(red[0] + sb[0])));
}

// ---------------- out_proj, packed-k layout for MFMA B-fragments.
__global__ void outprojT_k(const float* __restrict__ emb, const float* __restrict__ Wvoc,
                           __hip_bfloat16* __restrict__ outT2) {
    int j0 = blockIdx.x * 32;
    int jl = threadIdx.x & 31, oq = threadIdx.x >> 5;   // oq in 0..7
    __shared__ float er[32][E + 1];                      // +1 pad
    for (int i = threadIdx.x; i < 32 * E; i += 256) {
        int jj = i >> 7, e = i & 127;
        int j = j0 + jj;
        er[jj][e] = (j < VO) ? emb[(size_t)(3 + j) * E + e] : 0.f;
    }
    __syncthreads();
    int j = j0 + jl;
#pragma unroll 1
    for (int i = 0; i < 24; i++) {
        int o = oq * 24 + i;                             // octet index 0..191
        int k0 = o * 8;
        float acc[8];
#pragma unroll
        for (int kk = 0; kk < 8; kk++) acc[kk] = 0.f;
#pragma unroll 4
        for (int e = 0; e < E; e++) {
            float x = er[jl][e];
            float4 w0 = *(const float4*)(Wvoc + (size_t)e * C3 + k0);
            float4 w1 = *(const float4*)(Wvoc + (size_t)e * C3 + k0 + 4);
            acc[0] += x * w0.x; acc[1] += x * w0.y; acc[2] += x * w0.z; acc[3] += x * w0.w;
            acc[4] += x * w1.x; acc[5] += x * w1.y; acc[6] += x * w1.z; acc[7] += x * w1.w;
        }
        short8 v;
#pragma unroll
        for (int kk = 0; kk < 8; kk++) v[kk] = bf16s(tanhf(acc[kk]));
        *reinterpret_cast<short8*>((char*)outT2 + ((size_t)o * JS + j) * 16) = v;
    }
}

// ---------------- vocab GEMM via MFMA + fused online softmax partials.
__global__ void __launch_bounds__(512) vocab_mfma(
        const __hip_bfloat16* __restrict__ outT2, const float* __restrict__ cc,
        const float* __restrict__ ob, const int* __restrict__ tgt,
        float* __restrict__ pbuf) {
    __shared__ __align__(16) short As[32 * 1536];        // bf16 A tile, chunk-XOR swizzled
    __shared__ float wm[8][32], ws_[8][32], wg[8][32];
    __shared__ int jstar_s[32];
    int bid = blockIdx.x;
    int rb = bid & 63, q = bid >> 6;
    int row0 = rb * 32;
    int tid = threadIdx.x;

    {
        int r = tid >> 4, cpos = tid & 15;
        const float* src = cc + (size_t)(row0 + r) * C3;
        int r7 = r & 7;
        short* dst = As + r * C3;
#pragma unroll
        for (int ii = 0; ii < 12; ii++) {
            int c = ii * 16 + cpos;                      // chunk 0..191 (8 bf16 each)
            float4 f0 = *(const float4*)(src + c * 8);
            float4 f1 = *(const float4*)(src + c * 8 + 4);
            short8 v;
            v[0] = bf16s(f0.x); v[1] = bf16s(f0.y); v[2] = bf16s(f0.z); v[3] = bf16s(f0.w);
            v[4] = bf16s(f1.x); v[5] = bf16s(f1.y); v[6] = bf16s(f1.z); v[7] = bf16s(f1.w);
            *reinterpret_cast<short8*>(dst + ((c ^ r7) << 3)) = v;
        }
    }
    if (tid < 32) {
        int nt = tgt[row0 + tid];
        int ix = nt - 3;
        ix = ix < 0 ? 0 : (ix > VO - 1 ? VO - 1 : ix);
        jstar_s[tid] = ix;
    }
    __syncthreads();

    int lane = tid & 63, wid = tid >> 6;
    int wr = wid >> 2, wc = wid & 3;
    int cl = lane & 15, g = lane >> 4;
    int rowA = wr * 16 + cl;
    const short* Abase = As + rowA * C3;
    int r7 = rowA & 7;
    int jst[4];
    float m[4], sacc[4], gl[4];
#pragma unroll
    for (int i = 0; i < 4; i++) {
        jst[i] = jstar_s[wr * 16 + g * 4 + i];
        m[i] = -1e30f; sacc[i] = 0.f; gl[i] = -1e30f;
    }

    int jb0 = q * 8192;
    int jqend = (jb0 + 8192 < VO) ? jb0 + 8192 : VO;
    int nmt = (jqend - jb0 + 127) >> 7;
    for (int ti = 0; ti < nmt; ti++) {
        int jA = jb0 + ti * 128 + wc * 32 + cl;
        const char* pB = (const char*)outT2 + ((size_t)g * JS + jA) * 16;
        f32x4 acc0 = {0.f, 0.f, 0.f, 0.f}, acc1 = {0.f, 0.f, 0.f, 0.f};
#pragma unroll
        for (int s = 0; s < 48; s++) {
            short8 a = *reinterpret_cast<const short8*>(Abase + (((s * 4 + g) ^ r7) << 3));
            short8 b0 = *reinterpret_cast<const short8*>(pB + (size_t)s * (4 * JS * 16));
            short8 b1 = *reinterpret_cast<const short8*>(pB + (size_t)s * (4 * JS * 16) + 256);
            acc0 = __builtin_amdgcn_mfma_f32_16x16x32_bf16(a, b0, acc0, 0, 0, 0);
            acc1 = __builtin_amdgcn_mfma_f32_16x16x32_bf16(a, b1, acc1, 0, 0, 0);
        }
#pragma unroll
        for (int X = 0; X < 2; X++) {
            int j = jA + X * 16;
            if (j < jqend) {
                float obj = ob[j];
#pragma unroll
                for (int i = 0; i < 4; i++) {
                    float L = (X ? acc1[i] : acc0[i]) + obj;
                    if (j == jst[i]) gl[i] = L;
                    float mn = fmaxf(m[i], L);
                    sacc[i] = sacc[i] * __expf(m[i] - mn) + __expf(L - mn);
                    m[i] = mn;
                }
            }
        }
    }

#pragma unroll
    for (int i = 0; i < 4; i++) {
        for (int mask = 1; mask < 16; mask <<= 1) {
            float om = __shfl_xor(m[i], mask);
            float os = __shfl_xor(sacc[i], mask);
            float mn = fmaxf(m[i], om);
            sacc[i] = sacc[i] * __expf(m[i] - mn) + os * __expf(om - mn);
            m[i] = mn;
            gl[i] = fmaxf(gl[i], __shfl_xor(gl[i], mask));
        }
    }
    if (cl == 0) {
#pragma unroll
        for (int i = 0; i < 4; i++) {
            int rl = wr * 16 + g * 4 + i;
            wm[wid][rl] = m[i]; ws_[wid][rl] = sacc[i]; wg[wid][rl] = gl[i];
        }
    }
    __syncthreads();
    if (tid < 32) {
        float M = -1e30f, SS = 0.f, GL = -1e30f;
        int w0 = (tid >> 4) * 4;
#pragma unroll
        for (int w = 0; w < 4; w++) {
            float mq = wm[w0 + w][tid], sq = ws_[w0 + w][tid], gq = wg[w0 + w][tid];
            float mn = fmaxf(M, mq);
            SS = SS * __expf(M - mn) + sq * __expf(mq - mn);
            M = mn;
            GL = fmaxf(GL, gq);
        }
        float* o = pbuf + ((size_t)bid * 32 + tid) * 4;
        o[0] = M; o[1] = SS; o[2] = GL;
    }
}

// ---------------- combine quarter-partials + pointer mix + NLL. grid B, 128 threads.
__global__ void combine_nll_k(const float* __restrict__ pbuf, const int* __restrict__ tgt,
                              const float* __restrict__ pgen, const float* __restrict__ copyp,
                              const int* __restrict__ tlen, float* __restrict__ out) {
    int b = blockIdx.x, t = threadIdx.x;
    int row = b * T + t;
    int rb = row >> 5, r = row & 31;
    float M = -1e30f, SS = 0.f, GL = -1e30f;
#pragma unroll
    for (int q = 0; q < 4; q++) {
        const float* p = pbuf + ((size_t)(q * 64 + rb) * 32 + r) * 4;
        float mq = p[0], sq = p[1], gq = p[2];
        float mn = fmaxf(M, mq);
        SS = SS * __expf(M - mn) + sq * __expf(mq - mn);
        M = mn;
        GL = fmaxf(GL, gq);
    }
    int nt = tgt[row];
    float genp = (nt >= 3 && nt < V) ? __expf(GL - M) / SS : 0.f;
    float pg = pgen[row];
    float p = pg * genp + (1.f - pg) * copyp[row];
    __shared__ float red[128];
    red[t] = (t < tlen[b]) ? -logf(p + 1e-9f) : 0.f;
    __syncthreads();
    for (int w = 64; w > 0; w >>= 1) { if (t < w) red[t] += red[t + w]; __syncthreads(); }
    if (t == 0) out[b] = red[0];
}

extern "C" void kernel_launch(void* const* d_in, const int* in_sizes, int n_in,
                              void* d_out, int out_size, void* d_ws, size_t ws_size,
                              hipStream_t stream) {
    const int* input_ids = (const int*)d_in[0];
    const int* target_ids = (const int*)d_in[1];
    const int* tlen = (const int*)d_in[3];
    const float* emb = (const float*)d_in[5];
    const float* eWih0f = (const float*)d_in[6],  *eWhh0f = (const float*)d_in[7],  *eb0f = (const float*)d_in[8];
    const float* eWih0b = (const float*)d_in[9],  *eWhh0b = (const float*)d_in[10], *eb0b = (const float*)d_in[11];
    const float* eWih1f = (const float*)d_in[12], *eWhh1f = (const float*)d_in[13], *eb1f = (const float*)d_in[14];
    const float* eWih1b = (const float*)d_in[15], *eWhh1b = (const float*)d_in[16], *eb1b = (const float*)d_in[17];
    const float* dWih0 = (const float*)d_in[18], *dWhh0 = (const float*)d_in[19], *db0 = (const float*)d_in[20];
    const float* dWih1 = (const float*)d_in[21], *dWhh1 = (const float*)d_in[22], *db1 = (const float*)d_in[23];
    const float* Wenc = (const float*)d_in[24], *Wdec = (const float*)d_in[25];
    const float* Wvoc = (const float*)d_in[26], *sW = (const float*)d_in[27], *sb = (const float*)d_in[28];
    const float* ob = (const float*)d_in[29];
    float* out = (float*)d_out;
    (void)ws_size; (void)n_in; (void)in_sizes; (void)out_size;

    // ============ workspace layout (~145 MB, phase-aliased) ============
    char* A = (char*)d_ws;
    float4* pWih0f = (float4*)(A + 0);              //  512 KB f32 gate-packed
    float4* pWih0b = (float4*)(A + 524288);
    float4* pWih1f = (float4*)(A + 1048576);        //  2 MB
    float4* pWih1b = (float4*)(A + 3145728);
    float4* pdWih0 = (float4*)(A + 5242880);        //  1 MB
    ushort* peW0f  = (ushort*)(A + 6291456);        //  512 KB bf16 [u][g][k]
    ushort* peW0b  = (ushort*)(A + 6815744);
    ushort* peW1f  = (ushort*)(A + 7340032);
    ushort* peW1b  = (ushort*)(A + 7864320);
    ushort* pb0    = (ushort*)(A + 8388608);        //  2 MB bf16 [u][g][k]
    ushort* pb1i   = (ushort*)(A + 10485760);
    ushort* pb1h   = (ushort*)(A + 12582912);       //  ends 14,680,064
    float* G0f = (float*)(A + 23068672);
    float* G0b = (float*)(A + 56623104);
    float* Gd0 = (float*)(A + 23068672);            // aliases G0f (dead after enc scans)
    float* ench = (float*)(A + 39845888);
    float* ectx = (float*)(A + 56623104);
    float* dctx = (float*)(A + 60817408);
    __hip_bfloat16* outT2 = (__hip_bfloat16*)A;     // whole region, after concat_k

    char* Bh = A + 98304000;
    float* h0f = (float*)(Bh + 0);
    float* h0b = (float*)(Bh + 8388608);
    float* h1d = (float*)(Bh + 0);                  // aliases h0f (dead after enc1_gates)
    float* qe  = (float*)(Bh + 4194304);
    float* qd  = (float*)(Bh + 8388608);
    float* ew  = (float*)(Bh + 12582912);
    char* Cr = Bh + 16777216;
    float* h1f = (float*)(Cr + 0);                  // 8,388,608
    float* h1b = (float*)(Cr + 8388608);            // 8,388,608
    float* cc  = (float*)(Cr + 16777216);           // 12,582,912
    float* dec_init = (float*)(Cr + 29360128);      // 65,536
    float* pgen  = (float*)(Cr + 29425664);         // 8,192
    float* copyp = (float*)(Cr + 29433856);         // 8,192
    float* pbuf  = (float*)(Cr + 29442048);         // 131,072
    float* h0g   = (float*)(Cr + 29573120);         // 65,536 (2x[B][D])
    float* h1g   = (float*)(Cr + 29638656);         // 65,536
    float* encg  = (float*)(Cr + 29704192);         // 65,536 (2buf x 2dir x B x H)
    int*   barDec = (int*)(Cr + 29769728);          // 128*64B flags + 64B go = 8,256 (pad 8,448)
    int*   barE0  = (int*)(Cr + 29778176);          // 64*64B flags + 64B go = 4,160 (pad 4,224)
    int*   barE1  = (int*)(Cr + 29782400);          // 4,224
    // total ≈ 144.87 MB

    hipMemsetAsync(barDec, 0, 16896, stream);       // zero all three barrier regions

    auto pack = [&](const float* W, float4* P, int Hn, int K) {
        int total = Hn * K;
        hipLaunchKernelGGL(pack4_kernel, dim3((total + 255) / 256), dim3(256), 0, stream, W, P, Hn, K);
    };
    pack(eWih0f, pWih0f, H, E);
    pack(eWih0b, pWih0b, H, E);
    pack(eWih1f, pWih1f, H, D);
    pack(eWih1b, pWih1b, H, D);
    pack(dWih0, pdWih0, D, E);
    hipLaunchKernelGGL(packencT_k, dim3(4 * H * H / 256), dim3(256), 0, stream, eWhh0f, peW0f);
    hipLaunchKernelGGL(packencT_k, dim3(4 * H * H / 256), dim3(256), 0, stream, eWhh0b, peW0b);
    hipLaunchKernelGGL(packencT_k, dim3(4 * H * H / 256), dim3(256), 0, stream, eWhh1f, peW1f);
    hipLaunchKernelGGL(packencT_k, dim3(4 * H * H / 256), dim3(256), 0, stream, eWhh1b, peW1b);
    hipLaunchKernelGGL(packdec_k, dim3(D * D * 4 / 256), dim3(256), 0, stream, dWhh0, pb0);
    hipLaunchKernelGGL(packdec_k, dim3(D * D * 4 / 256), dim3(256), 0, stream, dWih1, pb1i);
    hipLaunchKernelGGL(packdec_k, dim3(D * D * 4 / 256), dim3(256), 0, stream, dWhh1, pb1h);

    hipLaunchKernelGGL(enc0_gates, dim3(S * B), dim3(H), 0, stream,
                       input_ids, emb, pWih0f, eb0f, pWih0b, eb0b, G0f, G0b);
    hipLaunchKernelGGL(enc_pscan, dim3(NBLK_ENC), dim3(256), 0, stream,
                       G0f, G0b, peW0f, peW0b, h0f, h0b, dec_init, encg, barE0);
    hipLaunchKernelGGL(enc1_gates, dim3(S * B), dim3(H), 0, stream,
                       h0f, h0b, pWih1f, eb1f, pWih1b, eb1b, G0f, G0b);
    hipLaunchKernelGGL(enc_pscan, dim3(NBLK_ENC), dim3(256), 0, stream,
                       G0f, G0b, peW1f, peW1b, h1f, h1b, dec_init + B * D, encg, barE1);
    hipLaunchKernelGGL(dec0_gates, dim3(T * B), dim3(D), 0, stream,
                       target_ids, emb, pdWih0, db0, Gd0);
    hipLaunchKernelGGL(dec_scan2, dim3(NBLK_DEC), dim3(512), 0, stream,
                       Gd0, pb0, pb1i, pb1h, db1, dec_init, h0g, h1g, h1d, barDec);
    hipLaunchKernelGGL(build_encht, dim3(B * 256), dim3(256), 0, stream, h1f, h1b, ench);
    hipLaunchKernelGGL(qproj, dim3(T * B), dim3(D), 0, stream, h1d, Wenc, Wdec, qe, qd);
    hipLaunchKernelGGL(escore, dim3(B * T), dim3(S), 0, stream, qe, ench, ew);
    hipLaunchKernelGGL(temporal_k, dim3((B * S + 255) / 256), dim3(256), 0, stream, ew);
    hipLaunchKernelGGL(attnctx, dim3(B * T), dim3(S), 0, stream,
                       ew, input_ids, target_ids, h1f, h1b, ectx, copyp);
    hipLaunchKernelGGL(decattn, dim3(B * T), dim3(T), 0, stream, qd, h1d, dctx);
    hipLaunchKernelGGL(concat_k, dim3(B * T), dim3(D), 0, stream,
                       h1d, ectx, dctx, sW, sb, cc, pgen);
    hipLaunchKernelGGL(outprojT_k, dim3(1000), dim3(256), 0, stream, emb, Wvoc, outT2);
    hipLaunchKernelGGL(vocab_mfma, dim3(256), dim3(512), 0, stream,
                       outT2, cc, ob, target_ids, pbuf);
    hipLaunchKernelGGL(combine_nll_k, dim3(B), dim3(T), 0, stream,
                       pbuf, target_ids, pgen, copyp, tlen, out);
}

// Round 7
// 12497.111 us; speedup vs baseline: 1.8412x; 1.8412x over previous
//
#include <hip/hip_runtime.h>
#include <hip/hip_bf16.h>
#include <math.h>

#define PAD_ID 0
#define UNK_ID 1
#define START_ID 2
#define END_ID 3

constexpr int B = 16, S = 512, T = 128, V = 32000, E = 128, H = 256, D = 512;
constexpr int C3 = 1536;        // 3*D
constexpr int VO = 31997;       // V-3
constexpr int JS = 32000;       // padded col count for outT2
constexpr int NBLK_DEC = 128;   // decoder persistent blocks (u-slice = 4)
constexpr int NBLK_ENC = 64;    // encoder persistent blocks (2 dir x 32 u-slices of 8)

typedef short short8 __attribute__((ext_vector_type(8)));
typedef float f32x4 __attribute__((ext_vector_type(4)));

__device__ __forceinline__ float sigm(float x) { return 1.0f / (1.0f + __expf(-x)); }
__device__ __forceinline__ short bf16s(float x) {
    __hip_bfloat16 h = __float2bfloat16(x);
    return *reinterpret_cast<short*>(&h);
}
__device__ __forceinline__ float bflo(unsigned int u) { return __uint_as_float(u << 16); }
__device__ __forceinline__ float bfhi(unsigned int u) { return __uint_as_float(u & 0xffff0000u); }

// ---------------- coherent-ops grid barrier: relaxed agent atomics only (sc0sc1 path,
// NO L2 invalidate/writeback). Ordering: vmcnt(0) drain per wave at entry; compiler
// barrier at exit. flags: one 64B line per block; go word at flags[nblk*16].
__device__ __forceinline__ void cohbar(int* flags, int nblk, int ep, int myidx, bool leader) {
    asm volatile("s_waitcnt vmcnt(0)" ::: "memory");   // drain this wave's h-stores
    __syncthreads();                                   // all waves drained
    int tid = threadIdx.x;
    int* go = flags + nblk * 16;
    if (leader) {
        if (tid < 64) {
            if (tid == 0)
                __hip_atomic_store(flags + myidx * 16, ep, __ATOMIC_RELAXED, __HIP_MEMORY_SCOPE_AGENT);
            for (int i = tid; i < nblk; i += 64)
                while (__hip_atomic_load(flags + i * 16, __ATOMIC_RELAXED, __HIP_MEMORY_SCOPE_AGENT) < ep)
                    __builtin_amdgcn_s_sleep(1);
        }
        __syncthreads();
        if (tid == 0)
            __hip_atomic_store(go, ep, __ATOMIC_RELAXED, __HIP_MEMORY_SCOPE_AGENT);
    } else {
        if (tid == 0) {
            __hip_atomic_store(flags + myidx * 16, ep, __ATOMIC_RELAXED, __HIP_MEMORY_SCOPE_AGENT);
            while (__hip_atomic_load(go, __ATOMIC_RELAXED, __HIP_MEMORY_SCOPE_AGENT) < ep)
                __builtin_amdgcn_s_sleep(1);
        }
        __syncthreads();
    }
    asm volatile("" ::: "memory");                     // no hoisting of post-barrier loads
}

__device__ __forceinline__ float aload(const float* p) {
    return __hip_atomic_load(p, __ATOMIC_RELAXED, __HIP_MEMORY_SCOPE_AGENT);
}
__device__ __forceinline__ void astore(float* p, float v) {
    __hip_atomic_store(p, v, __ATOMIC_RELAXED, __HIP_MEMORY_SCOPE_AGENT);
}

// ---------------- weight packing: W[4H][K] -> P[k][u] = float4 of 4 gates (f32, for gate kernels)
__global__ void pack4_kernel(const float* __restrict__ W, float4* __restrict__ P, int Hn, int K) {
    int i = blockIdx.x * blockDim.x + threadIdx.x;
    if (i >= K * Hn) return;
    int k = i / Hn, u = i - k * Hn;
    float4 v;
    v.x = W[(size_t)(0 * Hn + u) * K + k];
    v.y = W[(size_t)(1 * Hn + u) * K + k];
    v.z = W[(size_t)(2 * Hn + u) * K + k];
    v.w = W[(size_t)(3 * Hn + u) * K + k];
    P[(size_t)k * Hn + u] = v;
}

// ---------------- encoder Whh pack: W[4H][H] -> P[u][g][k] bf16 (i = u*1024 + g*256 + k)
__global__ void packencT_k(const float* __restrict__ W, ushort* __restrict__ P) {
    int i = blockIdx.x * blockDim.x + threadIdx.x;
    if (i >= 4 * H * H) return;
    int k = i & 255, g = (i >> 8) & 3, u = i >> 10;
    P[i] = (ushort)bf16s(W[(size_t)(g * H + u) * H + k]);
}

// ---------------- decoder weight pack: W[4D][D] -> P[u][g][k] bf16 (i = ((u*4+g)*512)+k)
__global__ void packdec_k(const float* __restrict__ W, ushort* __restrict__ P) {
    int i = blockIdx.x * blockDim.x + threadIdx.x;
    if (i >= D * D * 4) return;
    int k = i & 511, g = (i >> 9) & 3, u = i >> 11;
    P[i] = (ushort)bf16s(W[(size_t)(g * D + u) * D + k]);
}

// ---------------- encoder layer-0 gate preactivations for both directions
__global__ void enc0_gates(const int* __restrict__ ids, const float* __restrict__ emb,
                           const float4* __restrict__ Pf, const float* __restrict__ bf_,
                           const float4* __restrict__ Pb, const float* __restrict__ bb_,
                           float* __restrict__ Gf, float* __restrict__ Gb) {
    int n = blockIdx.x;
    int s = n / B, b = n - s * B;
    int u = threadIdx.x;
    __shared__ float xr[E];
    int tok = ids[b * S + s];
    if (tok >= V) tok = UNK_ID;
    if (u < E) xr[u] = emb[(size_t)tok * E + u];
    __syncthreads();
    float a0 = bf_[0 * H + u], a1 = bf_[1 * H + u], a2 = bf_[2 * H + u], a3 = bf_[3 * H + u];
#pragma unroll 4
    for (int k = 0; k < E; k++) {
        float xv = xr[k]; float4 w = Pf[k * H + u];
        a0 += xv * w.x; a1 += xv * w.y; a2 += xv * w.z; a3 += xv * w.w;
    }
    float* g = Gf + (size_t)n * 4 * H;
    g[0 * H + u] = a0; g[1 * H + u] = a1; g[2 * H + u] = a2; g[3 * H + u] = a3;
    a0 = bb_[0 * H + u]; a1 = bb_[1 * H + u]; a2 = bb_[2 * H + u]; a3 = bb_[3 * H + u];
#pragma unroll 4
    for (int k = 0; k < E; k++) {
        float xv = xr[k]; float4 w = Pb[k * H + u];
        a0 += xv * w.x; a1 += xv * w.y; a2 += xv * w.z; a3 += xv * w.w;
    }
    g = Gb + (size_t)n * 4 * H;
    g[0 * H + u] = a0; g[1 * H + u] = a1; g[2 * H + u] = a2; g[3 * H + u] = a3;
}

// ---------------- encoder layer-1 gate preactivations (input = concat(h0f,h0b))
__global__ void enc1_gates(const float* __restrict__ h0f, const float* __restrict__ h0b,
                           const float4* __restrict__ Pf, const float* __restrict__ bf_,
                           const float4* __restrict__ Pb, const float* __restrict__ bb_,
                           float* __restrict__ Gf, float* __restrict__ Gb) {
    int n = blockIdx.x;      // s*B+b
    int u = threadIdx.x;     // 256
    __shared__ float xr[D];
    xr[u] = h0f[(size_t)n * H + u];
    xr[H + u] = h0b[(size_t)n * H + u];
    __syncthreads();
    float a0 = bf_[0 * H + u], a1 = bf_[1 * H + u], a2 = bf_[2 * H + u], a3 = bf_[3 * H + u];
#pragma unroll 4
    for (int k = 0; k < D; k++) {
        float xv = xr[k]; float4 w = Pf[k * H + u];
        a0 += xv * w.x; a1 += xv * w.y; a2 += xv * w.z; a3 += xv * w.w;
    }
    float* g = Gf + (size_t)n * 4 * H;
    g[0 * H + u] = a0; g[1 * H + u] = a1; g[2 * H + u] = a2; g[3 * H + u] = a3;
    a0 = bb_[0 * H + u]; a1 = bb_[1 * H + u]; a2 = bb_[2 * H + u]; a3 = bb_[3 * H + u];
#pragma unroll 4
    for (int k = 0; k < D; k++) {
        float xv = xr[k]; float4 w = Pb[k * H + u];
        a0 += xv * w.x; a1 += xv * w.y; a2 += xv * w.z; a3 += xv * w.w;
    }
    g = Gb + (size_t)n * 4 * H;
    g[0 * H + u] = a0; g[1 * H + u] = a1; g[2 * H + u] = a2; g[3 * H + u] = a3;
}

// ---------------- encoder persistent scan, one layer, both dirs.
// grid 64 = dir*32 + ub (u-slice 8). 256 threads = (uh 4)(g 4)(b 16); cell threads = 128.
// Per-dir barrier groups (32 blocks each) — fwd/bwd never exchange data.
__global__ void __launch_bounds__(256) enc_pscan(
        const float* __restrict__ Gf, const float* __restrict__ Gb,
        const ushort* __restrict__ Pf, const ushort* __restrict__ Pb,   // [u][g][k] bf16
        float* __restrict__ hof, float* __restrict__ hob,
        float* __restrict__ hfin /* [B][2H] */,
        float* __restrict__ hg /* [2buf][2dir][B][H] f32 */, int* __restrict__ barbase) {
    __shared__ __align__(16) float Wl[32 * 258];   // [u_loc*4+g][256 + 2 pad]
    __shared__ float hh[256 * 17];                 // [k][b] padded
    __shared__ float gs[512];                      // [u_loc][b][g]
    int blk = blockIdx.x;
    int dirb = blk >> 5, ub = blk & 31;
    int* bar = barbase + dirb * 1024;              // independent 4KB region per dir
    const float* G = dirb ? Gb : Gf;
    const ushort* P = dirb ? Pb : Pf;
    float* ho = dirb ? hob : hof;
    int tid = threadIdx.x;
    int b = tid & 15, g = (tid >> 4) & 3, uh = tid >> 6;

    // stage + unpack weight slice (8 u x 4 g x 256 k) to f32 LDS
    const uint* wsrc = (const uint*)(P + (size_t)ub * 8192);
    for (int i = tid; i < 4096; i += 256) {
        int r = i >> 7, c = i & 127;
        uint wv = wsrc[i];
        Wl[r * 258 + 2 * c] = bflo(wv);
        Wl[r * 258 + 2 * c + 1] = bfhi(wv);
    }
    if (tid < 128) {
        int u_loc = tid >> 4, bb = tid & 15;
        astore(&hg[dirb * (B * H) + bb * H + ub * 8 + u_loc], 0.f);
    }
    float c_st = 0.f;
    int ep = 1;
    cohbar(bar, 32, ep, ub, ub == 0);

    int u0 = uh * 2, u1 = u0 + 1;
    const float* w0 = Wl + (u0 * 4 + g) * 258;
    const float* w1 = Wl + (u1 * 4 + g) * 258;
    for (int step = 0; step < S; step++) {
        int s = dirb ? (S - 1 - step) : step;
        int cur = step & 1;
        const float* hgd = hg + cur * (2 * B * H) + dirb * (B * H);   // [b][k]
        // stage h (coherent loads) -> hh[k][b] transposed
        float v[16];
#pragma unroll
        for (int j = 0; j < 16; j++) v[j] = aload(&hgd[j * 256 + tid]);
#pragma unroll
        for (int j = 0; j < 16; j++) {
            int flat = j * 256 + tid;
            hh[(flat & 255) * 17 + (flat >> 8)] = v[j];
        }
        __syncthreads();
        float acc0 = 0.f, acc1 = 0.f;
#pragma unroll 8
        for (int k = 0; k < 256; k++) {
            float hv = hh[k * 17 + b];
            acc0 += w0[k] * hv;
            acc1 += w1[k] * hv;
        }
        gs[u0 * 64 + b * 4 + g] = acc0;
        gs[u1 * 64 + b * 4 + g] = acc1;
        __syncthreads();
        if (tid < 128) {
            int u_loc = tid >> 4, bb = tid & 15;
            int uu = ub * 8 + u_loc;
            const float* base = gs + u_loc * 64 + bb * 4;
            const float* gG = G + ((size_t)(s * B + bb)) * 1024 + uu;
            float g0 = gG[0]   + base[0];
            float g1 = gG[256] + base[1];
            float g2 = gG[512] + base[2];
            float g3 = gG[768] + base[3];
            float ig = sigm(g0), fg = sigm(g1), gt = tanhf(g2), og = sigm(g3);
            c_st = fg * c_st + ig * gt;
            float hn = og * tanhf(c_st);
            astore(&hg[(cur ^ 1) * (2 * B * H) + dirb * (B * H) + bb * H + uu], hn);
            ho[((size_t)(s * B + bb)) * H + uu] = hn;
            if (step == S - 1) hfin[bb * (2 * H) + dirb * H + uu] = hn;
        }
        cohbar(bar, 32, ++ep, ub, ub == 0);
    }
}

// ---------------- decoder layer-0 input gates (teacher tokens). grid T*B (n=t*B+b), 512 thr.
__global__ void dec0_gates(const int* __restrict__ tgt, const float* __restrict__ emb,
                           const float4* __restrict__ P, const float* __restrict__ bias,
                           float* __restrict__ G) {
    int n = blockIdx.x;
    int t = n / B, b = n - t * B;
    int u = threadIdx.x;
    __shared__ float xr[E];
    int tok;
    if (t == 0) tok = START_ID;
    else { tok = tgt[b * T + (t - 1)]; if (tok >= V) tok = UNK_ID; }
    if (u < E) xr[u] = emb[(size_t)tok * E + u];
    __syncthreads();
    float a0 = bias[0 * D + u], a1 = bias[1 * D + u], a2 = bias[2 * D + u], a3 = bias[3 * D + u];
#pragma unroll 4
    for (int k = 0; k < E; k++) {
        float xv = xr[k]; float4 w = P[k * D + u];
        a0 += xv * w.x; a1 += xv * w.y; a2 += xv * w.z; a3 += xv * w.w;
    }
    float* g = G + (size_t)n * 4 * D;
    g[0 * D + u] = a0; g[1 * D + u] = a1; g[2 * D + u] = a2; g[3 * D + u] = a3;
}

// ---------------- decoder persistent 2-layer scan.
// grid 128 blocks (u-slice 4), 512 threads = (u_loc 4, g 4, kq 2, b 16).
// h exchange: coherent atomics -> LDS staging (bufA=h0, bufB=h1, stride 516 pad).
// 1 grid barrier per step (after phase A).
__global__ void __launch_bounds__(512) dec_scan2(
        const float* __restrict__ G0, const ushort* __restrict__ pb0,
        const ushort* __restrict__ pb1i, const ushort* __restrict__ pb1h,
        const float* __restrict__ b1, const float* __restrict__ hinit,
        float* __restrict__ h0g /* [2][B][D] */, float* __restrict__ h1g /* [2][B][D] */,
        float* __restrict__ h1out, int* __restrict__ bar) {
    __shared__ __align__(16) ushort W0s[16 * 528];
    __shared__ __align__(16) ushort W1is[16 * 528];
    __shared__ __align__(16) ushort W1hs[16 * 528];
    __shared__ __align__(16) float bufA[16 * 516];   // h0 staging [b][516]
    __shared__ __align__(16) float bufB[16 * 516];   // h1 staging
    __shared__ float red[4][4][2][16];
    int tid = threadIdx.x;
    int u0 = blockIdx.x * 4;
    int u_loc = tid >> 7, g = (tid >> 5) & 3, kq = (tid >> 4) & 1, b = tid & 15;

    // stage weight slices (row stride 528 ushorts = 66 uint4)
    {
        const uint4* s0 = (const uint4*)(pb0 + (size_t)u0 * 2048);
        const uint4* s1 = (const uint4*)(pb1i + (size_t)u0 * 2048);
        const uint4* s2 = (const uint4*)(pb1h + (size_t)u0 * 2048);
        uint4* d0 = (uint4*)W0s; uint4* d1 = (uint4*)W1is; uint4* d2 = (uint4*)W1hs;
        for (int i = tid; i < 1024; i += 512) {
            int r = i >> 6, c = i & 63;
            d0[r * 66 + c] = s0[i]; d1[r * 66 + c] = s1[i]; d2[r * 66 + c] = s2[i];
        }
    }
    // init: bufA <- hinit layer0 (normal loads OK: written by a prior kernel);
    //       h1g parity-1 <- hinit layer1 (coherent stores, own slice)
    for (int i = tid; i < B * D; i += 512) {
        int bb = i >> 9, kk = i & 511;
        bufA[bb * 516 + kk] = hinit[i];
    }
    if (tid < 64) {
        int ul = tid >> 4, bb = tid & 15;
        astore(&h1g[B * D + bb * 512 + u0 + ul], hinit[B * D + bb * 512 + u0 + ul]);
    }
    float c0v = 0.f, c1v = 0.f;
    int ep = 1;
    cohbar(bar, NBLK_DEC, ep, blockIdx.x, blockIdx.x == 0);

    for (int t = 0; t < T; t++) {
        int cur = t & 1;
        // ---- phase A: layer-0 gate partial from bufA (= h0(t-1))
        {
            const uint2* w = (const uint2*)(W0s + (u_loc * 4 + g) * 528) + kq * 64;
            const float* hp = bufA + b * 516 + kq * 256;
            float acc = 0.f;
#pragma unroll 4
            for (int i = 0; i < 64; i++) {
                uint2 wv = w[i];
                float4 hv = *(const float4*)(hp + i * 4);
                acc += bflo(wv.x) * hv.x + bfhi(wv.x) * hv.y + bflo(wv.y) * hv.z + bfhi(wv.y) * hv.w;
            }
            red[u_loc][g][kq][b] = acc;
        }
        __syncthreads();
        if (tid < 64) {
            int ul = tid >> 4, bb = tid & 15;
            const float* gg = G0 + ((size_t)(t * B + bb)) * 2048 + (u0 + ul);
            float g0 = gg[0]    + red[ul][0][0][bb] + red[ul][0][1][bb];
            float g1 = gg[512]  + red[ul][1][0][bb] + red[ul][1][1][bb];
            float g2 = gg[1024] + red[ul][2][0][bb] + red[ul][2][1][bb];
            float g3 = gg[1536] + red[ul][3][0][bb] + red[ul][3][1][bb];
            float ig = sigm(g0), fg = sigm(g1), gt = tanhf(g2), og = sigm(g3);
            c0v = fg * c0v + ig * gt;
            astore(&h0g[cur * (B * D) + bb * 512 + u0 + ul], og * tanhf(c0v));
        }
        cohbar(bar, NBLK_DEC, ++ep, blockIdx.x, blockIdx.x == 0);   // h0(t) all visible
        // ---- phase B staging: bufA <- h0(t), bufB <- h1(t-1)  (coherent loads)
        {
            float v0[16], v1[16];
            const float* p0 = h0g + cur * (B * D);
            const float* p1 = h1g + (cur ^ 1) * (B * D);
#pragma unroll
            for (int j = 0; j < 16; j++) {
                v0[j] = aload(&p0[j * 512 + tid]);
                v1[j] = aload(&p1[j * 512 + tid]);
            }
#pragma unroll
            for (int j = 0; j < 16; j++) {
                int i = j * 512 + tid;
                int bb = i >> 9, kk = i & 511;
                bufA[bb * 516 + kk] = v0[j];
                bufB[bb * 516 + kk] = v1[j];
            }
        }
        __syncthreads();
        // ---- phase B: layer-1 gates = b1 + W1i*h0(t) + W1h*h1(t-1)
        {
            const uint2* wA = (const uint2*)(W1is + (u_loc * 4 + g) * 528) + kq * 64;
            const uint2* wB = (const uint2*)(W1hs + (u_loc * 4 + g) * 528) + kq * 64;
            const float* hA = bufA + b * 516 + kq * 256;
            const float* hB = bufB + b * 516 + kq * 256;
            float acc = 0.f;
#pragma unroll 4
            for (int i = 0; i < 64; i++) {
                uint2 wv = wA[i];
                float4 hv = *(const float4*)(hA + i * 4);
                acc += bflo(wv.x) * hv.x + bfhi(wv.x) * hv.y + bflo(wv.y) * hv.z + bfhi(wv.y) * hv.w;
                uint2 wv2 = wB[i];
                float4 hv2 = *(const float4*)(hB + i * 4);
                acc += bflo(wv2.x) * hv2.x + bfhi(wv2.x) * hv2.y + bflo(wv2.y) * hv2.z + bfhi(wv2.y) * hv2.w;
            }
            red[u_loc][g][kq][b] = acc;
        }
        __syncthreads();
        if (tid < 64) {
            int ul = tid >> 4, bb = tid & 15;
            int uu = u0 + ul;
            float g0 = b1[uu]        + red[ul][0][0][bb] + red[ul][0][1][bb];
            float g1 = b1[512 + uu]  + red[ul][1][0][bb] + red[ul][1][1][bb];
            float g2 = b1[1024 + uu] + red[ul][2][0][bb] + red[ul][2][1][bb];
            float g3 = b1[1536 + uu] + red[ul][3][0][bb] + red[ul][3][1][bb];
            float ig = sigm(g0), fg = sigm(g1), gt = tanhf(g2), og = sigm(g3);
            c1v = fg * c1v + ig * gt;
            float h1n_v = og * tanhf(c1v);
            astore(&h1g[cur * (B * D) + bb * 512 + uu], h1n_v);
            h1out[((size_t)(t * B + bb)) * 512 + uu] = h1n_v;
        }
        __syncthreads();   // protect red/bufA/bufB reuse next iteration
    }
}

// ---------------- transpose enc hidden to [b][k(512)][s] for coalesced score dots
__global__ void build_encht(const float* __restrict__ h1f, const float* __restrict__ h1b,
                            float* __restrict__ et) {
    int blk = blockIdx.x;                 // b*256 + kt*16 + st
    int b = blk >> 8, rem = blk & 255;
    int kt = rem >> 4, st = rem & 15;
    int c = threadIdx.x & 31, r = threadIdx.x >> 5;   // r in 0..7
    __shared__ float tile[32][33];
#pragma unroll
    for (int i = 0; i < 4; i++) {
        int sl = r + i * 8;               // s_local
        int s = st * 32 + sl;
        int k = kt * 32 + c;              // lane-contiguous over k
        float v = (k < H) ? h1f[((size_t)(s * B + b)) * H + k]
                          : h1b[((size_t)(s * B + b)) * H + (k - H)];
        tile[c][sl] = v;                  // tile[k_local][s_local]
    }
    __syncthreads();
#pragma unroll
    for (int i = 0; i < 4; i++) {
        int kl = r + i * 8;
        et[(size_t)b * D * S + (size_t)(kt * 32 + kl) * S + st * 32 + c] = tile[kl][c];
    }
}

// ---------------- q projections. grid T*B (n=t*B+b), 512 threads
__global__ void qproj(const float* __restrict__ h1d, const float* __restrict__ Wenc,
                      const float* __restrict__ Wdec, float* __restrict__ qe, float* __restrict__ qd) {
    int n = blockIdx.x;
    int o = threadIdx.x;
    __shared__ float hr[D];
    hr[o] = h1d[(size_t)n * D + o];
    __syncthreads();
    float ae = 0.f, ad = 0.f;
#pragma unroll 4
    for (int k = 0; k < D; k++) {
        float hk = hr[k];
        ae += hk * Wenc[k * D + o];
        ad += hk * Wdec[k * D + o];
    }
    qe[(size_t)n * D + o] = ae;
    qd[(size_t)n * D + o] = ad;
}

// ---------------- e = exp(min(score,30)). grid B*T (bt=b*T+t), 512 threads (s)
__global__ void escore(const float* __restrict__ qe, const float* __restrict__ et,
                       float* __restrict__ ew) {
    int bt = blockIdx.x;
    int b = bt / T, t = bt - b * T;
    int sx = threadIdx.x;
    __shared__ float q[D];
    q[sx] = qe[((size_t)(t * B + b)) * D + sx];
    __syncthreads();
    float acc = 0.f;
    const float* eb = et + (size_t)b * D * S + sx;
#pragma unroll 4
    for (int k = 0; k < D; k++) { acc += q[k] * eb[0]; eb += S; }
    acc = fminf(acc, 30.0f);
    ew[(size_t)bt * S + sx] = __expf(acc);
}

// ---------------- temporal normalization (prefix over t, in place)
__global__ void temporal_k(float* __restrict__ ew) {
    int i = blockIdx.x * blockDim.x + threadIdx.x;
    if (i >= B * S) return;
    int b = i / S, sx = i - b * S;
    float cum = 0.f;
    for (int t = 0; t < T; t++) {
        size_t idx = ((size_t)(b * T + t)) * S + sx;
        float v = ew[idx];
        ew[idx] = v / (t == 0 ? 1.0f : (cum + 1e-8f));
        cum += v;
    }
}

// ---------------- attention softmax over s + enc context + copy prob. grid B*T, 512 thr
__global__ void attnctx(const float* __restrict__ ew, const int* __restrict__ ids,
                        const int* __restrict__ tgt,
                        const float* __restrict__ h1f, const float* __restrict__ h1b,
                        float* __restrict__ ectx, float* __restrict__ copyp) {
    int bt = blockIdx.x;
    int b = bt / T, t = bt - b * T;
    int tid = threadIdx.x;
    __shared__ float aw[S];
    __shared__ float red[512];
    float v = ew[(size_t)bt * S + tid];
    int tok = ids[b * S + tid];
    bool pad = (tok == PAD_ID);
    float vm = pad ? -INFINITY : v;
    red[tid] = vm; __syncthreads();
    for (int w = 256; w > 0; w >>= 1) { if (tid < w) red[tid] = fmaxf(red[tid], red[tid + w]); __syncthreads(); }
    float m = red[0]; __syncthreads();
    float ex = pad ? 0.f : __expf(vm - m);
    red[tid] = ex; __syncthreads();
    for (int w = 256; w > 0; w >>= 1) { if (tid < w) red[tid] += red[tid + w]; __syncthreads(); }
    float Z = red[0]; __syncthreads();
    float a = ex / Z;
    aw[tid] = a;
    int nt = tgt[b * T + t];
    red[tid] = (tok == nt) ? a : 0.f; __syncthreads();
    for (int w = 256; w > 0; w >>= 1) { if (tid < w) red[tid] += red[tid + w]; __syncthreads(); }
    if (tid == 0) copyp[bt] = red[0];
    __syncthreads();
    int d = tid;
    const float* hp = (d < H) ? (h1f + (size_t)b * H + d) : (h1b + (size_t)b * H + (d - H));
    float acc = 0.f;
#pragma unroll 4
    for (int s2 = 0; s2 < S; s2++) { acc += aw[s2] * hp[0]; hp += B * H; }
    ectx[(size_t)bt * D + d] = acc;
}

// ---------------- intra-decoder attention. grid B*T, 128 threads
__global__ void decattn(const float* __restrict__ qd, const float* __restrict__ h1d,
                        float* __restrict__ dctx) {
    int bt = blockIdx.x;
    int b = bt / T, t = bt - b * T;
    int tid = threadIdx.x;
    __shared__ float q[D];
    __shared__ float wl[T];
    __shared__ float red[128];
    for (int i = tid; i < D; i += 128) q[i] = qd[((size_t)(t * B + b)) * D + i];
    __syncthreads();
    float sc = -INFINITY;
    if (tid < t) {
        const float* hu = h1d + ((size_t)(tid * B + b)) * D;
        float a = 0.f;
#pragma unroll 4
        for (int k = 0; k < D; k++) a += q[k] * hu[k];
        sc = a;
    }
    red[tid] = sc; __syncthreads();
    for (int w = 64; w > 0; w >>= 1) { if (tid < w) red[tid] = fmaxf(red[tid], red[tid + w]); __syncthreads(); }
    float m = red[0]; __syncthreads();
    float ex = (tid < t) ? __expf(sc - m) : 0.f;
    red[tid] = ex; __syncthreads();
    for (int w = 64; w > 0; w >>= 1) { if (tid < w) red[tid] += red[tid + w]; __syncthreads(); }
    float Z = red[0]; __syncthreads();
    wl[tid] = (t > 0) ? (ex / Z) : 0.f;
    __syncthreads();
    for (int d = tid; d < D; d += 128) {
        float acc = 0.f;
        for (int u = 0; u < t; u++) acc += wl[u] * h1d[((size_t)(u * B + b)) * D + d];
        dctx[(size_t)bt * D + d] = acc;
    }
}

// ---------------- concat + p_gen. grid B*T, 512 threads
__global__ void concat_k(const float* __restrict__ h1d, const float* __restrict__ ectx,
                         const float* __restrict__ dctx, const float* __restrict__ sW,
                         const float* __restrict__ sb, float* __restrict__ cc,
                         float* __restrict__ pgen) {
    int bt = blockIdx.x;
    int b = bt / T, t = bt - b * T;
    int d = threadIdx.x;
    __shared__ float red[512];
    float v0 = h1d[((size_t)(t * B + b)) * D + d];
    float v1 = ectx[(size_t)bt * D + d];
    float v2 = dctx[(size_t)bt * D + d];
    float* c = cc + (size_t)bt * C3;
    c[d] = v0; c[D + d] = v1; c[2 * D + d] = v2;
    red[d] = v0 * sW[d] + v1 * sW[D + d] + v2 * sW[2 * D + d];
    __syncthreads();
    for (int w = 256; w > 0; w >>= 1) { if (d < w) red[d] += red[d + w]; __syncthreads(); }
    if (d == 0) pgen[bt] = 1.f / (1.f + __expf(-(red[0] + sb[0])));
}

// ---------------- out_proj, packed-k layout for MFMA B-fragments.
__global__ void outprojT_k(const float* __restrict__ emb, const float* __restrict__ Wvoc,
                           __hip_bfloat16* __restrict__ outT2) {
    int j0 = blockIdx.x * 32;
    int jl = threadIdx.x & 31, oq = threadIdx.x >> 5;   // oq in 0..7
    __shared__ float er[32][E + 1];                      // +1 pad
    for (int i = threadIdx.x; i < 32 * E; i += 256) {
        int jj = i >> 7, e = i & 127;
        int j = j0 + jj;
        er[jj][e] = (j < VO) ? emb[(size_t)(3 + j) * E + e] : 0.f;
    }
    __syncthreads();
    int j = j0 + jl;
#pragma unroll 1
    for (int i = 0; i < 24; i++) {
        int o = oq * 24 + i;                             // octet index 0..191
        int k0 = o * 8;
        float acc[8];
#pragma unroll
        for (int kk = 0; kk < 8; kk++) acc[kk] = 0.f;
#pragma unroll 4
        for (int e = 0; e < E; e++) {
            float x = er[jl][e];
            float4 w0 = *(const float4*)(Wvoc + (size_t)e * C3 + k0);
            float4 w1 = *(const float4*)(Wvoc + (size_t)e * C3 + k0 + 4);
            acc[0] += x * w0.x; acc[1] += x * w0.y; acc[2] += x * w0.z; acc[3] += x * w0.w;
            acc[4] += x * w1.x; acc[5] += x * w1.y; acc[6] += x * w1.z; acc[7] += x * w1.w;
        }
        short8 v;
#pragma unroll
        for (int kk = 0; kk < 8; kk++) v[kk] = bf16s(tanhf(acc[kk]));
        *reinterpret_cast<short8*>((char*)outT2 + ((size_t)o * JS + j) * 16) = v;
    }
}

// ---------------- vocab GEMM via MFMA + fused online softmax partials.
__global__ void __launch_bounds__(512) vocab_mfma(
        const __hip_bfloat16* __restrict__ outT2, const float* __restrict__ cc,
        const float* __restrict__ ob, const int* __restrict__ tgt,
        float* __restrict__ pbuf) {
    __shared__ __align__(16) short As[32 * 1536];        // bf16 A tile, chunk-XOR swizzled
    __shared__ float wm[8][32], ws_[8][32], wg[8][32];
    __shared__ int jstar_s[32];
    int bid = blockIdx.x;
    int rb = bid & 63, q = bid >> 6;
    int row0 = rb * 32;
    int tid = threadIdx.x;

    {
        int r = tid >> 4, cpos = tid & 15;
        const float* src = cc + (size_t)(row0 + r) * C3;
        int r7 = r & 7;
        short* dst = As + r * C3;
#pragma unroll
        for (int ii = 0; ii < 12; ii++) {
            int c = ii * 16 + cpos;                      // chunk 0..191 (8 bf16 each)
            float4 f0 = *(const float4*)(src + c * 8);
            float4 f1 = *(const float4*)(src + c * 8 + 4);
            short8 v;
            v[0] = bf16s(f0.x); v[1] = bf16s(f0.y); v[2] = bf16s(f0.z); v[3] = bf16s(f0.w);
            v[4] = bf16s(f1.x); v[5] = bf16s(f1.y); v[6] = bf16s(f1.z); v[7] = bf16s(f1.w);
            *reinterpret_cast<short8*>(dst + ((c ^ r7) << 3)) = v;
        }
    }
    if (tid < 32) {
        int nt = tgt[row0 + tid];
        int ix = nt - 3;
        ix = ix < 0 ? 0 : (ix > VO - 1 ? VO - 1 : ix);
        jstar_s[tid] = ix;
    }
    __syncthreads();

    int lane = tid & 63, wid = tid >> 6;
    int wr = wid >> 2, wc = wid & 3;
    int cl = lane & 15, g = lane >> 4;
    int rowA = wr * 16 + cl;
    const short* Abase = As + rowA * C3;
    int r7 = rowA & 7;
    int jst[4];
    float m[4], sacc[4], gl[4];
#pragma unroll
    for (int i = 0; i < 4; i++) {
        jst[i] = jstar_s[wr * 16 + g * 4 + i];
        m[i] = -1e30f; sacc[i] = 0.f; gl[i] = -1e30f;
    }

    int jb0 = q * 8192;
    int jqend = (jb0 + 8192 < VO) ? jb0 + 8192 : VO;
    int nmt = (jqend - jb0 + 127) >> 7;
    for (int ti = 0; ti < nmt; ti++) {
        int jA = jb0 + ti * 128 + wc * 32 + cl;
        const char* pB = (const char*)outT2 + ((size_t)g * JS + jA) * 16;
        f32x4 acc0 = {0.f, 0.f, 0.f, 0.f}, acc1 = {0.f, 0.f, 0.f, 0.f};
#pragma unroll
        for (int s = 0; s < 48; s++) {
            short8 a = *reinterpret_cast<const short8*>(Abase + (((s * 4 + g) ^ r7) << 3));
            short8 b0 = *reinterpret_cast<const short8*>(pB + (size_t)s * (4 * JS * 16));
            short8 b1 = *reinterpret_cast<const short8*>(pB + (size_t)s * (4 * JS * 16) + 256);
            acc0 = __builtin_amdgcn_mfma_f32_16x16x32_bf16(a, b0, acc0, 0, 0, 0);
            acc1 = __builtin_amdgcn_mfma_f32_16x16x32_bf16(a, b1, acc1, 0, 0, 0);
        }
#pragma unroll
        for (int X = 0; X < 2; X++) {
            int j = jA + X * 16;
            if (j < jqend) {
                float obj = ob[j];
#pragma unroll
                for (int i = 0; i < 4; i++) {
                    float L = (X ? acc1[i] : acc0[i]) + obj;
                    if (j == jst[i]) gl[i] = L;
                    float mn = fmaxf(m[i], L);
                    sacc[i] = sacc[i] * __expf(m[i] - mn) + __expf(L - mn);
                    m[i] = mn;
                }
            }
        }
    }

#pragma unroll
    for (int i = 0; i < 4; i++) {
        for (int mask = 1; mask < 16; mask <<= 1) {
            float om = __shfl_xor(m[i], mask);
            float os = __shfl_xor(sacc[i], mask);
            float mn = fmaxf(m[i], om);
            sacc[i] = sacc[i] * __expf(m[i] - mn) + os * __expf(om - mn);
            m[i] = mn;
            gl[i] = fmaxf(gl[i], __shfl_xor(gl[i], mask));
        }
    }
    if (cl == 0) {
#pragma unroll
        for (int i = 0; i < 4; i++) {
            int rl = wr * 16 + g * 4 + i;
            wm[wid][rl] = m[i]; ws_[wid][rl] = sacc[i]; wg[wid][rl] = gl[i];
        }
    }
    __syncthreads();
    if (tid < 32) {
        float M = -1e30f, SS = 0.f, GL = -1e30f;
        int w0 = (tid >> 4) * 4;
#pragma unroll
        for (int w = 0; w < 4; w++) {
            float mq = wm[w0 + w][tid], sq = ws_[w0 + w][tid], gq = wg[w0 + w][tid];
            float mn = fmaxf(M, mq);
            SS = SS * __expf(M - mn) + sq * __expf(mq - mn);
            M = mn;
            GL = fmaxf(GL, gq);
        }
        float* o = pbuf + ((size_t)bid * 32 + tid) * 4;
        o[0] = M; o[1] = SS; o[2] = GL;
    }
}

// ---------------- combine quarter-partials + pointer mix + NLL. grid B, 128 threads.
__global__ void combine_nll_k(const float* __restrict__ pbuf, const int* __restrict__ tgt,
                              const float* __restrict__ pgen, const float* __restrict__ copyp,
                              const int* __restrict__ tlen, float* __restrict__ out) {
    int b = blockIdx.x, t = threadIdx.x;
    int row = b * T + t;
    int rb = row >> 5, r = row & 31;
    float M = -1e30f, SS = 0.f, GL = -1e30f;
#pragma unroll
    for (int q = 0; q < 4; q++) {
        const float* p = pbuf + ((size_t)(q * 64 + rb) * 32 + r) * 4;
        float mq = p[0], sq = p[1], gq = p[2];
        float mn = fmaxf(M, mq);
        SS = SS * __expf(M - mn) + sq * __expf(mq - mn);
        M = mn;
        GL = fmaxf(GL, gq);
    }
    int nt = tgt[row];
    float genp = (nt >= 3 && nt < V) ? __expf(GL - M) / SS : 0.f;
    float pg = pgen[row];
    float p = pg * genp + (1.f - pg) * copyp[row];
    __shared__ float red[128];
    red[t] = (t < tlen[b]) ? -logf(p + 1e-9f) : 0.f;
    __syncthreads();
    for (int w = 64; w > 0; w >>= 1) { if (t < w) red[t] += red[t + w]; __syncthreads(); }
    if (t == 0) out[b] = red[0];
}

extern "C" void kernel_launch(void* const* d_in, const int* in_sizes, int n_in,
                              void* d_out, int out_size, void* d_ws, size_t ws_size,
                              hipStream_t stream) {
    const int* input_ids = (const int*)d_in[0];
    const int* target_ids = (const int*)d_in[1];
    const int* tlen = (const int*)d_in[3];
    const float* emb = (const float*)d_in[5];
    const float* eWih0f = (const float*)d_in[6],  *eWhh0f = (const float*)d_in[7],  *eb0f = (const float*)d_in[8];
    const float* eWih0b = (const float*)d_in[9],  *eWhh0b = (const float*)d_in[10], *eb0b = (const float*)d_in[11];
    const float* eWih1f = (const float*)d_in[12], *eWhh1f = (const float*)d_in[13], *eb1f = (const float*)d_in[14];
    const float* eWih1b = (const float*)d_in[15], *eWhh1b = (const float*)d_in[16], *eb1b = (const float*)d_in[17];
    const float* dWih0 = (const float*)d_in[18], *dWhh0 = (const float*)d_in[19], *db0 = (const float*)d_in[20];
    const float* dWih1 = (const float*)d_in[21], *dWhh1 = (const float*)d_in[22], *db1 = (const float*)d_in[23];
    const float* Wenc = (const float*)d_in[24], *Wdec = (const float*)d_in[25];
    const float* Wvoc = (const float*)d_in[26], *sW = (const float*)d_in[27], *sb = (const float*)d_in[28];
    const float* ob = (const float*)d_in[29];
    float* out = (float*)d_out;
    (void)ws_size; (void)n_in; (void)in_sizes; (void)out_size;

    // ============ workspace layout (~145 MB, phase-aliased) ============
    char* A = (char*)d_ws;
    float4* pWih0f = (float4*)(A + 0);              //  512 KB f32 gate-packed
    float4* pWih0b = (float4*)(A + 524288);
    float4* pWih1f = (float4*)(A + 1048576);        //  2 MB
    float4* pWih1b = (float4*)(A + 3145728);
    float4* pdWih0 = (float4*)(A + 5242880);        //  1 MB
    ushort* peW0f  = (ushort*)(A + 6291456);        //  512 KB bf16 [u][g][k]
    ushort* peW0b  = (ushort*)(A + 6815744);
    ushort* peW1f  = (ushort*)(A + 7340032);
    ushort* peW1b  = (ushort*)(A + 7864320);
    ushort* pb0    = (ushort*)(A + 8388608);        //  2 MB bf16 [u][g][k]
    ushort* pb1i   = (ushort*)(A + 10485760);
    ushort* pb1h   = (ushort*)(A + 12582912);       //  ends 14,680,064
    float* G0f = (float*)(A + 23068672);
    float* G0b = (float*)(A + 56623104);
    float* Gd0 = (float*)(A + 23068672);            // aliases G0f (dead after enc scans)
    float* ench = (float*)(A + 39845888);
    float* ectx = (float*)(A + 56623104);
    float* dctx = (float*)(A + 60817408);
    __hip_bfloat16* outT2 = (__hip_bfloat16*)A;     // whole region, after concat_k

    char* Bh = A + 98304000;
    float* h0f = (float*)(Bh + 0);
    float* h0b = (float*)(Bh + 8388608);
    float* h1d = (float*)(Bh + 0);                  // aliases h0f (dead after enc1_gates)
    float* qe  = (float*)(Bh + 4194304);
    float* qd  = (float*)(Bh + 8388608);
    float* ew  = (float*)(Bh + 12582912);
    char* Cr = Bh + 16777216;
    float* h1f = (float*)(Cr + 0);                  // 8,388,608
    float* h1b = (float*)(Cr + 8388608);            // 8,388,608
    float* cc  = (float*)(Cr + 16777216);           // 12,582,912
    float* dec_init = (float*)(Cr + 29360128);      // 65,536
    float* pgen  = (float*)(Cr + 29425664);         // 8,192
    float* copyp = (float*)(Cr + 29433856);         // 8,192
    float* pbuf  = (float*)(Cr + 29442048);         // 131,072
    float* h0g   = (float*)(Cr + 29573120);         // 65,536 (2x[B][D])
    float* h1g   = (float*)(Cr + 29638656);         // 65,536
    float* encg  = (float*)(Cr + 29704192);         // 65,536 (2buf x 2dir x B x H)
    int*   barDec = (int*)(Cr + 29769728);          // 16 KB (128 flag lines + go)
    int*   barEnc0 = (int*)(Cr + 29786112);         // 16 KB (2 dir regions x 4KB)
    int*   barEnc1 = (int*)(Cr + 29802496);         // 16 KB
    // total ≈ 144.90 MB

    hipMemsetAsync(barDec, 0, 49152, stream);       // zero all barrier regions

    auto pack = [&](const float* W, float4* P, int Hn, int K) {
        int total = Hn * K;
        hipLaunchKernelGGL(pack4_kernel, dim3((total + 255) / 256), dim3(256), 0, stream, W, P, Hn, K);
    };
    pack(eWih0f, pWih0f, H, E);
    pack(eWih0b, pWih0b, H, E);
    pack(eWih1f, pWih1f, H, D);
    pack(eWih1b, pWih1b, H, D);
    pack(dWih0, pdWih0, D, E);
    hipLaunchKernelGGL(packencT_k, dim3(4 * H * H / 256), dim3(256), 0, stream, eWhh0f, peW0f);
    hipLaunchKernelGGL(packencT_k, dim3(4 * H * H / 256), dim3(256), 0, stream, eWhh0b, peW0b);
    hipLaunchKernelGGL(packencT_k, dim3(4 * H * H / 256), dim3(256), 0, stream, eWhh1f, peW1f);
    hipLaunchKernelGGL(packencT_k, dim3(4 * H * H / 256), dim3(256), 0, stream, eWhh1b, peW1b);
    hipLaunchKernelGGL(packdec_k, dim3(D * D * 4 / 256), dim3(256), 0, stream, dWhh0, pb0);
    hipLaunchKernelGGL(packdec_k, dim3(D * D * 4 / 256), dim3(256), 0, stream, dWih1, pb1i);
    hipLaunchKernelGGL(packdec_k, dim3(D * D * 4 / 256), dim3(256), 0, stream, dWhh1, pb1h);

    hipLaunchKernelGGL(enc0_gates, dim3(S * B), dim3(H), 0, stream,
                       input_ids, emb, pWih0f, eb0f, pWih0b, eb0b, G0f, G0b);
    hipLaunchKernelGGL(enc_pscan, dim3(NBLK_ENC), dim3(256), 0, stream,
                       G0f, G0b, peW0f, peW0b, h0f, h0b, dec_init, encg, barEnc0);
    hipLaunchKernelGGL(enc1_gates, dim3(S * B), dim3(H), 0, stream,
                       h0f, h0b, pWih1f, eb1f, pWih1b, eb1b, G0f, G0b);
    hipLaunchKernelGGL(enc_pscan, dim3(NBLK_ENC), dim3(256), 0, stream,
                       G0f, G0b, peW1f, peW1b, h1f, h1b, dec_init + B * D, encg, barEnc1);
    hipLaunchKernelGGL(dec0_gates, dim3(T * B), dim3(D), 0, stream,
                       target_ids, emb, pdWih0, db0, Gd0);
    hipLaunchKernelGGL(dec_scan2, dim3(NBLK_DEC), dim3(512), 0, stream,
                       Gd0, pb0, pb1i, pb1h, db1, dec_init, h0g, h1g, h1d, barDec);
    hipLaunchKernelGGL(build_encht, dim3(B * 256), dim3(256), 0, stream, h1f, h1b, ench);
    hipLaunchKernelGGL(qproj, dim3(T * B), dim3(D), 0, stream, h1d, Wenc, Wdec, qe, qd);
    hipLaunchKernelGGL(escore, dim3(B * T), dim3(S), 0, stream, qe, ench, ew);
    hipLaunchKernelGGL(temporal_k, dim3((B * S + 255) / 256), dim3(256), 0, stream, ew);
    hipLaunchKernelGGL(attnctx, dim3(B * T), dim3(S), 0, stream,
                       ew, input_ids, target_ids, h1f, h1b, ectx, copyp);
    hipLaunchKernelGGL(decattn, dim3(B * T), dim3(T), 0, stream, qd, h1d, dctx);
    hipLaunchKernelGGL(concat_k, dim3(B * T), dim3(D), 0, stream,
                       h1d, ectx, dctx, sW, sb, cc, pgen);
    hipLaunchKernelGGL(outprojT_k, dim3(1000), dim3(256), 0, stream, emb, Wvoc, outT2);
    hipLaunchKernelGGL(vocab_mfma, dim3(256), dim3(512), 0, stream,
                       outT2, cc, ob, target_ids, pbuf);
    hipLaunchKernelGGL(combine_nll_k, dim3(B), dim3(T), 0, stream,
                       pbuf, target_ids, pgen, copyp, tlen, out);
}

// Round 8
// 10234.401 us; speedup vs baseline: 2.2483x; 1.2211x over previous
//
#include <hip/hip_runtime.h>
#include <hip/hip_bf16.h>
#include <math.h>

#define PAD_ID 0
#define UNK_ID 1
#define START_ID 2
#define END_ID 3

constexpr int B = 16, S = 512, T = 128, V = 32000, E = 128, H = 256, D = 512;
constexpr int C3 = 1536;        // 3*D
constexpr int VO = 31997;       // V-3
constexpr int JS = 32000;       // padded col count for outT2
constexpr int NBLK_DEC = 128;   // decoder persistent blocks (u-slice = 4)
constexpr int NBLK_ENC = 64;    // encoder persistent blocks (2 dir x 32 u-slices of 8)

typedef short short8 __attribute__((ext_vector_type(8)));
typedef float f32x4 __attribute__((ext_vector_type(4)));

__device__ __forceinline__ float sigm(float x) { return 1.0f / (1.0f + __expf(-x)); }
__device__ __forceinline__ short bf16s(float x) {
    __hip_bfloat16 h = __float2bfloat16(x);
    return *reinterpret_cast<short*>(&h);
}
__device__ __forceinline__ float bflo(unsigned int u) { return __uint_as_float(u << 16); }
__device__ __forceinline__ float bfhi(unsigned int u) { return __uint_as_float(u & 0xffff0000u); }

// coherent (sc0 sc1) 16B load — bypasses L1/L2, reads coherent point. Caller must
// s_waitcnt vmcnt(0) before consuming.
__device__ __forceinline__ float4 cload4(const float* p) {
    float4 v;
    asm volatile("global_load_dwordx4 %0, %1, off sc0 sc1" : "=v"(v) : "v"(p));
    return v;
}

__device__ __forceinline__ float aload(const float* p) {
    return __hip_atomic_load(p, __ATOMIC_RELAXED, __HIP_MEMORY_SCOPE_AGENT);
}
__device__ __forceinline__ void astore(float* p, float v) {
    __hip_atomic_store(p, v, __ATOMIC_RELAXED, __HIP_MEMORY_SCOPE_AGENT);
}

// ---------------- all-to-all grid barrier (small groups): every block stores its own
// 64B flag line and polls ALL flags. One fabric RTT. Relaxed coherent ops only.
__device__ __forceinline__ void aabar(int* flags, int nblk, int ep, int myidx) {
    asm volatile("s_waitcnt vmcnt(0)" ::: "memory");   // my h-stores globally visible
    __syncthreads();
    int tid = threadIdx.x;
    if (tid == 0)
        __hip_atomic_store(flags + myidx * 16, ep, __ATOMIC_RELAXED, __HIP_MEMORY_SCOPE_AGENT);
    if (tid < 64) {
        for (int i = tid; i < nblk; i += 64)
            while (__hip_atomic_load(flags + i * 16, __ATOMIC_RELAXED, __HIP_MEMORY_SCOPE_AGENT) < ep)
                __builtin_amdgcn_s_sleep(1);
    }
    __syncthreads();
    asm volatile("" ::: "memory");
}

// ---------------- leader-gather barrier (large groups, proven for 128 blocks)
__device__ __forceinline__ void cohbar(int* flags, int nblk, int ep, int myidx, bool leader) {
    asm volatile("s_waitcnt vmcnt(0)" ::: "memory");
    __syncthreads();
    int tid = threadIdx.x;
    int* go = flags + nblk * 16;
    if (leader) {
        if (tid < 64) {
            if (tid == 0)
                __hip_atomic_store(flags + myidx * 16, ep, __ATOMIC_RELAXED, __HIP_MEMORY_SCOPE_AGENT);
            for (int i = tid; i < nblk; i += 64)
                while (__hip_atomic_load(flags + i * 16, __ATOMIC_RELAXED, __HIP_MEMORY_SCOPE_AGENT) < ep)
                    __builtin_amdgcn_s_sleep(1);
        }
        __syncthreads();
        if (tid == 0)
            __hip_atomic_store(go, ep, __ATOMIC_RELAXED, __HIP_MEMORY_SCOPE_AGENT);
    } else {
        if (tid == 0) {
            __hip_atomic_store(flags + myidx * 16, ep, __ATOMIC_RELAXED, __HIP_MEMORY_SCOPE_AGENT);
            while (__hip_atomic_load(go, __ATOMIC_RELAXED, __HIP_MEMORY_SCOPE_AGENT) < ep)
                __builtin_amdgcn_s_sleep(1);
        }
        __syncthreads();
    }
    asm volatile("" ::: "memory");
}

// ---------------- weight packing: W[4H][K] -> P[k][u] = float4 of 4 gates
__global__ void pack4_kernel(const float* __restrict__ W, float4* __restrict__ P, int Hn, int K) {
    int i = blockIdx.x * blockDim.x + threadIdx.x;
    if (i >= K * Hn) return;
    int k = i / Hn, u = i - k * Hn;
    float4 v;
    v.x = W[(size_t)(0 * Hn + u) * K + k];
    v.y = W[(size_t)(1 * Hn + u) * K + k];
    v.z = W[(size_t)(2 * Hn + u) * K + k];
    v.w = W[(size_t)(3 * Hn + u) * K + k];
    P[(size_t)k * Hn + u] = v;
}

// ---------------- encoder Whh pack: W[4H][H] -> P[u][g][k] bf16
__global__ void packencT_k(const float* __restrict__ W, ushort* __restrict__ P) {
    int i = blockIdx.x * blockDim.x + threadIdx.x;
    if (i >= 4 * H * H) return;
    int k = i & 255, g = (i >> 8) & 3, u = i >> 10;
    P[i] = (ushort)bf16s(W[(size_t)(g * H + u) * H + k]);
}

// ---------------- decoder weight pack: W[4D][D] -> P[u][g][k] bf16
__global__ void packdec_k(const float* __restrict__ W, ushort* __restrict__ P) {
    int i = blockIdx.x * blockDim.x + threadIdx.x;
    if (i >= D * D * 4) return;
    int k = i & 511, g = (i >> 9) & 3, u = i >> 11;
    P[i] = (ushort)bf16s(W[(size_t)(g * D + u) * D + k]);
}

// ---------------- encoder layer-0 gate preactivations for both directions
__global__ void enc0_gates(const int* __restrict__ ids, const float* __restrict__ emb,
                           const float4* __restrict__ Pf, const float* __restrict__ bf_,
                           const float4* __restrict__ Pb, const float* __restrict__ bb_,
                           float* __restrict__ Gf, float* __restrict__ Gb) {
    int n = blockIdx.x;
    int s = n / B, b = n - s * B;
    int u = threadIdx.x;
    __shared__ float xr[E];
    int tok = ids[b * S + s];
    if (tok >= V) tok = UNK_ID;
    if (u < E) xr[u] = emb[(size_t)tok * E + u];
    __syncthreads();
    float a0 = bf_[0 * H + u], a1 = bf_[1 * H + u], a2 = bf_[2 * H + u], a3 = bf_[3 * H + u];
#pragma unroll 4
    for (int k = 0; k < E; k++) {
        float xv = xr[k]; float4 w = Pf[k * H + u];
        a0 += xv * w.x; a1 += xv * w.y; a2 += xv * w.z; a3 += xv * w.w;
    }
    float* g = Gf + (size_t)n * 4 * H;
    g[0 * H + u] = a0; g[1 * H + u] = a1; g[2 * H + u] = a2; g[3 * H + u] = a3;
    a0 = bb_[0 * H + u]; a1 = bb_[1 * H + u]; a2 = bb_[2 * H + u]; a3 = bb_[3 * H + u];
#pragma unroll 4
    for (int k = 0; k < E; k++) {
        float xv = xr[k]; float4 w = Pb[k * H + u];
        a0 += xv * w.x; a1 += xv * w.y; a2 += xv * w.z; a3 += xv * w.w;
    }
    g = Gb + (size_t)n * 4 * H;
    g[0 * H + u] = a0; g[1 * H + u] = a1; g[2 * H + u] = a2; g[3 * H + u] = a3;
}

// ---------------- encoder layer-1 gate preactivations (input = concat(h0f,h0b))
__global__ void enc1_gates(const float* __restrict__ h0f, const float* __restrict__ h0b,
                           const float4* __restrict__ Pf, const float* __restrict__ bf_,
                           const float4* __restrict__ Pb, const float* __restrict__ bb_,
                           float* __restrict__ Gf, float* __restrict__ Gb) {
    int n = blockIdx.x;      // s*B+b
    int u = threadIdx.x;     // 256
    __shared__ float xr[D];
    xr[u] = h0f[(size_t)n * H + u];
    xr[H + u] = h0b[(size_t)n * H + u];
    __syncthreads();
    float a0 = bf_[0 * H + u], a1 = bf_[1 * H + u], a2 = bf_[2 * H + u], a3 = bf_[3 * H + u];
#pragma unroll 4
    for (int k = 0; k < D; k++) {
        float xv = xr[k]; float4 w = Pf[k * H + u];
        a0 += xv * w.x; a1 += xv * w.y; a2 += xv * w.z; a3 += xv * w.w;
    }
    float* g = Gf + (size_t)n * 4 * H;
    g[0 * H + u] = a0; g[1 * H + u] = a1; g[2 * H + u] = a2; g[3 * H + u] = a3;
    a0 = bb_[0 * H + u]; a1 = bb_[1 * H + u]; a2 = bb_[2 * H + u]; a3 = bb_[3 * H + u];
#pragma unroll 4
    for (int k = 0; k < D; k++) {
        float xv = xr[k]; float4 w = Pb[k * H + u];
        a0 += xv * w.x; a1 += xv * w.y; a2 += xv * w.z; a3 += xv * w.w;
    }
    g = Gb + (size_t)n * 4 * H;
    g[0 * H + u] = a0; g[1 * H + u] = a1; g[2 * H + u] = a2; g[3 * H + u] = a3;
}

// ---------------- encoder persistent scan, one layer, both dirs.
// grid 64 = dir*32 + ub (u-slice 8). 256 threads = (uh 4)(g 4)(b 16); cell threads = 128.
// Vectorized LDS (float4), coherent dwordx4 staging, all-to-all per-dir barrier.
__global__ void __launch_bounds__(256) enc_pscan(
        const float* __restrict__ Gf, const float* __restrict__ Gb,
        const ushort* __restrict__ Pf, const ushort* __restrict__ Pb,   // [u][g][k] bf16
        float* __restrict__ hof, float* __restrict__ hob,
        float* __restrict__ hfin /* [B][2H] */,
        float* __restrict__ hg /* [2buf][2dir][B][H] f32 */, int* __restrict__ barbase) {
    __shared__ __align__(16) float Wl[32 * 260];   // [u_loc*4+g][256 + 4 pad] f32
    __shared__ __align__(16) float hh[16 * 260];   // [b][256 + 4 pad]
    __shared__ float gs[512];                      // [u_loc][b][g]
    int blk = blockIdx.x;
    int dirb = blk >> 5, ub = blk & 31;
    int* bar = barbase + dirb * 1024;              // independent 4KB region per dir
    const float* G = dirb ? Gb : Gf;
    const ushort* P = dirb ? Pb : Pf;
    float* ho = dirb ? hob : hof;
    int tid = threadIdx.x;
    int b = tid & 15, g = (tid >> 4) & 3, uh = tid >> 6;

    // stage + unpack weight slice (8 u x 4 g x 256 k) to f32 LDS, row stride 260
    const uint* wsrc = (const uint*)(P + (size_t)ub * 8192);
    for (int i = tid; i < 4096; i += 256) {
        int r = i >> 7, c = i & 127;
        uint wv = wsrc[i];
        Wl[r * 260 + 2 * c] = bflo(wv);
        Wl[r * 260 + 2 * c + 1] = bfhi(wv);
    }
    if (tid < 128) {
        int u_loc = tid >> 4, bb = tid & 15;
        astore(&hg[dirb * (B * H) + bb * H + ub * 8 + u_loc], 0.f);
    }
    float c_st = 0.f;
    int ep = 1;
    aabar(bar, 32, ep, ub);

    int u0 = uh * 2, u1 = u0 + 1;
    const float4* wp0 = (const float4*)(Wl + (u0 * 4 + g) * 260);
    const float4* wp1 = (const float4*)(Wl + (u1 * 4 + g) * 260);
    for (int step = 0; step < S; step++) {
        int s = dirb ? (S - 1 - step) : step;
        int cur = step & 1;
        // prefetch gate biases (cached loads; latency overlaps coherent staging wait)
        float g0, g1, g2, g3;
        if (tid < 128) {
            int u_loc = tid >> 4, bb = tid & 15;
            const float* gG = G + ((size_t)(s * B + bb)) * 1024 + (ub * 8 + u_loc);
            g0 = gG[0]; g1 = gG[256]; g2 = gG[512]; g3 = gG[768];
        }
        // coherent staging: hg[cur] (layout [b][k]) -> hh[b][260] straight copy
        const float* hgd = hg + cur * (2 * B * H) + dirb * (B * H);
        float4 sv[4];
#pragma unroll
        for (int r = 0; r < 4; r++) sv[r] = cload4(hgd + r * 1024 + tid * 4);
        asm volatile("s_waitcnt vmcnt(0)" ::: "memory");
        __builtin_amdgcn_sched_barrier(0);
#pragma unroll
        for (int r = 0; r < 4; r++) {
            int flat = r * 1024 + tid * 4;
            *(float4*)(hh + (flat >> 8) * 260 + (flat & 255)) = sv[r];
        }
        __syncthreads();
        const float4* hp = (const float4*)(hh + b * 260);
        float acc0 = 0.f, acc1 = 0.f;
#pragma unroll 8
        for (int kq = 0; kq < 64; kq++) {
            float4 hv = hp[kq];
            float4 wa = wp0[kq];
            float4 wb = wp1[kq];
            acc0 += wa.x * hv.x + wa.y * hv.y + wa.z * hv.z + wa.w * hv.w;
            acc1 += wb.x * hv.x + wb.y * hv.y + wb.z * hv.z + wb.w * hv.w;
        }
        gs[u0 * 64 + b * 4 + g] = acc0;
        gs[u1 * 64 + b * 4 + g] = acc1;
        __syncthreads();
        if (tid < 128) {
            int u_loc = tid >> 4, bb = tid & 15;
            int uu = ub * 8 + u_loc;
            const float* base = gs + u_loc * 64 + bb * 4;
            float gg0 = g0 + base[0];
            float gg1 = g1 + base[1];
            float gg2 = g2 + base[2];
            float gg3 = g3 + base[3];
            float ig = sigm(gg0), fg = sigm(gg1), gt = tanhf(gg2), og = sigm(gg3);
            c_st = fg * c_st + ig * gt;
            float hn = og * tanhf(c_st);
            astore(&hg[(cur ^ 1) * (2 * B * H) + dirb * (B * H) + bb * H + uu], hn);
            ho[((size_t)(s * B + bb)) * H + uu] = hn;
            if (step == S - 1) hfin[bb * (2 * H) + dirb * H + uu] = hn;
        }
        aabar(bar, 32, ++ep, ub);
    }
}

// ---------------- decoder layer-0 input gates (teacher tokens). grid T*B (n=t*B+b), 512 thr.
__global__ void dec0_gates(const int* __restrict__ tgt, const float* __restrict__ emb,
                           const float4* __restrict__ P, const float* __restrict__ bias,
                           float* __restrict__ G) {
    int n = blockIdx.x;
    int t = n / B, b = n - t * B;
    int u = threadIdx.x;
    __shared__ float xr[E];
    int tok;
    if (t == 0) tok = START_ID;
    else { tok = tgt[b * T + (t - 1)]; if (tok >= V) tok = UNK_ID; }
    if (u < E) xr[u] = emb[(size_t)tok * E + u];
    __syncthreads();
    float a0 = bias[0 * D + u], a1 = bias[1 * D + u], a2 = bias[2 * D + u], a3 = bias[3 * D + u];
#pragma unroll 4
    for (int k = 0; k < E; k++) {
        float xv = xr[k]; float4 w = P[k * D + u];
        a0 += xv * w.x; a1 += xv * w.y; a2 += xv * w.z; a3 += xv * w.w;
    }
    float* g = G + (size_t)n * 4 * D;
    g[0 * D + u] = a0; g[1 * D + u] = a1; g[2 * D + u] = a2; g[3 * D + u] = a3;
}

// ---------------- decoder persistent 2-layer scan.
// grid 128 blocks (u-slice 4), 512 threads = (u_loc 4, g 4, kq 2, b 16).
// Coherent dwordx4 staging; 1 grid barrier per step.
__global__ void __launch_bounds__(512) dec_scan2(
        const float* __restrict__ G0, const ushort* __restrict__ pb0,
        const ushort* __restrict__ pb1i, const ushort* __restrict__ pb1h,
        const float* __restrict__ b1, const float* __restrict__ hinit,
        float* __restrict__ h0g /* [2][B][D] */, float* __restrict__ h1g /* [2][B][D] */,
        float* __restrict__ h1out, int* __restrict__ bar) {
    __shared__ __align__(16) ushort W0s[16 * 528];
    __shared__ __align__(16) ushort W1is[16 * 528];
    __shared__ __align__(16) ushort W1hs[16 * 528];
    __shared__ __align__(16) float bufA[16 * 516];   // h0 staging [b][516]
    __shared__ __align__(16) float bufB[16 * 516];   // h1 staging
    __shared__ float red[4][4][2][16];
    int tid = threadIdx.x;
    int u0 = blockIdx.x * 4;
    int u_loc = tid >> 7, g = (tid >> 5) & 3, kq = (tid >> 4) & 1, b = tid & 15;

    {
        const uint4* s0 = (const uint4*)(pb0 + (size_t)u0 * 2048);
        const uint4* s1 = (const uint4*)(pb1i + (size_t)u0 * 2048);
        const uint4* s2 = (const uint4*)(pb1h + (size_t)u0 * 2048);
        uint4* d0 = (uint4*)W0s; uint4* d1 = (uint4*)W1is; uint4* d2 = (uint4*)W1hs;
        for (int i = tid; i < 1024; i += 512) {
            int r = i >> 6, c = i & 63;
            d0[r * 66 + c] = s0[i]; d1[r * 66 + c] = s1[i]; d2[r * 66 + c] = s2[i];
        }
    }
    for (int i = tid; i < B * D; i += 512) {
        int bb = i >> 9, kk = i & 511;
        bufA[bb * 516 + kk] = hinit[i];
    }
    if (tid < 64) {
        int ul = tid >> 4, bb = tid & 15;
        astore(&h1g[B * D + bb * 512 + u0 + ul], hinit[B * D + bb * 512 + u0 + ul]);
    }
    float c0v = 0.f, c1v = 0.f;
    int ep = 1;
    cohbar(bar, NBLK_DEC, ep, blockIdx.x, blockIdx.x == 0);

    for (int t = 0; t < T; t++) {
        int cur = t & 1;
        // ---- phase A: layer-0 gate partial from bufA (= h0(t-1))
        {
            const uint2* w = (const uint2*)(W0s + (u_loc * 4 + g) * 528) + kq * 64;
            const float* hp = bufA + b * 516 + kq * 256;
            float acc = 0.f;
#pragma unroll 4
            for (int i = 0; i < 64; i++) {
                uint2 wv = w[i];
                float4 hv = *(const float4*)(hp + i * 4);
                acc += bflo(wv.x) * hv.x + bfhi(wv.x) * hv.y + bflo(wv.y) * hv.z + bfhi(wv.y) * hv.w;
            }
            red[u_loc][g][kq][b] = acc;
        }
        __syncthreads();
        if (tid < 64) {
            int ul = tid >> 4, bb = tid & 15;
            const float* gg = G0 + ((size_t)(t * B + bb)) * 2048 + (u0 + ul);
            float g0 = gg[0]    + red[ul][0][0][bb] + red[ul][0][1][bb];
            float g1 = gg[512]  + red[ul][1][0][bb] + red[ul][1][1][bb];
            float g2 = gg[1024] + red[ul][2][0][bb] + red[ul][2][1][bb];
            float g3 = gg[1536] + red[ul][3][0][bb] + red[ul][3][1][bb];
            float ig = sigm(g0), fg = sigm(g1), gt = tanhf(g2), og = sigm(g3);
            c0v = fg * c0v + ig * gt;
            astore(&h0g[cur * (B * D) + bb * 512 + u0 + ul], og * tanhf(c0v));
        }
        cohbar(bar, NBLK_DEC, ++ep, blockIdx.x, blockIdx.x == 0);   // h0(t) all visible
        // ---- phase B staging: bufA <- h0(t), bufB <- h1(t-1)  (coherent dwordx4)
        {
            float4 s0[4], s1[4];
            const float* p0 = h0g + cur * (B * D);
            const float* p1 = h1g + (cur ^ 1) * (B * D);
#pragma unroll
            for (int r = 0; r < 4; r++) {
                s0[r] = cload4(p0 + r * 2048 + tid * 4);
                s1[r] = cload4(p1 + r * 2048 + tid * 4);
            }
            asm volatile("s_waitcnt vmcnt(0)" ::: "memory");
            __builtin_amdgcn_sched_barrier(0);
#pragma unroll
            for (int r = 0; r < 4; r++) {
                int flat = r * 2048 + tid * 4;
                int bb = flat >> 9, kk = flat & 511;
                *(float4*)(bufA + bb * 516 + kk) = s0[r];
                *(float4*)(bufB + bb * 516 + kk) = s1[r];
            }
        }
        __syncthreads();
        // ---- phase B: layer-1 gates = b1 + W1i*h0(t) + W1h*h1(t-1)
        {
            const uint2* wA = (const uint2*)(W1is + (u_loc * 4 + g) * 528) + kq * 64;
            const uint2* wB = (const uint2*)(W1hs + (u_loc * 4 + g) * 528) + kq * 64;
            const float* hA = bufA + b * 516 + kq * 256;
            const float* hB = bufB + b * 516 + kq * 256;
            float acc = 0.f;
#pragma unroll 4
            for (int i = 0; i < 64; i++) {
                uint2 wv = wA[i];
                float4 hv = *(const float4*)(hA + i * 4);
                acc += bflo(wv.x) * hv.x + bfhi(wv.x) * hv.y + bflo(wv.y) * hv.z + bfhi(wv.y) * hv.w;
                uint2 wv2 = wB[i];
                float4 hv2 = *(const float4*)(hB + i * 4);
                acc += bflo(wv2.x) * hv2.x + bfhi(wv2.x) * hv2.y + bflo(wv2.y) * hv2.z + bfhi(wv2.y) * hv2.w;
            }
            red[u_loc][g][kq][b] = acc;
        }
        __syncthreads();
        if (tid < 64) {
            int ul = tid >> 4, bb = tid & 15;
            int uu = u0 + ul;
            float g0 = b1[uu]        + red[ul][0][0][bb] + red[ul][0][1][bb];
            float g1 = b1[512 + uu]  + red[ul][1][0][bb] + red[ul][1][1][bb];
            float g2 = b1[1024 + uu] + red[ul][2][0][bb] + red[ul][2][1][bb];
            float g3 = b1[1536 + uu] + red[ul][3][0][bb] + red[ul][3][1][bb];
            float ig = sigm(g0), fg = sigm(g1), gt = tanhf(g2), og = sigm(g3);
            c1v = fg * c1v + ig * gt;
            float h1n_v = og * tanhf(c1v);
            astore(&h1g[cur * (B * D) + bb * 512 + uu], h1n_v);
            h1out[((size_t)(t * B + bb)) * 512 + uu] = h1n_v;
        }
        __syncthreads();   // protect red/bufA/bufB reuse next iteration
    }
}

// ---------------- transpose enc hidden to [b][k(512)][s] for coalesced score dots
__global__ void build_encht(const float* __restrict__ h1f, const float* __restrict__ h1b,
                            float* __restrict__ et) {
    int blk = blockIdx.x;                 // b*256 + kt*16 + st
    int b = blk >> 8, rem = blk & 255;
    int kt = rem >> 4, st = rem & 15;
    int c = threadIdx.x & 31, r = threadIdx.x >> 5;   // r in 0..7
    __shared__ float tile[32][33];
#pragma unroll
    for (int i = 0; i < 4; i++) {
        int sl = r + i * 8;               // s_local
        int s = st * 32 + sl;
        int k = kt * 32 + c;              // lane-contiguous over k
        float v = (k < H) ? h1f[((size_t)(s * B + b)) * H + k]
                          : h1b[((size_t)(s * B + b)) * H + (k - H)];
        tile[c][sl] = v;                  // tile[k_local][s_local]
    }
    __syncthreads();
#pragma unroll
    for (int i = 0; i < 4; i++) {
        int kl = r + i * 8;
        et[(size_t)b * D * S + (size_t)(kt * 32 + kl) * S + st * 32 + c] = tile[kl][c];
    }
}

// ---------------- q projections. grid T*B (n=t*B+b), 512 threads
__global__ void qproj(const float* __restrict__ h1d, const float* __restrict__ Wenc,
                      const float* __restrict__ Wdec, float* __restrict__ qe, float* __restrict__ qd) {
    int n = blockIdx.x;
    int o = threadIdx.x;
    __shared__ float hr[D];
    hr[o] = h1d[(size_t)n * D + o];
    __syncthreads();
    float ae = 0.f, ad = 0.f;
#pragma unroll 4
    for (int k = 0; k < D; k++) {
        float hk = hr[k];
        ae += hk * Wenc[k * D + o];
        ad += hk * Wdec[k * D + o];
    }
    qe[(size_t)n * D + o] = ae;
    qd[(size_t)n * D + o] = ad;
}

// ---------------- e = exp(min(score,30)). grid B*T (bt=b*T+t), 512 threads (s)
__global__ void escore(const float* __restrict__ qe, const float* __restrict__ et,
                       float* __restrict__ ew) {
    int bt = blockIdx.x;
    int b = bt / T, t = bt - b * T;
    int sx = threadIdx.x;
    __shared__ float q[D];
    q[sx] = qe[((size_t)(t * B + b)) * D + sx];
    __syncthreads();
    float acc = 0.f;
    const float* eb = et + (size_t)b * D * S + sx;
#pragma unroll 4
    for (int k = 0; k < D; k++) { acc += q[k] * eb[0]; eb += S; }
    acc = fminf(acc, 30.0f);
    ew[(size_t)bt * S + sx] = __expf(acc);
}

// ---------------- temporal normalization (prefix over t, in place)
__global__ void temporal_k(float* __restrict__ ew) {
    int i = blockIdx.x * blockDim.x + threadIdx.x;
    if (i >= B * S) return;
    int b = i / S, sx = i - b * S;
    float cum = 0.f;
    for (int t = 0; t < T; t++) {
        size_t idx = ((size_t)(b * T + t)) * S + sx;
        float v = ew[idx];
        ew[idx] = v / (t == 0 ? 1.0f : (cum + 1e-8f));
        cum += v;
    }
}

// ---------------- attention softmax over s + enc context + copy prob. grid B*T, 512 thr
__global__ void attnctx(const float* __restrict__ ew, const int* __restrict__ ids,
                        const int* __restrict__ tgt,
                        const float* __restrict__ h1f, const float* __restrict__ h1b,
                        float* __restrict__ ectx, float* __restrict__ copyp) {
    int bt = blockIdx.x;
    int b = bt / T, t = bt - b * T;
    int tid = threadIdx.x;
    __shared__ float aw[S];
    __shared__ float red[512];
    float v = ew[(size_t)bt * S + tid];
    int tok = ids[b * S + tid];
    bool pad = (tok == PAD_ID);
    float vm = pad ? -INFINITY : v;
    red[tid] = vm; __syncthreads();
    for (int w = 256; w > 0; w >>= 1) { if (tid < w) red[tid] = fmaxf(red[tid], red[tid + w]); __syncthreads(); }
    float m = red[0]; __syncthreads();
    float ex = pad ? 0.f : __expf(vm - m);
    red[tid] = ex; __syncthreads();
    for (int w = 256; w > 0; w >>= 1) { if (tid < w) red[tid] += red[tid + w]; __syncthreads(); }
    float Z = red[0]; __syncthreads();
    float a = ex / Z;
    aw[tid] = a;
    int nt = tgt[b * T + t];
    red[tid] = (tok == nt) ? a : 0.f; __syncthreads();
    for (int w = 256; w > 0; w >>= 1) { if (tid < w) red[tid] += red[tid + w]; __syncthreads(); }
    if (tid == 0) copyp[bt] = red[0];
    __syncthreads();
    int d = tid;
    const float* hp = (d < H) ? (h1f + (size_t)b * H + d) : (h1b + (size_t)b * H + (d - H));
    float acc = 0.f;
#pragma unroll 4
    for (int s2 = 0; s2 < S; s2++) { acc += aw[s2] * hp[0]; hp += B * H; }
    ectx[(size_t)bt * D + d] = acc;
}

// ---------------- intra-decoder attention. grid B*T, 128 threads
__global__ void decattn(const float* __restrict__ qd, const float* __restrict__ h1d,
                        float* __restrict__ dctx) {
    int bt = blockIdx.x;
    int b = bt / T, t = bt - b * T;
    int tid = threadIdx.x;
    __shared__ float q[D];
    __shared__ float wl[T];
    __shared__ float red[128];
    for (int i = tid; i < D; i += 128) q[i] = qd[((size_t)(t * B + b)) * D + i];
    __syncthreads();
    float sc = -INFINITY;
    if (tid < t) {
        const float* hu = h1d + ((size_t)(tid * B + b)) * D;
        float a = 0.f;
#pragma unroll 4
        for (int k = 0; k < D; k++) a += q[k] * hu[k];
        sc = a;
    }
    red[tid] = sc; __syncthreads();
    for (int w = 64; w > 0; w >>= 1) { if (tid < w) red[tid] = fmaxf(red[tid], red[tid + w]); __syncthreads(); }
    float m = red[0]; __syncthreads();
    float ex = (tid < t) ? __expf(sc - m) : 0.f;
    red[tid] = ex; __syncthreads();
    for (int w = 64; w > 0; w >>= 1) { if (tid < w) red[tid] += red[tid + w]; __syncthreads(); }
    float Z = red[0]; __syncthreads();
    wl[tid] = (t > 0) ? (ex / Z) : 0.f;
    __syncthreads();
    for (int d = tid; d < D; d += 128) {
        float acc = 0.f;
        for (int u = 0; u < t; u++) acc += wl[u] * h1d[((size_t)(u * B + b)) * D + d];
        dctx[(size_t)bt * D + d] = acc;
    }
}

// ---------------- concat + p_gen. grid B*T, 512 threads
__global__ void concat_k(const float* __restrict__ h1d, const float* __restrict__ ectx,
                         const float* __restrict__ dctx, const float* __restrict__ sW,
                         const float* __restrict__ sb, float* __restrict__ cc,
                         float* __restrict__ pgen) {
    int bt = blockIdx.x;
    int b = bt / T, t = bt - b * T;
    int d = threadIdx.x;
    __shared__ float red[512];
    float v0 = h1d[((size_t)(t * B + b)) * D + d];
    float v1 = ectx[(size_t)bt * D + d];
    float v2 = dctx[(size_t)bt * D + d];
    float* c = cc + (size_t)bt * C3;
    c[d] = v0; c[D + d] = v1; c[2 * D + d] = v2;
    red[d] = v0 * sW[d] + v1 * sW[D + d] + v2 * sW[2 * D + d];
    __syncthreads();
    for (int w = 256; w > 0; w >>= 1) { if (d < w) red[d] += red[d + w]; __syncthreads(); }
    if (d == 0) pgen[bt] = 1.f / (1.f + __expf(-(red[0] + sb[0])));
}

// ---------------- out_proj, packed-k layout for MFMA B-fragments.
__global__ void outprojT_k(const float* __restrict__ emb, const float* __restrict__ Wvoc,
                           __hip_bfloat16* __restrict__ outT2) {
    int j0 = blockIdx.x * 32;
    int jl = threadIdx.x & 31, oq = threadIdx.x >> 5;   // oq in 0..7
    __shared__ float er[32][E + 1];                      // +1 pad
    for (int i = threadIdx.x; i < 32 * E; i += 256) {
        int jj = i >> 7, e = i & 127;
        int j = j0 + jj;
        er[jj][e] = (j < VO) ? emb[(size_t)(3 + j) * E + e] : 0.f;
    }
    __syncthreads();
    int j = j0 + jl;
#pragma unroll 1
    for (int i = 0; i < 24; i++) {
        int o = oq * 24 + i;                             // octet index 0..191
        int k0 = o * 8;
        float acc[8];
#pragma unroll
        for (int kk = 0; kk < 8; kk++) acc[kk] = 0.f;
#pragma unroll 4
        for (int e = 0; e < E; e++) {
            float x = er[jl][e];
            float4 w0 = *(const float4*)(Wvoc + (size_t)e * C3 + k0);
            float4 w1 = *(const float4*)(Wvoc + (size_t)e * C3 + k0 + 4);
            acc[0] += x * w0.x; acc[1] += x * w0.y; acc[2] += x * w0.z; acc[3] += x * w0.w;
            acc[4] += x * w1.x; acc[5] += x * w1.y; acc[6] += x * w1.z; acc[7] += x * w1.w;
        }
        short8 v;
#pragma unroll
        for (int kk = 0; kk < 8; kk++) v[kk] = bf16s(tanhf(acc[kk]));
        *reinterpret_cast<short8*>((char*)outT2 + ((size_t)o * JS + j) * 16) = v;
    }
}

// ---------------- vocab GEMM via MFMA + fused online softmax partials.
__global__ void __launch_bounds__(512) vocab_mfma(
        const __hip_bfloat16* __restrict__ outT2, const float* __restrict__ cc,
        const float* __restrict__ ob, const int* __restrict__ tgt,
        float* __restrict__ pbuf) {
    __shared__ __align__(16) short As[32 * 1536];        // bf16 A tile, chunk-XOR swizzled
    __shared__ float wm[8][32], ws_[8][32], wg[8][32];
    __shared__ int jstar_s[32];
    int bid = blockIdx.x;
    int rb = bid & 63, q = bid >> 6;
    int row0 = rb * 32;
    int tid = threadIdx.x;

    {
        int r = tid >> 4, cpos = tid & 15;
        const float* src = cc + (size_t)(row0 + r) * C3;
        int r7 = r & 7;
        short* dst = As + r * C3;
#pragma unroll
        for (int ii = 0; ii < 12; ii++) {
            int c = ii * 16 + cpos;                      // chunk 0..191 (8 bf16 each)
            float4 f0 = *(const float4*)(src + c * 8);
            float4 f1 = *(const float4*)(src + c * 8 + 4);
            short8 v;
            v[0] = bf16s(f0.x); v[1] = bf16s(f0.y); v[2] = bf16s(f0.z); v[3] = bf16s(f0.w);
            v[4] = bf16s(f1.x); v[5] = bf16s(f1.y); v[6] = bf16s(f1.z); v[7] = bf16s(f1.w);
            *reinterpret_cast<short8*>(dst + ((c ^ r7) << 3)) = v;
        }
    }
    if (tid < 32) {
        int nt = tgt[row0 + tid];
        int ix = nt - 3;
        ix = ix < 0 ? 0 : (ix > VO - 1 ? VO - 1 : ix);
        jstar_s[tid] = ix;
    }
    __syncthreads();

    int lane = tid & 63, wid = tid >> 6;
    int wr = wid >> 2, wc = wid & 3;
    int cl = lane & 15, g = lane >> 4;
    int rowA = wr * 16 + cl;
    const short* Abase = As + rowA * C3;
    int r7 = rowA & 7;
    int jst[4];
    float m[4], sacc[4], gl[4];
#pragma unroll
    for (int i = 0; i < 4; i++) {
        jst[i] = jstar_s[wr * 16 + g * 4 + i];
        m[i] = -1e30f; sacc[i] = 0.f; gl[i] = -1e30f;
    }

    int jb0 = q * 8192;
    int jqend = (jb0 + 8192 < VO) ? jb0 + 8192 : VO;
    int nmt = (jqend - jb0 + 127) >> 7;
    for (int ti = 0; ti < nmt; ti++) {
        int jA = jb0 + ti * 128 + wc * 32 + cl;
        const char* pB = (const char*)outT2 + ((size_t)g * JS + jA) * 16;
        f32x4 acc0 = {0.f, 0.f, 0.f, 0.f}, acc1 = {0.f, 0.f, 0.f, 0.f};
#pragma unroll
        for (int s = 0; s < 48; s++) {
            short8 a = *reinterpret_cast<const short8*>(Abase + (((s * 4 + g) ^ r7) << 3));
            short8 b0 = *reinterpret_cast<const short8*>(pB + (size_t)s * (4 * JS * 16));
            short8 b1 = *reinterpret_cast<const short8*>(pB + (size_t)s * (4 * JS * 16) + 256);
            acc0 = __builtin_amdgcn_mfma_f32_16x16x32_bf16(a, b0, acc0, 0, 0, 0);
            acc1 = __builtin_amdgcn_mfma_f32_16x16x32_bf16(a, b1, acc1, 0, 0, 0);
        }
#pragma unroll
        for (int X = 0; X < 2; X++) {
            int j = jA + X * 16;
            if (j < jqend) {
                float obj = ob[j];
#pragma unroll
                for (int i = 0; i < 4; i++) {
                    float L = (X ? acc1[i] : acc0[i]) + obj;
                    if (j == jst[i]) gl[i] = L;
                    float mn = fmaxf(m[i], L);
                    sacc[i] = sacc[i] * __expf(m[i] - mn) + __expf(L - mn);
                    m[i] = mn;
                }
            }
        }
    }

#pragma unroll
    for (int i = 0; i < 4; i++) {
        for (int mask = 1; mask < 16; mask <<= 1) {
            float om = __shfl_xor(m[i], mask);
            float os = __shfl_xor(sacc[i], mask);
            float mn = fmaxf(m[i], om);
            sacc[i] = sacc[i] * __expf(m[i] - mn) + os * __expf(om - mn);
            m[i] = mn;
            gl[i] = fmaxf(gl[i], __shfl_xor(gl[i], mask));
        }
    }
    if (cl == 0) {
#pragma unroll
        for (int i = 0; i < 4; i++) {
            int rl = wr * 16 + g * 4 + i;
            wm[wid][rl] = m[i]; ws_[wid][rl] = sacc[i]; wg[wid][rl] = gl[i];
        }
    }
    __syncthreads();
    if (tid < 32) {
        float M = -1e30f, SS = 0.f, GL = -1e30f;
        int w0 = (tid >> 4) * 4;
#pragma unroll
        for (int w = 0; w < 4; w++) {
            float mq = wm[w0 + w][tid], sq = ws_[w0 + w][tid], gq = wg[w0 + w][tid];
            float mn = fmaxf(M, mq);
            SS = SS * __expf(M - mn) + sq * __expf(mq - mn);
            M = mn;
            GL = fmaxf(GL, gq);
        }
        float* o = pbuf + ((size_t)bid * 32 + tid) * 4;
        o[0] = M; o[1] = SS; o[2] = GL;
    }
}

// ---------------- combine quarter-partials + pointer mix + NLL. grid B, 128 threads.
__global__ void combine_nll_k(const float* __restrict__ pbuf, const int* __restrict__ tgt,
                              const float* __restrict__ pgen, const float* __restrict__ copyp,
                              const int* __restrict__ tlen, float* __restrict__ out) {
    int b = blockIdx.x, t = threadIdx.x;
    int row = b * T + t;
    int rb = row >> 5, r = row & 31;
    float M = -1e30f, SS = 0.f, GL = -1e30f;
#pragma unroll
    for (int q = 0; q < 4; q++) {
        const float* p = pbuf + ((size_t)(q * 64 + rb) * 32 + r) * 4;
        float mq = p[0], sq = p[1], gq = p[2];
        float mn = fmaxf(M, mq);
        SS = SS * __expf(M - mn) + sq * __expf(mq - mn);
        M = mn;
        GL = fmaxf(GL, gq);
    }
    int nt = tgt[row];
    float genp = (nt >= 3 && nt < V) ? __expf(GL - M) / SS : 0.f;
    float pg = pgen[row];
    float p = pg * genp + (1.f - pg) * copyp[row];
    __shared__ float red[128];
    red[t] = (t < tlen[b]) ? -logf(p + 1e-9f) : 0.f;
    __syncthreads();
    for (int w = 64; w > 0; w >>= 1) { if (t < w) red[t] += red[t + w]; __syncthreads(); }
    if (t == 0) out[b] = red[0];
}

extern "C" void kernel_launch(void* const* d_in, const int* in_sizes, int n_in,
                              void* d_out, int out_size, void* d_ws, size_t ws_size,
                              hipStream_t stream) {
    const int* input_ids = (const int*)d_in[0];
    const int* target_ids = (const int*)d_in[1];
    const int* tlen = (const int*)d_in[3];
    const float* emb = (const float*)d_in[5];
    const float* eWih0f = (const float*)d_in[6],  *eWhh0f = (const float*)d_in[7],  *eb0f = (const float*)d_in[8];
    const float* eWih0b = (const float*)d_in[9],  *eWhh0b = (const float*)d_in[10], *eb0b = (const float*)d_in[11];
    const float* eWih1f = (const float*)d_in[12], *eWhh1f = (const float*)d_in[13], *eb1f = (const float*)d_in[14];
    const float* eWih1b = (const float*)d_in[15], *eWhh1b = (const float*)d_in[16], *eb1b = (const float*)d_in[17];
    const float* dWih0 = (const float*)d_in[18], *dWhh0 = (const float*)d_in[19], *db0 = (const float*)d_in[20];
    const float* dWih1 = (const float*)d_in[21], *dWhh1 = (const float*)d_in[22], *db1 = (const float*)d_in[23];
    const float* Wenc = (const float*)d_in[24], *Wdec = (const float*)d_in[25];
    const float* Wvoc = (const float*)d_in[26], *sW = (const float*)d_in[27], *sb = (const float*)d_in[28];
    const float* ob = (const float*)d_in[29];
    float* out = (float*)d_out;
    (void)ws_size; (void)n_in; (void)in_sizes; (void)out_size;

    // ============ workspace layout (~145 MB, phase-aliased) ============
    char* A = (char*)d_ws;
    float4* pWih0f = (float4*)(A + 0);              //  512 KB f32 gate-packed
    float4* pWih0b = (float4*)(A + 524288);
    float4* pWih1f = (float4*)(A + 1048576);        //  2 MB
    float4* pWih1b = (float4*)(A + 3145728);
    float4* pdWih0 = (float4*)(A + 5242880);        //  1 MB
    ushort* peW0f  = (ushort*)(A + 6291456);        //  512 KB bf16 [u][g][k]
    ushort* peW0b  = (ushort*)(A + 6815744);
    ushort* peW1f  = (ushort*)(A + 7340032);
    ushort* peW1b  = (ushort*)(A + 7864320);
    ushort* pb0    = (ushort*)(A + 8388608);        //  2 MB bf16 [u][g][k]
    ushort* pb1i   = (ushort*)(A + 10485760);
    ushort* pb1h   = (ushort*)(A + 12582912);       //  ends 14,680,064
    float* G0f = (float*)(A + 23068672);
    float* G0b = (float*)(A + 56623104);
    float* Gd0 = (float*)(A + 23068672);            // aliases G0f (dead after enc scans)
    float* ench = (float*)(A + 39845888);
    float* ectx = (float*)(A + 56623104);
    float* dctx = (float*)(A + 60817408);
    __hip_bfloat16* outT2 = (__hip_bfloat16*)A;     // whole region, after concat_k

    char* Bh = A + 98304000;
    float* h0f = (float*)(Bh + 0);
    float* h0b = (float*)(Bh + 8388608);
    float* h1d = (float*)(Bh + 0);                  // aliases h0f (dead after enc1_gates)
    float* qe  = (float*)(Bh + 4194304);
    float* qd  = (float*)(Bh + 8388608);
    float* ew  = (float*)(Bh + 12582912);
    char* Cr = Bh + 16777216;
    float* h1f = (float*)(Cr + 0);                  // 8,388,608
    float* h1b = (float*)(Cr + 8388608);            // 8,388,608
    float* cc  = (float*)(Cr + 16777216);           // 12,582,912
    float* dec_init = (float*)(Cr + 29360128);      // 65,536
    float* pgen  = (float*)(Cr + 29425664);         // 8,192
    float* copyp = (float*)(Cr + 29433856);         // 8,192
    float* pbuf  = (float*)(Cr + 29442048);         // 131,072
    float* h0g   = (float*)(Cr + 29573120);         // 65,536 (2x[B][D])
    float* h1g   = (float*)(Cr + 29638656);         // 65,536
    float* encg  = (float*)(Cr + 29704192);         // 65,536 (2buf x 2dir x B x H)
    int*   barDec = (int*)(Cr + 29769728);          // 16 KB (128 flag lines + go)
    int*   barEnc0 = (int*)(Cr + 29786112);         // 16 KB (2 dir regions x 4KB)
    int*   barEnc1 = (int*)(Cr + 29802496);         // 16 KB
    // total ≈ 144.90 MB

    hipMemsetAsync(barDec, 0, 49152, stream);       // zero all barrier regions

    auto pack = [&](const float* W, float4* P, int Hn, int K) {
        int total = Hn * K;
        hipLaunchKernelGGL(pack4_kernel, dim3((total + 255) / 256), dim3(256), 0, stream, W, P, Hn, K);
    };
    pack(eWih0f, pWih0f, H, E);
    pack(eWih0b, pWih0b, H, E);
    pack(eWih1f, pWih1f, H, D);
    pack(eWih1b, pWih1b, H, D);
    pack(dWih0, pdWih0, D, E);
    hipLaunchKernelGGL(packencT_k, dim3(4 * H * H / 256), dim3(256), 0, stream, eWhh0f, peW0f);
    hipLaunchKernelGGL(packencT_k, dim3(4 * H * H / 256), dim3(256), 0, stream, eWhh0b, peW0b);
    hipLaunchKernelGGL(packencT_k, dim3(4 * H * H / 256), dim3(256), 0, stream, eWhh1f, peW1f);
    hipLaunchKernelGGL(packencT_k, dim3(4 * H * H / 256), dim3(256), 0, stream, eWhh1b, peW1b);
    hipLaunchKernelGGL(packdec_k, dim3(D * D * 4 / 256), dim3(256), 0, stream, dWhh0, pb0);
    hipLaunchKernelGGL(packdec_k, dim3(D * D * 4 / 256), dim3(256), 0, stream, dWih1, pb1i);
    hipLaunchKernelGGL(packdec_k, dim3(D * D * 4 / 256), dim3(256), 0, stream, dWhh1, pb1h);

    hipLaunchKernelGGL(enc0_gates, dim3(S * B), dim3(H), 0, stream,
                       input_ids, emb, pWih0f, eb0f, pWih0b, eb0b, G0f, G0b);
    hipLaunchKernelGGL(enc_pscan, dim3(NBLK_ENC), dim3(256), 0, stream,
                       G0f, G0b, peW0f, peW0b, h0f, h0b, dec_init, encg, barEnc0);
    hipLaunchKernelGGL(enc1_gates, dim3(S * B), dim3(H), 0, stream,
                       h0f, h0b, pWih1f, eb1f, pWih1b, eb1b, G0f, G0b);
    hipLaunchKernelGGL(enc_pscan, dim3(NBLK_ENC), dim3(256), 0, stream,
                       G0f, G0b, peW1f, peW1b, h1f, h1b, dec_init + B * D, encg, barEnc1);
    hipLaunchKernelGGL(dec0_gates, dim3(T * B), dim3(D), 0, stream,
                       target_ids, emb, pdWih0, db0, Gd0);
    hipLaunchKernelGGL(dec_scan2, dim3(NBLK_DEC), dim3(512), 0, stream,
                       Gd0, pb0, pb1i, pb1h, db1, dec_init, h0g, h1g, h1d, barDec);
    hipLaunchKernelGGL(build_encht, dim3(B * 256), dim3(256), 0, stream, h1f, h1b, ench);
    hipLaunchKernelGGL(qproj, dim3(T * B), dim3(D), 0, stream, h1d, Wenc, Wdec, qe, qd);
    hipLaunchKernelGGL(escore, dim3(B * T), dim3(S), 0, stream, qe, ench, ew);
    hipLaunchKernelGGL(temporal_k, dim3((B * S + 255) / 256), dim3(256), 0, stream, ew);
    hipLaunchKernelGGL(attnctx, dim3(B * T), dim3(S), 0, stream,
                       ew, input_ids, target_ids, h1f, h1b, ectx, copyp);
    hipLaunchKernelGGL(decattn, dim3(B * T), dim3(T), 0, stream, qd, h1d, dctx);
    hipLaunchKernelGGL(concat_k, dim3(B * T), dim3(D), 0, stream,
                       h1d, ectx, dctx, sW, sb, cc, pgen);
    hipLaunchKernelGGL(outprojT_k, dim3(1000), dim3(256), 0, stream, emb, Wvoc, outT2);
    hipLaunchKernelGGL(vocab_mfma, dim3(256), dim3(512), 0, stream,
                       outT2, cc, ob, target_ids, pbuf);
    hipLaunchKernelGGL(combine_nll_k, dim3(B), dim3(T), 0, stream,
                       pbuf, target_ids, pgen, copyp, tlen, out);
}

// Round 9
// 8272.805 us; speedup vs baseline: 2.7814x; 1.2371x over previous
//
#include <hip/hip_runtime.h>
#include <hip/hip_bf16.h>
#include <math.h>

#define PAD_ID 0
#define UNK_ID 1
#define START_ID 2
#define END_ID 3

constexpr int B = 16, S = 512, T = 128, V = 32000, E = 128, H = 256, D = 512;
constexpr int C3 = 1536;        // 3*D
constexpr int VO = 31997;       // V-3
constexpr int JS = 32000;       // padded col count for outT2
constexpr int NBLK_DEC = 128;   // decoder persistent blocks (u-slice = 4)

typedef short short8 __attribute__((ext_vector_type(8)));
typedef float f32x4 __attribute__((ext_vector_type(4)));

__device__ __forceinline__ float sigm(float x) { return 1.0f / (1.0f + __expf(-x)); }
__device__ __forceinline__ short bf16s(float x) {
    __hip_bfloat16 h = __float2bfloat16(x);
    return *reinterpret_cast<short*>(&h);
}
__device__ __forceinline__ float bflo(unsigned int u) { return __uint_as_float(u << 16); }
__device__ __forceinline__ float bfhi(unsigned int u) { return __uint_as_float(u & 0xffff0000u); }

// coherent (sc0 sc1) 16B load — bypasses caches to the coherent point. Caller must
// s_waitcnt vmcnt(0) before consuming.
__device__ __forceinline__ float4 cload4(const float* p) {
    float4 v;
    asm volatile("global_load_dwordx4 %0, %1, off sc0 sc1" : "=v"(v) : "v"(p));
    return v;
}

__device__ __forceinline__ void astore(float* p, float v) {
    __hip_atomic_store(p, v, __ATOMIC_RELAXED, __HIP_MEMORY_SCOPE_AGENT);
}

// ---------------- all-to-all grid barrier (small groups): every block stores its own
// 64B flag line and polls ALL flags. One fabric RTT. Relaxed coherent ops only.
__device__ __forceinline__ void aabar(int* flags, int nblk, int ep, int myidx) {
    asm volatile("s_waitcnt vmcnt(0)" ::: "memory");   // my h-stores globally visible
    __syncthreads();
    int tid = threadIdx.x;
    if (tid == 0)
        __hip_atomic_store(flags + myidx * 16, ep, __ATOMIC_RELAXED, __HIP_MEMORY_SCOPE_AGENT);
    if (tid < 64) {
        for (int i = tid; i < nblk; i += 64)
            while (__hip_atomic_load(flags + i * 16, __ATOMIC_RELAXED, __HIP_MEMORY_SCOPE_AGENT) < ep)
                __builtin_amdgcn_s_sleep(1);
    }
    __syncthreads();
    asm volatile("" ::: "memory");
}

// ---------------- leader-gather barrier (large groups, proven for 128 blocks)
__device__ __forceinline__ void cohbar(int* flags, int nblk, int ep, int myidx, bool leader) {
    asm volatile("s_waitcnt vmcnt(0)" ::: "memory");
    __syncthreads();
    int tid = threadIdx.x;
    int* go = flags + nblk * 16;
    if (leader) {
        if (tid < 64) {
            if (tid == 0)
                __hip_atomic_store(flags + myidx * 16, ep, __ATOMIC_RELAXED, __HIP_MEMORY_SCOPE_AGENT);
            for (int i = tid; i < nblk; i += 64)
                while (__hip_atomic_load(flags + i * 16, __ATOMIC_RELAXED, __HIP_MEMORY_SCOPE_AGENT) < ep)
                    __builtin_amdgcn_s_sleep(1);
        }
        __syncthreads();
        if (tid == 0)
            __hip_atomic_store(go, ep, __ATOMIC_RELAXED, __HIP_MEMORY_SCOPE_AGENT);
    } else {
        if (tid == 0) {
            __hip_atomic_store(flags + myidx * 16, ep, __ATOMIC_RELAXED, __HIP_MEMORY_SCOPE_AGENT);
            while (__hip_atomic_load(go, __ATOMIC_RELAXED, __HIP_MEMORY_SCOPE_AGENT) < ep)
                __builtin_amdgcn_s_sleep(1);
        }
        __syncthreads();
    }
    asm volatile("" ::: "memory");
}

// ---------------- weight packing: W[4H][K] -> P[k][u] = float4 of 4 gates
__global__ void pack4_kernel(const float* __restrict__ W, float4* __restrict__ P, int Hn, int K) {
    int i = blockIdx.x * blockDim.x + threadIdx.x;
    if (i >= K * Hn) return;
    int k = i / Hn, u = i - k * Hn;
    float4 v;
    v.x = W[(size_t)(0 * Hn + u) * K + k];
    v.y = W[(size_t)(1 * Hn + u) * K + k];
    v.z = W[(size_t)(2 * Hn + u) * K + k];
    v.w = W[(size_t)(3 * Hn + u) * K + k];
    P[(size_t)k * Hn + u] = v;
}

// ---------------- encoder Whh pack for MFMA: W[4H][H] -> PM[row][k] bf16,
// row = (u>>3)*32 + g*8 + (u&7)  (wave-fragment order)
__global__ void packencM_k(const float* __restrict__ W, ushort* __restrict__ P) {
    int i = blockIdx.x * blockDim.x + threadIdx.x;
    if (i >= 4 * H * H) return;
    int k = i & 255, row = i >> 8;
    int g = (row >> 3) & 3, ul = row & 7, uh = row >> 5;
    int u = uh * 8 + ul;
    P[i] = (ushort)bf16s(W[(size_t)(g * H + u) * H + k]);
}

// ---------------- decoder weight pack: W[4D][D] -> P[u][g][k] bf16
__global__ void packdec_k(const float* __restrict__ W, ushort* __restrict__ P) {
    int i = blockIdx.x * blockDim.x + threadIdx.x;
    if (i >= D * D * 4) return;
    int k = i & 511, g = (i >> 9) & 3, u = i >> 11;
    P[i] = (ushort)bf16s(W[(size_t)(g * D + u) * D + k]);
}

// ---------------- encoder layer-0 gate preactivations for both directions
__global__ void enc0_gates(const int* __restrict__ ids, const float* __restrict__ emb,
                           const float4* __restrict__ Pf, const float* __restrict__ bf_,
                           const float4* __restrict__ Pb, const float* __restrict__ bb_,
                           float* __restrict__ Gf, float* __restrict__ Gb) {
    int n = blockIdx.x;
    int s = n / B, b = n - s * B;
    int u = threadIdx.x;
    __shared__ float xr[E];
    int tok = ids[b * S + s];
    if (tok >= V) tok = UNK_ID;
    if (u < E) xr[u] = emb[(size_t)tok * E + u];
    __syncthreads();
    float a0 = bf_[0 * H + u], a1 = bf_[1 * H + u], a2 = bf_[2 * H + u], a3 = bf_[3 * H + u];
#pragma unroll 4
    for (int k = 0; k < E; k++) {
        float xv = xr[k]; float4 w = Pf[k * H + u];
        a0 += xv * w.x; a1 += xv * w.y; a2 += xv * w.z; a3 += xv * w.w;
    }
    float* g = Gf + (size_t)n * 4 * H;
    g[0 * H + u] = a0; g[1 * H + u] = a1; g[2 * H + u] = a2; g[3 * H + u] = a3;
    a0 = bb_[0 * H + u]; a1 = bb_[1 * H + u]; a2 = bb_[2 * H + u]; a3 = bb_[3 * H + u];
#pragma unroll 4
    for (int k = 0; k < E; k++) {
        float xv = xr[k]; float4 w = Pb[k * H + u];
        a0 += xv * w.x; a1 += xv * w.y; a2 += xv * w.z; a3 += xv * w.w;
    }
    g = Gb + (size_t)n * 4 * H;
    g[0 * H + u] = a0; g[1 * H + u] = a1; g[2 * H + u] = a2; g[3 * H + u] = a3;
}

// ---------------- encoder layer-1 gate preactivations (input = concat(h0f,h0b))
__global__ void enc1_gates(const float* __restrict__ h0f, const float* __restrict__ h0b,
                           const float4* __restrict__ Pf, const float* __restrict__ bf_,
                           const float4* __restrict__ Pb, const float* __restrict__ bb_,
                           float* __restrict__ Gf, float* __restrict__ Gb) {
    int n = blockIdx.x;      // s*B+b
    int u = threadIdx.x;     // 256
    __shared__ float xr[D];
    xr[u] = h0f[(size_t)n * H + u];
    xr[H + u] = h0b[(size_t)n * H + u];
    __syncthreads();
    float a0 = bf_[0 * H + u], a1 = bf_[1 * H + u], a2 = bf_[2 * H + u], a3 = bf_[3 * H + u];
#pragma unroll 4
    for (int k = 0; k < D; k++) {
        float xv = xr[k]; float4 w = Pf[k * H + u];
        a0 += xv * w.x; a1 += xv * w.y; a2 += xv * w.z; a3 += xv * w.w;
    }
    float* g = Gf + (size_t)n * 4 * H;
    g[0 * H + u] = a0; g[1 * H + u] = a1; g[2 * H + u] = a2; g[3 * H + u] = a3;
    a0 = bb_[0 * H + u]; a1 = bb_[1 * H + u]; a2 = bb_[2 * H + u]; a3 = bb_[3 * H + u];
#pragma unroll 4
    for (int k = 0; k < D; k++) {
        float xv = xr[k]; float4 w = Pb[k * H + u];
        a0 += xv * w.x; a1 += xv * w.y; a2 += xv * w.z; a3 += xv * w.w;
    }
    g = Gb + (size_t)n * 4 * H;
    g[0 * H + u] = a0; g[1 * H + u] = a1; g[2 * H + u] = a2; g[3 * H + u] = a3;
}

// ---------------- MFMA encoder persistent scan, one layer, both dirs.
// grid 16 = dir*8 + bk. 256 threads = 4 waves; wave w owns 32 weight rows
// (u = bk*32 + w*8 + ul, 4 gates) as A-fragments IN REGISTERS for all 512 steps.
// h staged per step as bf16 [b][264] LDS feeding MFMA B-fragments.
__global__ void __launch_bounds__(256) enc_pscan2(
        const float* __restrict__ Gf, const float* __restrict__ Gb,
        const ushort* __restrict__ PMf, const ushort* __restrict__ PMb,
        float* __restrict__ hof, float* __restrict__ hob,
        float* __restrict__ hfin /* [B][2H] */,
        float* __restrict__ hg /* [2buf][2dir][B][H] f32 */, int* __restrict__ barbase) {
    __shared__ __align__(16) ushort hh[16 * 264];   // [b][264] bf16
    __shared__ float gs[4][32][17];                 // [wave][row=g*8+ul][b]
    int blk = blockIdx.x;
    int dirb = blk >> 3, bk = blk & 7;
    int* bar = barbase + dirb * 1024;
    const float* G = dirb ? Gb : Gf;
    const ushort* PM = dirb ? PMb : PMf;
    float* ho = dirb ? hob : hof;
    int tid = threadIdx.x;
    int lane = tid & 63, w = tid >> 6;
    int cl = lane & 15, hi = lane >> 4;

    // ---- load weight A-fragments into registers (once)
    short8 afr[2][8];
    {
        int rowbase = (bk * 4 + w) * 32;
#pragma unroll
        for (int mt = 0; mt < 2; mt++)
#pragma unroll
            for (int kt = 0; kt < 8; kt++)
                afr[mt][kt] = *(const short8*)(PM + (size_t)(rowbase + mt * 16 + cl) * 256 + kt * 32 + hi * 8);
    }
    // assembly mapping: thread -> cells (ub, bb) and (ub, bb+8)
    int ub = tid & 31, bb = tid >> 5;
    int u_glob = bk * 32 + ub;
    int gsw = ub >> 3, ul = ub & 7;
    float c_a = 0.f, c_b = 0.f;
    astore(&hg[dirb * (B * H) + bb * H + u_glob], 0.f);
    astore(&hg[dirb * (B * H) + (bb + 8) * H + u_glob], 0.f);
    int ep = 1;
    aabar(bar, 8, ep, bk);

    for (int step = 0; step < S; step++) {
        int s = dirb ? (S - 1 - step) : step;
        int cur = step & 1;
        // G-bias prefetch (cached; latency overlaps the coherent staging wait)
        const float* gA = G + ((size_t)(s * B + bb)) * 1024 + u_glob;
        const float* gB = G + ((size_t)(s * B + bb + 8)) * 1024 + u_glob;
        float pa0 = gA[0], pa1 = gA[256], pa2 = gA[512], pa3 = gA[768];
        float pb0 = gB[0], pb1 = gB[256], pb2 = gB[512], pb3 = gB[768];
        // ---- stage h (coherent f32) -> bf16 LDS [b][264]
        {
            int sb = tid >> 4, kseg = tid & 15;
            const float* src = hg + cur * (2 * B * H) + dirb * (B * H) + sb * H + kseg * 16;
            float4 v0 = cload4(src), v1 = cload4(src + 4), v2 = cload4(src + 8), v3 = cload4(src + 12);
            asm volatile("s_waitcnt vmcnt(0)" ::: "memory");
            __builtin_amdgcn_sched_barrier(0);
            short8 o0, o1;
            o0[0] = bf16s(v0.x); o0[1] = bf16s(v0.y); o0[2] = bf16s(v0.z); o0[3] = bf16s(v0.w);
            o0[4] = bf16s(v1.x); o0[5] = bf16s(v1.y); o0[6] = bf16s(v1.z); o0[7] = bf16s(v1.w);
            o1[0] = bf16s(v2.x); o1[1] = bf16s(v2.y); o1[2] = bf16s(v2.z); o1[3] = bf16s(v2.w);
            o1[4] = bf16s(v3.x); o1[5] = bf16s(v3.y); o1[6] = bf16s(v3.z); o1[7] = bf16s(v3.w);
            *(short8*)(hh + sb * 264 + kseg * 16) = o0;
            *(short8*)(hh + sb * 264 + kseg * 16 + 8) = o1;
        }
        __syncthreads();
        // ---- MFMA: gates(32 rows x 16 b) = W(32x256) . h(256x16)
        {
            f32x4 acc0 = {0.f, 0.f, 0.f, 0.f}, acc1 = {0.f, 0.f, 0.f, 0.f};
            const ushort* hp = hh + cl * 264 + hi * 8;
#pragma unroll
            for (int kt = 0; kt < 8; kt++) {
                short8 bfr = *(const short8*)(hp + kt * 32);
                acc0 = __builtin_amdgcn_mfma_f32_16x16x32_bf16(afr[0][kt], bfr, acc0, 0, 0, 0);
                acc1 = __builtin_amdgcn_mfma_f32_16x16x32_bf16(afr[1][kt], bfr, acc1, 0, 0, 0);
            }
#pragma unroll
            for (int i = 0; i < 4; i++) {
                gs[w][hi * 4 + i][cl] = acc0[i];
                gs[w][16 + hi * 4 + i][cl] = acc1[i];
            }
        }
        __syncthreads();
        // ---- assembly: LSTM cell math for 2 cells per thread
        {
            float q0 = gs[gsw][0 + ul][bb];
            float q1 = gs[gsw][8 + ul][bb];
            float q2 = gs[gsw][16 + ul][bb];
            float q3 = gs[gsw][24 + ul][bb];
            float ig = sigm(pa0 + q0), fg = sigm(pa1 + q1), gt = tanhf(pa2 + q2), og = sigm(pa3 + q3);
            c_a = fg * c_a + ig * gt;
            float hA = og * tanhf(c_a);
            q0 = gs[gsw][0 + ul][bb + 8];
            q1 = gs[gsw][8 + ul][bb + 8];
            q2 = gs[gsw][16 + ul][bb + 8];
            q3 = gs[gsw][24 + ul][bb + 8];
            ig = sigm(pb0 + q0); fg = sigm(pb1 + q1); gt = tanhf(pb2 + q2); og = sigm(pb3 + q3);
            c_b = fg * c_b + ig * gt;
            float hB = og * tanhf(c_b);
            float* dst = hg + (cur ^ 1) * (2 * B * H) + dirb * (B * H);
            astore(&dst[bb * H + u_glob], hA);
            astore(&dst[(bb + 8) * H + u_glob], hB);
            ho[((size_t)(s * B + bb)) * H + u_glob] = hA;
            ho[((size_t)(s * B + bb + 8)) * H + u_glob] = hB;
            if (step == S - 1) {
                hfin[bb * (2 * H) + dirb * H + u_glob] = hA;
                hfin[(bb + 8) * (2 * H) + dirb * H + u_glob] = hB;
            }
        }
        aabar(bar, 8, ++ep, bk);
    }
}

// ---------------- decoder layer-0 input gates (teacher tokens). grid T*B (n=t*B+b), 512 thr.
__global__ void dec0_gates(const int* __restrict__ tgt, const float* __restrict__ emb,
                           const float4* __restrict__ P, const float* __restrict__ bias,
                           float* __restrict__ G) {
    int n = blockIdx.x;
    int t = n / B, b = n - t * B;
    int u = threadIdx.x;
    __shared__ float xr[E];
    int tok;
    if (t == 0) tok = START_ID;
    else { tok = tgt[b * T + (t - 1)]; if (tok >= V) tok = UNK_ID; }
    if (u < E) xr[u] = emb[(size_t)tok * E + u];
    __syncthreads();
    float a0 = bias[0 * D + u], a1 = bias[1 * D + u], a2 = bias[2 * D + u], a3 = bias[3 * D + u];
#pragma unroll 4
    for (int k = 0; k < E; k++) {
        float xv = xr[k]; float4 w = P[k * D + u];
        a0 += xv * w.x; a1 += xv * w.y; a2 += xv * w.z; a3 += xv * w.w;
    }
    float* g = G + (size_t)n * 4 * D;
    g[0 * D + u] = a0; g[1 * D + u] = a1; g[2 * D + u] = a2; g[3 * D + u] = a3;
}

// ---------------- decoder persistent 2-layer scan (R8 version, passing).
__global__ void __launch_bounds__(512) dec_scan2(
        const float* __restrict__ G0, const ushort* __restrict__ pb0,
        const ushort* __restrict__ pb1i, const ushort* __restrict__ pb1h,
        const float* __restrict__ b1, const float* __restrict__ hinit,
        float* __restrict__ h0g /* [2][B][D] */, float* __restrict__ h1g /* [2][B][D] */,
        float* __restrict__ h1out, int* __restrict__ bar) {
    __shared__ __align__(16) ushort W0s[16 * 528];
    __shared__ __align__(16) ushort W1is[16 * 528];
    __shared__ __align__(16) ushort W1hs[16 * 528];
    __shared__ __align__(16) float bufA[16 * 516];
    __shared__ __align__(16) float bufB[16 * 516];
    __shared__ float red[4][4][2][16];
    int tid = threadIdx.x;
    int u0 = blockIdx.x * 4;
    int u_loc = tid >> 7, g = (tid >> 5) & 3, kq = (tid >> 4) & 1, b = tid & 15;

    {
        const uint4* s0 = (const uint4*)(pb0 + (size_t)u0 * 2048);
        const uint4* s1 = (const uint4*)(pb1i + (size_t)u0 * 2048);
        const uint4* s2 = (const uint4*)(pb1h + (size_t)u0 * 2048);
        uint4* d0 = (uint4*)W0s; uint4* d1 = (uint4*)W1is; uint4* d2 = (uint4*)W1hs;
        for (int i = tid; i < 1024; i += 512) {
            int r = i >> 6, c = i & 63;
            d0[r * 66 + c] = s0[i]; d1[r * 66 + c] = s1[i]; d2[r * 66 + c] = s2[i];
        }
    }
    for (int i = tid; i < B * D; i += 512) {
        int bb = i >> 9, kk = i & 511;
        bufA[bb * 516 + kk] = hinit[i];
    }
    if (tid < 64) {
        int ul = tid >> 4, bb = tid & 15;
        astore(&h1g[B * D + bb * 512 + u0 + ul], hinit[B * D + bb * 512 + u0 + ul]);
    }
    float c0v = 0.f, c1v = 0.f;
    int ep = 1;
    cohbar(bar, NBLK_DEC, ep, blockIdx.x, blockIdx.x == 0);

    for (int t = 0; t < T; t++) {
        int cur = t & 1;
        {
            const uint2* w = (const uint2*)(W0s + (u_loc * 4 + g) * 528) + kq * 64;
            const float* hp = bufA + b * 516 + kq * 256;
            float acc = 0.f;
#pragma unroll 4
            for (int i = 0; i < 64; i++) {
                uint2 wv = w[i];
                float4 hv = *(const float4*)(hp + i * 4);
                acc += bflo(wv.x) * hv.x + bfhi(wv.x) * hv.y + bflo(wv.y) * hv.z + bfhi(wv.y) * hv.w;
            }
            red[u_loc][g][kq][b] = acc;
        }
        __syncthreads();
        if (tid < 64) {
            int ul = tid >> 4, bb = tid & 15;
            const float* gg = G0 + ((size_t)(t * B + bb)) * 2048 + (u0 + ul);
            float g0 = gg[0]    + red[ul][0][0][bb] + red[ul][0][1][bb];
            float g1 = gg[512]  + red[ul][1][0][bb] + red[ul][1][1][bb];
            float g2 = gg[1024] + red[ul][2][0][bb] + red[ul][2][1][bb];
            float g3 = gg[1536] + red[ul][3][0][bb] + red[ul][3][1][bb];
            float ig = sigm(g0), fg = sigm(g1), gt = tanhf(g2), og = sigm(g3);
            c0v = fg * c0v + ig * gt;
            astore(&h0g[cur * (B * D) + bb * 512 + u0 + ul], og * tanhf(c0v));
        }
        cohbar(bar, NBLK_DEC, ++ep, blockIdx.x, blockIdx.x == 0);
        {
            float4 s0[4], s1[4];
            const float* p0 = h0g + cur * (B * D);
            const float* p1 = h1g + (cur ^ 1) * (B * D);
#pragma unroll
            for (int r = 0; r < 4; r++) {
                s0[r] = cload4(p0 + r * 2048 + tid * 4);
                s1[r] = cload4(p1 + r * 2048 + tid * 4);
            }
            asm volatile("s_waitcnt vmcnt(0)" ::: "memory");
            __builtin_amdgcn_sched_barrier(0);
#pragma unroll
            for (int r = 0; r < 4; r++) {
                int flat = r * 2048 + tid * 4;
                int bb = flat >> 9, kk = flat & 511;
                *(float4*)(bufA + bb * 516 + kk) = s0[r];
                *(float4*)(bufB + bb * 516 + kk) = s1[r];
            }
        }
        __syncthreads();
        {
            const uint2* wA = (const uint2*)(W1is + (u_loc * 4 + g) * 528) + kq * 64;
            const uint2* wB = (const uint2*)(W1hs + (u_loc * 4 + g) * 528) + kq * 64;
            const float* hA = bufA + b * 516 + kq * 256;
            const float* hB = bufB + b * 516 + kq * 256;
            float acc = 0.f;
#pragma unroll 4
            for (int i = 0; i < 64; i++) {
                uint2 wv = wA[i];
                float4 hv = *(const float4*)(hA + i * 4);
                acc += bflo(wv.x) * hv.x + bfhi(wv.x) * hv.y + bflo(wv.y) * hv.z + bfhi(wv.y) * hv.w;
                uint2 wv2 = wB[i];
                float4 hv2 = *(const float4*)(hB + i * 4);
                acc += bflo(wv2.x) * hv2.x + bfhi(wv2.x) * hv2.y + bflo(wv2.y) * hv2.z + bfhi(wv2.y) * hv2.w;
            }
            red[u_loc][g][kq][b] = acc;
        }
        __syncthreads();
        if (tid < 64) {
            int ul = tid >> 4, bb = tid & 15;
            int uu = u0 + ul;
            float g0 = b1[uu]        + red[ul][0][0][bb] + red[ul][0][1][bb];
            float g1 = b1[512 + uu]  + red[ul][1][0][bb] + red[ul][1][1][bb];
            float g2 = b1[1024 + uu] + red[ul][2][0][bb] + red[ul][2][1][bb];
            float g3 = b1[1536 + uu] + red[ul][3][0][bb] + red[ul][3][1][bb];
            float ig = sigm(g0), fg = sigm(g1), gt = tanhf(g2), og = sigm(g3);
            c1v = fg * c1v + ig * gt;
            float h1n_v = og * tanhf(c1v);
            astore(&h1g[cur * (B * D) + bb * 512 + uu], h1n_v);
            h1out[((size_t)(t * B + bb)) * 512 + uu] = h1n_v;
        }
        __syncthreads();
    }
}

// ---------------- transpose enc hidden to [b][k(512)][s] for coalesced score dots
__global__ void build_encht(const float* __restrict__ h1f, const float* __restrict__ h1b,
                            float* __restrict__ et) {
    int blk = blockIdx.x;                 // b*256 + kt*16 + st
    int b = blk >> 8, rem = blk & 255;
    int kt = rem >> 4, st = rem & 15;
    int c = threadIdx.x & 31, r = threadIdx.x >> 5;   // r in 0..7
    __shared__ float tile[32][33];
#pragma unroll
    for (int i = 0; i < 4; i++) {
        int sl = r + i * 8;               // s_local
        int s = st * 32 + sl;
        int k = kt * 32 + c;              // lane-contiguous over k
        float v = (k < H) ? h1f[((size_t)(s * B + b)) * H + k]
                          : h1b[((size_t)(s * B + b)) * H + (k - H)];
        tile[c][sl] = v;                  // tile[k_local][s_local]
    }
    __syncthreads();
#pragma unroll
    for (int i = 0; i < 4; i++) {
        int kl = r + i * 8;
        et[(size_t)b * D * S + (size_t)(kt * 32 + kl) * S + st * 32 + c] = tile[kl][c];
    }
}

// ---------------- q projections. grid T*B (n=t*B+b), 512 threads
__global__ void qproj(const float* __restrict__ h1d, const float* __restrict__ Wenc,
                      const float* __restrict__ Wdec, float* __restrict__ qe, float* __restrict__ qd) {
    int n = blockIdx.x;
    int o = threadIdx.x;
    __shared__ float hr[D];
    hr[o] = h1d[(size_t)n * D + o];
    __syncthreads();
    float ae = 0.f, ad = 0.f;
#pragma unroll 4
    for (int k = 0; k < D; k++) {
        float hk = hr[k];
        ae += hk * Wenc[k * D + o];
        ad += hk * Wdec[k * D + o];
    }
    qe[(size_t)n * D + o] = ae;
    qd[(size_t)n * D + o] = ad;
}

// ---------------- e = exp(min(score,30)). grid B*T (bt=b*T+t), 512 threads (s)
__global__ void escore(const float* __restrict__ qe, const float* __restrict__ et,
                       float* __restrict__ ew) {
    int bt = blockIdx.x;
    int b = bt / T, t = bt - b * T;
    int sx = threadIdx.x;
    __shared__ float q[D];
    q[sx] = qe[((size_t)(t * B + b)) * D + sx];
    __syncthreads();
    float acc = 0.f;
    const float* eb = et + (size_t)b * D * S + sx;
#pragma unroll 4
    for (int k = 0; k < D; k++) { acc += q[k] * eb[0]; eb += S; }
    acc = fminf(acc, 30.0f);
    ew[(size_t)bt * S + sx] = __expf(acc);
}

// ---------------- temporal normalization (prefix over t, in place)
__global__ void temporal_k(float* __restrict__ ew) {
    int i = blockIdx.x * blockDim.x + threadIdx.x;
    if (i >= B * S) return;
    int b = i / S, sx = i - b * S;
    float cum = 0.f;
    for (int t = 0; t < T; t++) {
        size_t idx = ((size_t)(b * T + t)) * S + sx;
        float v = ew[idx];
        ew[idx] = v / (t == 0 ? 1.0f : (cum + 1e-8f));
        cum += v;
    }
}

// ---------------- attention softmax over s + enc context + copy prob. grid B*T, 512 thr
__global__ void attnctx(const float* __restrict__ ew, const int* __restrict__ ids,
                        const int* __restrict__ tgt,
                        const float* __restrict__ h1f, const float* __restrict__ h1b,
                        float* __restrict__ ectx, float* __restrict__ copyp) {
    int bt = blockIdx.x;
    int b = bt / T, t = bt - b * T;
    int tid = threadIdx.x;
    __shared__ float aw[S];
    __shared__ float red[512];
    float v = ew[(size_t)bt * S + tid];
    int tok = ids[b * S + tid];
    bool pad = (tok == PAD_ID);
    float vm = pad ? -INFINITY : v;
    red[tid] = vm; __syncthreads();
    for (int w = 256; w > 0; w >>= 1) { if (tid < w) red[tid] = fmaxf(red[tid], red[tid + w]); __syncthreads(); }
    float m = red[0]; __syncthreads();
    float ex = pad ? 0.f : __expf(vm - m);
    red[tid] = ex; __syncthreads();
    for (int w = 256; w > 0; w >>= 1) { if (tid < w) red[tid] += red[tid + w]; __syncthreads(); }
    float Z = red[0]; __syncthreads();
    float a = ex / Z;
    aw[tid] = a;
    int nt = tgt[b * T + t];
    red[tid] = (tok == nt) ? a : 0.f; __syncthreads();
    for (int w = 256; w > 0; w >>= 1) { if (tid < w) red[tid] += red[tid + w]; __syncthreads(); }
    if (tid == 0) copyp[bt] = red[0];
    __syncthreads();
    int d = tid;
    const float* hp = (d < H) ? (h1f + (size_t)b * H + d) : (h1b + (size_t)b * H + (d - H));
    float acc = 0.f;
#pragma unroll 4
    for (int s2 = 0; s2 < S; s2++) { acc += aw[s2] * hp[0]; hp += B * H; }
    ectx[(size_t)bt * D + d] = acc;
}

// ---------------- intra-decoder attention. grid B*T, 128 threads
__global__ void decattn(const float* __restrict__ qd, const float* __restrict__ h1d,
                        float* __restrict__ dctx) {
    int bt = blockIdx.x;
    int b = bt / T, t = bt - b * T;
    int tid = threadIdx.x;
    __shared__ float q[D];
    __shared__ float wl[T];
    __shared__ float red[128];
    for (int i = tid; i < D; i += 128) q[i] = qd[((size_t)(t * B + b)) * D + i];
    __syncthreads();
    float sc = -INFINITY;
    if (tid < t) {
        const float* hu = h1d + ((size_t)(tid * B + b)) * D;
        float a = 0.f;
#pragma unroll 4
        for (int k = 0; k < D; k++) a += q[k] * hu[k];
        sc = a;
    }
    red[tid] = sc; __syncthreads();
    for (int w = 64; w > 0; w >>= 1) { if (tid < w) red[tid] = fmaxf(red[tid], red[tid + w]); __syncthreads(); }
    float m = red[0]; __syncthreads();
    float ex = (tid < t) ? __expf(sc - m) : 0.f;
    red[tid] = ex; __syncthreads();
    for (int w = 64; w > 0; w >>= 1) { if (tid < w) red[tid] += red[tid + w]; __syncthreads(); }
    float Z = red[0]; __syncthreads();
    wl[tid] = (t > 0) ? (ex / Z) : 0.f;
    __syncthreads();
    for (int d = tid; d < D; d += 128) {
        float acc = 0.f;
        for (int u = 0; u < t; u++) acc += wl[u] * h1d[((size_t)(u * B + b)) * D + d];
        dctx[(size_t)bt * D + d] = acc;
    }
}

// ---------------- concat + p_gen. grid B*T, 512 threads
__global__ void concat_k(const float* __restrict__ h1d, const float* __restrict__ ectx,
                         const float* __restrict__ dctx, const float* __restrict__ sW,
                         const float* __restrict__ sb, float* __restrict__ cc,
                         float* __restrict__ pgen) {
    int bt = blockIdx.x;
    int b = bt / T, t = bt - b * T;
    int d = threadIdx.x;
    __shared__ float red[512];
    float v0 = h1d[((size_t)(t * B + b)) * D + d];
    float v1 = ectx[(size_t)bt * D + d];
    float v2 = dctx[(size_t)bt * D + d];
    float* c = cc + (size_t)bt * C3;
    c[d] = v0; c[D + d] = v1; c[2 * D + d] = v2;
    red[d] = v0 * sW[d] + v1 * sW[D + d] + v2 * sW[2 * D + d];
    __syncthreads();
    for (int w = 256; w > 0; w >>= 1) { if (d < w) red[d] += red[d + w]; __syncthreads(); }
    if (d == 0) pgen[bt] = 1.f / (1.f + __expf(-(red[0] + sb[0])));
}

// ---------------- out_proj, packed-k layout for MFMA B-fragments.
__global__ void outprojT_k(const float* __restrict__ emb, const float* __restrict__ Wvoc,
                           __hip_bfloat16* __restrict__ outT2) {
    int j0 = blockIdx.x * 32;
    int jl = threadIdx.x & 31, oq = threadIdx.x >> 5;   // oq in 0..7
    __shared__ float er[32][E + 1];                      // +1 pad
    for (int i = threadIdx.x; i < 32 * E; i += 256) {
        int jj = i >> 7, e = i & 127;
        int j = j0 + jj;
        er[jj][e] = (j < VO) ? emb[(size_t)(3 + j) * E + e] : 0.f;
    }
    __syncthreads();
    int j = j0 + jl;
#pragma unroll 1
    for (int i = 0; i < 24; i++) {
        int o = oq * 24 + i;                             // octet index 0..191
        int k0 = o * 8;
        float acc[8];
#pragma unroll
        for (int kk = 0; kk < 8; kk++) acc[kk] = 0.f;
#pragma unroll 4
        for (int e = 0; e < E; e++) {
            float x = er[jl][e];
            float4 w0 = *(const float4*)(Wvoc + (size_t)e * C3 + k0);
            float4 w1 = *(const float4*)(Wvoc + (size_t)e * C3 + k0 + 4);
            acc[0] += x * w0.x; acc[1] += x * w0.y; acc[2] += x * w0.z; acc[3] += x * w0.w;
            acc[4] += x * w1.x; acc[5] += x * w1.y; acc[6] += x * w1.z; acc[7] += x * w1.w;
        }
        short8 v;
#pragma unroll
        for (int kk = 0; kk < 8; kk++) v[kk] = bf16s(tanhf(acc[kk]));
        *reinterpret_cast<short8*>((char*)outT2 + ((size_t)o * JS + j) * 16) = v;
    }
}

// ---------------- vocab GEMM via MFMA + fused online softmax partials.
__global__ void __launch_bounds__(512) vocab_mfma(
        const __hip_bfloat16* __restrict__ outT2, const float* __restrict__ cc,
        const float* __restrict__ ob, const int* __restrict__ tgt,
        float* __restrict__ pbuf) {
    __shared__ __align__(16) short As[32 * 1536];        // bf16 A tile, chunk-XOR swizzled
    __shared__ float wm[8][32], ws_[8][32], wg[8][32];
    __shared__ int jstar_s[32];
    int bid = blockIdx.x;
    int rb = bid & 63, q = bid >> 6;
    int row0 = rb * 32;
    int tid = threadIdx.x;

    {
        int r = tid >> 4, cpos = tid & 15;
        const float* src = cc + (size_t)(row0 + r) * C3;
        int r7 = r & 7;
        short* dst = As + r * C3;
#pragma unroll
        for (int ii = 0; ii < 12; ii++) {
            int c = ii * 16 + cpos;                      // chunk 0..191 (8 bf16 each)
            float4 f0 = *(const float4*)(src + c * 8);
            float4 f1 = *(const float4*)(src + c * 8 + 4);
            short8 v;
            v[0] = bf16s(f0.x); v[1] = bf16s(f0.y); v[2] = bf16s(f0.z); v[3] = bf16s(f0.w);
            v[4] = bf16s(f1.x); v[5] = bf16s(f1.y); v[6] = bf16s(f1.z); v[7] = bf16s(f1.w);
            *reinterpret_cast<short8*>(dst + ((c ^ r7) << 3)) = v;
        }
    }
    if (tid < 32) {
        int nt = tgt[row0 + tid];
        int ix = nt - 3;
        ix = ix < 0 ? 0 : (ix > VO - 1 ? VO - 1 : ix);
        jstar_s[tid] = ix;
    }
    __syncthreads();

    int lane = tid & 63, wid = tid >> 6;
    int wr = wid >> 2, wc = wid & 3;
    int cl = lane & 15, g = lane >> 4;
    int rowA = wr * 16 + cl;
    const short* Abase = As + rowA * C3;
    int r7 = rowA & 7;
    int jst[4];
    float m[4], sacc[4], gl[4];
#pragma unroll
    for (int i = 0; i < 4; i++) {
        jst[i] = jstar_s[wr * 16 + g * 4 + i];
        m[i] = -1e30f; sacc[i] = 0.f; gl[i] = -1e30f;
    }

    int jb0 = q * 8192;
    int jqend = (jb0 + 8192 < VO) ? jb0 + 8192 : VO;
    int nmt = (jqend - jb0 + 127) >> 7;
    for (int ti = 0; ti < nmt; ti++) {
        int jA = jb0 + ti * 128 + wc * 32 + cl;
        const char* pB = (const char*)outT2 + ((size_t)g * JS + jA) * 16;
        f32x4 acc0 = {0.f, 0.f, 0.f, 0.f}, acc1 = {0.f, 0.f, 0.f, 0.f};
#pragma unroll
        for (int s = 0; s < 48; s++) {
            short8 a = *reinterpret_cast<const short8*>(Abase + (((s * 4 + g) ^ r7) << 3));
            short8 b0 = *reinterpret_cast<const short8*>(pB + (size_t)s * (4 * JS * 16));
            short8 b1 = *reinterpret_cast<const short8*>(pB + (size_t)s * (4 * JS * 16) + 256);
            acc0 = __builtin_amdgcn_mfma_f32_16x16x32_bf16(a, b0, acc0, 0, 0, 0);
            acc1 = __builtin_amdgcn_mfma_f32_16x16x32_bf16(a, b1, acc1, 0, 0, 0);
        }
#pragma unroll
        for (int X = 0; X < 2; X++) {
            int j = jA + X * 16;
            if (j < jqend) {
                float obj = ob[j];
#pragma unroll
                for (int i = 0; i < 4; i++) {
                    float L = (X ? acc1[i] : acc0[i]) + obj;
                    if (j == jst[i]) gl[i] = L;
                    float mn = fmaxf(m[i], L);
                    sacc[i] = sacc[i] * __expf(m[i] - mn) + __expf(L - mn);
                    m[i] = mn;
                }
            }
        }
    }

#pragma unroll
    for (int i = 0; i < 4; i++) {
        for (int mask = 1; mask < 16; mask <<= 1) {
            float om = __shfl_xor(m[i], mask);
            float os = __shfl_xor(sacc[i], mask);
            float mn = fmaxf(m[i], om);
            sacc[i] = sacc[i] * __expf(m[i] - mn) + os * __expf(om - mn);
            m[i] = mn;
            gl[i] = fmaxf(gl[i], __shfl_xor(gl[i], mask));
        }
    }
    if (cl == 0) {
#pragma unroll
        for (int i = 0; i < 4; i++) {
            int rl = wr * 16 + g * 4 + i;
            wm[wid][rl] = m[i]; ws_[wid][rl] = sacc[i]; wg[wid][rl] = gl[i];
        }
    }
    __syncthreads();
    if (tid < 32) {
        float M = -1e30f, SS = 0.f, GL = -1e30f;
        int w0 = (tid >> 4) * 4;
#pragma unroll
        for (int w = 0; w < 4; w++) {
            float mq = wm[w0 + w][tid], sq = ws_[w0 + w][tid], gq = wg[w0 + w][tid];
            float mn = fmaxf(M, mq);
            SS = SS * __expf(M - mn) + sq * __expf(mq - mn);
            M = mn;
            GL = fmaxf(GL, gq);
        }
        float* o = pbuf + ((size_t)bid * 32 + tid) * 4;
        o[0] = M; o[1] = SS; o[2] = GL;
    }
}

// ---------------- combine quarter-partials + pointer mix + NLL. grid B, 128 threads.
__global__ void combine_nll_k(const float* __restrict__ pbuf, const int* __restrict__ tgt,
                              const float* __restrict__ pgen, const float* __restrict__ copyp,
                              const int* __restrict__ tlen, float* __restrict__ out) {
    int b = blockIdx.x, t = threadIdx.x;
    int row = b * T + t;
    int rb = row >> 5, r = row & 31;
    float M = -1e30f, SS = 0.f, GL = -1e30f;
#pragma unroll
    for (int q = 0; q < 4; q++) {
        const float* p = pbuf + ((size_t)(q * 64 + rb) * 32 + r) * 4;
        float mq = p[0], sq = p[1], gq = p[2];
        float mn = fmaxf(M, mq);
        SS = SS * __expf(M - mn) + sq * __expf(mq - mn);
        M = mn;
        GL = fmaxf(GL, gq);
    }
    int nt = tgt[row];
    float genp = (nt >= 3 && nt < V) ? __expf(GL - M) / SS : 0.f;
    float pg = pgen[row];
    float p = pg * genp + (1.f - pg) * copyp[row];
    __shared__ float red[128];
    red[t] = (t < tlen[b]) ? -logf(p + 1e-9f) : 0.f;
    __syncthreads();
    for (int w = 64; w > 0; w >>= 1) { if (t < w) red[t] += red[t + w]; __syncthreads(); }
    if (t == 0) out[b] = red[0];
}

extern "C" void kernel_launch(void* const* d_in, const int* in_sizes, int n_in,
                              void* d_out, int out_size, void* d_ws, size_t ws_size,
                              hipStream_t stream) {
    const int* input_ids = (const int*)d_in[0];
    const int* target_ids = (const int*)d_in[1];
    const int* tlen = (const int*)d_in[3];
    const float* emb = (const float*)d_in[5];
    const float* eWih0f = (const float*)d_in[6],  *eWhh0f = (const float*)d_in[7],  *eb0f = (const float*)d_in[8];
    const float* eWih0b = (const float*)d_in[9],  *eWhh0b = (const float*)d_in[10], *eb0b = (const float*)d_in[11];
    const float* eWih1f = (const float*)d_in[12], *eWhh1f = (const float*)d_in[13], *eb1f = (const float*)d_in[14];
    const float* eWih1b = (const float*)d_in[15], *eWhh1b = (const float*)d_in[16], *eb1b = (const float*)d_in[17];
    const float* dWih0 = (const float*)d_in[18], *dWhh0 = (const float*)d_in[19], *db0 = (const float*)d_in[20];
    const float* dWih1 = (const float*)d_in[21], *dWhh1 = (const float*)d_in[22], *db1 = (const float*)d_in[23];
    const float* Wenc = (const float*)d_in[24], *Wdec = (const float*)d_in[25];
    const float* Wvoc = (const float*)d_in[26], *sW = (const float*)d_in[27], *sb = (const float*)d_in[28];
    const float* ob = (const float*)d_in[29];
    float* out = (float*)d_out;
    (void)ws_size; (void)n_in; (void)in_sizes; (void)out_size;

    // ============ workspace layout (~145 MB, phase-aliased) ============
    char* A = (char*)d_ws;
    float4* pWih0f = (float4*)(A + 0);              //  512 KB f32 gate-packed
    float4* pWih0b = (float4*)(A + 524288);
    float4* pWih1f = (float4*)(A + 1048576);        //  2 MB
    float4* pWih1b = (float4*)(A + 3145728);
    float4* pdWih0 = (float4*)(A + 5242880);        //  1 MB
    ushort* PMf0  = (ushort*)(A + 6291456);         //  512 KB bf16 MFMA-row packed
    ushort* PMb0  = (ushort*)(A + 6815744);
    ushort* PMf1  = (ushort*)(A + 7340032);
    ushort* PMb1  = (ushort*)(A + 7864320);
    ushort* pb0    = (ushort*)(A + 8388608);        //  2 MB bf16 [u][g][k]
    ushort* pb1i   = (ushort*)(A + 10485760);
    ushort* pb1h   = (ushort*)(A + 12582912);       //  ends 14,680,064
    float* G0f = (float*)(A + 23068672);
    float* G0b = (float*)(A + 56623104);
    float* Gd0 = (float*)(A + 23068672);            // aliases G0f (dead after enc scans)
    float* ench = (float*)(A + 39845888);
    float* ectx = (float*)(A + 56623104);
    float* dctx = (float*)(A + 60817408);
    __hip_bfloat16* outT2 = (__hip_bfloat16*)A;     // whole region, after concat_k

    char* Bh = A + 98304000;
    float* h0f = (float*)(Bh + 0);
    float* h0b = (float*)(Bh + 8388608);
    float* h1d = (float*)(Bh + 0);                  // aliases h0f (dead after enc1_gates)
    float* qe  = (float*)(Bh + 4194304);
    float* qd  = (float*)(Bh + 8388608);
    float* ew  = (float*)(Bh + 12582912);
    char* Cr = Bh + 16777216;
    float* h1f = (float*)(Cr + 0);                  // 8,388,608
    float* h1b = (float*)(Cr + 8388608);            // 8,388,608
    float* cc  = (float*)(Cr + 16777216);           // 12,582,912
    float* dec_init = (float*)(Cr + 29360128);      // 65,536
    float* pgen  = (float*)(Cr + 29425664);         // 8,192
    float* copyp = (float*)(Cr + 29433856);         // 8,192
    float* pbuf  = (float*)(Cr + 29442048);         // 131,072
    float* h0g   = (float*)(Cr + 29573120);         // 65,536 (2x[B][D])
    float* h1g   = (float*)(Cr + 29638656);         // 65,536
    float* encg  = (float*)(Cr + 29704192);         // 65,536 (2buf x 2dir x B x H)
    int*   barDec = (int*)(Cr + 29769728);          // 16 KB (128 flag lines + go)
    int*   barEnc0 = (int*)(Cr + 29786112);         // 16 KB (2 dir regions x 4KB)
    int*   barEnc1 = (int*)(Cr + 29802496);         // 16 KB
    // total ≈ 144.90 MB

    hipMemsetAsync(barDec, 0, 49152, stream);       // zero all barrier regions

    auto pack = [&](const float* W, float4* P, int Hn, int K) {
        int total = Hn * K;
        hipLaunchKernelGGL(pack4_kernel, dim3((total + 255) / 256), dim3(256), 0, stream, W, P, Hn, K);
    };
    pack(eWih0f, pWih0f, H, E);
    pack(eWih0b, pWih0b, H, E);
    pack(eWih1f, pWih1f, H, D);
    pack(eWih1b, pWih1b, H, D);
    pack(dWih0, pdWih0, D, E);
    hipLaunchKernelGGL(packencM_k, dim3(4 * H * H / 256), dim3(256), 0, stream, eWhh0f, PMf0);
    hipLaunchKernelGGL(packencM_k, dim3(4 * H * H / 256), dim3(256), 0, stream, eWhh0b, PMb0);
    hipLaunchKernelGGL(packencM_k, dim3(4 * H * H / 256), dim3(256), 0, stream, eWhh1f, PMf1);
    hipLaunchKernelGGL(packencM_k, dim3(4 * H * H / 256), dim3(256), 0, stream, eWhh1b, PMb1);
    hipLaunchKernelGGL(packdec_k, dim3(D * D * 4 / 256), dim3(256), 0, stream, dWhh0, pb0);
    hipLaunchKernelGGL(packdec_k, dim3(D * D * 4 / 256), dim3(256), 0, stream, dWih1, pb1i);
    hipLaunchKernelGGL(packdec_k, dim3(D * D * 4 / 256), dim3(256), 0, stream, dWhh1, pb1h);

    hipLaunchKernelGGL(enc0_gates, dim3(S * B), dim3(H), 0, stream,
                       input_ids, emb, pWih0f, eb0f, pWih0b, eb0b, G0f, G0b);
    hipLaunchKernelGGL(enc_pscan2, dim3(16), dim3(256), 0, stream,
                       G0f, G0b, PMf0, PMb0, h0f, h0b, dec_init, encg, barEnc0);
    hipLaunchKernelGGL(enc1_gates, dim3(S * B), dim3(H), 0, stream,
                       h0f, h0b, pWih1f, eb1f, pWih1b, eb1b, G0f, G0b);
    hipLaunchKernelGGL(enc_pscan2, dim3(16), dim3(256), 0, stream,
                       G0f, G0b, PMf1, PMb1, h1f, h1b, dec_init + B * D, encg, barEnc1);
    hipLaunchKernelGGL(dec0_gates, dim3(T * B), dim3(D), 0, stream,
                       target_ids, emb, pdWih0, db0, Gd0);
    hipLaunchKernelGGL(dec_scan2, dim3(NBLK_DEC), dim3(512), 0, stream,
                       Gd0, pb0, pb1i, pb1h, db1, dec_init, h0g, h1g, h1d, barDec);
    hipLaunchKernelGGL(build_encht, dim3(B * 256), dim3(256), 0, stream, h1f, h1b, ench);
    hipLaunchKernelGGL(qproj, dim3(T * B), dim3(D), 0, stream, h1d, Wenc, Wdec, qe, qd);
    hipLaunchKernelGGL(escore, dim3(B * T), dim3(S), 0, stream, qe, ench, ew);
    hipLaunchKernelGGL(temporal_k, dim3((B * S + 255) / 256), dim3(256), 0, stream, ew);
    hipLaunchKernelGGL(attnctx, dim3(B * T), dim3(S), 0, stream,
                       ew, input_ids, target_ids, h1f, h1b, ectx, copyp);
    hipLaunchKernelGGL(decattn, dim3(B * T), dim3(T), 0, stream, qd, h1d, dctx);
    hipLaunchKernelGGL(concat_k, dim3(B * T), dim3(D), 0, stream,
                       h1d, ectx, dctx, sW, sb, cc, pgen);
    hipLaunchKernelGGL(outprojT_k, dim3(1000), dim3(256), 0, stream, emb, Wvoc, outT2);
    hipLaunchKernelGGL(vocab_mfma, dim3(256), dim3(512), 0, stream,
                       outT2, cc, ob, target_ids, pbuf);
    hipLaunchKernelGGL(combine_nll_k, dim3(B), dim3(T), 0, stream,
                       pbuf, target_ids, pgen, copyp, tlen, out);
}

// Round 10
// 6680.523 us; speedup vs baseline: 3.4443x; 1.2383x over previous
//
#include <hip/hip_runtime.h>
#include <hip/hip_bf16.h>
#include <math.h>

#define PAD_ID 0
#define UNK_ID 1
#define START_ID 2
#define END_ID 3

constexpr int B = 16, S = 512, T = 128, V = 32000, E = 128, H = 256, D = 512;
constexpr int C3 = 1536;        // 3*D
constexpr int VO = 31997;       // V-3
constexpr int JS = 32000;       // padded col count for outT2

typedef short short8 __attribute__((ext_vector_type(8)));
typedef float f32x4 __attribute__((ext_vector_type(4)));

__device__ __forceinline__ float sigm(float x) { return 1.0f / (1.0f + __expf(-x)); }
__device__ __forceinline__ short bf16s(float x) {
    __hip_bfloat16 h = __float2bfloat16(x);
    return *reinterpret_cast<short*>(&h);
}
__device__ __forceinline__ float bflo(unsigned int u) { return __uint_as_float(u << 16); }
__device__ __forceinline__ float bfhi(unsigned int u) { return __uint_as_float(u & 0xffff0000u); }

// coherent (sc0 sc1) 16B load — bypasses caches to the coherent point. Caller must
// s_waitcnt vmcnt(0) before consuming.
__device__ __forceinline__ float4 cload4(const float* p) {
    float4 v;
    asm volatile("global_load_dwordx4 %0, %1, off sc0 sc1" : "=v"(v) : "v"(p));
    return v;
}

__device__ __forceinline__ void astore(float* p, float v) {
    __hip_atomic_store(p, v, __ATOMIC_RELAXED, __HIP_MEMORY_SCOPE_AGENT);
}

__device__ __forceinline__ void st_bf8(ushort* dst, float4 a, float4 b) {
    short8 o;
    o[0] = bf16s(a.x); o[1] = bf16s(a.y); o[2] = bf16s(a.z); o[3] = bf16s(a.w);
    o[4] = bf16s(b.x); o[5] = bf16s(b.y); o[6] = bf16s(b.z); o[7] = bf16s(b.w);
    *(short8*)dst = o;
}

// ---------------- all-to-all grid barrier: every block stores its own 64B flag line
// and polls ALL flags. Relaxed coherent ops only (no L2 inv/wb).
__device__ __forceinline__ void aabar(int* flags, int nblk, int ep, int myidx) {
    asm volatile("s_waitcnt vmcnt(0)" ::: "memory");   // my stores globally visible
    __syncthreads();
    int tid = threadIdx.x;
    if (tid == 0)
        __hip_atomic_store(flags + myidx * 16, ep, __ATOMIC_RELAXED, __HIP_MEMORY_SCOPE_AGENT);
    if (tid < 64) {
        for (int i = tid; i < nblk; i += 64)
            while (__hip_atomic_load(flags + i * 16, __ATOMIC_RELAXED, __HIP_MEMORY_SCOPE_AGENT) < ep)
                __builtin_amdgcn_s_sleep(1);
    }
    __syncthreads();
    asm volatile("" ::: "memory");
}

// ---------------- weight packing: W[4H][K] -> P[k][u] = float4 of 4 gates
__global__ void pack4_kernel(const float* __restrict__ W, float4* __restrict__ P, int Hn, int K) {
    int i = blockIdx.x * blockDim.x + threadIdx.x;
    if (i >= K * Hn) return;
    int k = i / Hn, u = i - k * Hn;
    float4 v;
    v.x = W[(size_t)(0 * Hn + u) * K + k];
    v.y = W[(size_t)(1 * Hn + u) * K + k];
    v.z = W[(size_t)(2 * Hn + u) * K + k];
    v.w = W[(size_t)(3 * Hn + u) * K + k];
    P[(size_t)k * Hn + u] = v;
}

// ---------------- encoder Whh pack for MFMA: W[4H][H] -> PM[row][k] bf16,
// row = (u>>3)*32 + g*8 + (u&7)  (wave-fragment order)
__global__ void packencM_k(const float* __restrict__ W, ushort* __restrict__ P) {
    int i = blockIdx.x * blockDim.x + threadIdx.x;
    if (i >= 4 * H * H) return;
    int k = i & 255, row = i >> 8;
    int g = (row >> 3) & 3, ul = row & 7, uh = row >> 5;
    int u = uh * 8 + ul;
    P[i] = (ushort)bf16s(W[(size_t)(g * H + u) * H + k]);
}

// ---------------- decoder W0 pack for MFMA: W[4D][D] -> PM0[row][512] bf16,
// row = bk*64 + g*16 + (u&15), with bk = u>>4  (g = (row>>4)&3, u = (row>>6)*16 + (row&15))
__global__ void packdecM_k(const float* __restrict__ W, ushort* __restrict__ P) {
    int i = blockIdx.x * blockDim.x + threadIdx.x;
    if (i >= 4 * D * D) return;
    int k = i & 511, row = i >> 9;
    int g = (row >> 4) & 3, u = (row >> 6) * 16 + (row & 15);
    P[i] = (ushort)bf16s(W[(size_t)(g * D + u) * D + k]);
}

// ---------------- decoder layer1 pack: [W1i | W1h] -> PM1[row][1024] bf16, same row order
__global__ void packdecM2_k(const float* __restrict__ Wi, const float* __restrict__ Wh,
                            ushort* __restrict__ P) {
    int i = blockIdx.x * blockDim.x + threadIdx.x;
    if (i >= 4 * D * D * 2) return;
    int k = i & 1023, row = i >> 10;
    int g = (row >> 4) & 3, u = (row >> 6) * 16 + (row & 15);
    float v = (k < 512) ? Wi[(size_t)(g * D + u) * D + k]
                        : Wh[(size_t)(g * D + u) * D + (k - 512)];
    P[i] = (ushort)bf16s(v);
}

// ---------------- encoder layer-0 gates, tiled (8 rows/block). grid S*B/8, 256 thr.
__global__ void enc0_gates2(const int* __restrict__ ids, const float* __restrict__ emb,
                            const float4* __restrict__ Pf, const float* __restrict__ bf_,
                            const float4* __restrict__ Pb, const float* __restrict__ bb_,
                            float* __restrict__ Gf, float* __restrict__ Gb) {
    int n0 = blockIdx.x * 8;
    int u = threadIdx.x;
    __shared__ float xr[8][E];
    for (int i = u; i < 8 * E; i += 256) {
        int r = i >> 7, e = i & 127;
        int n = n0 + r, s = n / B, b = n - s * B;
        int tok = ids[b * S + s];
        if (tok >= V) tok = UNK_ID;
        xr[r][e] = emb[(size_t)tok * E + e];
    }
    __syncthreads();
#pragma unroll
    for (int dir = 0; dir < 2; dir++) {
        const float4* P = dir ? Pb : Pf;
        const float* bs = dir ? bb_ : bf_;
        float* G = dir ? Gb : Gf;
        float acc[8][4];
#pragma unroll
        for (int r = 0; r < 8; r++)
#pragma unroll
            for (int g = 0; g < 4; g++) acc[r][g] = 0.f;
#pragma unroll 4
        for (int k = 0; k < E; k++) {
            float4 w = P[k * H + u];
#pragma unroll
            for (int r = 0; r < 8; r++) {
                float x = xr[r][k];
                acc[r][0] += x * w.x; acc[r][1] += x * w.y;
                acc[r][2] += x * w.z; acc[r][3] += x * w.w;
            }
        }
        float b0 = bs[u], b1 = bs[H + u], b2 = bs[2 * H + u], b3 = bs[3 * H + u];
#pragma unroll
        for (int r = 0; r < 8; r++) {
            float* g = G + (size_t)(n0 + r) * (4 * H);
            g[u] = acc[r][0] + b0; g[H + u] = acc[r][1] + b1;
            g[2 * H + u] = acc[r][2] + b2; g[3 * H + u] = acc[r][3] + b3;
        }
    }
}

// ---------------- encoder layer-1 gates, tiled (8 rows/block). grid S*B/8, 256 thr.
__global__ void enc1_gates2(const float* __restrict__ h0f, const float* __restrict__ h0b,
                            const float4* __restrict__ Pf, const float* __restrict__ bf_,
                            const float4* __restrict__ Pb, const float* __restrict__ bb_,
                            float* __restrict__ Gf, float* __restrict__ Gb) {
    int n0 = blockIdx.x * 8;
    int u = threadIdx.x;
    __shared__ float xr[8][520];
    for (int i = u; i < 8 * 512; i += 256) {
        int r = i >> 9, k = i & 511;
        int n = n0 + r;
        xr[r][k] = (k < H) ? h0f[(size_t)n * H + k] : h0b[(size_t)n * H + (k - H)];
    }
    __syncthreads();
#pragma unroll
    for (int dir = 0; dir < 2; dir++) {
        const float4* P = dir ? Pb : Pf;
        const float* bs = dir ? bb_ : bf_;
        float* G = dir ? Gb : Gf;
        float acc[8][4];
#pragma unroll
        for (int r = 0; r < 8; r++)
#pragma unroll
            for (int g = 0; g < 4; g++) acc[r][g] = 0.f;
#pragma unroll 4
        for (int k = 0; k < D; k++) {
            float4 w = P[k * H + u];
#pragma unroll
            for (int r = 0; r < 8; r++) {
                float x = xr[r][k];
                acc[r][0] += x * w.x; acc[r][1] += x * w.y;
                acc[r][2] += x * w.z; acc[r][3] += x * w.w;
            }
        }
        float b0 = bs[u], b1 = bs[H + u], b2 = bs[2 * H + u], b3 = bs[3 * H + u];
#pragma unroll
        for (int r = 0; r < 8; r++) {
            float* g = G + (size_t)(n0 + r) * (4 * H);
            g[u] = acc[r][0] + b0; g[H + u] = acc[r][1] + b1;
            g[2 * H + u] = acc[r][2] + b2; g[3 * H + u] = acc[r][3] + b3;
        }
    }
}

// ---------------- decoder layer-0 input gates, tiled (8 rows/block). grid T*B/8, 512 thr.
__global__ void dec0_gates2(const int* __restrict__ tgt, const float* __restrict__ emb,
                            const float4* __restrict__ P, const float* __restrict__ bias,
                            float* __restrict__ G) {
    int n0 = blockIdx.x * 8;
    int u = threadIdx.x;
    __shared__ float xr[8][E];
    for (int i = u; i < 8 * E; i += 512) {
        int r = i >> 7, e = i & 127;
        int n = n0 + r, t = n / B, b = n - t * B;
        int tok;
        if (t == 0) tok = START_ID;
        else { tok = tgt[b * T + (t - 1)]; if (tok >= V) tok = UNK_ID; }
        xr[r][e] = emb[(size_t)tok * E + e];
    }
    __syncthreads();
    float acc[8][4];
#pragma unroll
    for (int r = 0; r < 8; r++)
#pragma unroll
        for (int g = 0; g < 4; g++) acc[r][g] = 0.f;
#pragma unroll 4
    for (int k = 0; k < E; k++) {
        float4 w = P[k * D + u];
#pragma unroll
        for (int r = 0; r < 8; r++) {
            float x = xr[r][k];
            acc[r][0] += x * w.x; acc[r][1] += x * w.y;
            acc[r][2] += x * w.z; acc[r][3] += x * w.w;
        }
    }
    float b0 = bias[u], b1 = bias[D + u], b2 = bias[2 * D + u], b3 = bias[3 * D + u];
#pragma unroll
    for (int r = 0; r < 8; r++) {
        float* g = G + (size_t)(n0 + r) * (4 * D);
        g[u] = acc[r][0] + b0; g[D + u] = acc[r][1] + b1;
        g[2 * D + u] = acc[r][2] + b2; g[3 * D + u] = acc[r][3] + b3;
    }
}

// ---------------- MFMA encoder persistent scan (R9, passing). grid 16 = dir*8 + bk, 256 thr.
__global__ void __launch_bounds__(256) enc_pscan2(
        const float* __restrict__ Gf, const float* __restrict__ Gb,
        const ushort* __restrict__ PMf, const ushort* __restrict__ PMb,
        float* __restrict__ hof, float* __restrict__ hob,
        float* __restrict__ hfin /* [B][2H] */,
        float* __restrict__ hg /* [2buf][2dir][B][H] f32 */, int* __restrict__ barbase) {
    __shared__ __align__(16) ushort hh[16 * 264];   // [b][264] bf16
    __shared__ float gs[4][32][17];                 // [wave][row=g*8+ul][b]
    int blk = blockIdx.x;
    int dirb = blk >> 3, bk = blk & 7;
    int* bar = barbase + dirb * 1024;
    const float* G = dirb ? Gb : Gf;
    const ushort* PM = dirb ? PMb : PMf;
    float* ho = dirb ? hob : hof;
    int tid = threadIdx.x;
    int lane = tid & 63, w = tid >> 6;
    int cl = lane & 15, hi = lane >> 4;

    short8 afr[2][8];
    {
        int rowbase = (bk * 4 + w) * 32;
#pragma unroll
        for (int mt = 0; mt < 2; mt++)
#pragma unroll
            for (int kt = 0; kt < 8; kt++)
                afr[mt][kt] = *(const short8*)(PM + (size_t)(rowbase + mt * 16 + cl) * 256 + kt * 32 + hi * 8);
    }
    int ub = tid & 31, bb = tid >> 5;
    int u_glob = bk * 32 + ub;
    int gsw = ub >> 3, ul = ub & 7;
    float c_a = 0.f, c_b = 0.f;
    astore(&hg[dirb * (B * H) + bb * H + u_glob], 0.f);
    astore(&hg[dirb * (B * H) + (bb + 8) * H + u_glob], 0.f);
    int ep = 1;
    aabar(bar, 8, ep, bk);

    for (int step = 0; step < S; step++) {
        int s = dirb ? (S - 1 - step) : step;
        int cur = step & 1;
        const float* gA = G + ((size_t)(s * B + bb)) * 1024 + u_glob;
        const float* gB = G + ((size_t)(s * B + bb + 8)) * 1024 + u_glob;
        float pa0 = gA[0], pa1 = gA[256], pa2 = gA[512], pa3 = gA[768];
        float pb0 = gB[0], pb1 = gB[256], pb2 = gB[512], pb3 = gB[768];
        {
            int sb = tid >> 4, kseg = tid & 15;
            const float* src = hg + cur * (2 * B * H) + dirb * (B * H) + sb * H + kseg * 16;
            float4 v0 = cload4(src), v1 = cload4(src + 4), v2 = cload4(src + 8), v3 = cload4(src + 12);
            asm volatile("s_waitcnt vmcnt(0)" ::: "memory");
            __builtin_amdgcn_sched_barrier(0);
            st_bf8(hh + sb * 264 + kseg * 16, v0, v1);
            st_bf8(hh + sb * 264 + kseg * 16 + 8, v2, v3);
        }
        __syncthreads();
        {
            f32x4 acc0 = {0.f, 0.f, 0.f, 0.f}, acc1 = {0.f, 0.f, 0.f, 0.f};
            const ushort* hp = hh + cl * 264 + hi * 8;
#pragma unroll
            for (int kt = 0; kt < 8; kt++) {
                short8 bfr = *(const short8*)(hp + kt * 32);
                acc0 = __builtin_amdgcn_mfma_f32_16x16x32_bf16(afr[0][kt], bfr, acc0, 0, 0, 0);
                acc1 = __builtin_amdgcn_mfma_f32_16x16x32_bf16(afr[1][kt], bfr, acc1, 0, 0, 0);
            }
#pragma unroll
            for (int i = 0; i < 4; i++) {
                gs[w][hi * 4 + i][cl] = acc0[i];
                gs[w][16 + hi * 4 + i][cl] = acc1[i];
            }
        }
        __syncthreads();
        {
            float q0 = gs[gsw][0 + ul][bb];
            float q1 = gs[gsw][8 + ul][bb];
            float q2 = gs[gsw][16 + ul][bb];
            float q3 = gs[gsw][24 + ul][bb];
            float ig = sigm(pa0 + q0), fg = sigm(pa1 + q1), gt = tanhf(pa2 + q2), og = sigm(pa3 + q3);
            c_a = fg * c_a + ig * gt;
            float hA = og * tanhf(c_a);
            q0 = gs[gsw][0 + ul][bb + 8];
            q1 = gs[gsw][8 + ul][bb + 8];
            q2 = gs[gsw][16 + ul][bb + 8];
            q3 = gs[gsw][24 + ul][bb + 8];
            ig = sigm(pb0 + q0); fg = sigm(pb1 + q1); gt = tanhf(pb2 + q2); og = sigm(pb3 + q3);
            c_b = fg * c_b + ig * gt;
            float hB = og * tanhf(c_b);
            float* dst = hg + (cur ^ 1) * (2 * B * H) + dirb * (B * H);
            astore(&dst[bb * H + u_glob], hA);
            astore(&dst[(bb + 8) * H + u_glob], hB);
            ho[((size_t)(s * B + bb)) * H + u_glob] = hA;
            ho[((size_t)(s * B + bb + 8)) * H + u_glob] = hB;
            if (step == S - 1) {
                hfin[bb * (2 * H) + dirb * H + u_glob] = hA;
                hfin[(bb + 8) * (2 * H) + dirb * H + u_glob] = hB;
            }
        }
        aabar(bar, 8, ++ep, bk);
    }
}

// ---------------- MFMA decoder persistent 2-layer scan. grid 32, 256 threads (4 waves).
// Wave w holds gate-w weight rows (16 u) for BOTH layers as A-fragments in registers.
// h staged per phase as bf16 [b][1032] LDS; 1 grid barrier per step (between phases).
__global__ void __launch_bounds__(256) dec_mfma(
        const float* __restrict__ G0, const ushort* __restrict__ PM0,
        const ushort* __restrict__ PM1, const float* __restrict__ b1,
        const float* __restrict__ hinit,
        float* __restrict__ h0g /* [2][B][D] */, float* __restrict__ h1g /* [2][B][D] */,
        float* __restrict__ h1out, int* __restrict__ bar) {
    __shared__ __align__(16) ushort hb[16 * 1032];  // [b][k] bf16
    __shared__ float gs[4][16][17];                 // [gate][u_loc][b]
    int tid = threadIdx.x;
    int bk = blockIdx.x;
    int lane = tid & 63, w = tid >> 6;
    int cl = lane & 15, hi = lane >> 4;

    // A-fragments: layer0 16 k-tiles, layer1 32 k-tiles (both layers resident)
    short8 a0[16], a1[32];
    {
        const ushort* base0 = PM0 + (size_t)(bk * 64 + w * 16 + cl) * 512 + hi * 8;
#pragma unroll
        for (int kt = 0; kt < 16; kt++) a0[kt] = *(const short8*)(base0 + kt * 32);
        const ushort* base1 = PM1 + (size_t)(bk * 64 + w * 16 + cl) * 1024 + hi * 8;
#pragma unroll
        for (int kt = 0; kt < 32; kt++) a1[kt] = *(const short8*)(base1 + kt * 32);
    }
    int u_loc = tid & 15, b = tid >> 4;
    int u = bk * 16 + u_loc;
    float bi0 = b1[u], bi1 = b1[512 + u], bi2 = b1[1024 + u], bi3 = b1[1536 + u];
    float c0v = 0.f, c1v = 0.f;
    astore(&h0g[B * D + b * 512 + u], hinit[b * 512 + u]);
    astore(&h1g[B * D + b * 512 + u], hinit[B * D + b * 512 + u]);
    int ep = 1;
    aabar(bar, 32, ep, bk);

    int sb = tid >> 4, kseg = tid & 15;   // 32 k per thread
    for (int t = 0; t < T; t++) {
        int cur = t & 1;
        // ---- phase A staging: h0(t-1) -> hb[.][0..511]
        {
            const float* src = h0g + (cur ^ 1) * (B * D) + sb * 512 + kseg * 32;
            float4 v0 = cload4(src),      v1 = cload4(src + 4),
                   v2 = cload4(src + 8),  v3 = cload4(src + 12),
                   v4 = cload4(src + 16), v5 = cload4(src + 20),
                   v6 = cload4(src + 24), v7 = cload4(src + 28);
            asm volatile("s_waitcnt vmcnt(0)" ::: "memory");
            __builtin_amdgcn_sched_barrier(0);
            ushort* dst = hb + sb * 1032 + kseg * 32;
            st_bf8(dst, v0, v1); st_bf8(dst + 8, v2, v3);
            st_bf8(dst + 16, v4, v5); st_bf8(dst + 24, v6, v7);
        }
        __syncthreads();
        // ---- MFMA layer0: wave w = gate w, 16 u x 16 b
        {
            f32x4 acc = {0.f, 0.f, 0.f, 0.f};
            const ushort* hp = hb + cl * 1032 + hi * 8;
#pragma unroll
            for (int kt = 0; kt < 16; kt++) {
                short8 bfr = *(const short8*)(hp + kt * 32);
                acc = __builtin_amdgcn_mfma_f32_16x16x32_bf16(a0[kt], bfr, acc, 0, 0, 0);
            }
#pragma unroll
            for (int i = 0; i < 4; i++) gs[w][hi * 4 + i][cl] = acc[i];
        }
        __syncthreads();
        // ---- assembly layer0
        {
            const float* gg = G0 + ((size_t)(t * B + b)) * 2048 + u;
            float g0 = gg[0]    + gs[0][u_loc][b];
            float g1 = gg[512]  + gs[1][u_loc][b];
            float g2 = gg[1024] + gs[2][u_loc][b];
            float g3 = gg[1536] + gs[3][u_loc][b];
            float ig = sigm(g0), fg = sigm(g1), gt = tanhf(g2), og = sigm(g3);
            c0v = fg * c0v + ig * gt;
            astore(&h0g[cur * (B * D) + b * 512 + u], og * tanhf(c0v));
        }
        aabar(bar, 32, ++ep, bk);                  // h0(t) visible everywhere
        // ---- phase B staging: hb[.][0..511] <- h0(t), hb[.][512..1023] <- h1(t-1)
        {
            const float* s0 = h0g + cur * (B * D) + sb * 512 + kseg * 32;
            float4 v0 = cload4(s0),      v1 = cload4(s0 + 4),
                   v2 = cload4(s0 + 8),  v3 = cload4(s0 + 12),
                   v4 = cload4(s0 + 16), v5 = cload4(s0 + 20),
                   v6 = cload4(s0 + 24), v7 = cload4(s0 + 28);
            asm volatile("s_waitcnt vmcnt(0)" ::: "memory");
            __builtin_amdgcn_sched_barrier(0);
            ushort* dst = hb + sb * 1032 + kseg * 32;
            st_bf8(dst, v0, v1); st_bf8(dst + 8, v2, v3);
            st_bf8(dst + 16, v4, v5); st_bf8(dst + 24, v6, v7);
            const float* s1 = h1g + (cur ^ 1) * (B * D) + sb * 512 + kseg * 32;
            v0 = cload4(s1);      v1 = cload4(s1 + 4);
            v2 = cload4(s1 + 8);  v3 = cload4(s1 + 12);
            v4 = cload4(s1 + 16); v5 = cload4(s1 + 20);
            v6 = cload4(s1 + 24); v7 = cload4(s1 + 28);
            asm volatile("s_waitcnt vmcnt(0)" ::: "memory");
            __builtin_amdgcn_sched_barrier(0);
            dst = hb + sb * 1032 + 512 + kseg * 32;
            st_bf8(dst, v0, v1); st_bf8(dst + 8, v2, v3);
            st_bf8(dst + 16, v4, v5); st_bf8(dst + 24, v6, v7);
        }
        __syncthreads();
        // ---- MFMA layer1 (k = 1024: [W1i|W1h] . [h0(t); h1(t-1)])
        {
            f32x4 acc = {0.f, 0.f, 0.f, 0.f};
            const ushort* hp = hb + cl * 1032 + hi * 8;
#pragma unroll
            for (int kt = 0; kt < 32; kt++) {
                short8 bfr = *(const short8*)(hp + kt * 32);
                acc = __builtin_amdgcn_mfma_f32_16x16x32_bf16(a1[kt], bfr, acc, 0, 0, 0);
            }
#pragma unroll
            for (int i = 0; i < 4; i++) gs[w][hi * 4 + i][cl] = acc[i];
        }
        __syncthreads();
        // ---- assembly layer1
        {
            float g0 = bi0 + gs[0][u_loc][b];
            float g1 = bi1 + gs[1][u_loc][b];
            float g2 = bi2 + gs[2][u_loc][b];
            float g3 = bi3 + gs[3][u_loc][b];
            float ig = sigm(g0), fg = sigm(g1), gt = tanhf(g2), og = sigm(g3);
            c1v = fg * c1v + ig * gt;
            float h1n = og * tanhf(c1v);
            astore(&h1g[cur * (B * D) + b * 512 + u], h1n);
            h1out[((size_t)(t * B + b)) * 512 + u] = h1n;
        }
        // next-iter staging's hb writes are fenced by the __syncthreads after them;
        // MFMA-B hb reads were fenced by the __syncthreads before this assembly.
    }
}

// ---------------- transpose enc hidden to [b][k(512)][s] for coalesced score dots
__global__ void build_encht(const float* __restrict__ h1f, const float* __restrict__ h1b,
                            float* __restrict__ et) {
    int blk = blockIdx.x;                 // b*256 + kt*16 + st
    int b = blk >> 8, rem = blk & 255;
    int kt = rem >> 4, st = rem & 15;
    int c = threadIdx.x & 31, r = threadIdx.x >> 5;   // r in 0..7
    __shared__ float tile[32][33];
#pragma unroll
    for (int i = 0; i < 4; i++) {
        int sl = r + i * 8;               // s_local
        int s = st * 32 + sl;
        int k = kt * 32 + c;              // lane-contiguous over k
        float v = (k < H) ? h1f[((size_t)(s * B + b)) * H + k]
                          : h1b[((size_t)(s * B + b)) * H + (k - H)];
        tile[c][sl] = v;                  // tile[k_local][s_local]
    }
    __syncthreads();
#pragma unroll
    for (int i = 0; i < 4; i++) {
        int kl = r + i * 8;
        et[(size_t)b * D * S + (size_t)(kt * 32 + kl) * S + st * 32 + c] = tile[kl][c];
    }
}

// ---------------- q projections. grid T*B (n=t*B+b), 512 threads
__global__ void qproj(const float* __restrict__ h1d, const float* __restrict__ Wenc,
                      const float* __restrict__ Wdec, float* __restrict__ qe, float* __restrict__ qd) {
    int n = blockIdx.x;
    int o = threadIdx.x;
    __shared__ float hr[D];
    hr[o] = h1d[(size_t)n * D + o];
    __syncthreads();
    float ae = 0.f, ad = 0.f;
#pragma unroll 4
    for (int k = 0; k < D; k++) {
        float hk = hr[k];
        ae += hk * Wenc[k * D + o];
        ad += hk * Wdec[k * D + o];
    }
    qe[(size_t)n * D + o] = ae;
    qd[(size_t)n * D + o] = ad;
}

// ---------------- e = exp(min(score,30)). grid B*T (bt=b*T+t), 512 threads (s)
__global__ void escore(const float* __restrict__ qe, const float* __restrict__ et,
                       float* __restrict__ ew) {
    int bt = blockIdx.x;
    int b = bt / T, t = bt - b * T;
    int sx = threadIdx.x;
    __shared__ float q[D];
    q[sx] = qe[((size_t)(t * B + b)) * D + sx];
    __syncthreads();
    float acc = 0.f;
    const float* eb = et + (size_t)b * D * S + sx;
#pragma unroll 4
    for (int k = 0; k < D; k++) { acc += q[k] * eb[0]; eb += S; }
    acc = fminf(acc, 30.0f);
    ew[(size_t)bt * S + sx] = __expf(acc);
}

// ---------------- temporal normalization (prefix over t, in place)
__global__ void temporal_k(float* __restrict__ ew) {
    int i = blockIdx.x * blockDim.x + threadIdx.x;
    if (i >= B * S) return;
    int b = i / S, sx = i - b * S;
    float cum = 0.f;
    for (int t = 0; t < T; t++) {
        size_t idx = ((size_t)(b * T + t)) * S + sx;
        float v = ew[idx];
        ew[idx] = v / (t == 0 ? 1.0f : (cum + 1e-8f));
        cum += v;
    }
}

// ---------------- attention softmax over s + enc context + copy prob. grid B*T, 512 thr
__global__ void attnctx(const float* __restrict__ ew, const int* __restrict__ ids,
                        const int* __restrict__ tgt,
                        const float* __restrict__ h1f, const float* __restrict__ h1b,
                        float* __restrict__ ectx, float* __restrict__ copyp) {
    int bt = blockIdx.x;
    int b = bt / T, t = bt - b * T;
    int tid = threadIdx.x;
    __shared__ float aw[S];
    __shared__ float red[512];
    float v = ew[(size_t)bt * S + tid];
    int tok = ids[b * S + tid];
    bool pad = (tok == PAD_ID);
    float vm = pad ? -INFINITY : v;
    red[tid] = vm; __syncthreads();
    for (int w = 256; w > 0; w >>= 1) { if (tid < w) red[tid] = fmaxf(red[tid], red[tid + w]); __syncthreads(); }
    float m = red[0]; __syncthreads();
    float ex = pad ? 0.f : __expf(vm - m);
    red[tid] = ex; __syncthreads();
    for (int w = 256; w > 0; w >>= 1) { if (tid < w) red[tid] += red[tid + w]; __syncthreads(); }
    float Z = red[0]; __syncthreads();
    float a = ex / Z;
    aw[tid] = a;
    int nt = tgt[b * T + t];
    red[tid] = (tok == nt) ? a : 0.f; __syncthreads();
    for (int w = 256; w > 0; w >>= 1) { if (tid < w) red[tid] += red[tid + w]; __syncthreads(); }
    if (tid == 0) copyp[bt] = red[0];
    __syncthreads();
    int d = tid;
    const float* hp = (d < H) ? (h1f + (size_t)b * H + d) : (h1b + (size_t)b * H + (d - H));
    float acc = 0.f;
#pragma unroll 4
    for (int s2 = 0; s2 < S; s2++) { acc += aw[s2] * hp[0]; hp += B * H; }
    ectx[(size_t)bt * D + d] = acc;
}

// ---------------- intra-decoder attention. grid B*T, 128 threads
__global__ void decattn(const float* __restrict__ qd, const float* __restrict__ h1d,
                        float* __restrict__ dctx) {
    int bt = blockIdx.x;
    int b = bt / T, t = bt - b * T;
    int tid = threadIdx.x;
    __shared__ float q[D];
    __shared__ float wl[T];
    __shared__ float red[128];
    for (int i = tid; i < D; i += 128) q[i] = qd[((size_t)(t * B + b)) * D + i];
    __syncthreads();
    float sc = -INFINITY;
    if (tid < t) {
        const float* hu = h1d + ((size_t)(tid * B + b)) * D;
        float a = 0.f;
#pragma unroll 4
        for (int k = 0; k < D; k++) a += q[k] * hu[k];
        sc = a;
    }
    red[tid] = sc; __syncthreads();
    for (int w = 64; w > 0; w >>= 1) { if (tid < w) red[tid] = fmaxf(red[tid], red[tid + w]); __syncthreads(); }
    float m = red[0]; __syncthreads();
    float ex = (tid < t) ? __expf(sc - m) : 0.f;
    red[tid] = ex; __syncthreads();
    for (int w = 64; w > 0; w >>= 1) { if (tid < w) red[tid] += red[tid + w]; __syncthreads(); }
    float Z = red[0]; __syncthreads();
    wl[tid] = (t > 0) ? (ex / Z) : 0.f;
    __syncthreads();
    for (int d = tid; d < D; d += 128) {
        float acc = 0.f;
        for (int u = 0; u < t; u++) acc += wl[u] * h1d[((size_t)(u * B + b)) * D + d];
        dctx[(size_t)bt * D + d] = acc;
    }
}

// ---------------- concat + p_gen. grid B*T, 512 threads
__global__ void concat_k(const float* __restrict__ h1d, const float* __restrict__ ectx,
                         const float* __restrict__ dctx, const float* __restrict__ sW,
                         const float* __restrict__ sb, float* __restrict__ cc,
                         float* __restrict__ pgen) {
    int bt = blockIdx.x;
    int b = bt / T, t = bt - b * T;
    int d = threadIdx.x;
    __shared__ float red[512];
    float v0 = h1d[((size_t)(t * B + b)) * D + d];
    float v1 = ectx[(size_t)bt * D + d];
    float v2 = dctx[(size_t)bt * D + d];
    float* c = cc + (size_t)bt * C3;
    c[d] = v0; c[D + d] = v1; c[2 * D + d] = v2;
    red[d] = v0 * sW[d] + v1 * sW[D + d] + v2 * sW[2 * D + d];
    __syncthreads();
    for (int w = 256; w > 0; w >>= 1) { if (d < w) red[d] += red[d + w]; __syncthreads(); }
    if (d == 0) pgen[bt] = 1.f / (1.f + __expf(-(red[0] + sb[0])));
}

// ---------------- out_proj, packed-k layout for MFMA B-fragments.
__global__ void outprojT_k(const float* __restrict__ emb, const float* __restrict__ Wvoc,
                           __hip_bfloat16* __restrict__ outT2) {
    int j0 = blockIdx.x * 32;
    int jl = threadIdx.x & 31, oq = threadIdx.x >> 5;   // oq in 0..7
    __shared__ float er[32][E + 1];                      // +1 pad
    for (int i = threadIdx.x; i < 32 * E; i += 256) {
        int jj = i >> 7, e = i & 127;
        int j = j0 + jj;
        er[jj][e] = (j < VO) ? emb[(size_t)(3 + j) * E + e] : 0.f;
    }
    __syncthreads();
    int j = j0 + jl;
#pragma unroll 1
    for (int i = 0; i < 24; i++) {
        int o = oq * 24 + i;                             // octet index 0..191
        int k0 = o * 8;
        float acc[8];
#pragma unroll
        for (int kk = 0; kk < 8; kk++) acc[kk] = 0.f;
#pragma unroll 4
        for (int e = 0; e < E; e++) {
            float x = er[jl][e];
            float4 w0 = *(const float4*)(Wvoc + (size_t)e * C3 + k0);
            float4 w1 = *(const float4*)(Wvoc + (size_t)e * C3 + k0 + 4);
            acc[0] += x * w0.x; acc[1] += x * w0.y; acc[2] += x * w0.z; acc[3] += x * w0.w;
            acc[4] += x * w1.x; acc[5] += x * w1.y; acc[6] += x * w1.z; acc[7] += x * w1.w;
        }
        short8 v;
#pragma unroll
        for (int kk = 0; kk < 8; kk++) v[kk] = bf16s(tanhf(acc[kk]));
        *reinterpret_cast<short8*>((char*)outT2 + ((size_t)o * JS + j) * 16) = v;
    }
}

// ---------------- vocab GEMM via MFMA + fused online softmax partials.
__global__ void __launch_bounds__(512) vocab_mfma(
        const __hip_bfloat16* __restrict__ outT2, const float* __restrict__ cc,
        const float* __restrict__ ob, const int* __restrict__ tgt,
        float* __restrict__ pbuf) {
    __shared__ __align__(16) short As[32 * 1536];        // bf16 A tile, chunk-XOR swizzled
    __shared__ float wm[8][32], ws_[8][32], wg[8][32];
    __shared__ int jstar_s[32];
    int bid = blockIdx.x;
    int rb = bid & 63, q = bid >> 6;
    int row0 = rb * 32;
    int tid = threadIdx.x;

    {
        int r = tid >> 4, cpos = tid & 15;
        const float* src = cc + (size_t)(row0 + r) * C3;
        int r7 = r & 7;
        short* dst = As + r * C3;
#pragma unroll
        for (int ii = 0; ii < 12; ii++) {
            int c = ii * 16 + cpos;                      // chunk 0..191 (8 bf16 each)
            float4 f0 = *(const float4*)(src + c * 8);
            float4 f1 = *(const float4*)(src + c * 8 + 4);
            short8 v;
            v[0] = bf16s(f0.x); v[1] = bf16s(f0.y); v[2] = bf16s(f0.z); v[3] = bf16s(f0.w);
            v[4] = bf16s(f1.x); v[5] = bf16s(f1.y); v[6] = bf16s(f1.z); v[7] = bf16s(f1.w);
            *reinterpret_cast<short8*>(dst + ((c ^ r7) << 3)) = v;
        }
    }
    if (tid < 32) {
        int nt = tgt[row0 + tid];
        int ix = nt - 3;
        ix = ix < 0 ? 0 : (ix > VO - 1 ? VO - 1 : ix);
        jstar_s[tid] = ix;
    }
    __syncthreads();

    int lane = tid & 63, wid = tid >> 6;
    int wr = wid >> 2, wc = wid & 3;
    int cl = lane & 15, g = lane >> 4;
    int rowA = wr * 16 + cl;
    const short* Abase = As + rowA * C3;
    int r7 = rowA & 7;
    int jst[4];
    float m[4], sacc[4], gl[4];
#pragma unroll
    for (int i = 0; i < 4; i++) {
        jst[i] = jstar_s[wr * 16 + g * 4 + i];
        m[i] = -1e30f; sacc[i] = 0.f; gl[i] = -1e30f;
    }

    int jb0 = q * 8192;
    int jqend = (jb0 + 8192 < VO) ? jb0 + 8192 : VO;
    int nmt = (jqend - jb0 + 127) >> 7;
    for (int ti = 0; ti < nmt; ti++) {
        int jA = jb0 + ti * 128 + wc * 32 + cl;
        const char* pB = (const char*)outT2 + ((size_t)g * JS + jA) * 16;
        f32x4 acc0 = {0.f, 0.f, 0.f, 0.f}, acc1 = {0.f, 0.f, 0.f, 0.f};
#pragma unroll
        for (int s = 0; s < 48; s++) {
            short8 a = *reinterpret_cast<const short8*>(Abase + (((s * 4 + g) ^ r7) << 3));
            short8 b0 = *reinterpret_cast<const short8*>(pB + (size_t)s * (4 * JS * 16));
            short8 b1 = *reinterpret_cast<const short8*>(pB + (size_t)s * (4 * JS * 16) + 256);
            acc0 = __builtin_amdgcn_mfma_f32_16x16x32_bf16(a, b0, acc0, 0, 0, 0);
            acc1 = __builtin_amdgcn_mfma_f32_16x16x32_bf16(a, b1, acc1, 0, 0, 0);
        }
#pragma unroll
        for (int X = 0; X < 2; X++) {
            int j = jA + X * 16;
            if (j < jqend) {
                float obj = ob[j];
#pragma unroll
                for (int i = 0; i < 4; i++) {
                    float L = (X ? acc1[i] : acc0[i]) + obj;
                    if (j == jst[i]) gl[i] = L;
                    float mn = fmaxf(m[i], L);
                    sacc[i] = sacc[i] * __expf(m[i] - mn) + __expf(L - mn);
                    m[i] = mn;
                }
            }
        }
    }

#pragma unroll
    for (int i = 0; i < 4; i++) {
        for (int mask = 1; mask < 16; mask <<= 1) {
            float om = __shfl_xor(m[i], mask);
            float os = __shfl_xor(sacc[i], mask);
            float mn = fmaxf(m[i], om);
            sacc[i] = sacc[i] * __expf(m[i] - mn) + os * __expf(om - mn);
            m[i] = mn;
            gl[i] = fmaxf(gl[i], __shfl_xor(gl[i], mask));
        }
    }
    if (cl == 0) {
#pragma unroll
        for (int i = 0; i < 4; i++) {
            int rl = wr * 16 + g * 4 + i;
            wm[wid][rl] = m[i]; ws_[wid][rl] = sacc[i]; wg[wid][rl] = gl[i];
        }
    }
    __syncthreads();
    if (tid < 32) {
        float M = -1e30f, SS = 0.f, GL = -1e30f;
        int w0 = (tid >> 4) * 4;
#pragma unroll
        for (int w = 0; w < 4; w++) {
            float mq = wm[w0 + w][tid], sq = ws_[w0 + w][tid], gq = wg[w0 + w][tid];
            float mn = fmaxf(M, mq);
            SS = SS * __expf(M - mn) + sq * __expf(mq - mn);
            M = mn;
            GL = fmaxf(GL, gq);
        }
        float* o = pbuf + ((size_t)bid * 32 + tid) * 4;
        o[0] = M; o[1] = SS; o[2] = GL;
    }
}

// ---------------- combine quarter-partials + pointer mix + NLL. grid B, 128 threads.
__global__ void combine_nll_k(const float* __restrict__ pbuf, const int* __restrict__ tgt,
                              const float* __restrict__ pgen, const float* __restrict__ copyp,
                              const int* __restrict__ tlen, float* __restrict__ out) {
    int b = blockIdx.x, t = threadIdx.x;
    int row = b * T + t;
    int rb = row >> 5, r = row & 31;
    float M = -1e30f, SS = 0.f, GL = -1e30f;
#pragma unroll
    for (int q = 0; q < 4; q++) {
        const float* p = pbuf + ((size_t)(q * 64 + rb) * 32 + r) * 4;
        float mq = p[0], sq = p[1], gq = p[2];
        float mn = fmaxf(M, mq);
        SS = SS * __expf(M - mn) + sq * __expf(mq - mn);
        M = mn;
        GL = fmaxf(GL, gq);
    }
    int nt = tgt[row];
    float genp = (nt >= 3 && nt < V) ? __expf(GL - M) / SS : 0.f;
    float pg = pgen[row];
    float p = pg * genp + (1.f - pg) * copyp[row];
    __shared__ float red[128];
    red[t] = (t < tlen[b]) ? -logf(p + 1e-9f) : 0.f;
    __syncthreads();
    for (int w = 64; w > 0; w >>= 1) { if (t < w) red[t] += red[t + w]; __syncthreads(); }
    if (t == 0) out[b] = red[0];
}

extern "C" void kernel_launch(void* const* d_in, const int* in_sizes, int n_in,
                              void* d_out, int out_size, void* d_ws, size_t ws_size,
                              hipStream_t stream) {
    const int* input_ids = (const int*)d_in[0];
    const int* target_ids = (const int*)d_in[1];
    const int* tlen = (const int*)d_in[3];
    const float* emb = (const float*)d_in[5];
    const float* eWih0f = (const float*)d_in[6],  *eWhh0f = (const float*)d_in[7],  *eb0f = (const float*)d_in[8];
    const float* eWih0b = (const float*)d_in[9],  *eWhh0b = (const float*)d_in[10], *eb0b = (const float*)d_in[11];
    const float* eWih1f = (const float*)d_in[12], *eWhh1f = (const float*)d_in[13], *eb1f = (const float*)d_in[14];
    const float* eWih1b = (const float*)d_in[15], *eWhh1b = (const float*)d_in[16], *eb1b = (const float*)d_in[17];
    const float* dWih0 = (const float*)d_in[18], *dWhh0 = (const float*)d_in[19], *db0 = (const float*)d_in[20];
    const float* dWih1 = (const float*)d_in[21], *dWhh1 = (const float*)d_in[22], *db1 = (const float*)d_in[23];
    const float* Wenc = (const float*)d_in[24], *Wdec = (const float*)d_in[25];
    const float* Wvoc = (const float*)d_in[26], *sW = (const float*)d_in[27], *sb = (const float*)d_in[28];
    const float* ob = (const float*)d_in[29];
    float* out = (float*)d_out;
    (void)ws_size; (void)n_in; (void)in_sizes; (void)out_size;

    // ============ workspace layout (~145 MB, phase-aliased) ============
    char* A = (char*)d_ws;
    float4* pWih0f = (float4*)(A + 0);              //  512 KB f32 gate-packed
    float4* pWih0b = (float4*)(A + 524288);
    float4* pWih1f = (float4*)(A + 1048576);        //  2 MB
    float4* pWih1b = (float4*)(A + 3145728);
    float4* pdWih0 = (float4*)(A + 5242880);        //  1 MB
    ushort* PMf0  = (ushort*)(A + 6291456);         //  512 KB bf16 MFMA-row packed
    ushort* PMb0  = (ushort*)(A + 6815744);
    ushort* PMf1  = (ushort*)(A + 7340032);
    ushort* PMb1  = (ushort*)(A + 7864320);
    ushort* PM0   = (ushort*)(A + 8388608);         //  2 MB dec layer0 MFMA pack
    ushort* PM1   = (ushort*)(A + 10485760);        //  4 MB dec layer1 MFMA pack (ends 14,680,064)
    float* G0f = (float*)(A + 23068672);
    float* G0b = (float*)(A + 56623104);
    float* Gd0 = (float*)(A + 23068672);            // aliases G0f (dead after enc scans)
    float* ench = (float*)(A + 39845888);
    float* ectx = (float*)(A + 56623104);
    float* dctx = (float*)(A + 60817408);
    __hip_bfloat16* outT2 = (__hip_bfloat16*)A;     // whole region, after concat_k

    char* Bh = A + 98304000;
    float* h0f = (float*)(Bh + 0);
    float* h0b = (float*)(Bh + 8388608);
    float* h1d = (float*)(Bh + 0);                  // aliases h0f (dead after enc1_gates)
    float* qe  = (float*)(Bh + 4194304);
    float* qd  = (float*)(Bh + 8388608);
    float* ew  = (float*)(Bh + 12582912);
    char* Cr = Bh + 16777216;
    float* h1f = (float*)(Cr + 0);                  // 8,388,608
    float* h1b = (float*)(Cr + 8388608);            // 8,388,608
    float* cc  = (float*)(Cr + 16777216);           // 12,582,912
    float* dec_init = (float*)(Cr + 29360128);      // 65,536
    float* pgen  = (float*)(Cr + 29425664);         // 8,192
    float* copyp = (float*)(Cr + 29433856);         // 8,192
    float* pbuf  = (float*)(Cr + 29442048);         // 131,072
    float* h0g   = (float*)(Cr + 29573120);         // 65,536 (2x[B][D])
    float* h1g   = (float*)(Cr + 29638656);         // 65,536
    float* encg  = (float*)(Cr + 29704192);         // 65,536 (2buf x 2dir x B x H)
    int*   barDec = (int*)(Cr + 29769728);          // 16 KB
    int*   barEnc0 = (int*)(Cr + 29786112);         // 16 KB (2 dir regions x 4KB)
    int*   barEnc1 = (int*)(Cr + 29802496);         // 16 KB
    // total ≈ 144.90 MB

    hipMemsetAsync(barDec, 0, 49152, stream);       // zero all barrier regions

    auto pack = [&](const float* W, float4* P, int Hn, int K) {
        int total = Hn * K;
        hipLaunchKernelGGL(pack4_kernel, dim3((total + 255) / 256), dim3(256), 0, stream, W, P, Hn, K);
    };
    pack(eWih0f, pWih0f, H, E);
    pack(eWih0b, pWih0b, H, E);
    pack(eWih1f, pWih1f, H, D);
    pack(eWih1b, pWih1b, H, D);
    pack(dWih0, pdWih0, D, E);
    hipLaunchKernelGGL(packencM_k, dim3(4 * H * H / 256), dim3(256), 0, stream, eWhh0f, PMf0);
    hipLaunchKernelGGL(packencM_k, dim3(4 * H * H / 256), dim3(256), 0, stream, eWhh0b, PMb0);
    hipLaunchKernelGGL(packencM_k, dim3(4 * H * H / 256), dim3(256), 0, stream, eWhh1f, PMf1);
    hipLaunchKernelGGL(packencM_k, dim3(4 * H * H / 256), dim3(256), 0, stream, eWhh1b, PMb1);
    hipLaunchKernelGGL(packdecM_k, dim3(4 * D * D / 256), dim3(256), 0, stream, dWhh0, PM0);
    hipLaunchKernelGGL(packdecM2_k, dim3(8 * D * D / 256), dim3(256), 0, stream, dWih1, dWhh1, PM1);

    hipLaunchKernelGGL(enc0_gates2, dim3(S * B / 8), dim3(256), 0, stream,
                       input_ids, emb, pWih0f, eb0f, pWih0b, eb0b, G0f, G0b);
    hipLaunchKernelGGL(enc_pscan2, dim3(16), dim3(256), 0, stream,
                       G0f, G0b, PMf0, PMb0, h0f, h0b, dec_init, encg, barEnc0);
    hipLaunchKernelGGL(enc1_gates2, dim3(S * B / 8), dim3(256), 0, stream,
                       h0f, h0b, pWih1f, eb1f, pWih1b, eb1b, G0f, G0b);
    hipLaunchKernelGGL(enc_pscan2, dim3(16), dim3(256), 0, stream,
                       G0f, G0b, PMf1, PMb1, h1f, h1b, dec_init + B * D, encg, barEnc1);
    hipLaunchKernelGGL(dec0_gates2, dim3(T * B / 8), dim3(512), 0, stream,
                       target_ids, emb, pdWih0, db0, Gd0);
    hipLaunchKernelGGL(dec_mfma, dim3(32), dim3(256), 0, stream,
                       Gd0, PM0, PM1, db1, dec_init, h0g, h1g, h1d, barDec);
    hipLaunchKernelGGL(build_encht, dim3(B * 256), dim3(256), 0, stream, h1f, h1b, ench);
    hipLaunchKernelGGL(qproj, dim3(T * B), dim3(D), 0, stream, h1d, Wenc, Wdec, qe, qd);
    hipLaunchKernelGGL(escore, dim3(B * T), dim3(S), 0, stream, qe, ench, ew);
    hipLaunchKernelGGL(temporal_k, dim3((B * S + 255) / 256), dim3(256), 0, stream, ew);
    hipLaunchKernelGGL(attnctx, dim3(B * T), dim3(S), 0, stream,
                       ew, input_ids, target_ids, h1f, h1b, ectx, copyp);
    hipLaunchKernelGGL(decattn, dim3(B * T), dim3(T), 0, stream, qd, h1d, dctx);
    hipLaunchKernelGGL(concat_k, dim3(B * T), dim3(D), 0, stream,
                       h1d, ectx, dctx, sW, sb, cc, pgen);
    hipLaunchKernelGGL(outprojT_k, dim3(1000), dim3(256), 0, stream, emb, Wvoc, outT2);
    hipLaunchKernelGGL(vocab_mfma, dim3(256), dim3(512), 0, stream,
                       outT2, cc, ob, target_ids, pbuf);
    hipLaunchKernelGGL(combine_nll_k, dim3(B), dim3(T), 0, stream,
                       pbuf, target_ids, pgen, copyp, tlen, out);
}

// Round 11
// 6650.540 us; speedup vs baseline: 3.4598x; 1.0045x over previous
//
#include <hip/hip_runtime.h>
#include <hip/hip_bf16.h>
#include <math.h>

#define PAD_ID 0
#define UNK_ID 1
#define START_ID 2
#define END_ID 3

constexpr int B = 16, S = 512, T = 128, V = 32000, E = 128, H = 256, D = 512;
constexpr int C3 = 1536;        // 3*D
constexpr int VO = 31997;       // V-3
constexpr int JS = 32000;       // padded col count for outT2

typedef short short8 __attribute__((ext_vector_type(8)));
typedef float f32x4 __attribute__((ext_vector_type(4)));

__device__ __forceinline__ float sigm(float x) { return 1.0f / (1.0f + __expf(-x)); }
__device__ __forceinline__ short bf16s(float x) {
    __hip_bfloat16 h = __float2bfloat16(x);
    return *reinterpret_cast<short*>(&h);
}
__device__ __forceinline__ float bflo(unsigned int u) { return __uint_as_float(u << 16); }
__device__ __forceinline__ float bfhi(unsigned int u) { return __uint_as_float(u & 0xffff0000u); }

__device__ __forceinline__ float4 cload4(const float* p) {
    float4 v;
    asm volatile("global_load_dwordx4 %0, %1, off sc0 sc1" : "=v"(v) : "v"(p));
    return v;
}

__device__ __forceinline__ void astore(float* p, float v) {
    __hip_atomic_store(p, v, __ATOMIC_RELAXED, __HIP_MEMORY_SCOPE_AGENT);
}

__device__ __forceinline__ void st_bf8(ushort* dst, float4 a, float4 b) {
    short8 o;
    o[0] = bf16s(a.x); o[1] = bf16s(a.y); o[2] = bf16s(a.z); o[3] = bf16s(a.w);
    o[4] = bf16s(b.x); o[5] = bf16s(b.y); o[6] = bf16s(b.z); o[7] = bf16s(b.w);
    *(short8*)dst = o;
}

// ---------------- all-to-all grid barrier (relaxed coherent ops only)
__device__ __forceinline__ void aabar(int* flags, int nblk, int ep, int myidx) {
    asm volatile("s_waitcnt vmcnt(0)" ::: "memory");
    __syncthreads();
    int tid = threadIdx.x;
    if (tid == 0)
        __hip_atomic_store(flags + myidx * 16, ep, __ATOMIC_RELAXED, __HIP_MEMORY_SCOPE_AGENT);
    if (tid < 64) {
        for (int i = tid; i < nblk; i += 64)
            while (__hip_atomic_load(flags + i * 16, __ATOMIC_RELAXED, __HIP_MEMORY_SCOPE_AGENT) < ep)
                __builtin_amdgcn_s_sleep(1);
    }
    __syncthreads();
    asm volatile("" ::: "memory");
}

// ---------------- weight packing: W[4H][K] -> P[k][u] = float4 of 4 gates
__global__ void pack4_kernel(const float* __restrict__ W, float4* __restrict__ P, int Hn, int K) {
    int i = blockIdx.x * blockDim.x + threadIdx.x;
    if (i >= K * Hn) return;
    int k = i / Hn, u = i - k * Hn;
    float4 v;
    v.x = W[(size_t)(0 * Hn + u) * K + k];
    v.y = W[(size_t)(1 * Hn + u) * K + k];
    v.z = W[(size_t)(2 * Hn + u) * K + k];
    v.w = W[(size_t)(3 * Hn + u) * K + k];
    P[(size_t)k * Hn + u] = v;
}

// ---------------- MFMA-row pack (H=256 outputs): W[4H][K] -> P[row][k] bf16,
// row = (u>>3)*32 + g*8 + (u&7)
__global__ void packencMK_k(const float* __restrict__ W, ushort* __restrict__ P, int K) {
    int i = blockIdx.x * blockDim.x + threadIdx.x;
    if (i >= 4 * H * K) return;
    int k = i % K, row = i / K;
    int g = (row >> 3) & 3, ul = row & 7, uh = row >> 5;
    int u = uh * 8 + ul;
    P[i] = (ushort)bf16s(W[(size_t)(g * H + u) * K + k]);
}

// ---------------- decoder W0 pack for MFMA (row = bk*64 + g*16 + u%16)
__global__ void packdecM_k(const float* __restrict__ W, ushort* __restrict__ P) {
    int i = blockIdx.x * blockDim.x + threadIdx.x;
    if (i >= 4 * D * D) return;
    int k = i & 511, row = i >> 9;
    int g = (row >> 4) & 3, u = (row >> 6) * 16 + (row & 15);
    P[i] = (ushort)bf16s(W[(size_t)(g * D + u) * D + k]);
}

// ---------------- decoder layer1 pack: [W1i | W1h] -> PM1[row][1024] bf16
__global__ void packdecM2_k(const float* __restrict__ Wi, const float* __restrict__ Wh,
                            ushort* __restrict__ P) {
    int i = blockIdx.x * blockDim.x + threadIdx.x;
    if (i >= 4 * D * D * 2) return;
    int k = i & 1023, row = i >> 10;
    int g = (row >> 4) & 3, u = (row >> 6) * 16 + (row & 15);
    float v = (k < 512) ? Wi[(size_t)(g * D + u) * D + k]
                        : Wh[(size_t)(g * D + u) * D + (k - 512)];
    P[i] = (ushort)bf16s(v);
}

// ---------------- encoder layer-0 gates, tiled (8 rows/block). grid S*B/8, 256 thr.
__global__ void enc0_gates2(const int* __restrict__ ids, const float* __restrict__ emb,
                            const float4* __restrict__ Pf, const float* __restrict__ bf_,
                            const float4* __restrict__ Pb, const float* __restrict__ bb_,
                            float* __restrict__ Gf, float* __restrict__ Gb) {
    int n0 = blockIdx.x * 8;
    int u = threadIdx.x;
    __shared__ float xr[8][E];
    for (int i = u; i < 8 * E; i += 256) {
        int r = i >> 7, e = i & 127;
        int n = n0 + r, s = n / B, b = n - s * B;
        int tok = ids[b * S + s];
        if (tok >= V) tok = UNK_ID;
        xr[r][e] = emb[(size_t)tok * E + e];
    }
    __syncthreads();
#pragma unroll
    for (int dir = 0; dir < 2; dir++) {
        const float4* P = dir ? Pb : Pf;
        const float* bs = dir ? bb_ : bf_;
        float* G = dir ? Gb : Gf;
        float acc[8][4];
#pragma unroll
        for (int r = 0; r < 8; r++)
#pragma unroll
            for (int g = 0; g < 4; g++) acc[r][g] = 0.f;
#pragma unroll 4
        for (int k = 0; k < E; k++) {
            float4 w = P[k * H + u];
#pragma unroll
            for (int r = 0; r < 8; r++) {
                float x = xr[r][k];
                acc[r][0] += x * w.x; acc[r][1] += x * w.y;
                acc[r][2] += x * w.z; acc[r][3] += x * w.w;
            }
        }
        float b0 = bs[u], b1 = bs[H + u], b2 = bs[2 * H + u], b3 = bs[3 * H + u];
#pragma unroll
        for (int r = 0; r < 8; r++) {
            float* g = G + (size_t)(n0 + r) * (4 * H);
            g[u] = acc[r][0] + b0; g[H + u] = acc[r][1] + b1;
            g[2 * H + u] = acc[r][2] + b2; g[3 * H + u] = acc[r][3] + b3;
        }
    }
}

// ---------------- encoder layer-1 gates via MFMA. grid 256 = ns(16)*16 + dirb*8 + bk.
// 256 threads = 4 waves. Wave w holds 32 weight rows x 512 k as A-frags in registers.
// Loops 32 n-tiles (16 n each); X staged bf16 [16][520] LDS.
__global__ void __launch_bounds__(256) enc1g_mfma(
        const float* __restrict__ h0f, const float* __restrict__ h0b,
        const ushort* __restrict__ PMf, const ushort* __restrict__ PMb,
        const float* __restrict__ bf_, const float* __restrict__ bb_,
        float* __restrict__ Gf, float* __restrict__ Gb) {
    __shared__ __align__(16) ushort X[16 * 520];
    __shared__ float gs[4][32][17];
    __shared__ float bias_s[128];
    int bid = blockIdx.x;
    int dirb = (bid >> 3) & 1, bk = bid & 7, ns = bid >> 4;
    const ushort* PM = dirb ? PMb : PMf;
    const float* bs = dirb ? bb_ : bf_;
    float* G = dirb ? Gb : Gf;
    int tid = threadIdx.x;
    int lane = tid & 63, w = tid >> 6;
    int cl = lane & 15, hi = lane >> 4;

    // A-fragments (rows (bk*4+w)*32 .. +32, k 512) in registers
    short8 afr[2][16];
    {
        int rowbase = (bk * 4 + w) * 32;
#pragma unroll
        for (int mt = 0; mt < 2; mt++)
#pragma unroll
            for (int kt = 0; kt < 16; kt++)
                afr[mt][kt] = *(const short8*)(PM + (size_t)(rowbase + mt * 16 + cl) * 512 + kt * 32 + hi * 8);
    }
    if (tid < 128) {
        int g = (tid >> 3) & 3;
        int u = (bk * 4 + (tid >> 5)) * 8 + (tid & 7);
        bias_s[tid] = bs[g * H + u];
    }
    int nl = tid >> 4, kseg = tid & 15;
    int en = tid & 15, rgrp = tid >> 4;          // epilogue mapping
    for (int tt = 0; tt < 32; tt++) {
        int nt = ns * 32 + tt;
        __syncthreads();
        // stage X: n-tile 16 x 512 k -> bf16 LDS
        {
            int n = nt * 16 + nl;
            const float* src = (kseg < 8) ? (h0f + (size_t)n * H + kseg * 32)
                                          : (h0b + (size_t)n * H + (kseg - 8) * 32);
            float4 v0 = *(const float4*)(src), v1 = *(const float4*)(src + 4);
            float4 v2 = *(const float4*)(src + 8), v3 = *(const float4*)(src + 12);
            float4 v4 = *(const float4*)(src + 16), v5 = *(const float4*)(src + 20);
            float4 v6 = *(const float4*)(src + 24), v7 = *(const float4*)(src + 28);
            ushort* dst = X + nl * 520 + kseg * 32;
            st_bf8(dst, v0, v1); st_bf8(dst + 8, v2, v3);
            st_bf8(dst + 16, v4, v5); st_bf8(dst + 24, v6, v7);
        }
        __syncthreads();
        {
            f32x4 acc0 = {0.f, 0.f, 0.f, 0.f}, acc1 = {0.f, 0.f, 0.f, 0.f};
            const ushort* hp = X + cl * 520 + hi * 8;
#pragma unroll
            for (int kt = 0; kt < 16; kt++) {
                short8 bfr = *(const short8*)(hp + kt * 32);
                acc0 = __builtin_amdgcn_mfma_f32_16x16x32_bf16(afr[0][kt], bfr, acc0, 0, 0, 0);
                acc1 = __builtin_amdgcn_mfma_f32_16x16x32_bf16(afr[1][kt], bfr, acc1, 0, 0, 0);
            }
#pragma unroll
            for (int i = 0; i < 4; i++) {
                gs[w][hi * 4 + i][cl] = acc0[i];
                gs[w][16 + hi * 4 + i][cl] = acc1[i];
            }
        }
        __syncthreads();
        // epilogue: thread (rgrp, en): rows rgrp*8..+8 -> contiguous u, two float4 stores
        {
            int wv = rgrp >> 2, g = rgrp & 3;
            int u0 = (bk * 4 + wv) * 8;
            float* dst = G + (size_t)(nt * 16 + en) * 1024 + g * 256 + u0;
            float4 o0, o1;
            o0.x = gs[wv][g * 8 + 0][en] + bias_s[rgrp * 8 + 0];
            o0.y = gs[wv][g * 8 + 1][en] + bias_s[rgrp * 8 + 1];
            o0.z = gs[wv][g * 8 + 2][en] + bias_s[rgrp * 8 + 2];
            o0.w = gs[wv][g * 8 + 3][en] + bias_s[rgrp * 8 + 3];
            o1.x = gs[wv][g * 8 + 4][en] + bias_s[rgrp * 8 + 4];
            o1.y = gs[wv][g * 8 + 5][en] + bias_s[rgrp * 8 + 5];
            o1.z = gs[wv][g * 8 + 6][en] + bias_s[rgrp * 8 + 6];
            o1.w = gs[wv][g * 8 + 7][en] + bias_s[rgrp * 8 + 7];
            *(float4*)dst = o0;
            *(float4*)(dst + 4) = o1;
        }
    }
}

// ---------------- decoder layer-0 input gates, tiled (8 rows/block). grid T*B/8, 512 thr.
__global__ void dec0_gates2(const int* __restrict__ tgt, const float* __restrict__ emb,
                            const float4* __restrict__ P, const float* __restrict__ bias,
                            float* __restrict__ G) {
    int n0 = blockIdx.x * 8;
    int u = threadIdx.x;
    __shared__ float xr[8][E];
    for (int i = u; i < 8 * E; i += 512) {
        int r = i >> 7, e = i & 127;
        int n = n0 + r, t = n / B, b = n - t * B;
        int tok;
        if (t == 0) tok = START_ID;
        else { tok = tgt[b * T + (t - 1)]; if (tok >= V) tok = UNK_ID; }
        xr[r][e] = emb[(size_t)tok * E + e];
    }
    __syncthreads();
    float acc[8][4];
#pragma unroll
    for (int r = 0; r < 8; r++)
#pragma unroll
        for (int g = 0; g < 4; g++) acc[r][g] = 0.f;
#pragma unroll 4
    for (int k = 0; k < E; k++) {
        float4 w = P[k * D + u];
#pragma unroll
        for (int r = 0; r < 8; r++) {
            float x = xr[r][k];
            acc[r][0] += x * w.x; acc[r][1] += x * w.y;
            acc[r][2] += x * w.z; acc[r][3] += x * w.w;
        }
    }
    float b0 = bias[u], b1 = bias[D + u], b2 = bias[2 * D + u], b3 = bias[3 * D + u];
#pragma unroll
    for (int r = 0; r < 8; r++) {
        float* g = G + (size_t)(n0 + r) * (4 * D);
        g[u] = acc[r][0] + b0; g[D + u] = acc[r][1] + b1;
        g[2 * D + u] = acc[r][2] + b2; g[3 * D + u] = acc[r][3] + b3;
    }
}

// ---------------- MFMA encoder persistent scan. grid 16 = dir*8 + bk, 256 thr.
// ho writes delayed to after the barrier (out of the vmcnt(0) critical path).
__global__ void __launch_bounds__(256) enc_pscan2(
        const float* __restrict__ Gf, const float* __restrict__ Gb,
        const ushort* __restrict__ PMf, const ushort* __restrict__ PMb,
        float* __restrict__ hof, float* __restrict__ hob,
        float* __restrict__ hfin /* [B][2H] */,
        float* __restrict__ hg /* [2buf][2dir][B][H] f32 */, int* __restrict__ barbase) {
    __shared__ __align__(16) ushort hh[16 * 264];
    __shared__ float gs[4][32][17];
    int blk = blockIdx.x;
    int dirb = blk >> 3, bk = blk & 7;
    int* bar = barbase + dirb * 1024;
    const float* G = dirb ? Gb : Gf;
    const ushort* PM = dirb ? PMb : PMf;
    float* ho = dirb ? hob : hof;
    int tid = threadIdx.x;
    int lane = tid & 63, w = tid >> 6;
    int cl = lane & 15, hi = lane >> 4;

    short8 afr[2][8];
    {
        int rowbase = (bk * 4 + w) * 32;
#pragma unroll
        for (int mt = 0; mt < 2; mt++)
#pragma unroll
            for (int kt = 0; kt < 8; kt++)
                afr[mt][kt] = *(const short8*)(PM + (size_t)(rowbase + mt * 16 + cl) * 256 + kt * 32 + hi * 8);
    }
    int ub = tid & 31, bb = tid >> 5;
    int u_glob = bk * 32 + ub;
    int gsw = ub >> 3, ul = ub & 7;
    float c_a = 0.f, c_b = 0.f;
    astore(&hg[dirb * (B * H) + bb * H + u_glob], 0.f);
    astore(&hg[dirb * (B * H) + (bb + 8) * H + u_glob], 0.f);
    int ep = 1;
    aabar(bar, 8, ep, bk);

    for (int step = 0; step < S; step++) {
        int s = dirb ? (S - 1 - step) : step;
        int cur = step & 1;
        const float* gA = G + ((size_t)(s * B + bb)) * 1024 + u_glob;
        const float* gB = G + ((size_t)(s * B + bb + 8)) * 1024 + u_glob;
        float pa0 = gA[0], pa1 = gA[256], pa2 = gA[512], pa3 = gA[768];
        float pb0 = gB[0], pb1 = gB[256], pb2 = gB[512], pb3 = gB[768];
        {
            int sb = tid >> 4, kseg = tid & 15;
            const float* src = hg + cur * (2 * B * H) + dirb * (B * H) + sb * H + kseg * 16;
            float4 v0 = cload4(src), v1 = cload4(src + 4), v2 = cload4(src + 8), v3 = cload4(src + 12);
            asm volatile("s_waitcnt vmcnt(0)" ::: "memory");
            __builtin_amdgcn_sched_barrier(0);
            st_bf8(hh + sb * 264 + kseg * 16, v0, v1);
            st_bf8(hh + sb * 264 + kseg * 16 + 8, v2, v3);
        }
        __syncthreads();
        {
            f32x4 acc0 = {0.f, 0.f, 0.f, 0.f}, acc1 = {0.f, 0.f, 0.f, 0.f};
            const ushort* hp = hh + cl * 264 + hi * 8;
#pragma unroll
            for (int kt = 0; kt < 8; kt++) {
                short8 bfr = *(const short8*)(hp + kt * 32);
                acc0 = __builtin_amdgcn_mfma_f32_16x16x32_bf16(afr[0][kt], bfr, acc0, 0, 0, 0);
                acc1 = __builtin_amdgcn_mfma_f32_16x16x32_bf16(afr[1][kt], bfr, acc1, 0, 0, 0);
            }
#pragma unroll
            for (int i = 0; i < 4; i++) {
                gs[w][hi * 4 + i][cl] = acc0[i];
                gs[w][16 + hi * 4 + i][cl] = acc1[i];
            }
        }
        __syncthreads();
        float hA, hB;
        {
            float q0 = gs[gsw][0 + ul][bb];
            float q1 = gs[gsw][8 + ul][bb];
            float q2 = gs[gsw][16 + ul][bb];
            float q3 = gs[gsw][24 + ul][bb];
            float ig = sigm(pa0 + q0), fg = sigm(pa1 + q1), gt = tanhf(pa2 + q2), og = sigm(pa3 + q3);
            c_a = fg * c_a + ig * gt;
            hA = og * tanhf(c_a);
            q0 = gs[gsw][0 + ul][bb + 8];
            q1 = gs[gsw][8 + ul][bb + 8];
            q2 = gs[gsw][16 + ul][bb + 8];
            q3 = gs[gsw][24 + ul][bb + 8];
            ig = sigm(pb0 + q0); fg = sigm(pb1 + q1); gt = tanhf(pb2 + q2); og = sigm(pb3 + q3);
            c_b = fg * c_b + ig * gt;
            hB = og * tanhf(c_b);
            float* dst = hg + (cur ^ 1) * (2 * B * H) + dirb * (B * H);
            astore(&dst[bb * H + u_glob], hA);
            astore(&dst[(bb + 8) * H + u_glob], hB);
            if (step == S - 1) {
                hfin[bb * (2 * H) + dirb * H + u_glob] = hA;
                hfin[(bb + 8) * (2 * H) + dirb * H + u_glob] = hB;
            }
        }
        aabar(bar, 8, ++ep, bk);
        // delayed ho writes: drain cost lands in NEXT step's barrier, fully acked
        ho[((size_t)(s * B + bb)) * H + u_glob] = hA;
        ho[((size_t)(s * B + bb + 8)) * H + u_glob] = hB;
    }
}

// ---------------- MFMA decoder persistent 2-layer scan (R10, passing). grid 32, 256 thr.
__global__ void __launch_bounds__(256) dec_mfma(
        const float* __restrict__ G0, const ushort* __restrict__ PM0,
        const ushort* __restrict__ PM1, const float* __restrict__ b1,
        const float* __restrict__ hinit,
        float* __restrict__ h0g, float* __restrict__ h1g,
        float* __restrict__ h1out, int* __restrict__ bar) {
    __shared__ __align__(16) ushort hb[16 * 1032];
    __shared__ float gs[4][16][17];
    int tid = threadIdx.x;
    int bk = blockIdx.x;
    int lane = tid & 63, w = tid >> 6;
    int cl = lane & 15, hi = lane >> 4;

    short8 a0[16], a1[32];
    {
        const ushort* base0 = PM0 + (size_t)(bk * 64 + w * 16 + cl) * 512 + hi * 8;
#pragma unroll
        for (int kt = 0; kt < 16; kt++) a0[kt] = *(const short8*)(base0 + kt * 32);
        const ushort* base1 = PM1 + (size_t)(bk * 64 + w * 16 + cl) * 1024 + hi * 8;
#pragma unroll
        for (int kt = 0; kt < 32; kt++) a1[kt] = *(const short8*)(base1 + kt * 32);
    }
    int u_loc = tid & 15, b = tid >> 4;
    int u = bk * 16 + u_loc;
    float bi0 = b1[u], bi1 = b1[512 + u], bi2 = b1[1024 + u], bi3 = b1[1536 + u];
    float c0v = 0.f, c1v = 0.f;
    astore(&h0g[B * D + b * 512 + u], hinit[b * 512 + u]);
    astore(&h1g[B * D + b * 512 + u], hinit[B * D + b * 512 + u]);
    int ep = 1;
    aabar(bar, 32, ep, bk);

    int sb = tid >> 4, kseg = tid & 15;
    for (int t = 0; t < T; t++) {
        int cur = t & 1;
        {
            const float* src = h0g + (cur ^ 1) * (B * D) + sb * 512 + kseg * 32;
            float4 v0 = cload4(src),      v1 = cload4(src + 4),
                   v2 = cload4(src + 8),  v3 = cload4(src + 12),
                   v4 = cload4(src + 16), v5 = cload4(src + 20),
                   v6 = cload4(src + 24), v7 = cload4(src + 28);
            asm volatile("s_waitcnt vmcnt(0)" ::: "memory");
            __builtin_amdgcn_sched_barrier(0);
            ushort* dst = hb + sb * 1032 + kseg * 32;
            st_bf8(dst, v0, v1); st_bf8(dst + 8, v2, v3);
            st_bf8(dst + 16, v4, v5); st_bf8(dst + 24, v6, v7);
        }
        __syncthreads();
        {
            f32x4 acc = {0.f, 0.f, 0.f, 0.f};
            const ushort* hp = hb + cl * 1032 + hi * 8;
#pragma unroll
            for (int kt = 0; kt < 16; kt++) {
                short8 bfr = *(const short8*)(hp + kt * 32);
                acc = __builtin_amdgcn_mfma_f32_16x16x32_bf16(a0[kt], bfr, acc, 0, 0, 0);
            }
#pragma unroll
            for (int i = 0; i < 4; i++) gs[w][hi * 4 + i][cl] = acc[i];
        }
        __syncthreads();
        {
            const float* gg = G0 + ((size_t)(t * B + b)) * 2048 + u;
            float g0 = gg[0]    + gs[0][u_loc][b];
            float g1 = gg[512]  + gs[1][u_loc][b];
            float g2 = gg[1024] + gs[2][u_loc][b];
            float g3 = gg[1536] + gs[3][u_loc][b];
            float ig = sigm(g0), fg = sigm(g1), gt = tanhf(g2), og = sigm(g3);
            c0v = fg * c0v + ig * gt;
            astore(&h0g[cur * (B * D) + b * 512 + u], og * tanhf(c0v));
        }
        aabar(bar, 32, ++ep, bk);
        {
            const float* s0 = h0g + cur * (B * D) + sb * 512 + kseg * 32;
            float4 v0 = cload4(s0),      v1 = cload4(s0 + 4),
                   v2 = cload4(s0 + 8),  v3 = cload4(s0 + 12),
                   v4 = cload4(s0 + 16), v5 = cload4(s0 + 20),
                   v6 = cload4(s0 + 24), v7 = cload4(s0 + 28);
            asm volatile("s_waitcnt vmcnt(0)" ::: "memory");
            __builtin_amdgcn_sched_barrier(0);
            ushort* dst = hb + sb * 1032 + kseg * 32;
            st_bf8(dst, v0, v1); st_bf8(dst + 8, v2, v3);
            st_bf8(dst + 16, v4, v5); st_bf8(dst + 24, v6, v7);
            const float* s1 = h1g + (cur ^ 1) * (B * D) + sb * 512 + kseg * 32;
            v0 = cload4(s1);      v1 = cload4(s1 + 4);
            v2 = cload4(s1 + 8);  v3 = cload4(s1 + 12);
            v4 = cload4(s1 + 16); v5 = cload4(s1 + 20);
            v6 = cload4(s1 + 24); v7 = cload4(s1 + 28);
            asm volatile("s_waitcnt vmcnt(0)" ::: "memory");
            __builtin_amdgcn_sched_barrier(0);
            dst = hb + sb * 1032 + 512 + kseg * 32;
            st_bf8(dst, v0, v1); st_bf8(dst + 8, v2, v3);
            st_bf8(dst + 16, v4, v5); st_bf8(dst + 24, v6, v7);
        }
        __syncthreads();
        {
            f32x4 acc = {0.f, 0.f, 0.f, 0.f};
            const ushort* hp = hb + cl * 1032 + hi * 8;
#pragma unroll
            for (int kt = 0; kt < 32; kt++) {
                short8 bfr = *(const short8*)(hp + kt * 32);
                acc = __builtin_amdgcn_mfma_f32_16x16x32_bf16(a1[kt], bfr, acc, 0, 0, 0);
            }
#pragma unroll
            for (int i = 0; i < 4; i++) gs[w][hi * 4 + i][cl] = acc[i];
        }
        __syncthreads();
        {
            float g0 = bi0 + gs[0][u_loc][b];
            float g1 = bi1 + gs[1][u_loc][b];
            float g2 = bi2 + gs[2][u_loc][b];
            float g3 = bi3 + gs[3][u_loc][b];
            float ig = sigm(g0), fg = sigm(g1), gt = tanhf(g2), og = sigm(g3);
            c1v = fg * c1v + ig * gt;
            float h1n = og * tanhf(c1v);
            astore(&h1g[cur * (B * D) + b * 512 + u], h1n);
            h1out[((size_t)(t * B + b)) * 512 + u] = h1n;
        }
    }
}

// ---------------- transpose enc hidden to [b][k(512)][s]
__global__ void build_encht(const float* __restrict__ h1f, const float* __restrict__ h1b,
                            float* __restrict__ et) {
    int blk = blockIdx.x;
    int b = blk >> 8, rem = blk & 255;
    int kt = rem >> 4, st = rem & 15;
    int c = threadIdx.x & 31, r = threadIdx.x >> 5;
    __shared__ float tile[32][33];
#pragma unroll
    for (int i = 0; i < 4; i++) {
        int sl = r + i * 8;
        int s = st * 32 + sl;
        int k = kt * 32 + c;
        float v = (k < H) ? h1f[((size_t)(s * B + b)) * H + k]
                          : h1b[((size_t)(s * B + b)) * H + (k - H)];
        tile[c][sl] = v;
    }
    __syncthreads();
#pragma unroll
    for (int i = 0; i < 4; i++) {
        int kl = r + i * 8;
        et[(size_t)b * D * S + (size_t)(kt * 32 + kl) * S + st * 32 + c] = tile[kl][c];
    }
}

// ---------------- q projections. grid T*B, 512 threads
__global__ void qproj(const float* __restrict__ h1d, const float* __restrict__ Wenc,
                      const float* __restrict__ Wdec, float* __restrict__ qe, float* __restrict__ qd) {
    int n = blockIdx.x;
    int o = threadIdx.x;
    __shared__ float hr[D];
    hr[o] = h1d[(size_t)n * D + o];
    __syncthreads();
    float ae = 0.f, ad = 0.f;
#pragma unroll 4
    for (int k = 0; k < D; k++) {
        float hk = hr[k];
        ae += hk * Wenc[k * D + o];
        ad += hk * Wdec[k * D + o];
    }
    qe[(size_t)n * D + o] = ae;
    qd[(size_t)n * D + o] = ad;
}

// ---------------- e = exp(min(score,30)). grid B*T, 512 threads
__global__ void escore(const float* __restrict__ qe, const float* __restrict__ et,
                       float* __restrict__ ew) {
    int bt = blockIdx.x;
    int b = bt / T, t = bt - b * T;
    int sx = threadIdx.x;
    __shared__ float q[D];
    q[sx] = qe[((size_t)(t * B + b)) * D + sx];
    __syncthreads();
    float acc = 0.f;
    const float* eb = et + (size_t)b * D * S + sx;
#pragma unroll 4
    for (int k = 0; k < D; k++) { acc += q[k] * eb[0]; eb += S; }
    acc = fminf(acc, 30.0f);
    ew[(size_t)bt * S + sx] = __expf(acc);
}

// ---------------- temporal normalization (prefix over t)
__global__ void temporal_k(float* __restrict__ ew) {
    int i = blockIdx.x * blockDim.x + threadIdx.x;
    if (i >= B * S) return;
    int b = i / S, sx = i - b * S;
    float cum = 0.f;
    for (int t = 0; t < T; t++) {
        size_t idx = ((size_t)(b * T + t)) * S + sx;
        float v = ew[idx];
        ew[idx] = v / (t == 0 ? 1.0f : (cum + 1e-8f));
        cum += v;
    }
}

// ---------------- attention softmax + enc context + copy prob. grid B*T, 512 thr
__global__ void attnctx(const float* __restrict__ ew, const int* __restrict__ ids,
                        const int* __restrict__ tgt,
                        const float* __restrict__ h1f, const float* __restrict__ h1b,
                        float* __restrict__ ectx, float* __restrict__ copyp) {
    int bt = blockIdx.x;
    int b = bt / T, t = bt - b * T;
    int tid = threadIdx.x;
    __shared__ float aw[S];
    __shared__ float red[512];
    float v = ew[(size_t)bt * S + tid];
    int tok = ids[b * S + tid];
    bool pad = (tok == PAD_ID);
    float vm = pad ? -INFINITY : v;
    red[tid] = vm; __syncthreads();
    for (int w = 256; w > 0; w >>= 1) { if (tid < w) red[tid] = fmaxf(red[tid], red[tid + w]); __syncthreads(); }
    float m = red[0]; __syncthreads();
    float ex = pad ? 0.f : __expf(vm - m);
    red[tid] = ex; __syncthreads();
    for (int w = 256; w > 0; w >>= 1) { if (tid < w) red[tid] += red[tid + w]; __syncthreads(); }
    float Z = red[0]; __syncthreads();
    float a = ex / Z;
    aw[tid] = a;
    int nt = tgt[b * T + t];
    red[tid] = (tok == nt) ? a : 0.f; __syncthreads();
    for (int w = 256; w > 0; w >>= 1) { if (tid < w) red[tid] += red[tid + w]; __syncthreads(); }
    if (tid == 0) copyp[bt] = red[0];
    __syncthreads();
    int d = tid;
    const float* hp = (d < H) ? (h1f + (size_t)b * H + d) : (h1b + (size_t)b * H + (d - H));
    float acc = 0.f;
#pragma unroll 4
    for (int s2 = 0; s2 < S; s2++) { acc += aw[s2] * hp[0]; hp += B * H; }
    ectx[(size_t)bt * D + d] = acc;
}

// ---------------- intra-decoder attention. grid B*T, 128 threads
__global__ void decattn(const float* __restrict__ qd, const float* __restrict__ h1d,
                        float* __restrict__ dctx) {
    int bt = blockIdx.x;
    int b = bt / T, t = bt - b * T;
    int tid = threadIdx.x;
    __shared__ float q[D];
    __shared__ float wl[T];
    __shared__ float red[128];
    for (int i = tid; i < D; i += 128) q[i] = qd[((size_t)(t * B + b)) * D + i];
    __syncthreads();
    float sc = -INFINITY;
    if (tid < t) {
        const float* hu = h1d + ((size_t)(tid * B + b)) * D;
        float a = 0.f;
#pragma unroll 4
        for (int k = 0; k < D; k++) a += q[k] * hu[k];
        sc = a;
    }
    red[tid] = sc; __syncthreads();
    for (int w = 64; w > 0; w >>= 1) { if (tid < w) red[tid] = fmaxf(red[tid], red[tid + w]); __syncthreads(); }
    float m = red[0]; __syncthreads();
    float ex = (tid < t) ? __expf(sc - m) : 0.f;
    red[tid] = ex; __syncthreads();
    for (int w = 64; w > 0; w >>= 1) { if (tid < w) red[tid] += red[tid + w]; __syncthreads(); }
    float Z = red[0]; __syncthreads();
    wl[tid] = (t > 0) ? (ex / Z) : 0.f;
    __syncthreads();
    for (int d = tid; d < D; d += 128) {
        float acc = 0.f;
        for (int u = 0; u < t; u++) acc += wl[u] * h1d[((size_t)(u * B + b)) * D + d];
        dctx[(size_t)bt * D + d] = acc;
    }
}

// ---------------- concat + p_gen; writes bf16 ccb16 [row][1536]. grid B*T, 512 thr
__global__ void concat_k(const float* __restrict__ h1d, const float* __restrict__ ectx,
                         const float* __restrict__ dctx, const float* __restrict__ sW,
                         const float* __restrict__ sb, ushort* __restrict__ ccb16,
                         float* __restrict__ pgen) {
    int bt = blockIdx.x;
    int b = bt / T, t = bt - b * T;
    int d = threadIdx.x;
    __shared__ float red[512];
    float v0 = h1d[((size_t)(t * B + b)) * D + d];
    float v1 = ectx[(size_t)bt * D + d];
    float v2 = dctx[(size_t)bt * D + d];
    ushort* c = ccb16 + (size_t)bt * C3;
    c[d] = (ushort)bf16s(v0); c[D + d] = (ushort)bf16s(v1); c[2 * D + d] = (ushort)bf16s(v2);
    red[d] = v0 * sW[d] + v1 * sW[D + d] + v2 * sW[2 * D + d];
    __syncthreads();
    for (int w = 256; w > 0; w >>= 1) { if (d < w) red[d] += red[d + w]; __syncthreads(); }
    if (d == 0) pgen[bt] = 1.f / (1.f + __expf(-(red[0] + sb[0])));
}

// ---------------- out_proj, packed-k layout for MFMA B-fragments.
__global__ void outprojT_k(const float* __restrict__ emb, const float* __restrict__ Wvoc,
                           __hip_bfloat16* __restrict__ outT2) {
    int j0 = blockIdx.x * 32;
    int jl = threadIdx.x & 31, oq = threadIdx.x >> 5;
    __shared__ float er[32][E + 1];
    for (int i = threadIdx.x; i < 32 * E; i += 256) {
        int jj = i >> 7, e = i & 127;
        int j = j0 + jj;
        er[jj][e] = (j < VO) ? emb[(size_t)(3 + j) * E + e] : 0.f;
    }
    __syncthreads();
    int j = j0 + jl;
#pragma unroll 1
    for (int i = 0; i < 24; i++) {
        int o = oq * 24 + i;
        int k0 = o * 8;
        float acc[8];
#pragma unroll
        for (int kk = 0; kk < 8; kk++) acc[kk] = 0.f;
#pragma unroll 4
        for (int e = 0; e < E; e++) {
            float x = er[jl][e];
            float4 w0 = *(const float4*)(Wvoc + (size_t)e * C3 + k0);
            float4 w1 = *(const float4*)(Wvoc + (size_t)e * C3 + k0 + 4);
            acc[0] += x * w0.x; acc[1] += x * w0.y; acc[2] += x * w0.z; acc[3] += x * w0.w;
            acc[4] += x * w1.x; acc[5] += x * w1.y; acc[6] += x * w1.z; acc[7] += x * w1.w;
        }
        short8 v;
#pragma unroll
        for (int kk = 0; kk < 8; kk++) v[kk] = bf16s(tanhf(acc[kk]));
        *reinterpret_cast<short8*>((char*)outT2 + ((size_t)o * JS + j) * 16) = v;
    }
}

// ---------------- vocab GEMM via MFMA, M_tile=64, k-half As + fused softmax partials.
// grid 128 = q(0..3)*32 + rb(0..31). 512 threads = 8 waves (wr = wid>>2 in {0,1}, wc).
__global__ void __launch_bounds__(512) vocab_mfma2(
        const __hip_bfloat16* __restrict__ outT2, const ushort* __restrict__ ccb16,
        const float* __restrict__ ob, const int* __restrict__ tgt,
        float* __restrict__ pbuf) {
    __shared__ __align__(16) ushort As[64 * 768];        // one k-half, chunk-XOR swizzled
    __shared__ float wm[8][64], ws_[8][64], wg[8][64];
    __shared__ int jstar_s[64];
    int bid = blockIdx.x;
    int rb = bid & 31, q = bid >> 5;
    int row0 = rb * 64;
    int tid = threadIdx.x;

    if (tid < 64) {
        int nt = tgt[row0 + tid];
        int ix = nt - 3;
        ix = ix < 0 ? 0 : (ix > VO - 1 ? VO - 1 : ix);
        jstar_s[tid] = ix;
    }
    int lane = tid & 63, wid = tid >> 6;
    int wr = wid >> 2, wc = wid & 3;
    int cl = lane & 15, g = lane >> 4;
    int r7 = cl & 7;
    int rowA0 = wr * 32 + cl, rowA1 = rowA0 + 16;
    __syncthreads();
    int jst[8];
    float m[8], sacc[8], gl[8];
#pragma unroll
    for (int mm = 0; mm < 2; mm++)
#pragma unroll
        for (int i = 0; i < 4; i++) {
            int idx = mm * 4 + i;
            jst[idx] = jstar_s[wr * 32 + mm * 16 + g * 4 + i];
            m[idx] = -1e30f; sacc[idx] = 0.f; gl[idx] = -1e30f;
        }

    int jb0 = q * 8192;
    int jqend = (jb0 + 8192 < VO) ? jb0 + 8192 : VO;
    int nmt = (jqend - jb0 + 127) >> 7;
    int stc0 = (tid & 7) * 12;                           // staging: 12 chunks/thread
    int str = tid >> 3, str7 = str & 7;
    for (int ti = 0; ti < nmt; ti++) {
        int jA = jb0 + ti * 128 + wc * 32 + cl;
        f32x4 accA0 = {0.f, 0.f, 0.f, 0.f}, accA1 = {0.f, 0.f, 0.f, 0.f};
        f32x4 accB0 = {0.f, 0.f, 0.f, 0.f}, accB1 = {0.f, 0.f, 0.f, 0.f};
#pragma unroll
        for (int half = 0; half < 2; half++) {
            __syncthreads();
            {
                const ushort* src = ccb16 + (size_t)(row0 + str) * C3 + half * 768;
                ushort* dst = As + str * 768;
#pragma unroll
                for (int ii = 0; ii < 12; ii++) {
                    int c = stc0 + ii;
                    *(short8*)(dst + ((c ^ str7) << 3)) = *(const short8*)(src + c * 8);
                }
            }
            __syncthreads();
            const char* pB = (const char*)outT2 + ((size_t)g * JS + jA) * 16
                           + (size_t)(half * 96) * JS * 16;
            const ushort* A0 = As + rowA0 * 768;
            const ushort* A1 = As + rowA1 * 768;
#pragma unroll
            for (int s = 0; s < 24; s++) {
                int c = s * 4 + g;
                short8 a0 = *(const short8*)(A0 + ((c ^ r7) << 3));
                short8 a1 = *(const short8*)(A1 + ((c ^ r7) << 3));
                short8 b0 = *(const short8*)(pB + (size_t)s * (4 * JS * 16));
                short8 b1 = *(const short8*)(pB + (size_t)s * (4 * JS * 16) + 256);
                accA0 = __builtin_amdgcn_mfma_f32_16x16x32_bf16(a0, b0, accA0, 0, 0, 0);
                accA1 = __builtin_amdgcn_mfma_f32_16x16x32_bf16(a0, b1, accA1, 0, 0, 0);
                accB0 = __builtin_amdgcn_mfma_f32_16x16x32_bf16(a1, b0, accB0, 0, 0, 0);
                accB1 = __builtin_amdgcn_mfma_f32_16x16x32_bf16(a1, b1, accB1, 0, 0, 0);
            }
        }
#pragma unroll
        for (int X = 0; X < 2; X++) {
            int j = jA + X * 16;
            if (j < jqend) {
                float obj = ob[j];
#pragma unroll
                for (int mm = 0; mm < 2; mm++)
#pragma unroll
                    for (int i = 0; i < 4; i++) {
                        int idx = mm * 4 + i;
                        float L;
                        if (mm == 0) L = (X ? accA1[i] : accA0[i]) + obj;
                        else         L = (X ? accB1[i] : accB0[i]) + obj;
                        if (j == jst[idx]) gl[idx] = L;
                        float mn = fmaxf(m[idx], L);
                        sacc[idx] = sacc[idx] * __expf(m[idx] - mn) + __expf(L - mn);
                        m[idx] = mn;
                    }
            }
        }
    }

#pragma unroll
    for (int idx = 0; idx < 8; idx++) {
        for (int mask = 1; mask < 16; mask <<= 1) {
            float om = __shfl_xor(m[idx], mask);
            float os = __shfl_xor(sacc[idx], mask);
            float mn = fmaxf(m[idx], om);
            sacc[idx] = sacc[idx] * __expf(m[idx] - mn) + os * __expf(om - mn);
            m[idx] = mn;
            gl[idx] = fmaxf(gl[idx], __shfl_xor(gl[idx], mask));
        }
    }
    if (cl == 0) {
#pragma unroll
        for (int idx = 0; idx < 8; idx++) {
            int rl = wr * 32 + (idx >> 2) * 16 + g * 4 + (idx & 3);
            wm[wid][rl] = m[idx]; ws_[wid][rl] = sacc[idx]; wg[wid][rl] = gl[idx];
        }
    }
    __syncthreads();
    if (tid < 64) {
        float M = -1e30f, SS = 0.f, GL = -1e30f;
        int w0 = ((tid >> 5) & 1) * 4;
#pragma unroll
        for (int w = 0; w < 4; w++) {
            float mq = wm[w0 + w][tid], sq = ws_[w0 + w][tid], gq = wg[w0 + w][tid];
            float mn = fmaxf(M, mq);
            SS = SS * __expf(M - mn) + sq * __expf(mq - mn);
            M = mn;
            GL = fmaxf(GL, gq);
        }
        float* o = pbuf + ((size_t)bid * 64 + tid) * 4;
        o[0] = M; o[1] = SS; o[2] = GL;
    }
}

// ---------------- combine quarter-partials + pointer mix + NLL. grid B, 128 threads.
__global__ void combine_nll_k(const float* __restrict__ pbuf, const int* __restrict__ tgt,
                              const float* __restrict__ pgen, const float* __restrict__ copyp,
                              const int* __restrict__ tlen, float* __restrict__ out) {
    int b = blockIdx.x, t = threadIdx.x;
    int row = b * T + t;
    int rb = row >> 6, r = row & 63;
    float M = -1e30f, SS = 0.f, GL = -1e30f;
#pragma unroll
    for (int q = 0; q < 4; q++) {
        const float* p = pbuf + ((size_t)(q * 32 + rb) * 64 + r) * 4;
        float mq = p[0], sq = p[1], gq = p[2];
        float mn = fmaxf(M, mq);
        SS = SS * __expf(M - mn) + sq * __expf(mq - mn);
        M = mn;
        GL = fmaxf(GL, gq);
    }
    int nt = tgt[row];
    float genp = (nt >= 3 && nt < V) ? __expf(GL - M) / SS : 0.f;
    float pg = pgen[row];
    float p = pg * genp + (1.f - pg) * copyp[row];
    __shared__ float red[128];
    red[t] = (t < tlen[b]) ? -logf(p + 1e-9f) : 0.f;
    __syncthreads();
    for (int w = 64; w > 0; w >>= 1) { if (t < w) red[t] += red[t + w]; __syncthreads(); }
    if (t == 0) out[b] = red[0];
}

extern "C" void kernel_launch(void* const* d_in, const int* in_sizes, int n_in,
                              void* d_out, int out_size, void* d_ws, size_t ws_size,
                              hipStream_t stream) {
    const int* input_ids = (const int*)d_in[0];
    const int* target_ids = (const int*)d_in[1];
    const int* tlen = (const int*)d_in[3];
    const float* emb = (const float*)d_in[5];
    const float* eWih0f = (const float*)d_in[6],  *eWhh0f = (const float*)d_in[7],  *eb0f = (const float*)d_in[8];
    const float* eWih0b = (const float*)d_in[9],  *eWhh0b = (const float*)d_in[10], *eb0b = (const float*)d_in[11];
    const float* eWih1f = (const float*)d_in[12], *eWhh1f = (const float*)d_in[13], *eb1f = (const float*)d_in[14];
    const float* eWih1b = (const float*)d_in[15], *eWhh1b = (const float*)d_in[16], *eb1b = (const float*)d_in[17];
    const float* dWih0 = (const float*)d_in[18], *dWhh0 = (const float*)d_in[19], *db0 = (const float*)d_in[20];
    const float* dWih1 = (const float*)d_in[21], *dWhh1 = (const float*)d_in[22], *db1 = (const float*)d_in[23];
    const float* Wenc = (const float*)d_in[24], *Wdec = (const float*)d_in[25];
    const float* Wvoc = (const float*)d_in[26], *sW = (const float*)d_in[27], *sb = (const float*)d_in[28];
    const float* ob = (const float*)d_in[29];
    float* out = (float*)d_out;
    (void)ws_size; (void)n_in; (void)in_sizes; (void)out_size;

    // ============ workspace layout (~145 MB, phase-aliased) ============
    char* A = (char*)d_ws;
    float4* pWih0f = (float4*)(A + 0);              //  512 KB f32 gate-packed
    float4* pWih0b = (float4*)(A + 524288);
    ushort* PMW1f  = (ushort*)(A + 1048576);        //  1 MB bf16 MFMA pack (enc1 Wih f)
    ushort* PMW1b  = (ushort*)(A + 2097152);        //  1 MB
    float4* pdWih0 = (float4*)(A + 5242880);        //  1 MB
    ushort* PMf0  = (ushort*)(A + 6291456);         //  512 KB bf16 MFMA-row packed (Whh)
    ushort* PMb0  = (ushort*)(A + 6815744);
    ushort* PMf1  = (ushort*)(A + 7340032);
    ushort* PMb1  = (ushort*)(A + 7864320);
    ushort* PM0   = (ushort*)(A + 8388608);         //  2 MB dec layer0 MFMA pack
    ushort* PM1   = (ushort*)(A + 10485760);        //  4 MB dec layer1 MFMA pack
    float* G0f = (float*)(A + 23068672);
    float* G0b = (float*)(A + 56623104);
    float* Gd0 = (float*)(A + 23068672);            // aliases G0f (dead after enc scans)
    float* ench = (float*)(A + 39845888);
    float* ectx = (float*)(A + 56623104);
    float* dctx = (float*)(A + 60817408);
    __hip_bfloat16* outT2 = (__hip_bfloat16*)A;     // whole region, after concat_k

    char* Bh = A + 98304000;
    float* h0f = (float*)(Bh + 0);
    float* h0b = (float*)(Bh + 8388608);
    float* h1d = (float*)(Bh + 0);                  // aliases h0f (dead after enc1 gates)
    float* qe  = (float*)(Bh + 4194304);
    float* qd  = (float*)(Bh + 8388608);
    float* ew  = (float*)(Bh + 12582912);
    char* Cr = Bh + 16777216;
    float* h1f = (float*)(Cr + 0);                  // 8,388,608
    float* h1b = (float*)(Cr + 8388608);            // 8,388,608
    ushort* ccb16 = (ushort*)(Cr + 16777216);       // 6,291,456 (bf16 concat rows)
    float* dec_init = (float*)(Cr + 29360128);      // 65,536
    float* pgen  = (float*)(Cr + 29425664);         // 8,192
    float* copyp = (float*)(Cr + 29433856);         // 8,192
    float* pbuf  = (float*)(Cr + 29442048);         // 131,072
    float* h0g   = (float*)(Cr + 29573120);         // 65,536
    float* h1g   = (float*)(Cr + 29638656);         // 65,536
    float* encg  = (float*)(Cr + 29704192);         // 65,536
    int*   barDec = (int*)(Cr + 29769728);          // 16 KB
    int*   barEnc0 = (int*)(Cr + 29786112);         // 16 KB
    int*   barEnc1 = (int*)(Cr + 29802496);         // 16 KB
    // total ≈ 144.90 MB

    hipMemsetAsync(barDec, 0, 49152, stream);

    auto pack = [&](const float* W, float4* P, int Hn, int K) {
        int total = Hn * K;
        hipLaunchKernelGGL(pack4_kernel, dim3((total + 255) / 256), dim3(256), 0, stream, W, P, Hn, K);
    };
    pack(eWih0f, pWih0f, H, E);
    pack(eWih0b, pWih0b, H, E);
    pack(dWih0, pdWih0, D, E);
    hipLaunchKernelGGL(packencMK_k, dim3(4 * H * 256 / 256), dim3(256), 0, stream, eWhh0f, PMf0, 256);
    hipLaunchKernelGGL(packencMK_k, dim3(4 * H * 256 / 256), dim3(256), 0, stream, eWhh0b, PMb0, 256);
    hipLaunchKernelGGL(packencMK_k, dim3(4 * H * 256 / 256), dim3(256), 0, stream, eWhh1f, PMf1, 256);
    hipLaunchKernelGGL(packencMK_k, dim3(4 * H * 256 / 256), dim3(256), 0, stream, eWhh1b, PMb1, 256);
    hipLaunchKernelGGL(packencMK_k, dim3(4 * H * 512 / 256), dim3(256), 0, stream, eWih1f, PMW1f, 512);
    hipLaunchKernelGGL(packencMK_k, dim3(4 * H * 512 / 256), dim3(256), 0, stream, eWih1b, PMW1b, 512);
    hipLaunchKernelGGL(packdecM_k, dim3(4 * D * D / 256), dim3(256), 0, stream, dWhh0, PM0);
    hipLaunchKernelGGL(packdecM2_k, dim3(8 * D * D / 256), dim3(256), 0, stream, dWih1, dWhh1, PM1);

    hipLaunchKernelGGL(enc0_gates2, dim3(S * B / 8), dim3(256), 0, stream,
                       input_ids, emb, pWih0f, eb0f, pWih0b, eb0b, G0f, G0b);
    hipLaunchKernelGGL(enc_pscan2, dim3(16), dim3(256), 0, stream,
                       G0f, G0b, PMf0, PMb0, h0f, h0b, dec_init, encg, barEnc0);
    hipLaunchKernelGGL(enc1g_mfma, dim3(256), dim3(256), 0, stream,
                       h0f, h0b, PMW1f, PMW1b, eb1f, eb1b, G0f, G0b);
    hipLaunchKernelGGL(enc_pscan2, dim3(16), dim3(256), 0, stream,
                       G0f, G0b, PMf1, PMb1, h1f, h1b, dec_init + B * D, encg, barEnc1);
    hipLaunchKernelGGL(dec0_gates2, dim3(T * B / 8), dim3(512), 0, stream,
                       target_ids, emb, pdWih0, db0, Gd0);
    hipLaunchKernelGGL(dec_mfma, dim3(32), dim3(256), 0, stream,
                       Gd0, PM0, PM1, db1, dec_init, h0g, h1g, h1d, barDec);
    hipLaunchKernelGGL(build_encht, dim3(B * 256), dim3(256), 0, stream, h1f, h1b, ench);
    hipLaunchKernelGGL(qproj, dim3(T * B), dim3(D), 0, stream, h1d, Wenc, Wdec, qe, qd);
    hipLaunchKernelGGL(escore, dim3(B * T), dim3(S), 0, stream, qe, ench, ew);
    hipLaunchKernelGGL(temporal_k, dim3((B * S + 255) / 256), dim3(256), 0, stream, ew);
    hipLaunchKernelGGL(attnctx, dim3(B * T), dim3(S), 0, stream,
                       ew, input_ids, target_ids, h1f, h1b, ectx, copyp);
    hipLaunchKernelGGL(decattn, dim3(B * T), dim3(T), 0, stream, qd, h1d, dctx);
    hipLaunchKernelGGL(concat_k, dim3(B * T), dim3(D), 0, stream,
                       h1d, ectx, dctx, sW, sb, ccb16, pgen);
    hipLaunchKernelGGL(outprojT_k, dim3(1000), dim3(256), 0, stream, emb, Wvoc, outT2);
    hipLaunchKernelGGL(vocab_mfma2, dim3(128), dim3(512), 0, stream,
                       outT2, ccb16, ob, target_ids, pbuf);
    hipLaunchKernelGGL(combine_nll_k, dim3(B), dim3(T), 0, stream,
                       pbuf, target_ids, pgen, copyp, tlen, out);
}

// Round 12
// 5745.484 us; speedup vs baseline: 4.0048x; 1.1575x over previous
//
#include <hip/hip_runtime.h>
#include <hip/hip_bf16.h>
#include <math.h>

#define PAD_ID 0
#define UNK_ID 1
#define START_ID 2
#define END_ID 3

constexpr int B = 16, S = 512, T = 128, V = 32000, E = 128, H = 256, D = 512;
constexpr int C3 = 1536;        // 3*D
constexpr int VO = 31997;       // V-3
constexpr int JS = 32000;       // padded col count for outT2

typedef short short8 __attribute__((ext_vector_type(8)));
typedef float f32x4 __attribute__((ext_vector_type(4)));

__device__ __forceinline__ float sigm(float x) { return 1.0f / (1.0f + __expf(-x)); }
__device__ __forceinline__ short bf16s(float x) {
    __hip_bfloat16 h = __float2bfloat16(x);
    return *reinterpret_cast<short*>(&h);
}

__device__ __forceinline__ uint4 cloadu4(const uint* p) {
    uint4 v;
    asm volatile("global_load_dwordx4 %0, %1, off sc0 sc1" : "=v"(v) : "v"(p));
    return v;
}
__device__ __forceinline__ void pstore(uint* p, uint v) {
    __hip_atomic_store(p, v, __ATOMIC_RELAXED, __HIP_MEMORY_SCOPE_AGENT);
}

__device__ __forceinline__ void st_bf8(ushort* dst, float4 a, float4 b) {
    short8 o;
    o[0] = bf16s(a.x); o[1] = bf16s(a.y); o[2] = bf16s(a.z); o[3] = bf16s(a.w);
    o[4] = bf16s(b.x); o[5] = bf16s(b.y); o[6] = bf16s(b.z); o[7] = bf16s(b.w);
    *(short8*)dst = o;
}

// ---------------- poll 16 packets (4 dwordx4) tagged e; write 16 bf16 to dst
__device__ __forceinline__ void poll_stage16(const uint* src, uint e, ushort* dst) {
    uint4 a0, a1, a2, a3;
    for (;;) {
        a0 = cloadu4(src); a1 = cloadu4(src + 4); a2 = cloadu4(src + 8); a3 = cloadu4(src + 12);
        asm volatile("s_waitcnt vmcnt(0)" ::: "memory");
        __builtin_amdgcn_sched_barrier(0);
        uint d = (a0.x ^ e) | (a0.y ^ e) | (a0.z ^ e) | (a0.w ^ e)
               | (a1.x ^ e) | (a1.y ^ e) | (a1.z ^ e) | (a1.w ^ e)
               | (a2.x ^ e) | (a2.y ^ e) | (a2.z ^ e) | (a2.w ^ e)
               | (a3.x ^ e) | (a3.y ^ e) | (a3.z ^ e) | (a3.w ^ e);
        if ((d & 0xffffu) == 0) break;
        __builtin_amdgcn_s_sleep(1);
    }
    short8 o0, o1;
    o0[0] = (short)(a0.x >> 16); o0[1] = (short)(a0.y >> 16); o0[2] = (short)(a0.z >> 16); o0[3] = (short)(a0.w >> 16);
    o0[4] = (short)(a1.x >> 16); o0[5] = (short)(a1.y >> 16); o0[6] = (short)(a1.z >> 16); o0[7] = (short)(a1.w >> 16);
    o1[0] = (short)(a2.x >> 16); o1[1] = (short)(a2.y >> 16); o1[2] = (short)(a2.z >> 16); o1[3] = (short)(a2.w >> 16);
    o1[4] = (short)(a3.x >> 16); o1[5] = (short)(a3.y >> 16); o1[6] = (short)(a3.z >> 16); o1[7] = (short)(a3.w >> 16);
    *(short8*)dst = o0;
    *(short8*)(dst + 8) = o1;
}

// ---------------- poll 32 packets (8 dwordx4) tagged e; write 32 bf16 to dst
__device__ __forceinline__ void poll_stage32(const uint* src, uint e, ushort* dst) {
    uint4 a[8];
    for (;;) {
#pragma unroll
        for (int i = 0; i < 8; i++) a[i] = cloadu4(src + i * 4);
        asm volatile("s_waitcnt vmcnt(0)" ::: "memory");
        __builtin_amdgcn_sched_barrier(0);
        uint d = 0;
#pragma unroll
        for (int i = 0; i < 8; i++)
            d |= (a[i].x ^ e) | (a[i].y ^ e) | (a[i].z ^ e) | (a[i].w ^ e);
        if ((d & 0xffffu) == 0) break;
        __builtin_amdgcn_s_sleep(1);
    }
#pragma unroll
    for (int i = 0; i < 8; i += 2) {
        short8 o;
        o[0] = (short)(a[i].x >> 16);     o[1] = (short)(a[i].y >> 16);
        o[2] = (short)(a[i].z >> 16);     o[3] = (short)(a[i].w >> 16);
        o[4] = (short)(a[i + 1].x >> 16); o[5] = (short)(a[i + 1].y >> 16);
        o[6] = (short)(a[i + 1].z >> 16); o[7] = (short)(a[i + 1].w >> 16);
        *(short8*)(dst + i * 4) = o;
    }
}

// ---------------- weight packing: W[4H][K] -> P[k][u] = float4 of 4 gates
__global__ void pack4_kernel(const float* __restrict__ W, float4* __restrict__ P, int Hn, int K) {
    int i = blockIdx.x * blockDim.x + threadIdx.x;
    if (i >= K * Hn) return;
    int k = i / Hn, u = i - k * Hn;
    float4 v;
    v.x = W[(size_t)(0 * Hn + u) * K + k];
    v.y = W[(size_t)(1 * Hn + u) * K + k];
    v.z = W[(size_t)(2 * Hn + u) * K + k];
    v.w = W[(size_t)(3 * Hn + u) * K + k];
    P[(size_t)k * Hn + u] = v;
}

// ---------------- MFMA-row pack (H=256 outputs): row = (u>>3)*32 + g*8 + (u&7)
__global__ void packencMK_k(const float* __restrict__ W, ushort* __restrict__ P, int K) {
    int i = blockIdx.x * blockDim.x + threadIdx.x;
    if (i >= 4 * H * K) return;
    int k = i % K, row = i / K;
    int g = (row >> 3) & 3, ul = row & 7, uh = row >> 5;
    int u = uh * 8 + ul;
    P[i] = (ushort)bf16s(W[(size_t)(g * H + u) * K + k]);
}

// ---------------- decoder W0 pack for MFMA (row = bk*64 + g*16 + u%16)
__global__ void packdecM_k(const float* __restrict__ W, ushort* __restrict__ P) {
    int i = blockIdx.x * blockDim.x + threadIdx.x;
    if (i >= 4 * D * D) return;
    int k = i & 511, row = i >> 9;
    int g = (row >> 4) & 3, u = (row >> 6) * 16 + (row & 15);
    P[i] = (ushort)bf16s(W[(size_t)(g * D + u) * D + k]);
}

// ---------------- decoder layer1 pack: [W1i | W1h] -> PM1[row][1024] bf16
__global__ void packdecM2_k(const float* __restrict__ Wi, const float* __restrict__ Wh,
                            ushort* __restrict__ P) {
    int i = blockIdx.x * blockDim.x + threadIdx.x;
    if (i >= 4 * D * D * 2) return;
    int k = i & 1023, row = i >> 10;
    int g = (row >> 4) & 3, u = (row >> 6) * 16 + (row & 15);
    float v = (k < 512) ? Wi[(size_t)(g * D + u) * D + k]
                        : Wh[(size_t)(g * D + u) * D + (k - 512)];
    P[i] = (ushort)bf16s(v);
}

// ---------------- encoder layer-0 gates, tiled (8 rows/block). grid S*B/8, 256 thr.
__global__ void enc0_gates2(const int* __restrict__ ids, const float* __restrict__ emb,
                            const float4* __restrict__ Pf, const float* __restrict__ bf_,
                            const float4* __restrict__ Pb, const float* __restrict__ bb_,
                            float* __restrict__ Gf, float* __restrict__ Gb) {
    int n0 = blockIdx.x * 8;
    int u = threadIdx.x;
    __shared__ float xr[8][E];
    for (int i = u; i < 8 * E; i += 256) {
        int r = i >> 7, e = i & 127;
        int n = n0 + r, s = n / B, b = n - s * B;
        int tok = ids[b * S + s];
        if (tok >= V) tok = UNK_ID;
        xr[r][e] = emb[(size_t)tok * E + e];
    }
    __syncthreads();
#pragma unroll
    for (int dir = 0; dir < 2; dir++) {
        const float4* P = dir ? Pb : Pf;
        const float* bs = dir ? bb_ : bf_;
        float* G = dir ? Gb : Gf;
        float acc[8][4];
#pragma unroll
        for (int r = 0; r < 8; r++)
#pragma unroll
            for (int g = 0; g < 4; g++) acc[r][g] = 0.f;
#pragma unroll 4
        for (int k = 0; k < E; k++) {
            float4 w = P[k * H + u];
#pragma unroll
            for (int r = 0; r < 8; r++) {
                float x = xr[r][k];
                acc[r][0] += x * w.x; acc[r][1] += x * w.y;
                acc[r][2] += x * w.z; acc[r][3] += x * w.w;
            }
        }
        float b0 = bs[u], b1 = bs[H + u], b2 = bs[2 * H + u], b3 = bs[3 * H + u];
#pragma unroll
        for (int r = 0; r < 8; r++) {
            float* g = G + (size_t)(n0 + r) * (4 * H);
            g[u] = acc[r][0] + b0; g[H + u] = acc[r][1] + b1;
            g[2 * H + u] = acc[r][2] + b2; g[3 * H + u] = acc[r][3] + b3;
        }
    }
}

// ---------------- encoder layer-1 gates via MFMA (R11, passing). grid 256, 256 thr.
__global__ void __launch_bounds__(256) enc1g_mfma(
        const float* __restrict__ h0f, const float* __restrict__ h0b,
        const ushort* __restrict__ PMf, const ushort* __restrict__ PMb,
        const float* __restrict__ bf_, const float* __restrict__ bb_,
        float* __restrict__ Gf, float* __restrict__ Gb) {
    __shared__ __align__(16) ushort X[16 * 520];
    __shared__ float gs[4][32][17];
    __shared__ float bias_s[128];
    int bid = blockIdx.x;
    int dirb = (bid >> 3) & 1, bk = bid & 7, ns = bid >> 4;
    const ushort* PM = dirb ? PMb : PMf;
    const float* bs = dirb ? bb_ : bf_;
    float* G = dirb ? Gb : Gf;
    int tid = threadIdx.x;
    int lane = tid & 63, w = tid >> 6;
    int cl = lane & 15, hi = lane >> 4;

    short8 afr[2][16];
    {
        int rowbase = (bk * 4 + w) * 32;
#pragma unroll
        for (int mt = 0; mt < 2; mt++)
#pragma unroll
            for (int kt = 0; kt < 16; kt++)
                afr[mt][kt] = *(const short8*)(PM + (size_t)(rowbase + mt * 16 + cl) * 512 + kt * 32 + hi * 8);
    }
    if (tid < 128) {
        int g = (tid >> 3) & 3;
        int u = (bk * 4 + (tid >> 5)) * 8 + (tid & 7);
        bias_s[tid] = bs[g * H + u];
    }
    int nl = tid >> 4, kseg = tid & 15;
    int en = tid & 15, rgrp = tid >> 4;
    for (int tt = 0; tt < 32; tt++) {
        int nt = ns * 32 + tt;
        __syncthreads();
        {
            int n = nt * 16 + nl;
            const float* src = (kseg < 8) ? (h0f + (size_t)n * H + kseg * 32)
                                          : (h0b + (size_t)n * H + (kseg - 8) * 32);
            float4 v0 = *(const float4*)(src), v1 = *(const float4*)(src + 4);
            float4 v2 = *(const float4*)(src + 8), v3 = *(const float4*)(src + 12);
            float4 v4 = *(const float4*)(src + 16), v5 = *(const float4*)(src + 20);
            float4 v6 = *(const float4*)(src + 24), v7 = *(const float4*)(src + 28);
            ushort* dst = X + nl * 520 + kseg * 32;
            st_bf8(dst, v0, v1); st_bf8(dst + 8, v2, v3);
            st_bf8(dst + 16, v4, v5); st_bf8(dst + 24, v6, v7);
        }
        __syncthreads();
        {
            f32x4 acc0 = {0.f, 0.f, 0.f, 0.f}, acc1 = {0.f, 0.f, 0.f, 0.f};
            const ushort* hp = X + cl * 520 + hi * 8;
#pragma unroll
            for (int kt = 0; kt < 16; kt++) {
                short8 bfr = *(const short8*)(hp + kt * 32);
                acc0 = __builtin_amdgcn_mfma_f32_16x16x32_bf16(afr[0][kt], bfr, acc0, 0, 0, 0);
                acc1 = __builtin_amdgcn_mfma_f32_16x16x32_bf16(afr[1][kt], bfr, acc1, 0, 0, 0);
            }
#pragma unroll
            for (int i = 0; i < 4; i++) {
                gs[w][hi * 4 + i][cl] = acc0[i];
                gs[w][16 + hi * 4 + i][cl] = acc1[i];
            }
        }
        __syncthreads();
        {
            int wv = rgrp >> 2, g = rgrp & 3;
            int u0 = (bk * 4 + wv) * 8;
            float* dst = G + (size_t)(nt * 16 + en) * 1024 + g * 256 + u0;
            float4 o0, o1;
            o0.x = gs[wv][g * 8 + 0][en] + bias_s[rgrp * 8 + 0];
            o0.y = gs[wv][g * 8 + 1][en] + bias_s[rgrp * 8 + 1];
            o0.z = gs[wv][g * 8 + 2][en] + bias_s[rgrp * 8 + 2];
            o0.w = gs[wv][g * 8 + 3][en] + bias_s[rgrp * 8 + 3];
            o1.x = gs[wv][g * 8 + 4][en] + bias_s[rgrp * 8 + 4];
            o1.y = gs[wv][g * 8 + 5][en] + bias_s[rgrp * 8 + 5];
            o1.z = gs[wv][g * 8 + 6][en] + bias_s[rgrp * 8 + 6];
            o1.w = gs[wv][g * 8 + 7][en] + bias_s[rgrp * 8 + 7];
            *(float4*)dst = o0;
            *(float4*)(dst + 4) = o1;
        }
    }
}

// ---------------- decoder layer-0 input gates, tiled. grid T*B/8, 512 thr.
__global__ void dec0_gates2(const int* __restrict__ tgt, const float* __restrict__ emb,
                            const float4* __restrict__ P, const float* __restrict__ bias,
                            float* __restrict__ G) {
    int n0 = blockIdx.x * 8;
    int u = threadIdx.x;
    __shared__ float xr[8][E];
    for (int i = u; i < 8 * E; i += 512) {
        int r = i >> 7, e = i & 127;
        int n = n0 + r, t = n / B, b = n - t * B;
        int tok;
        if (t == 0) tok = START_ID;
        else { tok = tgt[b * T + (t - 1)]; if (tok >= V) tok = UNK_ID; }
        xr[r][e] = emb[(size_t)tok * E + e];
    }
    __syncthreads();
    float acc[8][4];
#pragma unroll
    for (int r = 0; r < 8; r++)
#pragma unroll
        for (int g = 0; g < 4; g++) acc[r][g] = 0.f;
#pragma unroll 4
    for (int k = 0; k < E; k++) {
        float4 w = P[k * D + u];
#pragma unroll
        for (int r = 0; r < 8; r++) {
            float x = xr[r][k];
            acc[r][0] += x * w.x; acc[r][1] += x * w.y;
            acc[r][2] += x * w.z; acc[r][3] += x * w.w;
        }
    }
    float b0 = bias[u], b1 = bias[D + u], b2 = bias[2 * D + u], b3 = bias[3 * D + u];
#pragma unroll
    for (int r = 0; r < 8; r++) {
        float* g = G + (size_t)(n0 + r) * (4 * D);
        g[u] = acc[r][0] + b0; g[D + u] = acc[r][1] + b1;
        g[2 * D + u] = acc[r][2] + b2; g[3 * D + u] = acc[r][3] + b3;
    }
}

// ---------------- MFMA encoder persistent scan, DATAFLOW sync (no barriers).
// grid 16 = dir*8 + bk, 256 thr. Packets: pk[parity][dir][4096] uint = bf16<<16 | tag.
// Tag of input-to-step-s = s. Memset(0) provides step-0 input (h=0, tag 0).
__global__ void __launch_bounds__(256) enc_pscan3(
        const float* __restrict__ Gf, const float* __restrict__ Gb,
        const ushort* __restrict__ PMf, const ushort* __restrict__ PMb,
        float* __restrict__ hof, float* __restrict__ hob,
        float* __restrict__ hfin /* [B][2H] */,
        uint* __restrict__ pk /* [2][2][4096] */) {
    __shared__ __align__(16) ushort hh[16 * 264];
    __shared__ float gs[4][32][17];
    int blk = blockIdx.x;
    int dirb = blk >> 3, bk = blk & 7;
    const float* G = dirb ? Gb : Gf;
    const ushort* PM = dirb ? PMb : PMf;
    float* ho = dirb ? hob : hof;
    int tid = threadIdx.x;
    int lane = tid & 63, w = tid >> 6;
    int cl = lane & 15, hi = lane >> 4;

    short8 afr[2][8];
    {
        int rowbase = (bk * 4 + w) * 32;
#pragma unroll
        for (int mt = 0; mt < 2; mt++)
#pragma unroll
            for (int kt = 0; kt < 8; kt++)
                afr[mt][kt] = *(const short8*)(PM + (size_t)(rowbase + mt * 16 + cl) * 256 + kt * 32 + hi * 8);
    }
    int ub = tid & 31, bb = tid >> 5;
    int u_glob = bk * 32 + ub;
    int gsw = ub >> 3, ul = ub & 7;
    float c_a = 0.f, c_b = 0.f;
    int b0s = tid >> 4, u0s = (tid & 15) * 16;          // staging coords

    for (int step = 0; step < S; step++) {
        int s = dirb ? (S - 1 - step) : step;
        int cur = step & 1;
        // G-bias prefetch (cached loads, latency hidden under the packet poll)
        const float* gA = G + ((size_t)(s * B + bb)) * 1024 + u_glob;
        const float* gB = G + ((size_t)(s * B + bb + 8)) * 1024 + u_glob;
        float pa0 = gA[0], pa1 = gA[256], pa2 = gA[512], pa3 = gA[768];
        float pb0 = gB[0], pb1 = gB[256], pb2 = gB[512], pb3 = gB[768];
        // poll-stage h packets (tag = step) directly into bf16 LDS
        poll_stage16(pk + cur * 8192 + dirb * 4096 + tid * 16,
                     (uint)step & 0xffffu, hh + b0s * 264 + u0s);
        __syncthreads();
        {
            f32x4 acc0 = {0.f, 0.f, 0.f, 0.f}, acc1 = {0.f, 0.f, 0.f, 0.f};
            const ushort* hp = hh + cl * 264 + hi * 8;
#pragma unroll
            for (int kt = 0; kt < 8; kt++) {
                short8 bfr = *(const short8*)(hp + kt * 32);
                acc0 = __builtin_amdgcn_mfma_f32_16x16x32_bf16(afr[0][kt], bfr, acc0, 0, 0, 0);
                acc1 = __builtin_amdgcn_mfma_f32_16x16x32_bf16(afr[1][kt], bfr, acc1, 0, 0, 0);
            }
#pragma unroll
            for (int i = 0; i < 4; i++) {
                gs[w][hi * 4 + i][cl] = acc0[i];
                gs[w][16 + hi * 4 + i][cl] = acc1[i];
            }
        }
        __syncthreads();
        {
            float q0 = gs[gsw][0 + ul][bb];
            float q1 = gs[gsw][8 + ul][bb];
            float q2 = gs[gsw][16 + ul][bb];
            float q3 = gs[gsw][24 + ul][bb];
            float ig = sigm(pa0 + q0), fg = sigm(pa1 + q1), gt = tanhf(pa2 + q2), og = sigm(pa3 + q3);
            c_a = fg * c_a + ig * gt;
            float hA = og * tanhf(c_a);
            q0 = gs[gsw][0 + ul][bb + 8];
            q1 = gs[gsw][8 + ul][bb + 8];
            q2 = gs[gsw][16 + ul][bb + 8];
            q3 = gs[gsw][24 + ul][bb + 8];
            ig = sigm(pb0 + q0); fg = sigm(pb1 + q1); gt = tanhf(pb2 + q2); og = sigm(pb3 + q3);
            c_b = fg * c_b + ig * gt;
            float hB = og * tanhf(c_b);
            uint tg = (uint)(step + 1) & 0xffffu;
            uint* dstp = pk + (cur ^ 1) * 8192 + dirb * 4096;
            pstore(&dstp[bb * 256 + u_glob], ((uint)(ushort)bf16s(hA) << 16) | tg);
            pstore(&dstp[(bb + 8) * 256 + u_glob], ((uint)(ushort)bf16s(hB) << 16) | tg);
            ho[((size_t)(s * B + bb)) * H + u_glob] = hA;
            ho[((size_t)(s * B + bb + 8)) * H + u_glob] = hB;
            if (step == S - 1) {
                hfin[bb * (2 * H) + dirb * H + u_glob] = hA;
                hfin[(bb + 8) * (2 * H) + dirb * H + u_glob] = hB;
            }
        }
        // no grid barrier — dataflow via packet tags
    }
}

// ---------------- decoder init packets (tag 1, parity 1)
__global__ void dec_initpk(const float* __restrict__ hinit,
                           uint* __restrict__ h0pk, uint* __restrict__ h1pk) {
    int i = blockIdx.x * blockDim.x + threadIdx.x;
    if (i >= B * D) return;
    pstore(&h0pk[8192 + i], ((uint)(ushort)bf16s(hinit[i]) << 16) | 1u);
    pstore(&h1pk[8192 + i], ((uint)(ushort)bf16s(hinit[B * D + i]) << 16) | 1u);
}

// ---------------- MFMA decoder persistent 2-layer scan, DATAFLOW sync.
// grid 32, 256 thr. h0pk/h1pk: [parity][8192] packets; tags: input-of-step-t = t+1.
__global__ void __launch_bounds__(256) dec_mfma2(
        const float* __restrict__ G0, const ushort* __restrict__ PM0,
        const ushort* __restrict__ PM1, const float* __restrict__ b1,
        uint* __restrict__ h0pk, uint* __restrict__ h1pk,
        float* __restrict__ h1out) {
    __shared__ __align__(16) ushort hb[16 * 1032];
    __shared__ float gs[4][16][17];
    int tid = threadIdx.x;
    int bk = blockIdx.x;
    int lane = tid & 63, w = tid >> 6;
    int cl = lane & 15, hi = lane >> 4;

    short8 a0[16], a1[32];
    {
        const ushort* base0 = PM0 + (size_t)(bk * 64 + w * 16 + cl) * 512 + hi * 8;
#pragma unroll
        for (int kt = 0; kt < 16; kt++) a0[kt] = *(const short8*)(base0 + kt * 32);
        const ushort* base1 = PM1 + (size_t)(bk * 64 + w * 16 + cl) * 1024 + hi * 8;
#pragma unroll
        for (int kt = 0; kt < 32; kt++) a1[kt] = *(const short8*)(base1 + kt * 32);
    }
    int u_loc = tid & 15, b = tid >> 4;
    int u = bk * 16 + u_loc;
    float bi0 = b1[u], bi1 = b1[512 + u], bi2 = b1[1024 + u], bi3 = b1[1536 + u];
    float c0v = 0.f, c1v = 0.f;
    int sb = tid >> 4, kseg = tid & 15;       // staging: 32 vals at [sb][kseg*32..]
    int sflat = sb * 512 + kseg * 32;

    for (int t = 0; t < T; t++) {
        int cur = t & 1;
        // ---- phase A: stage h0[t-1] (tag t+1, parity (t+1)&1)
        poll_stage32(h0pk + ((t + 1) & 1) * 8192 + sflat, (uint)(t + 1) & 0xffffu,
                     hb + sb * 1032 + kseg * 32);
        __syncthreads();
        {
            f32x4 acc = {0.f, 0.f, 0.f, 0.f};
            const ushort* hp = hb + cl * 1032 + hi * 8;
#pragma unroll
            for (int kt = 0; kt < 16; kt++) {
                short8 bfr = *(const short8*)(hp + kt * 32);
                acc = __builtin_amdgcn_mfma_f32_16x16x32_bf16(a0[kt], bfr, acc, 0, 0, 0);
            }
#pragma unroll
            for (int i = 0; i < 4; i++) gs[w][hi * 4 + i][cl] = acc[i];
        }
        __syncthreads();
        {
            const float* gg = G0 + ((size_t)(t * B + b)) * 2048 + u;
            float g0 = gg[0]    + gs[0][u_loc][b];
            float g1 = gg[512]  + gs[1][u_loc][b];
            float g2 = gg[1024] + gs[2][u_loc][b];
            float g3 = gg[1536] + gs[3][u_loc][b];
            float ig = sigm(g0), fg = sigm(g1), gt = tanhf(g2), og = sigm(g3);
            c0v = fg * c0v + ig * gt;
            float h0n = og * tanhf(c0v);
            pstore(&h0pk[cur * 8192 + b * 512 + u],
                   ((uint)(ushort)bf16s(h0n) << 16) | ((uint)(t + 2) & 0xffffu));
        }
        // ---- phase B: stage h0[t] (tag t+2, parity t&1) then h1[t-1] (tag t+1)
        poll_stage32(h0pk + cur * 8192 + sflat, (uint)(t + 2) & 0xffffu,
                     hb + sb * 1032 + kseg * 32);
        poll_stage32(h1pk + ((t + 1) & 1) * 8192 + sflat, (uint)(t + 1) & 0xffffu,
                     hb + sb * 1032 + 512 + kseg * 32);
        __syncthreads();
        {
            f32x4 acc = {0.f, 0.f, 0.f, 0.f};
            const ushort* hp = hb + cl * 1032 + hi * 8;
#pragma unroll
            for (int kt = 0; kt < 32; kt++) {
                short8 bfr = *(const short8*)(hp + kt * 32);
                acc = __builtin_amdgcn_mfma_f32_16x16x32_bf16(a1[kt], bfr, acc, 0, 0, 0);
            }
#pragma unroll
            for (int i = 0; i < 4; i++) gs[w][hi * 4 + i][cl] = acc[i];
        }
        __syncthreads();
        {
            float g0 = bi0 + gs[0][u_loc][b];
            float g1 = bi1 + gs[1][u_loc][b];
            float g2 = bi2 + gs[2][u_loc][b];
            float g3 = bi3 + gs[3][u_loc][b];
            float ig = sigm(g0), fg = sigm(g1), gt = tanhf(g2), og = sigm(g3);
            c1v = fg * c1v + ig * gt;
            float h1n = og * tanhf(c1v);
            pstore(&h1pk[cur * 8192 + b * 512 + u],
                   ((uint)(ushort)bf16s(h1n) << 16) | ((uint)(t + 2) & 0xffffu));
            h1out[((size_t)(t * B + b)) * 512 + u] = h1n;
        }
        __syncthreads();   // protect hb reuse by next phase A staging
    }
}

// ---------------- transpose enc hidden to [b][k(512)][s]
__global__ void build_encht(const float* __restrict__ h1f, const float* __restrict__ h1b,
                            float* __restrict__ et) {
    int blk = blockIdx.x;
    int b = blk >> 8, rem = blk & 255;
    int kt = rem >> 4, st = rem & 15;
    int c = threadIdx.x & 31, r = threadIdx.x >> 5;
    __shared__ float tile[32][33];
#pragma unroll
    for (int i = 0; i < 4; i++) {
        int sl = r + i * 8;
        int s = st * 32 + sl;
        int k = kt * 32 + c;
        float v = (k < H) ? h1f[((size_t)(s * B + b)) * H + k]
                          : h1b[((size_t)(s * B + b)) * H + (k - H)];
        tile[c][sl] = v;
    }
    __syncthreads();
#pragma unroll
    for (int i = 0; i < 4; i++) {
        int kl = r + i * 8;
        et[(size_t)b * D * S + (size_t)(kt * 32 + kl) * S + st * 32 + c] = tile[kl][c];
    }
}

// ---------------- q projections. grid T*B, 512 threads
__global__ void qproj(const float* __restrict__ h1d, const float* __restrict__ Wenc,
                      const float* __restrict__ Wdec, float* __restrict__ qe, float* __restrict__ qd) {
    int n = blockIdx.x;
    int o = threadIdx.x;
    __shared__ float hr[D];
    hr[o] = h1d[(size_t)n * D + o];
    __syncthreads();
    float ae = 0.f, ad = 0.f;
#pragma unroll 4
    for (int k = 0; k < D; k++) {
        float hk = hr[k];
        ae += hk * Wenc[k * D + o];
        ad += hk * Wdec[k * D + o];
    }
    qe[(size_t)n * D + o] = ae;
    qd[(size_t)n * D + o] = ad;
}

// ---------------- e = exp(min(score,30)). grid B*T, 512 threads
__global__ void escore(const float* __restrict__ qe, const float* __restrict__ et,
                       float* __restrict__ ew) {
    int bt = blockIdx.x;
    int b = bt / T, t = bt - b * T;
    int sx = threadIdx.x;
    __shared__ float q[D];
    q[sx] = qe[((size_t)(t * B + b)) * D + sx];
    __syncthreads();
    float acc = 0.f;
    const float* eb = et + (size_t)b * D * S + sx;
#pragma unroll 4
    for (int k = 0; k < D; k++) { acc += q[k] * eb[0]; eb += S; }
    acc = fminf(acc, 30.0f);
    ew[(size_t)bt * S + sx] = __expf(acc);
}

// ---------------- temporal normalization (prefix over t)
__global__ void temporal_k(float* __restrict__ ew) {
    int i = blockIdx.x * blockDim.x + threadIdx.x;
    if (i >= B * S) return;
    int b = i / S, sx = i - b * S;
    float cum = 0.f;
    for (int t = 0; t < T; t++) {
        size_t idx = ((size_t)(b * T + t)) * S + sx;
        float v = ew[idx];
        ew[idx] = v / (t == 0 ? 1.0f : (cum + 1e-8f));
        cum += v;
    }
}

// ---------------- attention softmax + enc context + copy prob. grid B*T, 512 thr
__global__ void attnctx(const float* __restrict__ ew, const int* __restrict__ ids,
                        const int* __restrict__ tgt,
                        const float* __restrict__ h1f, const float* __restrict__ h1b,
                        float* __restrict__ ectx, float* __restrict__ copyp) {
    int bt = blockIdx.x;
    int b = bt / T, t = bt - b * T;
    int tid = threadIdx.x;
    __shared__ float aw[S];
    __shared__ float red[512];
    float v = ew[(size_t)bt * S + tid];
    int tok = ids[b * S + tid];
    bool pad = (tok == PAD_ID);
    float vm = pad ? -INFINITY : v;
    red[tid] = vm; __syncthreads();
    for (int w = 256; w > 0; w >>= 1) { if (tid < w) red[tid] = fmaxf(red[tid], red[tid + w]); __syncthreads(); }
    float m = red[0]; __syncthreads();
    float ex = pad ? 0.f : __expf(vm - m);
    red[tid] = ex; __syncthreads();
    for (int w = 256; w > 0; w >>= 1) { if (tid < w) red[tid] += red[tid + w]; __syncthreads(); }
    float Z = red[0]; __syncthreads();
    float a = ex / Z;
    aw[tid] = a;
    int nt = tgt[b * T + t];
    red[tid] = (tok == nt) ? a : 0.f; __syncthreads();
    for (int w = 256; w > 0; w >>= 1) { if (tid < w) red[tid] += red[tid + w]; __syncthreads(); }
    if (tid == 0) copyp[bt] = red[0];
    __syncthreads();
    int d = tid;
    const float* hp = (d < H) ? (h1f + (size_t)b * H + d) : (h1b + (size_t)b * H + (d - H));
    float acc = 0.f;
#pragma unroll 4
    for (int s2 = 0; s2 < S; s2++) { acc += aw[s2] * hp[0]; hp += B * H; }
    ectx[(size_t)bt * D + d] = acc;
}

// ---------------- intra-decoder attention. grid B*T, 128 threads
__global__ void decattn(const float* __restrict__ qd, const float* __restrict__ h1d,
                        float* __restrict__ dctx) {
    int bt = blockIdx.x;
    int b = bt / T, t = bt - b * T;
    int tid = threadIdx.x;
    __shared__ float q[D];
    __shared__ float wl[T];
    __shared__ float red[128];
    for (int i = tid; i < D; i += 128) q[i] = qd[((size_t)(t * B + b)) * D + i];
    __syncthreads();
    float sc = -INFINITY;
    if (tid < t) {
        const float* hu = h1d + ((size_t)(tid * B + b)) * D;
        float a = 0.f;
#pragma unroll 4
        for (int k = 0; k < D; k++) a += q[k] * hu[k];
        sc = a;
    }
    red[tid] = sc; __syncthreads();
    for (int w = 64; w > 0; w >>= 1) { if (tid < w) red[tid] = fmaxf(red[tid], red[tid + w]); __syncthreads(); }
    float m = red[0]; __syncthreads();
    float ex = (tid < t) ? __expf(sc - m) : 0.f;
    red[tid] = ex; __syncthreads();
    for (int w = 64; w > 0; w >>= 1) { if (tid < w) red[tid] += red[tid + w]; __syncthreads(); }
    float Z = red[0]; __syncthreads();
    wl[tid] = (t > 0) ? (ex / Z) : 0.f;
    __syncthreads();
    for (int d = tid; d < D; d += 128) {
        float acc = 0.f;
        for (int u = 0; u < t; u++) acc += wl[u] * h1d[((size_t)(u * B + b)) * D + d];
        dctx[(size_t)bt * D + d] = acc;
    }
}

// ---------------- concat + p_gen; writes bf16 ccb16 [row][1536]. grid B*T, 512 thr
__global__ void concat_k(const float* __restrict__ h1d, const float* __restrict__ ectx,
                         const float* __restrict__ dctx, const float* __restrict__ sW,
                         const float* __restrict__ sb, ushort* __restrict__ ccb16,
                         float* __restrict__ pgen) {
    int bt = blockIdx.x;
    int b = bt / T, t = bt - b * T;
    int d = threadIdx.x;
    __shared__ float red[512];
    float v0 = h1d[((size_t)(t * B + b)) * D + d];
    float v1 = ectx[(size_t)bt * D + d];
    float v2 = dctx[(size_t)bt * D + d];
    ushort* c = ccb16 + (size_t)bt * C3;
    c[d] = (ushort)bf16s(v0); c[D + d] = (ushort)bf16s(v1); c[2 * D + d] = (ushort)bf16s(v2);
    red[d] = v0 * sW[d] + v1 * sW[D + d] + v2 * sW[2 * D + d];
    __syncthreads();
    for (int w = 256; w > 0; w >>= 1) { if (d < w) red[d] += red[d + w]; __syncthreads(); }
    if (d == 0) pgen[bt] = 1.f / (1.f + __expf(-(red[0] + sb[0])));
}

// ---------------- out_proj, packed-k layout for MFMA B-fragments.
__global__ void outprojT_k(const float* __restrict__ emb, const float* __restrict__ Wvoc,
                           __hip_bfloat16* __restrict__ outT2) {
    int j0 = blockIdx.x * 32;
    int jl = threadIdx.x & 31, oq = threadIdx.x >> 5;
    __shared__ float er[32][E + 1];
    for (int i = threadIdx.x; i < 32 * E; i += 256) {
        int jj = i >> 7, e = i & 127;
        int j = j0 + jj;
        er[jj][e] = (j < VO) ? emb[(size_t)(3 + j) * E + e] : 0.f;
    }
    __syncthreads();
    int j = j0 + jl;
#pragma unroll 1
    for (int i = 0; i < 24; i++) {
        int o = oq * 24 + i;
        int k0 = o * 8;
        float acc[8];
#pragma unroll
        for (int kk = 0; kk < 8; kk++) acc[kk] = 0.f;
#pragma unroll 4
        for (int e = 0; e < E; e++) {
            float x = er[jl][e];
            float4 w0 = *(const float4*)(Wvoc + (size_t)e * C3 + k0);
            float4 w1 = *(const float4*)(Wvoc + (size_t)e * C3 + k0 + 4);
            acc[0] += x * w0.x; acc[1] += x * w0.y; acc[2] += x * w0.z; acc[3] += x * w0.w;
            acc[4] += x * w1.x; acc[5] += x * w1.y; acc[6] += x * w1.z; acc[7] += x * w1.w;
        }
        short8 v;
#pragma unroll
        for (int kk = 0; kk < 8; kk++) v[kk] = bf16s(tanhf(acc[kk]));
        *reinterpret_cast<short8*>((char*)outT2 + ((size_t)o * JS + j) * 16) = v;
    }
}

// ---------------- vocab GEMM via MFMA, M_tile=64 (R11, passing). grid 128, 512 thr.
__global__ void __launch_bounds__(512) vocab_mfma2(
        const __hip_bfloat16* __restrict__ outT2, const ushort* __restrict__ ccb16,
        const float* __restrict__ ob, const int* __restrict__ tgt,
        float* __restrict__ pbuf) {
    __shared__ __align__(16) ushort As[64 * 768];
    __shared__ float wm[8][64], ws_[8][64], wg[8][64];
    __shared__ int jstar_s[64];
    int bid = blockIdx.x;
    int rb = bid & 31, q = bid >> 5;
    int row0 = rb * 64;
    int tid = threadIdx.x;

    if (tid < 64) {
        int nt = tgt[row0 + tid];
        int ix = nt - 3;
        ix = ix < 0 ? 0 : (ix > VO - 1 ? VO - 1 : ix);
        jstar_s[tid] = ix;
    }
    int lane = tid & 63, wid = tid >> 6;
    int wr = wid >> 2, wc = wid & 3;
    int cl = lane & 15, g = lane >> 4;
    int r7 = cl & 7;
    int rowA0 = wr * 32 + cl, rowA1 = rowA0 + 16;
    __syncthreads();
    int jst[8];
    float m[8], sacc[8], gl[8];
#pragma unroll
    for (int mm = 0; mm < 2; mm++)
#pragma unroll
        for (int i = 0; i < 4; i++) {
            int idx = mm * 4 + i;
            jst[idx] = jstar_s[wr * 32 + mm * 16 + g * 4 + i];
            m[idx] = -1e30f; sacc[idx] = 0.f; gl[idx] = -1e30f;
        }

    int jb0 = q * 8192;
    int jqend = (jb0 + 8192 < VO) ? jb0 + 8192 : VO;
    int nmt = (jqend - jb0 + 127) >> 7;
    int stc0 = (tid & 7) * 12;
    int str = tid >> 3, str7 = str & 7;
    for (int ti = 0; ti < nmt; ti++) {
        int jA = jb0 + ti * 128 + wc * 32 + cl;
        f32x4 accA0 = {0.f, 0.f, 0.f, 0.f}, accA1 = {0.f, 0.f, 0.f, 0.f};
        f32x4 accB0 = {0.f, 0.f, 0.f, 0.f}, accB1 = {0.f, 0.f, 0.f, 0.f};
#pragma unroll
        for (int half = 0; half < 2; half++) {
            __syncthreads();
            {
                const ushort* src = ccb16 + (size_t)(row0 + str) * C3 + half * 768;
                ushort* dst = As + str * 768;
#pragma unroll
                for (int ii = 0; ii < 12; ii++) {
                    int c = stc0 + ii;
                    *(short8*)(dst + ((c ^ str7) << 3)) = *(const short8*)(src + c * 8);
                }
            }
            __syncthreads();
            const char* pB = (const char*)outT2 + ((size_t)g * JS + jA) * 16
                           + (size_t)(half * 96) * JS * 16;
            const ushort* A0 = As + rowA0 * 768;
            const ushort* A1 = As + rowA1 * 768;
#pragma unroll
            for (int s = 0; s < 24; s++) {
                int c = s * 4 + g;
                short8 a0 = *(const short8*)(A0 + ((c ^ r7) << 3));
                short8 a1 = *(const short8*)(A1 + ((c ^ r7) << 3));
                short8 b0 = *(const short8*)(pB + (size_t)s * (4 * JS * 16));
                short8 b1 = *(const short8*)(pB + (size_t)s * (4 * JS * 16) + 256);
                accA0 = __builtin_amdgcn_mfma_f32_16x16x32_bf16(a0, b0, accA0, 0, 0, 0);
                accA1 = __builtin_amdgcn_mfma_f32_16x16x32_bf16(a0, b1, accA1, 0, 0, 0);
                accB0 = __builtin_amdgcn_mfma_f32_16x16x32_bf16(a1, b0, accB0, 0, 0, 0);
                accB1 = __builtin_amdgcn_mfma_f32_16x16x32_bf16(a1, b1, accB1, 0, 0, 0);
            }
        }
#pragma unroll
        for (int X = 0; X < 2; X++) {
            int j = jA + X * 16;
            if (j < jqend) {
                float obj = ob[j];
#pragma unroll
                for (int mm = 0; mm < 2; mm++)
#pragma unroll
                    for (int i = 0; i < 4; i++) {
                        int idx = mm * 4 + i;
                        float L;
                        if (mm == 0) L = (X ? accA1[i] : accA0[i]) + obj;
                        else         L = (X ? accB1[i] : accB0[i]) + obj;
                        if (j == jst[idx]) gl[idx] = L;
                        float mn = fmaxf(m[idx], L);
                        sacc[idx] = sacc[idx] * __expf(m[idx] - mn) + __expf(L - mn);
                        m[idx] = mn;
                    }
            }
        }
    }

#pragma unroll
    for (int idx = 0; idx < 8; idx++) {
        for (int mask = 1; mask < 16; mask <<= 1) {
            float om = __shfl_xor(m[idx], mask);
            float os = __shfl_xor(sacc[idx], mask);
            float mn = fmaxf(m[idx], om);
            sacc[idx] = sacc[idx] * __expf(m[idx] - mn) + os * __expf(om - mn);
            m[idx] = mn;
            gl[idx] = fmaxf(gl[idx], __shfl_xor(gl[idx], mask));
        }
    }
    if (cl == 0) {
#pragma unroll
        for (int idx = 0; idx < 8; idx++) {
            int rl = wr * 32 + (idx >> 2) * 16 + g * 4 + (idx & 3);
            wm[wid][rl] = m[idx]; ws_[wid][rl] = sacc[idx]; wg[wid][rl] = gl[idx];
        }
    }
    __syncthreads();
    if (tid < 64) {
        float M = -1e30f, SS = 0.f, GL = -1e30f;
        int w0 = ((tid >> 5) & 1) * 4;
#pragma unroll
        for (int w = 0; w < 4; w++) {
            float mq = wm[w0 + w][tid], sq = ws_[w0 + w][tid], gq = wg[w0 + w][tid];
            float mn = fmaxf(M, mq);
            SS = SS * __expf(M - mn) + sq * __expf(mq - mn);
            M = mn;
            GL = fmaxf(GL, gq);
        }
        float* o = pbuf + ((size_t)bid * 64 + tid) * 4;
        o[0] = M; o[1] = SS; o[2] = GL;
    }
}

// ---------------- combine quarter-partials + pointer mix + NLL. grid B, 128 threads.
__global__ void combine_nll_k(const float* __restrict__ pbuf, const int* __restrict__ tgt,
                              const float* __restrict__ pgen, const float* __restrict__ copyp,
                              const int* __restrict__ tlen, float* __restrict__ out) {
    int b = blockIdx.x, t = threadIdx.x;
    int row = b * T + t;
    int rb = row >> 6, r = row & 63;
    float M = -1e30f, SS = 0.f, GL = -1e30f;
#pragma unroll
    for (int q = 0; q < 4; q++) {
        const float* p = pbuf + ((size_t)(q * 32 + rb) * 64 + r) * 4;
        float mq = p[0], sq = p[1], gq = p[2];
        float mn = fmaxf(M, mq);
        SS = SS * __expf(M - mn) + sq * __expf(mq - mn);
        M = mn;
        GL = fmaxf(GL, gq);
    }
    int nt = tgt[row];
    float genp = (nt >= 3 && nt < V) ? __expf(GL - M) / SS : 0.f;
    float pg = pgen[row];
    float p = pg * genp + (1.f - pg) * copyp[row];
    __shared__ float red[128];
    red[t] = (t < tlen[b]) ? -logf(p + 1e-9f) : 0.f;
    __syncthreads();
    for (int w = 64; w > 0; w >>= 1) { if (t < w) red[t] += red[t + w]; __syncthreads(); }
    if (t == 0) out[b] = red[0];
}

extern "C" void kernel_launch(void* const* d_in, const int* in_sizes, int n_in,
                              void* d_out, int out_size, void* d_ws, size_t ws_size,
                              hipStream_t stream) {
    const int* input_ids = (const int*)d_in[0];
    const int* target_ids = (const int*)d_in[1];
    const int* tlen = (const int*)d_in[3];
    const float* emb = (const float*)d_in[5];
    const float* eWih0f = (const float*)d_in[6],  *eWhh0f = (const float*)d_in[7],  *eb0f = (const float*)d_in[8];
    const float* eWih0b = (const float*)d_in[9],  *eWhh0b = (const float*)d_in[10], *eb0b = (const float*)d_in[11];
    const float* eWih1f = (const float*)d_in[12], *eWhh1f = (const float*)d_in[13], *eb1f = (const float*)d_in[14];
    const float* eWih1b = (const float*)d_in[15], *eWhh1b = (const float*)d_in[16], *eb1b = (const float*)d_in[17];
    const float* dWih0 = (const float*)d_in[18], *dWhh0 = (const float*)d_in[19], *db0 = (const float*)d_in[20];
    const float* dWih1 = (const float*)d_in[21], *dWhh1 = (const float*)d_in[22], *db1 = (const float*)d_in[23];
    const float* Wenc = (const float*)d_in[24], *Wdec = (const float*)d_in[25];
    const float* Wvoc = (const float*)d_in[26], *sW = (const float*)d_in[27], *sb = (const float*)d_in[28];
    const float* ob = (const float*)d_in[29];
    float* out = (float*)d_out;
    (void)ws_size; (void)n_in; (void)in_sizes; (void)out_size;

    // ============ workspace layout (~145.1 MB, phase-aliased) ============
    char* A = (char*)d_ws;
    float4* pWih0f = (float4*)(A + 0);
    float4* pWih0b = (float4*)(A + 524288);
    ushort* PMW1f  = (ushort*)(A + 1048576);
    ushort* PMW1b  = (ushort*)(A + 2097152);
    float4* pdWih0 = (float4*)(A + 5242880);
    ushort* PMf0  = (ushort*)(A + 6291456);
    ushort* PMb0  = (ushort*)(A + 6815744);
    ushort* PMf1  = (ushort*)(A + 7340032);
    ushort* PMb1  = (ushort*)(A + 7864320);
    ushort* PM0   = (ushort*)(A + 8388608);
    ushort* PM1   = (ushort*)(A + 10485760);
    float* G0f = (float*)(A + 23068672);
    float* G0b = (float*)(A + 56623104);
    float* Gd0 = (float*)(A + 23068672);            // aliases G0f (dead after enc scans)
    float* ench = (float*)(A + 39845888);
    float* ectx = (float*)(A + 56623104);
    float* dctx = (float*)(A + 60817408);
    __hip_bfloat16* outT2 = (__hip_bfloat16*)A;     // whole region, after concat_k

    char* Bh = A + 98304000;
    float* h0f = (float*)(Bh + 0);
    float* h0b = (float*)(Bh + 8388608);
    float* h1d = (float*)(Bh + 0);                  // aliases h0f (dead after enc1 gates)
    float* qe  = (float*)(Bh + 4194304);
    float* qd  = (float*)(Bh + 8388608);
    float* ew  = (float*)(Bh + 12582912);
    char* Cr = Bh + 16777216;
    float* h1f = (float*)(Cr + 0);
    float* h1b = (float*)(Cr + 8388608);
    ushort* ccb16 = (ushort*)(Cr + 16777216);
    float* dec_init = (float*)(Cr + 29360128);
    float* pgen  = (float*)(Cr + 29425664);
    float* copyp = (float*)(Cr + 29433856);
    float* pbuf  = (float*)(Cr + 29442048);
    uint* hpkE0  = (uint*)(Cr + 29769728);          // 64 KB (enc L0 packets)
    uint* hpkE1  = (uint*)(Cr + 29835264);          // 64 KB (enc L1 packets)
    uint* h0pkD  = (uint*)(Cr + 29900800);          // 64 KB (dec h0 packets)
    uint* h1pkD  = (uint*)(Cr + 29966336);          // 64 KB (dec h1 packets)
    // total ≈ 145.1 MB

    hipMemsetAsync(hpkE0, 0, 262144, stream);       // all four packet regions (contiguous)

    auto pack = [&](const float* W, float4* P, int Hn, int K) {
        int total = Hn * K;
        hipLaunchKernelGGL(pack4_kernel, dim3((total + 255) / 256), dim3(256), 0, stream, W, P, Hn, K);
    };
    pack(eWih0f, pWih0f, H, E);
    pack(eWih0b, pWih0b, H, E);
    pack(dWih0, pdWih0, D, E);
    hipLaunchKernelGGL(packencMK_k, dim3(4 * H * 256 / 256), dim3(256), 0, stream, eWhh0f, PMf0, 256);
    hipLaunchKernelGGL(packencMK_k, dim3(4 * H * 256 / 256), dim3(256), 0, stream, eWhh0b, PMb0, 256);
    hipLaunchKernelGGL(packencMK_k, dim3(4 * H * 256 / 256), dim3(256), 0, stream, eWhh1f, PMf1, 256);
    hipLaunchKernelGGL(packencMK_k, dim3(4 * H * 256 / 256), dim3(256), 0, stream, eWhh1b, PMb1, 256);
    hipLaunchKernelGGL(packencMK_k, dim3(4 * H * 512 / 256), dim3(256), 0, stream, eWih1f, PMW1f, 512);
    hipLaunchKernelGGL(packencMK_k, dim3(4 * H * 512 / 256), dim3(256), 0, stream, eWih1b, PMW1b, 512);
    hipLaunchKernelGGL(packdecM_k, dim3(4 * D * D / 256), dim3(256), 0, stream, dWhh0, PM0);
    hipLaunchKernelGGL(packdecM2_k, dim3(8 * D * D / 256), dim3(256), 0, stream, dWih1, dWhh1, PM1);

    hipLaunchKernelGGL(enc0_gates2, dim3(S * B / 8), dim3(256), 0, stream,
                       input_ids, emb, pWih0f, eb0f, pWih0b, eb0b, G0f, G0b);
    hipLaunchKernelGGL(enc_pscan3, dim3(16), dim3(256), 0, stream,
                       G0f, G0b, PMf0, PMb0, h0f, h0b, dec_init, hpkE0);
    hipLaunchKernelGGL(enc1g_mfma, dim3(256), dim3(256), 0, stream,
                       h0f, h0b, PMW1f, PMW1b, eb1f, eb1b, G0f, G0b);
    hipLaunchKernelGGL(enc_pscan3, dim3(16), dim3(256), 0, stream,
                       G0f, G0b, PMf1, PMb1, h1f, h1b, dec_init + B * D, hpkE1);
    hipLaunchKernelGGL(dec0_gates2, dim3(T * B / 8), dim3(512), 0, stream,
                       target_ids, emb, pdWih0, db0, Gd0);
    hipLaunchKernelGGL(dec_initpk, dim3(B * D / 256), dim3(256), 0, stream,
                       dec_init, h0pkD, h1pkD);
    hipLaunchKernelGGL(dec_mfma2, dim3(32), dim3(256), 0, stream,
                       Gd0, PM0, PM1, db1, h0pkD, h1pkD, h1d);
    hipLaunchKernelGGL(build_encht, dim3(B * 256), dim3(256), 0, stream, h1f, h1b, ench);
    hipLaunchKernelGGL(qproj, dim3(T * B), dim3(D), 0, stream, h1d, Wenc, Wdec, qe, qd);
    hipLaunchKernelGGL(escore, dim3(B * T), dim3(S), 0, stream, qe, ench, ew);
    hipLaunchKernelGGL(temporal_k, dim3((B * S + 255) / 256), dim3(256), 0, stream, ew);
    hipLaunchKernelGGL(attnctx, dim3(B * T), dim3(S), 0, stream,
                       ew, input_ids, target_ids, h1f, h1b, ectx, copyp);
    hipLaunchKernelGGL(decattn, dim3(B * T), dim3(T), 0, stream, qd, h1d, dctx);
    hipLaunchKernelGGL(concat_k, dim3(B * T), dim3(D), 0, stream,
                       h1d, ectx, dctx, sW, sb, ccb16, pgen);
    hipLaunchKernelGGL(outprojT_k, dim3(1000), dim3(256), 0, stream, emb, Wvoc, outT2);
    hipLaunchKernelGGL(vocab_mfma2, dim3(128), dim3(512), 0, stream,
                       outT2, ccb16, ob, target_ids, pbuf);
    hipLaunchKernelGGL(combine_nll_k, dim3(B), dim3(T), 0, stream,
                       pbuf, target_ids, pgen, copyp, tlen, out);
}

// Round 13
// 4911.510 us; speedup vs baseline: 4.6849x; 1.1698x over previous
//
#include <hip/hip_runtime.h>
#include <hip/hip_bf16.h>
#include <math.h>

#define PAD_ID 0
#define UNK_ID 1
#define START_ID 2
#define END_ID 3

constexpr int B = 16, S = 512, T = 128, V = 32000, E = 128, H = 256, D = 512;
constexpr int C3 = 1536;        // 3*D
constexpr int VO = 31997;       // V-3
constexpr int JS = 32000;       // padded col count for outT2

typedef short short8 __attribute__((ext_vector_type(8)));
typedef float f32x4 __attribute__((ext_vector_type(4)));

__device__ __forceinline__ float sigm(float x) { return 1.0f / (1.0f + __expf(-x)); }
__device__ __forceinline__ short bf16s(float x) {
    __hip_bfloat16 h = __float2bfloat16(x);
    return *reinterpret_cast<short*>(&h);
}

__device__ __forceinline__ uint4 cloadu4(const uint* p) {
    uint4 v;
    asm volatile("global_load_dwordx4 %0, %1, off sc0 sc1" : "=v"(v) : "v"(p));
    return v;
}
__device__ __forceinline__ void pstore(uint* p, uint v) {
    __hip_atomic_store(p, v, __ATOMIC_RELAXED, __HIP_MEMORY_SCOPE_AGENT);
}

__device__ __forceinline__ void gload_lds16(const void* g, void* l) {
    __builtin_amdgcn_global_load_lds(
        (const __attribute__((address_space(1))) void*)(g),
        (__attribute__((address_space(3))) void*)(l), 16, 0, 0);
}

__device__ __forceinline__ void st_bf8(ushort* dst, float4 a, float4 b) {
    short8 o;
    o[0] = bf16s(a.x); o[1] = bf16s(a.y); o[2] = bf16s(a.z); o[3] = bf16s(a.w);
    o[4] = bf16s(b.x); o[5] = bf16s(b.y); o[6] = bf16s(b.z); o[7] = bf16s(b.w);
    *(short8*)dst = o;
}

// ---------------- poll 16 packets (4 dwordx4) tagged e; write 16 bf16 to dst
__device__ __forceinline__ void poll_stage16(const uint* src, uint e, ushort* dst) {
    uint4 a0, a1, a2, a3;
    for (;;) {
        a0 = cloadu4(src); a1 = cloadu4(src + 4); a2 = cloadu4(src + 8); a3 = cloadu4(src + 12);
        asm volatile("s_waitcnt vmcnt(0)" ::: "memory");
        __builtin_amdgcn_sched_barrier(0);
        uint d = (a0.x ^ e) | (a0.y ^ e) | (a0.z ^ e) | (a0.w ^ e)
               | (a1.x ^ e) | (a1.y ^ e) | (a1.z ^ e) | (a1.w ^ e)
               | (a2.x ^ e) | (a2.y ^ e) | (a2.z ^ e) | (a2.w ^ e)
               | (a3.x ^ e) | (a3.y ^ e) | (a3.z ^ e) | (a3.w ^ e);
        if ((d & 0xffffu) == 0) break;
        __builtin_amdgcn_s_sleep(1);
    }
    short8 o0, o1;
    o0[0] = (short)(a0.x >> 16); o0[1] = (short)(a0.y >> 16); o0[2] = (short)(a0.z >> 16); o0[3] = (short)(a0.w >> 16);
    o0[4] = (short)(a1.x >> 16); o0[5] = (short)(a1.y >> 16); o0[6] = (short)(a1.z >> 16); o0[7] = (short)(a1.w >> 16);
    o1[0] = (short)(a2.x >> 16); o1[1] = (short)(a2.y >> 16); o1[2] = (short)(a2.z >> 16); o1[3] = (short)(a2.w >> 16);
    o1[4] = (short)(a3.x >> 16); o1[5] = (short)(a3.y >> 16); o1[6] = (short)(a3.z >> 16); o1[7] = (short)(a3.w >> 16);
    *(short8*)dst = o0;
    *(short8*)(dst + 8) = o1;
}

// ---------------- poll 32 packets (8 dwordx4) tagged e; write 32 bf16 to dst
__device__ __forceinline__ void poll_stage32(const uint* src, uint e, ushort* dst) {
    uint4 a[8];
    for (;;) {
#pragma unroll
        for (int i = 0; i < 8; i++) a[i] = cloadu4(src + i * 4);
        asm volatile("s_waitcnt vmcnt(0)" ::: "memory");
        __builtin_amdgcn_sched_barrier(0);
        uint d = 0;
#pragma unroll
        for (int i = 0; i < 8; i++)
            d |= (a[i].x ^ e) | (a[i].y ^ e) | (a[i].z ^ e) | (a[i].w ^ e);
        if ((d & 0xffffu) == 0) break;
        __builtin_amdgcn_s_sleep(1);
    }
#pragma unroll
    for (int i = 0; i < 8; i += 2) {
        short8 o;
        o[0] = (short)(a[i].x >> 16);     o[1] = (short)(a[i].y >> 16);
        o[2] = (short)(a[i].z >> 16);     o[3] = (short)(a[i].w >> 16);
        o[4] = (short)(a[i + 1].x >> 16); o[5] = (short)(a[i + 1].y >> 16);
        o[6] = (short)(a[i + 1].z >> 16); o[7] = (short)(a[i + 1].w >> 16);
        *(short8*)(dst + i * 4) = o;
    }
}

// ---------------- weight packing: W[4H][K] -> P[k][u] = float4 of 4 gates
__global__ void pack4_kernel(const float* __restrict__ W, float4* __restrict__ P, int Hn, int K) {
    int i = blockIdx.x * blockDim.x + threadIdx.x;
    if (i >= K * Hn) return;
    int k = i / Hn, u = i - k * Hn;
    float4 v;
    v.x = W[(size_t)(0 * Hn + u) * K + k];
    v.y = W[(size_t)(1 * Hn + u) * K + k];
    v.z = W[(size_t)(2 * Hn + u) * K + k];
    v.w = W[(size_t)(3 * Hn + u) * K + k];
    P[(size_t)k * Hn + u] = v;
}

// ---------------- MFMA-row pack (H=256 outputs): row = (u>>3)*32 + g*8 + (u&7)
__global__ void packencMK_k(const float* __restrict__ W, ushort* __restrict__ P, int K) {
    int i = blockIdx.x * blockDim.x + threadIdx.x;
    if (i >= 4 * H * K) return;
    int k = i % K, row = i / K;
    int g = (row >> 3) & 3, ul = row & 7, uh = row >> 5;
    int u = uh * 8 + ul;
    P[i] = (ushort)bf16s(W[(size_t)(g * H + u) * K + k]);
}

// ---------------- decoder W0 pack for MFMA (row = bk*64 + g*16 + u%16)
__global__ void packdecM_k(const float* __restrict__ W, ushort* __restrict__ P) {
    int i = blockIdx.x * blockDim.x + threadIdx.x;
    if (i >= 4 * D * D) return;
    int k = i & 511, row = i >> 9;
    int g = (row >> 4) & 3, u = (row >> 6) * 16 + (row & 15);
    P[i] = (ushort)bf16s(W[(size_t)(g * D + u) * D + k]);
}

// ---------------- decoder layer1 pack: [W1i | W1h] -> PM1[row][1024] bf16
__global__ void packdecM2_k(const float* __restrict__ Wi, const float* __restrict__ Wh,
                            ushort* __restrict__ P) {
    int i = blockIdx.x * blockDim.x + threadIdx.x;
    if (i >= 4 * D * D * 2) return;
    int k = i & 1023, row = i >> 10;
    int g = (row >> 4) & 3, u = (row >> 6) * 16 + (row & 15);
    float v = (k < 512) ? Wi[(size_t)(g * D + u) * D + k]
                        : Wh[(size_t)(g * D + u) * D + (k - 512)];
    P[i] = (ushort)bf16s(v);
}

// ---------------- encoder layer-0 gates, tiled (8 rows/block). grid S*B/8, 256 thr.
__global__ void enc0_gates2(const int* __restrict__ ids, const float* __restrict__ emb,
                            const float4* __restrict__ Pf, const float* __restrict__ bf_,
                            const float4* __restrict__ Pb, const float* __restrict__ bb_,
                            float* __restrict__ Gf, float* __restrict__ Gb) {
    int n0 = blockIdx.x * 8;
    int u = threadIdx.x;
    __shared__ float xr[8][E];
    for (int i = u; i < 8 * E; i += 256) {
        int r = i >> 7, e = i & 127;
        int n = n0 + r, s = n / B, b = n - s * B;
        int tok = ids[b * S + s];
        if (tok >= V) tok = UNK_ID;
        xr[r][e] = emb[(size_t)tok * E + e];
    }
    __syncthreads();
#pragma unroll
    for (int dir = 0; dir < 2; dir++) {
        const float4* P = dir ? Pb : Pf;
        const float* bs = dir ? bb_ : bf_;
        float* G = dir ? Gb : Gf;
        float acc[8][4];
#pragma unroll
        for (int r = 0; r < 8; r++)
#pragma unroll
            for (int g = 0; g < 4; g++) acc[r][g] = 0.f;
#pragma unroll 4
        for (int k = 0; k < E; k++) {
            float4 w = P[k * H + u];
#pragma unroll
            for (int r = 0; r < 8; r++) {
                float x = xr[r][k];
                acc[r][0] += x * w.x; acc[r][1] += x * w.y;
                acc[r][2] += x * w.z; acc[r][3] += x * w.w;
            }
        }
        float b0 = bs[u], b1 = bs[H + u], b2 = bs[2 * H + u], b3 = bs[3 * H + u];
#pragma unroll
        for (int r = 0; r < 8; r++) {
            float* g = G + (size_t)(n0 + r) * (4 * H);
            g[u] = acc[r][0] + b0; g[H + u] = acc[r][1] + b1;
            g[2 * H + u] = acc[r][2] + b2; g[3 * H + u] = acc[r][3] + b3;
        }
    }
}

// ---------------- encoder layer-1 gates via MFMA (R11, passing). grid 256, 256 thr.
__global__ void __launch_bounds__(256) enc1g_mfma(
        const float* __restrict__ h0f, const float* __restrict__ h0b,
        const ushort* __restrict__ PMf, const ushort* __restrict__ PMb,
        const float* __restrict__ bf_, const float* __restrict__ bb_,
        float* __restrict__ Gf, float* __restrict__ Gb) {
    __shared__ __align__(16) ushort X[16 * 520];
    __shared__ float gs[4][32][17];
    __shared__ float bias_s[128];
    int bid = blockIdx.x;
    int dirb = (bid >> 3) & 1, bk = bid & 7, ns = bid >> 4;
    const ushort* PM = dirb ? PMb : PMf;
    const float* bs = dirb ? bb_ : bf_;
    float* G = dirb ? Gb : Gf;
    int tid = threadIdx.x;
    int lane = tid & 63, w = tid >> 6;
    int cl = lane & 15, hi = lane >> 4;

    short8 afr[2][16];
    {
        int rowbase = (bk * 4 + w) * 32;
#pragma unroll
        for (int mt = 0; mt < 2; mt++)
#pragma unroll
            for (int kt = 0; kt < 16; kt++)
                afr[mt][kt] = *(const short8*)(PM + (size_t)(rowbase + mt * 16 + cl) * 512 + kt * 32 + hi * 8);
    }
    if (tid < 128) {
        int g = (tid >> 3) & 3;
        int u = (bk * 4 + (tid >> 5)) * 8 + (tid & 7);
        bias_s[tid] = bs[g * H + u];
    }
    int nl = tid >> 4, kseg = tid & 15;
    int en = tid & 15, rgrp = tid >> 4;
    for (int tt = 0; tt < 32; tt++) {
        int nt = ns * 32 + tt;
        __syncthreads();
        {
            int n = nt * 16 + nl;
            const float* src = (kseg < 8) ? (h0f + (size_t)n * H + kseg * 32)
                                          : (h0b + (size_t)n * H + (kseg - 8) * 32);
            float4 v0 = *(const float4*)(src), v1 = *(const float4*)(src + 4);
            float4 v2 = *(const float4*)(src + 8), v3 = *(const float4*)(src + 12);
            float4 v4 = *(const float4*)(src + 16), v5 = *(const float4*)(src + 20);
            float4 v6 = *(const float4*)(src + 24), v7 = *(const float4*)(src + 28);
            ushort* dst = X + nl * 520 + kseg * 32;
            st_bf8(dst, v0, v1); st_bf8(dst + 8, v2, v3);
            st_bf8(dst + 16, v4, v5); st_bf8(dst + 24, v6, v7);
        }
        __syncthreads();
        {
            f32x4 acc0 = {0.f, 0.f, 0.f, 0.f}, acc1 = {0.f, 0.f, 0.f, 0.f};
            const ushort* hp = X + cl * 520 + hi * 8;
#pragma unroll
            for (int kt = 0; kt < 16; kt++) {
                short8 bfr = *(const short8*)(hp + kt * 32);
                acc0 = __builtin_amdgcn_mfma_f32_16x16x32_bf16(afr[0][kt], bfr, acc0, 0, 0, 0);
                acc1 = __builtin_amdgcn_mfma_f32_16x16x32_bf16(afr[1][kt], bfr, acc1, 0, 0, 0);
            }
#pragma unroll
            for (int i = 0; i < 4; i++) {
                gs[w][hi * 4 + i][cl] = acc0[i];
                gs[w][16 + hi * 4 + i][cl] = acc1[i];
            }
        }
        __syncthreads();
        {
            int wv = rgrp >> 2, g = rgrp & 3;
            int u0 = (bk * 4 + wv) * 8;
            float* dst = G + (size_t)(nt * 16 + en) * 1024 + g * 256 + u0;
            float4 o0, o1;
            o0.x = gs[wv][g * 8 + 0][en] + bias_s[rgrp * 8 + 0];
            o0.y = gs[wv][g * 8 + 1][en] + bias_s[rgrp * 8 + 1];
            o0.z = gs[wv][g * 8 + 2][en] + bias_s[rgrp * 8 + 2];
            o0.w = gs[wv][g * 8 + 3][en] + bias_s[rgrp * 8 + 3];
            o1.x = gs[wv][g * 8 + 4][en] + bias_s[rgrp * 8 + 4];
            o1.y = gs[wv][g * 8 + 5][en] + bias_s[rgrp * 8 + 5];
            o1.z = gs[wv][g * 8 + 6][en] + bias_s[rgrp * 8 + 6];
            o1.w = gs[wv][g * 8 + 7][en] + bias_s[rgrp * 8 + 7];
            *(float4*)dst = o0;
            *(float4*)(dst + 4) = o1;
        }
    }
}

// ---------------- decoder layer-0 input gates, tiled. grid T*B/8, 512 thr.
__global__ void dec0_gates2(const int* __restrict__ tgt, const float* __restrict__ emb,
                            const float4* __restrict__ P, const float* __restrict__ bias,
                            float* __restrict__ G) {
    int n0 = blockIdx.x * 8;
    int u = threadIdx.x;
    __shared__ float xr[8][E];
    for (int i = u; i < 8 * E; i += 512) {
        int r = i >> 7, e = i & 127;
        int n = n0 + r, t = n / B, b = n - t * B;
        int tok;
        if (t == 0) tok = START_ID;
        else { tok = tgt[b * T + (t - 1)]; if (tok >= V) tok = UNK_ID; }
        xr[r][e] = emb[(size_t)tok * E + e];
    }
    __syncthreads();
    float acc[8][4];
#pragma unroll
    for (int r = 0; r < 8; r++)
#pragma unroll
        for (int g = 0; g < 4; g++) acc[r][g] = 0.f;
#pragma unroll 4
    for (int k = 0; k < E; k++) {
        float4 w = P[k * D + u];
#pragma unroll
        for (int r = 0; r < 8; r++) {
            float x = xr[r][k];
            acc[r][0] += x * w.x; acc[r][1] += x * w.y;
            acc[r][2] += x * w.z; acc[r][3] += x * w.w;
        }
    }
    float b0 = bias[u], b1 = bias[D + u], b2 = bias[2 * D + u], b3 = bias[3 * D + u];
#pragma unroll
    for (int r = 0; r < 8; r++) {
        float* g = G + (size_t)(n0 + r) * (4 * D);
        g[u] = acc[r][0] + b0; g[D + u] = acc[r][1] + b1;
        g[2 * D + u] = acc[r][2] + b2; g[3 * D + u] = acc[r][3] + b3;
    }
}

// ---------------- MFMA encoder persistent scan, DATAFLOW sync (R12, passing).
__global__ void __launch_bounds__(256) enc_pscan3(
        const float* __restrict__ Gf, const float* __restrict__ Gb,
        const ushort* __restrict__ PMf, const ushort* __restrict__ PMb,
        float* __restrict__ hof, float* __restrict__ hob,
        float* __restrict__ hfin /* [B][2H] */,
        uint* __restrict__ pk /* [2][2][4096] */) {
    __shared__ __align__(16) ushort hh[16 * 264];
    __shared__ float gs[4][32][17];
    int blk = blockIdx.x;
    int dirb = blk >> 3, bk = blk & 7;
    const float* G = dirb ? Gb : Gf;
    const ushort* PM = dirb ? PMb : PMf;
    float* ho = dirb ? hob : hof;
    int tid = threadIdx.x;
    int lane = tid & 63, w = tid >> 6;
    int cl = lane & 15, hi = lane >> 4;

    short8 afr[2][8];
    {
        int rowbase = (bk * 4 + w) * 32;
#pragma unroll
        for (int mt = 0; mt < 2; mt++)
#pragma unroll
            for (int kt = 0; kt < 8; kt++)
                afr[mt][kt] = *(const short8*)(PM + (size_t)(rowbase + mt * 16 + cl) * 256 + kt * 32 + hi * 8);
    }
    int ub = tid & 31, bb = tid >> 5;
    int u_glob = bk * 32 + ub;
    int gsw = ub >> 3, ul = ub & 7;
    float c_a = 0.f, c_b = 0.f;
    int b0s = tid >> 4, u0s = (tid & 15) * 16;

    for (int step = 0; step < S; step++) {
        int s = dirb ? (S - 1 - step) : step;
        int cur = step & 1;
        const float* gA = G + ((size_t)(s * B + bb)) * 1024 + u_glob;
        const float* gB = G + ((size_t)(s * B + bb + 8)) * 1024 + u_glob;
        float pa0 = gA[0], pa1 = gA[256], pa2 = gA[512], pa3 = gA[768];
        float pb0 = gB[0], pb1 = gB[256], pb2 = gB[512], pb3 = gB[768];
        poll_stage16(pk + cur * 8192 + dirb * 4096 + tid * 16,
                     (uint)step & 0xffffu, hh + b0s * 264 + u0s);
        __syncthreads();
        {
            f32x4 acc0 = {0.f, 0.f, 0.f, 0.f}, acc1 = {0.f, 0.f, 0.f, 0.f};
            const ushort* hp = hh + cl * 264 + hi * 8;
#pragma unroll
            for (int kt = 0; kt < 8; kt++) {
                short8 bfr = *(const short8*)(hp + kt * 32);
                acc0 = __builtin_amdgcn_mfma_f32_16x16x32_bf16(afr[0][kt], bfr, acc0, 0, 0, 0);
                acc1 = __builtin_amdgcn_mfma_f32_16x16x32_bf16(afr[1][kt], bfr, acc1, 0, 0, 0);
            }
#pragma unroll
            for (int i = 0; i < 4; i++) {
                gs[w][hi * 4 + i][cl] = acc0[i];
                gs[w][16 + hi * 4 + i][cl] = acc1[i];
            }
        }
        __syncthreads();
        {
            float q0 = gs[gsw][0 + ul][bb];
            float q1 = gs[gsw][8 + ul][bb];
            float q2 = gs[gsw][16 + ul][bb];
            float q3 = gs[gsw][24 + ul][bb];
            float ig = sigm(pa0 + q0), fg = sigm(pa1 + q1), gt = tanhf(pa2 + q2), og = sigm(pa3 + q3);
            c_a = fg * c_a + ig * gt;
            float hA = og * tanhf(c_a);
            q0 = gs[gsw][0 + ul][bb + 8];
            q1 = gs[gsw][8 + ul][bb + 8];
            q2 = gs[gsw][16 + ul][bb + 8];
            q3 = gs[gsw][24 + ul][bb + 8];
            ig = sigm(pb0 + q0); fg = sigm(pb1 + q1); gt = tanhf(pb2 + q2); og = sigm(pb3 + q3);
            c_b = fg * c_b + ig * gt;
            float hB = og * tanhf(c_b);
            uint tg = (uint)(step + 1) & 0xffffu;
            uint* dstp = pk + (cur ^ 1) * 8192 + dirb * 4096;
            pstore(&dstp[bb * 256 + u_glob], ((uint)(ushort)bf16s(hA) << 16) | tg);
            pstore(&dstp[(bb + 8) * 256 + u_glob], ((uint)(ushort)bf16s(hB) << 16) | tg);
            ho[((size_t)(s * B + bb)) * H + u_glob] = hA;
            ho[((size_t)(s * B + bb + 8)) * H + u_glob] = hB;
            if (step == S - 1) {
                hfin[bb * (2 * H) + dirb * H + u_glob] = hA;
                hfin[(bb + 8) * (2 * H) + dirb * H + u_glob] = hB;
            }
        }
    }
}

// ---------------- decoder init packets (tag 1, parity 1)
__global__ void dec_initpk(const float* __restrict__ hinit,
                           uint* __restrict__ h0pk, uint* __restrict__ h1pk) {
    int i = blockIdx.x * blockDim.x + threadIdx.x;
    if (i >= B * D) return;
    pstore(&h0pk[8192 + i], ((uint)(ushort)bf16s(hinit[i]) << 16) | 1u);
    pstore(&h1pk[8192 + i], ((uint)(ushort)bf16s(hinit[B * D + i]) << 16) | 1u);
}

// ---------------- MFMA decoder persistent 2-layer scan, DATAFLOW sync (R12, passing).
__global__ void __launch_bounds__(256) dec_mfma2(
        const float* __restrict__ G0, const ushort* __restrict__ PM0,
        const ushort* __restrict__ PM1, const float* __restrict__ b1,
        uint* __restrict__ h0pk, uint* __restrict__ h1pk,
        float* __restrict__ h1out) {
    __shared__ __align__(16) ushort hb[16 * 1032];
    __shared__ float gs[4][16][17];
    int tid = threadIdx.x;
    int bk = blockIdx.x;
    int lane = tid & 63, w = tid >> 6;
    int cl = lane & 15, hi = lane >> 4;

    short8 a0[16], a1[32];
    {
        const ushort* base0 = PM0 + (size_t)(bk * 64 + w * 16 + cl) * 512 + hi * 8;
#pragma unroll
        for (int kt = 0; kt < 16; kt++) a0[kt] = *(const short8*)(base0 + kt * 32);
        const ushort* base1 = PM1 + (size_t)(bk * 64 + w * 16 + cl) * 1024 + hi * 8;
#pragma unroll
        for (int kt = 0; kt < 32; kt++) a1[kt] = *(const short8*)(base1 + kt * 32);
    }
    int u_loc = tid & 15, b = tid >> 4;
    int u = bk * 16 + u_loc;
    float bi0 = b1[u], bi1 = b1[512 + u], bi2 = b1[1024 + u], bi3 = b1[1536 + u];
    float c0v = 0.f, c1v = 0.f;
    int sb = tid >> 4, kseg = tid & 15;
    int sflat = sb * 512 + kseg * 32;

    for (int t = 0; t < T; t++) {
        int cur = t & 1;
        poll_stage32(h0pk + ((t + 1) & 1) * 8192 + sflat, (uint)(t + 1) & 0xffffu,
                     hb + sb * 1032 + kseg * 32);
        __syncthreads();
        {
            f32x4 acc = {0.f, 0.f, 0.f, 0.f};
            const ushort* hp = hb + cl * 1032 + hi * 8;
#pragma unroll
            for (int kt = 0; kt < 16; kt++) {
                short8 bfr = *(const short8*)(hp + kt * 32);
                acc = __builtin_amdgcn_mfma_f32_16x16x32_bf16(a0[kt], bfr, acc, 0, 0, 0);
            }
#pragma unroll
            for (int i = 0; i < 4; i++) gs[w][hi * 4 + i][cl] = acc[i];
        }
        __syncthreads();
        {
            const float* gg = G0 + ((size_t)(t * B + b)) * 2048 + u;
            float g0 = gg[0]    + gs[0][u_loc][b];
            float g1 = gg[512]  + gs[1][u_loc][b];
            float g2 = gg[1024] + gs[2][u_loc][b];
            float g3 = gg[1536] + gs[3][u_loc][b];
            float ig = sigm(g0), fg = sigm(g1), gt = tanhf(g2), og = sigm(g3);
            c0v = fg * c0v + ig * gt;
            float h0n = og * tanhf(c0v);
            pstore(&h0pk[cur * 8192 + b * 512 + u],
                   ((uint)(ushort)bf16s(h0n) << 16) | ((uint)(t + 2) & 0xffffu));
        }
        poll_stage32(h0pk + cur * 8192 + sflat, (uint)(t + 2) & 0xffffu,
                     hb + sb * 1032 + kseg * 32);
        poll_stage32(h1pk + ((t + 1) & 1) * 8192 + sflat, (uint)(t + 1) & 0xffffu,
                     hb + sb * 1032 + 512 + kseg * 32);
        __syncthreads();
        {
            f32x4 acc = {0.f, 0.f, 0.f, 0.f};
            const ushort* hp = hb + cl * 1032 + hi * 8;
#pragma unroll
            for (int kt = 0; kt < 32; kt++) {
                short8 bfr = *(const short8*)(hp + kt * 32);
                acc = __builtin_amdgcn_mfma_f32_16x16x32_bf16(a1[kt], bfr, acc, 0, 0, 0);
            }
#pragma unroll
            for (int i = 0; i < 4; i++) gs[w][hi * 4 + i][cl] = acc[i];
        }
        __syncthreads();
        {
            float g0 = bi0 + gs[0][u_loc][b];
            float g1 = bi1 + gs[1][u_loc][b];
            float g2 = bi2 + gs[2][u_loc][b];
            float g3 = bi3 + gs[3][u_loc][b];
            float ig = sigm(g0), fg = sigm(g1), gt = tanhf(g2), og = sigm(g3);
            c1v = fg * c1v + ig * gt;
            float h1n = og * tanhf(c1v);
            pstore(&h1pk[cur * 8192 + b * 512 + u],
                   ((uint)(ushort)bf16s(h1n) << 16) | ((uint)(t + 2) & 0xffffu));
            h1out[((size_t)(t * B + b)) * 512 + u] = h1n;
        }
        __syncthreads();
    }
}

// ---------------- transpose enc hidden to [b][k(512)][s]
__global__ void build_encht(const float* __restrict__ h1f, const float* __restrict__ h1b,
                            float* __restrict__ et) {
    int blk = blockIdx.x;
    int b = blk >> 8, rem = blk & 255;
    int kt = rem >> 4, st = rem & 15;
    int c = threadIdx.x & 31, r = threadIdx.x >> 5;
    __shared__ float tile[32][33];
#pragma unroll
    for (int i = 0; i < 4; i++) {
        int sl = r + i * 8;
        int s = st * 32 + sl;
        int k = kt * 32 + c;
        float v = (k < H) ? h1f[((size_t)(s * B + b)) * H + k]
                          : h1b[((size_t)(s * B + b)) * H + (k - H)];
        tile[c][sl] = v;
    }
    __syncthreads();
#pragma unroll
    for (int i = 0; i < 4; i++) {
        int kl = r + i * 8;
        et[(size_t)b * D * S + (size_t)(kt * 32 + kl) * S + st * 32 + c] = tile[kl][c];
    }
}

// ---------------- q projections. grid T*B, 512 threads
__global__ void qproj(const float* __restrict__ h1d, const float* __restrict__ Wenc,
                      const float* __restrict__ Wdec, float* __restrict__ qe, float* __restrict__ qd) {
    int n = blockIdx.x;
    int o = threadIdx.x;
    __shared__ float hr[D];
    hr[o] = h1d[(size_t)n * D + o];
    __syncthreads();
    float ae = 0.f, ad = 0.f;
#pragma unroll 4
    for (int k = 0; k < D; k++) {
        float hk = hr[k];
        ae += hk * Wenc[k * D + o];
        ad += hk * Wdec[k * D + o];
    }
    qe[(size_t)n * D + o] = ae;
    qd[(size_t)n * D + o] = ad;
}

// ---------------- e = exp(min(score,30)). grid B*T, 512 threads
__global__ void escore(const float* __restrict__ qe, const float* __restrict__ et,
                       float* __restrict__ ew) {
    int bt = blockIdx.x;
    int b = bt / T, t = bt - b * T;
    int sx = threadIdx.x;
    __shared__ float q[D];
    q[sx] = qe[((size_t)(t * B + b)) * D + sx];
    __syncthreads();
    float acc = 0.f;
    const float* eb = et + (size_t)b * D * S + sx;
#pragma unroll 4
    for (int k = 0; k < D; k++) { acc += q[k] * eb[0]; eb += S; }
    acc = fminf(acc, 30.0f);
    ew[(size_t)bt * S + sx] = __expf(acc);
}

// ---------------- temporal normalization (prefix over t)
__global__ void temporal_k(float* __restrict__ ew) {
    int i = blockIdx.x * blockDim.x + threadIdx.x;
    if (i >= B * S) return;
    int b = i / S, sx = i - b * S;
    float cum = 0.f;
    for (int t = 0; t < T; t++) {
        size_t idx = ((size_t)(b * T + t)) * S + sx;
        float v = ew[idx];
        ew[idx] = v / (t == 0 ? 1.0f : (cum + 1e-8f));
        cum += v;
    }
}

// ---------------- attention softmax + enc context + copy prob. grid B*T, 512 thr
__global__ void attnctx(const float* __restrict__ ew, const int* __restrict__ ids,
                        const int* __restrict__ tgt,
                        const float* __restrict__ h1f, const float* __restrict__ h1b,
                        float* __restrict__ ectx, float* __restrict__ copyp) {
    int bt = blockIdx.x;
    int b = bt / T, t = bt - b * T;
    int tid = threadIdx.x;
    __shared__ float aw[S];
    __shared__ float red[512];
    float v = ew[(size_t)bt * S + tid];
    int tok = ids[b * S + tid];
    bool pad = (tok == PAD_ID);
    float vm = pad ? -INFINITY : v;
    red[tid] = vm; __syncthreads();
    for (int w = 256; w > 0; w >>= 1) { if (tid < w) red[tid] = fmaxf(red[tid], red[tid + w]); __syncthreads(); }
    float m = red[0]; __syncthreads();
    float ex = pad ? 0.f : __expf(vm - m);
    red[tid] = ex; __syncthreads();
    for (int w = 256; w > 0; w >>= 1) { if (tid < w) red[tid] += red[tid + w]; __syncthreads(); }
    float Z = red[0]; __syncthreads();
    float a = ex / Z;
    aw[tid] = a;
    int nt = tgt[b * T + t];
    red[tid] = (tok == nt) ? a : 0.f; __syncthreads();
    for (int w = 256; w > 0; w >>= 1) { if (tid < w) red[tid] += red[tid + w]; __syncthreads(); }
    if (tid == 0) copyp[bt] = red[0];
    __syncthreads();
    int d = tid;
    const float* hp = (d < H) ? (h1f + (size_t)b * H + d) : (h1b + (size_t)b * H + (d - H));
    float acc = 0.f;
#pragma unroll 4
    for (int s2 = 0; s2 < S; s2++) { acc += aw[s2] * hp[0]; hp += B * H; }
    ectx[(size_t)bt * D + d] = acc;
}

// ---------------- intra-decoder attention. grid B*T, 128 threads
__global__ void decattn(const float* __restrict__ qd, const float* __restrict__ h1d,
                        float* __restrict__ dctx) {
    int bt = blockIdx.x;
    int b = bt / T, t = bt - b * T;
    int tid = threadIdx.x;
    __shared__ float q[D];
    __shared__ float wl[T];
    __shared__ float red[128];
    for (int i = tid; i < D; i += 128) q[i] = qd[((size_t)(t * B + b)) * D + i];
    __syncthreads();
    float sc = -INFINITY;
    if (tid < t) {
        const float* hu = h1d + ((size_t)(tid * B + b)) * D;
        float a = 0.f;
#pragma unroll 4
        for (int k = 0; k < D; k++) a += q[k] * hu[k];
        sc = a;
    }
    red[tid] = sc; __syncthreads();
    for (int w = 64; w > 0; w >>= 1) { if (tid < w) red[tid] = fmaxf(red[tid], red[tid + w]); __syncthreads(); }
    float m = red[0]; __syncthreads();
    float ex = (tid < t) ? __expf(sc - m) : 0.f;
    red[tid] = ex; __syncthreads();
    for (int w = 64; w > 0; w >>= 1) { if (tid < w) red[tid] += red[tid + w]; __syncthreads(); }
    float Z = red[0]; __syncthreads();
    wl[tid] = (t > 0) ? (ex / Z) : 0.f;
    __syncthreads();
    for (int d = tid; d < D; d += 128) {
        float acc = 0.f;
        for (int u = 0; u < t; u++) acc += wl[u] * h1d[((size_t)(u * B + b)) * D + d];
        dctx[(size_t)bt * D + d] = acc;
    }
}

// ---------------- concat + p_gen; writes bf16 ccb16 [row][1536]. grid B*T, 512 thr
__global__ void concat_k(const float* __restrict__ h1d, const float* __restrict__ ectx,
                         const float* __restrict__ dctx, const float* __restrict__ sW,
                         const float* __restrict__ sb, ushort* __restrict__ ccb16,
                         float* __restrict__ pgen) {
    int bt = blockIdx.x;
    int b = bt / T, t = bt - b * T;
    int d = threadIdx.x;
    __shared__ float red[512];
    float v0 = h1d[((size_t)(t * B + b)) * D + d];
    float v1 = ectx[(size_t)bt * D + d];
    float v2 = dctx[(size_t)bt * D + d];
    ushort* c = ccb16 + (size_t)bt * C3;
    c[d] = (ushort)bf16s(v0); c[D + d] = (ushort)bf16s(v1); c[2 * D + d] = (ushort)bf16s(v2);
    red[d] = v0 * sW[d] + v1 * sW[D + d] + v2 * sW[2 * D + d];
    __syncthreads();
    for (int w = 256; w > 0; w >>= 1) { if (d < w) red[d] += red[d + w]; __syncthreads(); }
    if (d == 0) pgen[bt] = 1.f / (1.f + __expf(-(red[0] + sb[0])));
}

// ---------------- out_proj, packed-k layout for MFMA B-fragments.
__global__ void outprojT_k(const float* __restrict__ emb, const float* __restrict__ Wvoc,
                           __hip_bfloat16* __restrict__ outT2) {
    int j0 = blockIdx.x * 32;
    int jl = threadIdx.x & 31, oq = threadIdx.x >> 5;
    __shared__ float er[32][E + 1];
    for (int i = threadIdx.x; i < 32 * E; i += 256) {
        int jj = i >> 7, e = i & 127;
        int j = j0 + jj;
        er[jj][e] = (j < VO) ? emb[(size_t)(3 + j) * E + e] : 0.f;
    }
    __syncthreads();
    int j = j0 + jl;
#pragma unroll 1
    for (int i = 0; i < 24; i++) {
        int o = oq * 24 + i;
        int k0 = o * 8;
        float acc[8];
#pragma unroll
        for (int kk = 0; kk < 8; kk++) acc[kk] = 0.f;
#pragma unroll 4
        for (int e = 0; e < E; e++) {
            float x = er[jl][e];
            float4 w0 = *(const float4*)(Wvoc + (size_t)e * C3 + k0);
            float4 w1 = *(const float4*)(Wvoc + (size_t)e * C3 + k0 + 4);
            acc[0] += x * w0.x; acc[1] += x * w0.y; acc[2] += x * w0.z; acc[3] += x * w0.w;
            acc[4] += x * w1.x; acc[5] += x * w1.y; acc[6] += x * w1.z; acc[7] += x * w1.w;
        }
        short8 v;
#pragma unroll
        for (int kk = 0; kk < 8; kk++) v[kk] = bf16s(tanhf(acc[kk]));
        *reinterpret_cast<short8*>((char*)outT2 + ((size_t)o * JS + j) * 16) = v;
    }
}

// ---------------- vocab GEMM: register-A (M=128/block), LDS double-buffered B stream.
// grid 256 = jg(0..15)*16 + rb(0..15). 512 threads = 8 waves; wave w owns rows
// row0 + w*16 with full K=1536 as 48 A-fragments in registers. Per 16-col tile:
// 48 MFMAs + fused online softmax. No cross-wave reduction.
__global__ void __launch_bounds__(512) vocab_mfma3(
        const __hip_bfloat16* __restrict__ outT2, const ushort* __restrict__ ccb16,
        const float* __restrict__ ob, const int* __restrict__ tgt,
        float* __restrict__ pbuf) {
    __shared__ __align__(16) ushort Bs[2][3072 * 8];   // 2 x 48 KB
    __shared__ int jstar_s[128];
    int bid = blockIdx.x;
    int rb = bid & 15, jg = bid >> 4;
    int row0 = rb * 128;
    int tid = threadIdx.x;
    int lane = tid & 63, w = tid >> 6;
    int cl = lane & 15, hi = lane >> 4;
    int j0base = jg * 2000;

    if (tid < 128) {
        int nt = tgt[row0 + tid];
        int ix = nt - 3;
        ix = ix < 0 ? 0 : (ix > VO - 1 ? VO - 1 : ix);
        jstar_s[tid] = ix;
    }
    // A-fragments: rows row0 + w*16 + cl, k-chunks kt*32 + hi*8
    short8 a[48];
    {
        const ushort* asrc = ccb16 + (size_t)(row0 + w * 16 + cl) * C3 + hi * 8;
#pragma unroll
        for (int kt = 0; kt < 48; kt++) a[kt] = *(const short8*)(asrc + kt * 32);
    }
    // prologue: stage tile 0 into buf 0
    {
#pragma unroll
        for (int ii = 0; ii < 6; ii++) {
            int c = w * 384 + ii * 64 + lane;
            int o = c >> 4, jl = c & 15;
            const char* g = (const char*)outT2 + ((size_t)o * JS + (size_t)(j0base + jl)) * 16;
            gload_lds16(g, (char*)&Bs[0][0] + (size_t)(w * 384 + ii * 64) * 16);
        }
    }
    asm volatile("s_waitcnt vmcnt(0)" ::: "memory");
    __syncthreads();
    int jst[4];
    float m[4], sacc[4], gl[4];
#pragma unroll
    for (int i = 0; i < 4; i++) {
        jst[i] = jstar_s[w * 16 + hi * 4 + i];
        m[i] = -1e30f; sacc[i] = 0.f; gl[i] = -1e30f;
    }
    int buf = 0;
    for (int t = 0; t < 125; t++) {
        if (t + 1 < 125) {
            int j0 = j0base + (t + 1) * 16;
#pragma unroll
            for (int ii = 0; ii < 6; ii++) {
                int c = w * 384 + ii * 64 + lane;
                int o = c >> 4, jl = c & 15;
                const char* g = (const char*)outT2 + ((size_t)o * JS + (size_t)(j0 + jl)) * 16;
                gload_lds16(g, (char*)&Bs[buf ^ 1][0] + (size_t)(w * 384 + ii * 64) * 16);
            }
        }
        f32x4 acc = {0.f, 0.f, 0.f, 0.f};
        const ushort* bp = &Bs[buf][0] + (size_t)(hi * 16 + cl) * 8;
#pragma unroll
        for (int kt = 0; kt < 48; kt++) {
            short8 b = *(const short8*)(bp + (size_t)kt * 512);
            acc = __builtin_amdgcn_mfma_f32_16x16x32_bf16(a[kt], b, acc, 0, 0, 0);
        }
        int j = j0base + t * 16 + cl;
        bool valid = j < VO;
        float obj = valid ? ob[j] : 0.f;
#pragma unroll
        for (int i = 0; i < 4; i++) {
            float L = acc[i] + obj;
            if (valid) {
                if (j == jst[i]) gl[i] = L;
                float mn = fmaxf(m[i], L);
                sacc[i] = sacc[i] * __expf(m[i] - mn) + __expf(L - mn);
                m[i] = mn;
            }
        }
        asm volatile("s_waitcnt vmcnt(0)" ::: "memory");
        __syncthreads();
        buf ^= 1;
    }
    // wave-local reduce over the 16 col-lanes (cl bits = low 4 of lane)
#pragma unroll
    for (int i = 0; i < 4; i++) {
        for (int mask = 1; mask < 16; mask <<= 1) {
            float om = __shfl_xor(m[i], mask);
            float os = __shfl_xor(sacc[i], mask);
            float mn = fmaxf(m[i], om);
            sacc[i] = sacc[i] * __expf(m[i] - mn) + os * __expf(om - mn);
            m[i] = mn;
            gl[i] = fmaxf(gl[i], __shfl_xor(gl[i], mask));
        }
    }
    if (cl == 0) {
#pragma unroll
        for (int i = 0; i < 4; i++) {
            int rl = w * 16 + hi * 4 + i;
            float* o = pbuf + ((size_t)(jg * 16 + rb) * 128 + rl) * 4;
            o[0] = m[i]; o[1] = sacc[i]; o[2] = gl[i];
        }
    }
}

// ---------------- combine 16 jg-partials + pointer mix + NLL. grid B, 128 threads.
__global__ void combine_nll_k(const float* __restrict__ pbuf, const int* __restrict__ tgt,
                              const float* __restrict__ pgen, const float* __restrict__ copyp,
                              const int* __restrict__ tlen, float* __restrict__ out) {
    int b = blockIdx.x, t = threadIdx.x;
    int row = b * T + t;
    int rb = row >> 7, rl = row & 127;
    float M = -1e30f, SS = 0.f, GL = -1e30f;
#pragma unroll
    for (int q = 0; q < 16; q++) {
        const float* p = pbuf + ((size_t)(q * 16 + rb) * 128 + rl) * 4;
        float mq = p[0], sq = p[1], gq = p[2];
        float mn = fmaxf(M, mq);
        SS = SS * __expf(M - mn) + sq * __expf(mq - mn);
        M = mn;
        GL = fmaxf(GL, gq);
    }
    int nt = tgt[row];
    float genp = (nt >= 3 && nt < V) ? __expf(GL - M) / SS : 0.f;
    float pg = pgen[row];
    float p = pg * genp + (1.f - pg) * copyp[row];
    __shared__ float red[128];
    red[t] = (t < tlen[b]) ? -logf(p + 1e-9f) : 0.f;
    __syncthreads();
    for (int w = 64; w > 0; w >>= 1) { if (t < w) red[t] += red[t + w]; __syncthreads(); }
    if (t == 0) out[b] = red[0];
}

extern "C" void kernel_launch(void* const* d_in, const int* in_sizes, int n_in,
                              void* d_out, int out_size, void* d_ws, size_t ws_size,
                              hipStream_t stream) {
    const int* input_ids = (const int*)d_in[0];
    const int* target_ids = (const int*)d_in[1];
    const int* tlen = (const int*)d_in[3];
    const float* emb = (const float*)d_in[5];
    const float* eWih0f = (const float*)d_in[6],  *eWhh0f = (const float*)d_in[7],  *eb0f = (const float*)d_in[8];
    const float* eWih0b = (const float*)d_in[9],  *eWhh0b = (const float*)d_in[10], *eb0b = (const float*)d_in[11];
    const float* eWih1f = (const float*)d_in[12], *eWhh1f = (const float*)d_in[13], *eb1f = (const float*)d_in[14];
    const float* eWih1b = (const float*)d_in[15], *eWhh1b = (const float*)d_in[16], *eb1b = (const float*)d_in[17];
    const float* dWih0 = (const float*)d_in[18], *dWhh0 = (const float*)d_in[19], *db0 = (const float*)d_in[20];
    const float* dWih1 = (const float*)d_in[21], *dWhh1 = (const float*)d_in[22], *db1 = (const float*)d_in[23];
    const float* Wenc = (const float*)d_in[24], *Wdec = (const float*)d_in[25];
    const float* Wvoc = (const float*)d_in[26], *sW = (const float*)d_in[27], *sb = (const float*)d_in[28];
    const float* ob = (const float*)d_in[29];
    float* out = (float*)d_out;
    (void)ws_size; (void)n_in; (void)in_sizes; (void)out_size;

    // ============ workspace layout (~145.1 MB, phase-aliased) ============
    char* A = (char*)d_ws;
    float4* pWih0f = (float4*)(A + 0);
    float4* pWih0b = (float4*)(A + 524288);
    ushort* PMW1f  = (ushort*)(A + 1048576);
    ushort* PMW1b  = (ushort*)(A + 2097152);
    float4* pdWih0 = (float4*)(A + 5242880);
    ushort* PMf0  = (ushort*)(A + 6291456);
    ushort* PMb0  = (ushort*)(A + 6815744);
    ushort* PMf1  = (ushort*)(A + 7340032);
    ushort* PMb1  = (ushort*)(A + 7864320);
    ushort* PM0   = (ushort*)(A + 8388608);
    ushort* PM1   = (ushort*)(A + 10485760);
    float* G0f = (float*)(A + 23068672);
    float* G0b = (float*)(A + 56623104);
    float* Gd0 = (float*)(A + 23068672);            // aliases G0f (dead after enc scans)
    float* ench = (float*)(A + 39845888);
    float* ectx = (float*)(A + 56623104);
    float* dctx = (float*)(A + 60817408);
    __hip_bfloat16* outT2 = (__hip_bfloat16*)A;     // whole region, after concat_k

    char* Bh = A + 98304000;
    float* h0f = (float*)(Bh + 0);
    float* h0b = (float*)(Bh + 8388608);
    float* h1d = (float*)(Bh + 0);                  // aliases h0f (dead after enc1 gates)
    float* qe  = (float*)(Bh + 4194304);
    float* qd  = (float*)(Bh + 8388608);
    float* ew  = (float*)(Bh + 12582912);
    float* pbuf = (float*)(Bh + 12582912);          // aliases ew (dead after attnctx); 512 KB
    char* Cr = Bh + 16777216;
    float* h1f = (float*)(Cr + 0);
    float* h1b = (float*)(Cr + 8388608);
    ushort* ccb16 = (ushort*)(Cr + 16777216);
    float* dec_init = (float*)(Cr + 29360128);
    float* pgen  = (float*)(Cr + 29425664);
    float* copyp = (float*)(Cr + 29433856);
    uint* hpkE0  = (uint*)(Cr + 29769728);          // 64 KB (enc L0 packets)
    uint* hpkE1  = (uint*)(Cr + 29835264);          // 64 KB (enc L1 packets)
    uint* h0pkD  = (uint*)(Cr + 29900800);          // 64 KB (dec h0 packets)
    uint* h1pkD  = (uint*)(Cr + 29966336);          // 64 KB (dec h1 packets)
    // total ≈ 145.1 MB

    hipMemsetAsync(hpkE0, 0, 262144, stream);       // all four packet regions (contiguous)

    auto pack = [&](const float* W, float4* P, int Hn, int K) {
        int total = Hn * K;
        hipLaunchKernelGGL(pack4_kernel, dim3((total + 255) / 256), dim3(256), 0, stream, W, P, Hn, K);
    };
    pack(eWih0f, pWih0f, H, E);
    pack(eWih0b, pWih0b, H, E);
    pack(dWih0, pdWih0, D, E);
    hipLaunchKernelGGL(packencMK_k, dim3(4 * H * 256 / 256), dim3(256), 0, stream, eWhh0f, PMf0, 256);
    hipLaunchKernelGGL(packencMK_k, dim3(4 * H * 256 / 256), dim3(256), 0, stream, eWhh0b, PMb0, 256);
    hipLaunchKernelGGL(packencMK_k, dim3(4 * H * 256 / 256), dim3(256), 0, stream, eWhh1f, PMf1, 256);
    hipLaunchKernelGGL(packencMK_k, dim3(4 * H * 256 / 256), dim3(256), 0, stream, eWhh1b, PMb1, 256);
    hipLaunchKernelGGL(packencMK_k, dim3(4 * H * 512 / 256), dim3(256), 0, stream, eWih1f, PMW1f, 512);
    hipLaunchKernelGGL(packencMK_k, dim3(4 * H * 512 / 256), dim3(256), 0, stream, eWih1b, PMW1b, 512);
    hipLaunchKernelGGL(packdecM_k, dim3(4 * D * D / 256), dim3(256), 0, stream, dWhh0, PM0);
    hipLaunchKernelGGL(packdecM2_k, dim3(8 * D * D / 256), dim3(256), 0, stream, dWih1, dWhh1, PM1);

    hipLaunchKernelGGL(enc0_gates2, dim3(S * B / 8), dim3(256), 0, stream,
                       input_ids, emb, pWih0f, eb0f, pWih0b, eb0b, G0f, G0b);
    hipLaunchKernelGGL(enc_pscan3, dim3(16), dim3(256), 0, stream,
                       G0f, G0b, PMf0, PMb0, h0f, h0b, dec_init, hpkE0);
    hipLaunchKernelGGL(enc1g_mfma, dim3(256), dim3(256), 0, stream,
                       h0f, h0b, PMW1f, PMW1b, eb1f, eb1b, G0f, G0b);
    hipLaunchKernelGGL(enc_pscan3, dim3(16), dim3(256), 0, stream,
                       G0f, G0b, PMf1, PMb1, h1f, h1b, dec_init + B * D, hpkE1);
    hipLaunchKernelGGL(dec0_gates2, dim3(T * B / 8), dim3(512), 0, stream,
                       target_ids, emb, pdWih0, db0, Gd0);
    hipLaunchKernelGGL(dec_initpk, dim3(B * D / 256), dim3(256), 0, stream,
                       dec_init, h0pkD, h1pkD);
    hipLaunchKernelGGL(dec_mfma2, dim3(32), dim3(256), 0, stream,
                       Gd0, PM0, PM1, db1, h0pkD, h1pkD, h1d);
    hipLaunchKernelGGL(build_encht, dim3(B * 256), dim3(256), 0, stream, h1f, h1b, ench);
    hipLaunchKernelGGL(qproj, dim3(T * B), dim3(D), 0, stream, h1d, Wenc, Wdec, qe, qd);
    hipLaunchKernelGGL(escore, dim3(B * T), dim3(S), 0, stream, qe, ench, ew);
    hipLaunchKernelGGL(temporal_k, dim3((B * S + 255) / 256), dim3(256), 0, stream, ew);
    hipLaunchKernelGGL(attnctx, dim3(B * T), dim3(S), 0, stream,
                       ew, input_ids, target_ids, h1f, h1b, ectx, copyp);
    hipLaunchKernelGGL(decattn, dim3(B * T), dim3(T), 0, stream, qd, h1d, dctx);
    hipLaunchKernelGGL(concat_k, dim3(B * T), dim3(D), 0, stream,
                       h1d, ectx, dctx, sW, sb, ccb16, pgen);
    hipLaunchKernelGGL(outprojT_k, dim3(1000), dim3(256), 0, stream, emb, Wvoc, outT2);
    hipLaunchKernelGGL(vocab_mfma3, dim3(256), dim3(512), 0, stream,
                       outT2, ccb16, ob, target_ids, pbuf);
    hipLaunchKernelGGL(combine_nll_k, dim3(B), dim3(T), 0, stream,
                       pbuf, target_ids, pgen, copyp, tlen, out);
}

// Round 14
// 4157.093 us; speedup vs baseline: 5.5351x; 1.1815x over previous
//
#include <hip/hip_runtime.h>
#include <hip/hip_bf16.h>
#include <math.h>

#define PAD_ID 0
#define UNK_ID 1
#define START_ID 2
#define END_ID 3

constexpr int B = 16, S = 512, T = 128, V = 32000, E = 128, H = 256, D = 512;
constexpr int C3 = 1536;        // 3*D
constexpr int VO = 31997;       // V-3
constexpr int JS = 32000;       // padded col count for outT2

typedef short short8 __attribute__((ext_vector_type(8)));
typedef float f32x4 __attribute__((ext_vector_type(4)));

__device__ __forceinline__ float sigm(float x) { return 1.0f / (1.0f + __expf(-x)); }
__device__ __forceinline__ short bf16s(float x) {
    __hip_bfloat16 h = __float2bfloat16(x);
    return *reinterpret_cast<short*>(&h);
}

__device__ __forceinline__ uint4 cloadu4(const uint* p) {
    uint4 v;
    asm volatile("global_load_dwordx4 %0, %1, off sc0 sc1" : "=v"(v) : "v"(p));
    return v;
}
__device__ __forceinline__ void pstore(uint* p, uint v) {
    __hip_atomic_store(p, v, __ATOMIC_RELAXED, __HIP_MEMORY_SCOPE_AGENT);
}

__device__ __forceinline__ void gload_lds16(const void* g, void* l) {
    __builtin_amdgcn_global_load_lds(
        (const __attribute__((address_space(1))) void*)(g),
        (__attribute__((address_space(3))) void*)(l), 16, 0, 0);
}

__device__ __forceinline__ void st_bf8(ushort* dst, float4 a, float4 b) {
    short8 o;
    o[0] = bf16s(a.x); o[1] = bf16s(a.y); o[2] = bf16s(a.z); o[3] = bf16s(a.w);
    o[4] = bf16s(b.x); o[5] = bf16s(b.y); o[6] = bf16s(b.z); o[7] = bf16s(b.w);
    *(short8*)dst = o;
}

// ---------------- poll 16 packets (4 dwordx4) tagged e; write 16 bf16 to dst
__device__ __forceinline__ void poll_stage16(const uint* src, uint e, ushort* dst) {
    uint4 a0, a1, a2, a3;
    for (;;) {
        a0 = cloadu4(src); a1 = cloadu4(src + 4); a2 = cloadu4(src + 8); a3 = cloadu4(src + 12);
        asm volatile("s_waitcnt vmcnt(0)" ::: "memory");
        __builtin_amdgcn_sched_barrier(0);
        uint d = (a0.x ^ e) | (a0.y ^ e) | (a0.z ^ e) | (a0.w ^ e)
               | (a1.x ^ e) | (a1.y ^ e) | (a1.z ^ e) | (a1.w ^ e)
               | (a2.x ^ e) | (a2.y ^ e) | (a2.z ^ e) | (a2.w ^ e)
               | (a3.x ^ e) | (a3.y ^ e) | (a3.z ^ e) | (a3.w ^ e);
        if ((d & 0xffffu) == 0) break;
        __builtin_amdgcn_s_sleep(1);
    }
    short8 o0, o1;
    o0[0] = (short)(a0.x >> 16); o0[1] = (short)(a0.y >> 16); o0[2] = (short)(a0.z >> 16); o0[3] = (short)(a0.w >> 16);
    o0[4] = (short)(a1.x >> 16); o0[5] = (short)(a1.y >> 16); o0[6] = (short)(a1.z >> 16); o0[7] = (short)(a1.w >> 16);
    o1[0] = (short)(a2.x >> 16); o1[1] = (short)(a2.y >> 16); o1[2] = (short)(a2.z >> 16); o1[3] = (short)(a2.w >> 16);
    o1[4] = (short)(a3.x >> 16); o1[5] = (short)(a3.y >> 16); o1[6] = (short)(a3.z >> 16); o1[7] = (short)(a3.w >> 16);
    *(short8*)dst = o0;
    *(short8*)(dst + 8) = o1;
}

// ---------------- poll 32 packets (8 dwordx4) tagged e; write 32 bf16 to dst
__device__ __forceinline__ void poll_stage32(const uint* src, uint e, ushort* dst) {
    uint4 a[8];
    for (;;) {
#pragma unroll
        for (int i = 0; i < 8; i++) a[i] = cloadu4(src + i * 4);
        asm volatile("s_waitcnt vmcnt(0)" ::: "memory");
        __builtin_amdgcn_sched_barrier(0);
        uint d = 0;
#pragma unroll
        for (int i = 0; i < 8; i++)
            d |= (a[i].x ^ e) | (a[i].y ^ e) | (a[i].z ^ e) | (a[i].w ^ e);
        if ((d & 0xffffu) == 0) break;
        __builtin_amdgcn_s_sleep(1);
    }
#pragma unroll
    for (int i = 0; i < 8; i += 2) {
        short8 o;
        o[0] = (short)(a[i].x >> 16);     o[1] = (short)(a[i].y >> 16);
        o[2] = (short)(a[i].z >> 16);     o[3] = (short)(a[i].w >> 16);
        o[4] = (short)(a[i + 1].x >> 16); o[5] = (short)(a[i + 1].y >> 16);
        o[6] = (short)(a[i + 1].z >> 16); o[7] = (short)(a[i + 1].w >> 16);
        *(short8*)(dst + i * 4) = o;
    }
}

// ---------------- weight packing: W[4H][K] -> P[k][u] = float4 of 4 gates
__global__ void pack4_kernel(const float* __restrict__ W, float4* __restrict__ P, int Hn, int K) {
    int i = blockIdx.x * blockDim.x + threadIdx.x;
    if (i >= K * Hn) return;
    int k = i / Hn, u = i - k * Hn;
    float4 v;
    v.x = W[(size_t)(0 * Hn + u) * K + k];
    v.y = W[(size_t)(1 * Hn + u) * K + k];
    v.z = W[(size_t)(2 * Hn + u) * K + k];
    v.w = W[(size_t)(3 * Hn + u) * K + k];
    P[(size_t)k * Hn + u] = v;
}

// ---------------- MFMA-row pack (H=256 outputs): row = (u>>3)*32 + g*8 + (u&7)
__global__ void packencMK_k(const float* __restrict__ W, ushort* __restrict__ P, int K) {
    int i = blockIdx.x * blockDim.x + threadIdx.x;
    if (i >= 4 * H * K) return;
    int k = i % K, row = i / K;
    int g = (row >> 3) & 3, ul = row & 7, uh = row >> 5;
    int u = uh * 8 + ul;
    P[i] = (ushort)bf16s(W[(size_t)(g * H + u) * K + k]);
}

// ---------------- decoder W0 pack for MFMA (row = bk*64 + g*16 + u%16)
__global__ void packdecM_k(const float* __restrict__ W, ushort* __restrict__ P) {
    int i = blockIdx.x * blockDim.x + threadIdx.x;
    if (i >= 4 * D * D) return;
    int k = i & 511, row = i >> 9;
    int g = (row >> 4) & 3, u = (row >> 6) * 16 + (row & 15);
    P[i] = (ushort)bf16s(W[(size_t)(g * D + u) * D + k]);
}

// ---------------- decoder layer1 pack: [W1i | W1h] -> PM1[row][1024] bf16
__global__ void packdecM2_k(const float* __restrict__ Wi, const float* __restrict__ Wh,
                            ushort* __restrict__ P) {
    int i = blockIdx.x * blockDim.x + threadIdx.x;
    if (i >= 4 * D * D * 2) return;
    int k = i & 1023, row = i >> 10;
    int g = (row >> 4) & 3, u = (row >> 6) * 16 + (row & 15);
    float v = (k < 512) ? Wi[(size_t)(g * D + u) * D + k]
                        : Wh[(size_t)(g * D + u) * D + (k - 512)];
    P[i] = (ushort)bf16s(v);
}

// ---------------- encoder layer-0 gates, tiled (8 rows/block). grid S*B/8, 256 thr.
__global__ void enc0_gates2(const int* __restrict__ ids, const float* __restrict__ emb,
                            const float4* __restrict__ Pf, const float* __restrict__ bf_,
                            const float4* __restrict__ Pb, const float* __restrict__ bb_,
                            float* __restrict__ Gf, float* __restrict__ Gb) {
    int n0 = blockIdx.x * 8;
    int u = threadIdx.x;
    __shared__ float xr[8][E];
    for (int i = u; i < 8 * E; i += 256) {
        int r = i >> 7, e = i & 127;
        int n = n0 + r, s = n / B, b = n - s * B;
        int tok = ids[b * S + s];
        if (tok >= V) tok = UNK_ID;
        xr[r][e] = emb[(size_t)tok * E + e];
    }
    __syncthreads();
#pragma unroll
    for (int dir = 0; dir < 2; dir++) {
        const float4* P = dir ? Pb : Pf;
        const float* bs = dir ? bb_ : bf_;
        float* G = dir ? Gb : Gf;
        float acc[8][4];
#pragma unroll
        for (int r = 0; r < 8; r++)
#pragma unroll
            for (int g = 0; g < 4; g++) acc[r][g] = 0.f;
#pragma unroll 4
        for (int k = 0; k < E; k++) {
            float4 w = P[k * H + u];
#pragma unroll
            for (int r = 0; r < 8; r++) {
                float x = xr[r][k];
                acc[r][0] += x * w.x; acc[r][1] += x * w.y;
                acc[r][2] += x * w.z; acc[r][3] += x * w.w;
            }
        }
        float b0 = bs[u], b1 = bs[H + u], b2 = bs[2 * H + u], b3 = bs[3 * H + u];
#pragma unroll
        for (int r = 0; r < 8; r++) {
            float* g = G + (size_t)(n0 + r) * (4 * H);
            g[u] = acc[r][0] + b0; g[H + u] = acc[r][1] + b1;
            g[2 * H + u] = acc[r][2] + b2; g[3 * H + u] = acc[r][3] + b3;
        }
    }
}

// ---------------- encoder layer-1 gates via MFMA (passing). grid 256, 256 thr.
__global__ void __launch_bounds__(256) enc1g_mfma(
        const float* __restrict__ h0f, const float* __restrict__ h0b,
        const ushort* __restrict__ PMf, const ushort* __restrict__ PMb,
        const float* __restrict__ bf_, const float* __restrict__ bb_,
        float* __restrict__ Gf, float* __restrict__ Gb) {
    __shared__ __align__(16) ushort X[16 * 520];
    __shared__ float gs[4][32][17];
    __shared__ float bias_s[128];
    int bid = blockIdx.x;
    int dirb = (bid >> 3) & 1, bk = bid & 7, ns = bid >> 4;
    const ushort* PM = dirb ? PMb : PMf;
    const float* bs = dirb ? bb_ : bf_;
    float* G = dirb ? Gb : Gf;
    int tid = threadIdx.x;
    int lane = tid & 63, w = tid >> 6;
    int cl = lane & 15, hi = lane >> 4;

    short8 afr[2][16];
    {
        int rowbase = (bk * 4 + w) * 32;
#pragma unroll
        for (int mt = 0; mt < 2; mt++)
#pragma unroll
            for (int kt = 0; kt < 16; kt++)
                afr[mt][kt] = *(const short8*)(PM + (size_t)(rowbase + mt * 16 + cl) * 512 + kt * 32 + hi * 8);
    }
    if (tid < 128) {
        int g = (tid >> 3) & 3;
        int u = (bk * 4 + (tid >> 5)) * 8 + (tid & 7);
        bias_s[tid] = bs[g * H + u];
    }
    int nl = tid >> 4, kseg = tid & 15;
    int en = tid & 15, rgrp = tid >> 4;
    for (int tt = 0; tt < 32; tt++) {
        int nt = ns * 32 + tt;
        __syncthreads();
        {
            int n = nt * 16 + nl;
            const float* src = (kseg < 8) ? (h0f + (size_t)n * H + kseg * 32)
                                          : (h0b + (size_t)n * H + (kseg - 8) * 32);
            float4 v0 = *(const float4*)(src), v1 = *(const float4*)(src + 4);
            float4 v2 = *(const float4*)(src + 8), v3 = *(const float4*)(src + 12);
            float4 v4 = *(const float4*)(src + 16), v5 = *(const float4*)(src + 20);
            float4 v6 = *(const float4*)(src + 24), v7 = *(const float4*)(src + 28);
            ushort* dst = X + nl * 520 + kseg * 32;
            st_bf8(dst, v0, v1); st_bf8(dst + 8, v2, v3);
            st_bf8(dst + 16, v4, v5); st_bf8(dst + 24, v6, v7);
        }
        __syncthreads();
        {
            f32x4 acc0 = {0.f, 0.f, 0.f, 0.f}, acc1 = {0.f, 0.f, 0.f, 0.f};
            const ushort* hp = X + cl * 520 + hi * 8;
#pragma unroll
            for (int kt = 0; kt < 16; kt++) {
                short8 bfr = *(const short8*)(hp + kt * 32);
                acc0 = __builtin_amdgcn_mfma_f32_16x16x32_bf16(afr[0][kt], bfr, acc0, 0, 0, 0);
                acc1 = __builtin_amdgcn_mfma_f32_16x16x32_bf16(afr[1][kt], bfr, acc1, 0, 0, 0);
            }
#pragma unroll
            for (int i = 0; i < 4; i++) {
                gs[w][hi * 4 + i][cl] = acc0[i];
                gs[w][16 + hi * 4 + i][cl] = acc1[i];
            }
        }
        __syncthreads();
        {
            int wv = rgrp >> 2, g = rgrp & 3;
            int u0 = (bk * 4 + wv) * 8;
            float* dst = G + (size_t)(nt * 16 + en) * 1024 + g * 256 + u0;
            float4 o0, o1;
            o0.x = gs[wv][g * 8 + 0][en] + bias_s[rgrp * 8 + 0];
            o0.y = gs[wv][g * 8 + 1][en] + bias_s[rgrp * 8 + 1];
            o0.z = gs[wv][g * 8 + 2][en] + bias_s[rgrp * 8 + 2];
            o0.w = gs[wv][g * 8 + 3][en] + bias_s[rgrp * 8 + 3];
            o1.x = gs[wv][g * 8 + 4][en] + bias_s[rgrp * 8 + 4];
            o1.y = gs[wv][g * 8 + 5][en] + bias_s[rgrp * 8 + 5];
            o1.z = gs[wv][g * 8 + 6][en] + bias_s[rgrp * 8 + 6];
            o1.w = gs[wv][g * 8 + 7][en] + bias_s[rgrp * 8 + 7];
            *(float4*)dst = o0;
            *(float4*)(dst + 4) = o1;
        }
    }
}

// ================= device bodies for mega-kernels =================

// ---- enc scan body (dataflow packets). blk in [0,16). smem >= 17152 B.
__device__ __forceinline__ void enc_scan_body(int blk, char* smem,
        const float* __restrict__ Gf, const float* __restrict__ Gb,
        const ushort* __restrict__ PMf, const ushort* __restrict__ PMb,
        float* __restrict__ hof, float* __restrict__ hob,
        float* __restrict__ hfin, uint* __restrict__ pk) {
    ushort* hh = (ushort*)smem;                                  // 8448 B
    float (*gs)[32][17] = (float(*)[32][17])(smem + 8448);       // 8704 B
    int dirb = blk >> 3, bk = blk & 7;
    const float* G = dirb ? Gb : Gf;
    const ushort* PM = dirb ? PMb : PMf;
    float* ho = dirb ? hob : hof;
    int tid = threadIdx.x;
    int lane = tid & 63, w = tid >> 6;
    int cl = lane & 15, hi = lane >> 4;

    short8 afr[2][8];
    {
        int rowbase = (bk * 4 + w) * 32;
#pragma unroll
        for (int mt = 0; mt < 2; mt++)
#pragma unroll
            for (int kt = 0; kt < 8; kt++)
                afr[mt][kt] = *(const short8*)(PM + (size_t)(rowbase + mt * 16 + cl) * 256 + kt * 32 + hi * 8);
    }
    int ub = tid & 31, bb = tid >> 5;
    int u_glob = bk * 32 + ub;
    int gsw = ub >> 3, ul = ub & 7;
    float c_a = 0.f, c_b = 0.f;
    int b0s = tid >> 4, u0s = (tid & 15) * 16;

    for (int step = 0; step < S; step++) {
        int s = dirb ? (S - 1 - step) : step;
        int cur = step & 1;
        const float* gA = G + ((size_t)(s * B + bb)) * 1024 + u_glob;
        const float* gB = G + ((size_t)(s * B + bb + 8)) * 1024 + u_glob;
        float pa0 = gA[0], pa1 = gA[256], pa2 = gA[512], pa3 = gA[768];
        float pb0 = gB[0], pb1 = gB[256], pb2 = gB[512], pb3 = gB[768];
        poll_stage16(pk + cur * 8192 + dirb * 4096 + tid * 16,
                     (uint)step & 0xffffu, hh + b0s * 264 + u0s);
        __syncthreads();
        {
            f32x4 acc0 = {0.f, 0.f, 0.f, 0.f}, acc1 = {0.f, 0.f, 0.f, 0.f};
            const ushort* hp = hh + cl * 264 + hi * 8;
#pragma unroll
            for (int kt = 0; kt < 8; kt++) {
                short8 bfr = *(const short8*)(hp + kt * 32);
                acc0 = __builtin_amdgcn_mfma_f32_16x16x32_bf16(afr[0][kt], bfr, acc0, 0, 0, 0);
                acc1 = __builtin_amdgcn_mfma_f32_16x16x32_bf16(afr[1][kt], bfr, acc1, 0, 0, 0);
            }
#pragma unroll
            for (int i = 0; i < 4; i++) {
                gs[w][hi * 4 + i][cl] = acc0[i];
                gs[w][16 + hi * 4 + i][cl] = acc1[i];
            }
        }
        __syncthreads();
        {
            float q0 = gs[gsw][0 + ul][bb];
            float q1 = gs[gsw][8 + ul][bb];
            float q2 = gs[gsw][16 + ul][bb];
            float q3 = gs[gsw][24 + ul][bb];
            float ig = sigm(pa0 + q0), fg = sigm(pa1 + q1), gt = tanhf(pa2 + q2), og = sigm(pa3 + q3);
            c_a = fg * c_a + ig * gt;
            float hA = og * tanhf(c_a);
            q0 = gs[gsw][0 + ul][bb + 8];
            q1 = gs[gsw][8 + ul][bb + 8];
            q2 = gs[gsw][16 + ul][bb + 8];
            q3 = gs[gsw][24 + ul][bb + 8];
            ig = sigm(pb0 + q0); fg = sigm(pb1 + q1); gt = tanhf(pb2 + q2); og = sigm(pb3 + q3);
            c_b = fg * c_b + ig * gt;
            float hB = og * tanhf(c_b);
            uint tg = (uint)(step + 1) & 0xffffu;
            uint* dstp = pk + (cur ^ 1) * 8192 + dirb * 4096;
            pstore(&dstp[bb * 256 + u_glob], ((uint)(ushort)bf16s(hA) << 16) | tg);
            pstore(&dstp[(bb + 8) * 256 + u_glob], ((uint)(ushort)bf16s(hB) << 16) | tg);
            ho[((size_t)(s * B + bb)) * H + u_glob] = hA;
            ho[((size_t)(s * B + bb + 8)) * H + u_glob] = hB;
            if (step == S - 1) {
                hfin[bb * (2 * H) + dirb * H + u_glob] = hA;
                hfin[(bb + 8) * (2 * H) + dirb * H + u_glob] = hB;
            }
        }
    }
}

// ---- dec0 gates body (256 thr, 8 rows, two u-passes). smem >= 4096 B.
__device__ __forceinline__ void dec0_body(int bid, char* smem,
        const int* __restrict__ tgt, const float* __restrict__ emb,
        const float4* __restrict__ P, const float* __restrict__ bias,
        float* __restrict__ G) {
    float (*xr)[E] = (float(*)[E])smem;
    int n0 = bid * 8;
    int tid = threadIdx.x;
    for (int i = tid; i < 8 * E; i += 256) {
        int r = i >> 7, e = i & 127;
        int n = n0 + r, t = n / B, b = n - t * B;
        int tok;
        if (t == 0) tok = START_ID;
        else { tok = tgt[b * T + (t - 1)]; if (tok >= V) tok = UNK_ID; }
        xr[r][e] = emb[(size_t)tok * E + e];
    }
    __syncthreads();
#pragma unroll
    for (int half = 0; half < 2; half++) {
        int u = tid + half * 256;
        float acc[8][4];
#pragma unroll
        for (int r = 0; r < 8; r++)
#pragma unroll
            for (int g = 0; g < 4; g++) acc[r][g] = 0.f;
#pragma unroll 4
        for (int k = 0; k < E; k++) {
            float4 w = P[k * D + u];
#pragma unroll
            for (int r = 0; r < 8; r++) {
                float x = xr[r][k];
                acc[r][0] += x * w.x; acc[r][1] += x * w.y;
                acc[r][2] += x * w.z; acc[r][3] += x * w.w;
            }
        }
        float b0 = bias[u], b1 = bias[D + u], b2 = bias[2 * D + u], b3 = bias[3 * D + u];
#pragma unroll
        for (int r = 0; r < 8; r++) {
            float* g = G + (size_t)(n0 + r) * (4 * D);
            g[u] = acc[r][0] + b0; g[D + u] = acc[r][1] + b1;
            g[2 * D + u] = acc[r][2] + b2; g[3 * D + u] = acc[r][3] + b3;
        }
    }
}

// ---- dec scan body (dataflow). blk in [0,32). smem >= 37376 B.
__device__ __forceinline__ void dec_body(int bk, char* smem,
        const float* __restrict__ G0, const ushort* __restrict__ PM0,
        const ushort* __restrict__ PM1, const float* __restrict__ b1,
        uint* __restrict__ h0pk, uint* __restrict__ h1pk,
        float* __restrict__ h1out) {
    ushort* hb = (ushort*)smem;                              // 33024 B
    float (*gs)[16][17] = (float(*)[16][17])(smem + 33024);  // 4352 B
    int tid = threadIdx.x;
    int lane = tid & 63, w = tid >> 6;
    int cl = lane & 15, hi = lane >> 4;

    short8 a0[16], a1[32];
    {
        const ushort* base0 = PM0 + (size_t)(bk * 64 + w * 16 + cl) * 512 + hi * 8;
#pragma unroll
        for (int kt = 0; kt < 16; kt++) a0[kt] = *(const short8*)(base0 + kt * 32);
        const ushort* base1 = PM1 + (size_t)(bk * 64 + w * 16 + cl) * 1024 + hi * 8;
#pragma unroll
        for (int kt = 0; kt < 32; kt++) a1[kt] = *(const short8*)(base1 + kt * 32);
    }
    int u_loc = tid & 15, b = tid >> 4;
    int u = bk * 16 + u_loc;
    float bi0 = b1[u], bi1 = b1[512 + u], bi2 = b1[1024 + u], bi3 = b1[1536 + u];
    float c0v = 0.f, c1v = 0.f;
    int sb = tid >> 4, kseg = tid & 15;
    int sflat = sb * 512 + kseg * 32;

    for (int t = 0; t < T; t++) {
        int cur = t & 1;
        poll_stage32(h0pk + ((t + 1) & 1) * 8192 + sflat, (uint)(t + 1) & 0xffffu,
                     hb + sb * 1032 + kseg * 32);
        __syncthreads();
        {
            f32x4 acc = {0.f, 0.f, 0.f, 0.f};
            const ushort* hp = hb + cl * 1032 + hi * 8;
#pragma unroll
            for (int kt = 0; kt < 16; kt++) {
                short8 bfr = *(const short8*)(hp + kt * 32);
                acc = __builtin_amdgcn_mfma_f32_16x16x32_bf16(a0[kt], bfr, acc, 0, 0, 0);
            }
#pragma unroll
            for (int i = 0; i < 4; i++) gs[w][hi * 4 + i][cl] = acc[i];
        }
        __syncthreads();
        {
            const float* gg = G0 + ((size_t)(t * B + b)) * 2048 + u;
            float g0 = gg[0]    + gs[0][u_loc][b];
            float g1 = gg[512]  + gs[1][u_loc][b];
            float g2 = gg[1024] + gs[2][u_loc][b];
            float g3 = gg[1536] + gs[3][u_loc][b];
            float ig = sigm(g0), fg = sigm(g1), gt = tanhf(g2), og = sigm(g3);
            c0v = fg * c0v + ig * gt;
            float h0n = og * tanhf(c0v);
            pstore(&h0pk[cur * 8192 + b * 512 + u],
                   ((uint)(ushort)bf16s(h0n) << 16) | ((uint)(t + 2) & 0xffffu));
        }
        poll_stage32(h0pk + cur * 8192 + sflat, (uint)(t + 2) & 0xffffu,
                     hb + sb * 1032 + kseg * 32);
        poll_stage32(h1pk + ((t + 1) & 1) * 8192 + sflat, (uint)(t + 1) & 0xffffu,
                     hb + sb * 1032 + 512 + kseg * 32);
        __syncthreads();
        {
            f32x4 acc = {0.f, 0.f, 0.f, 0.f};
            const ushort* hp = hb + cl * 1032 + hi * 8;
#pragma unroll
            for (int kt = 0; kt < 32; kt++) {
                short8 bfr = *(const short8*)(hp + kt * 32);
                acc = __builtin_amdgcn_mfma_f32_16x16x32_bf16(a1[kt], bfr, acc, 0, 0, 0);
            }
#pragma unroll
            for (int i = 0; i < 4; i++) gs[w][hi * 4 + i][cl] = acc[i];
        }
        __syncthreads();
        {
            float g0 = bi0 + gs[0][u_loc][b];
            float g1 = bi1 + gs[1][u_loc][b];
            float g2 = bi2 + gs[2][u_loc][b];
            float g3 = bi3 + gs[3][u_loc][b];
            float ig = sigm(g0), fg = sigm(g1), gt = tanhf(g2), og = sigm(g3);
            c1v = fg * c1v + ig * gt;
            float h1n = og * tanhf(c1v);
            pstore(&h1pk[cur * 8192 + b * 512 + u],
                   ((uint)(ushort)bf16s(h1n) << 16) | ((uint)(t + 2) & 0xffffu));
            h1out[((size_t)(t * B + b)) * 512 + u] = h1n;
        }
        __syncthreads();
    }
}

// ---- build enchB body: bf16 octet pack [b][o(64)][s(512)][8k]. bid in [0,2048).
__device__ __forceinline__ void encht2_body(int bid,
        const float* __restrict__ h1f, const float* __restrict__ h1b,
        ushort* __restrict__ enchB) {
    int idx = bid * 256 + threadIdx.x;      // 524288 total
    int b = idx >> 15;
    int r = idx & 32767;
    int o = r >> 9, s = r & 511;
    const float* src = (o < 32) ? (h1f + ((size_t)(s * B + b)) * H + o * 8)
                                : (h1b + ((size_t)(s * B + b)) * H + (o - 32) * 8);
    float4 v0 = *(const float4*)src, v1 = *(const float4*)(src + 4);
    st_bf8(enchB + ((size_t)b << 18) + o * 4096 + s * 8, v0, v1);
}

// ---- out_proj body (packed-k layout). bid in [0,1000). smem >= 16512 B.
__device__ __forceinline__ void outproj_body(int bid, char* smem,
        const float* __restrict__ emb, const float* __restrict__ Wvoc,
        __hip_bfloat16* __restrict__ outT2) {
    float (*er)[E + 1] = (float(*)[E + 1])smem;
    int j0 = bid * 32;
    int jl = threadIdx.x & 31, oq = threadIdx.x >> 5;
    for (int i = threadIdx.x; i < 32 * E; i += 256) {
        int jj = i >> 7, e = i & 127;
        int j = j0 + jj;
        er[jj][e] = (j < VO) ? emb[(size_t)(3 + j) * E + e] : 0.f;
    }
    __syncthreads();
    int j = j0 + jl;
#pragma unroll 1
    for (int i = 0; i < 24; i++) {
        int o = oq * 24 + i;
        int k0 = o * 8;
        float acc[8];
#pragma unroll
        for (int kk = 0; kk < 8; kk++) acc[kk] = 0.f;
#pragma unroll 4
        for (int e = 0; e < E; e++) {
            float x = er[jl][e];
            float4 w0 = *(const float4*)(Wvoc + (size_t)e * C3 + k0);
            float4 w1 = *(const float4*)(Wvoc + (size_t)e * C3 + k0 + 4);
            acc[0] += x * w0.x; acc[1] += x * w0.y; acc[2] += x * w0.z; acc[3] += x * w0.w;
            acc[4] += x * w1.x; acc[5] += x * w1.y; acc[6] += x * w1.z; acc[7] += x * w1.w;
        }
        short8 v;
#pragma unroll
        for (int kk = 0; kk < 8; kk++) v[kk] = bf16s(tanhf(acc[kk]));
        *reinterpret_cast<short8*>((char*)outT2 + ((size_t)o * JS + j) * 16) = v;
    }
}

// ================= mega-kernels =================

// megaA: blocks 0..15 = enc L0 scan; 16..271 = dec0 gates.
__global__ void __launch_bounds__(256) megaA(
        const float* Gf, const float* Gb, const ushort* PMf, const ushort* PMb,
        float* hof, float* hob, float* hfin, uint* pk,
        const int* tgt, const float* emb, const float4* PdW, const float* dbias,
        float* Gd0) {
    __shared__ __align__(16) char smem[17152];
    int blk = blockIdx.x;
    if (blk < 16) enc_scan_body(blk, smem, Gf, Gb, PMf, PMb, hof, hob, hfin, pk);
    else dec0_body(blk - 16, smem, tgt, emb, PdW, dbias, Gd0);
}

// plain L1 scan wrapper
__global__ void __launch_bounds__(256) enc_pscan3(
        const float* Gf, const float* Gb, const ushort* PMf, const ushort* PMb,
        float* hof, float* hob, float* hfin, uint* pk) {
    __shared__ __align__(16) char smem[17152];
    enc_scan_body(blockIdx.x, smem, Gf, Gb, PMf, PMb, hof, hob, hfin, pk);
}

// megaC: blocks 0..31 = dec scan; 32..2079 = enchB pack; 2080..3079 = outproj.
__global__ void __launch_bounds__(256) megaC(
        const float* G0, const ushort* PM0, const ushort* PM1, const float* b1,
        uint* h0pk, uint* h1pk, float* h1out,
        const float* h1f, const float* h1b, ushort* enchB,
        const float* emb, const float* Wvoc, __hip_bfloat16* outT2) {
    __shared__ __align__(16) char smem[37376];
    int blk = blockIdx.x;
    if (blk < 32) dec_body(blk, smem, G0, PM0, PM1, b1, h0pk, h1pk, h1out);
    else if (blk < 32 + 2048) encht2_body(blk - 32, h1f, h1b, enchB);
    else outproj_body(blk - 2080, smem, emb, Wvoc, outT2);
}

// ---------------- decoder init packets (tag 1, parity 1)
__global__ void dec_initpk(const float* __restrict__ hinit,
                           uint* __restrict__ h0pk, uint* __restrict__ h1pk) {
    int i = blockIdx.x * blockDim.x + threadIdx.x;
    if (i >= B * D) return;
    pstore(&h0pk[8192 + i], ((uint)(ushort)bf16s(hinit[i]) << 16) | 1u);
    pstore(&h1pk[8192 + i], ((uint)(ushort)bf16s(hinit[B * D + i]) << 16) | 1u);
}

// ---------------- q projections. grid T*B, 512 threads; writes bf16 qe + f32 qd.
__global__ void qproj(const float* __restrict__ h1d, const float* __restrict__ Wenc,
                      const float* __restrict__ Wdec, ushort* __restrict__ qeb16,
                      float* __restrict__ qd) {
    int n = blockIdx.x;
    int o = threadIdx.x;
    __shared__ float hr[D];
    hr[o] = h1d[(size_t)n * D + o];
    __syncthreads();
    float ae = 0.f, ad = 0.f;
#pragma unroll 4
    for (int k = 0; k < D; k++) {
        float hk = hr[k];
        ae += hk * Wenc[k * D + o];
        ad += hk * Wdec[k * D + o];
    }
    int b = n & 15, t = n >> 4;
    qeb16[((size_t)(b * 128 + t) << 9) + o] = (ushort)bf16s(ae);
    qd[(size_t)n * D + o] = ad;
}

// ---------------- escore via MFMA: scores = Q[128,512] @ enchB, fused exp(min(.,30)).
// grid 16 (b), 512 thr = 8 waves; A = q rows in registers (16 frags).
__global__ void __launch_bounds__(512) escore_mfma(
        const ushort* __restrict__ qeb16, const ushort* __restrict__ enchB,
        float* __restrict__ ew) {
    __shared__ __align__(16) ushort Bs[2][8192];
    int b = blockIdx.x;
    int tid = threadIdx.x;
    int lane = tid & 63, w = tid >> 6;
    int cl = lane & 15, hi = lane >> 4;
    short8 a[16];
    {
        const ushort* asrc = qeb16 + ((size_t)(b * 128 + w * 16 + cl) << 9) + hi * 8;
#pragma unroll
        for (int kt = 0; kt < 16; kt++) a[kt] = *(const short8*)(asrc + kt * 32);
    }
    const ushort* ebase = enchB + ((size_t)b << 18);
#pragma unroll
    for (int ii = 0; ii < 2; ii++) {
        int c = tid * 2 + ii;
        int o = c >> 4, sl = c & 15;
        gload_lds16(ebase + o * 4096 + sl * 8, (char*)&Bs[0][0] + (size_t)c * 16);
    }
    asm volatile("s_waitcnt vmcnt(0)" ::: "memory");
    __syncthreads();
    int buf = 0;
    for (int st = 0; st < 32; st++) {
        if (st + 1 < 32) {
#pragma unroll
            for (int ii = 0; ii < 2; ii++) {
                int c = tid * 2 + ii;
                int o = c >> 4, sl = c & 15;
                gload_lds16(ebase + o * 4096 + ((st + 1) * 16 + sl) * 8,
                            (char*)&Bs[buf ^ 1][0] + (size_t)c * 16);
            }
        }
        f32x4 acc = {0.f, 0.f, 0.f, 0.f};
        const ushort* bp = &Bs[buf][0] + (hi * 16 + cl) * 8;
#pragma unroll
        for (int kt = 0; kt < 16; kt++) {
            short8 bb = *(const short8*)(bp + kt * 512);
            acc = __builtin_amdgcn_mfma_f32_16x16x32_bf16(a[kt], bb, acc, 0, 0, 0);
        }
        int s = st * 16 + cl;
#pragma unroll
        for (int i = 0; i < 4; i++) {
            int t = w * 16 + hi * 4 + i;
            ew[((size_t)(b * T + t)) * S + s] = __expf(fminf(acc[i], 30.0f));
        }
        asm volatile("s_waitcnt vmcnt(0)" ::: "memory");
        __syncthreads();
        buf ^= 1;
    }
}

// ---------------- temporal normalization (prefix over t)
__global__ void temporal_k(float* __restrict__ ew) {
    int i = blockIdx.x * blockDim.x + threadIdx.x;
    if (i >= B * S) return;
    int b = i / S, sx = i - b * S;
    float cum = 0.f;
    for (int t = 0; t < T; t++) {
        size_t idx = ((size_t)(b * T + t)) * S + sx;
        float v = ew[idx];
        ew[idx] = v / (t == 0 ? 1.0f : (cum + 1e-8f));
        cum += v;
    }
}

// ---------------- attention softmax + enc context + copy prob. grid B*T, 512 thr
__global__ void attnctx(const float* __restrict__ ew, const int* __restrict__ ids,
                        const int* __restrict__ tgt,
                        const float* __restrict__ h1f, const float* __restrict__ h1b,
                        float* __restrict__ ectx, float* __restrict__ copyp) {
    int bt = blockIdx.x;
    int b = bt / T, t = bt - b * T;
    int tid = threadIdx.x;
    __shared__ float aw[S];
    __shared__ float red[512];
    float v = ew[(size_t)bt * S + tid];
    int tok = ids[b * S + tid];
    bool pad = (tok == PAD_ID);
    float vm = pad ? -INFINITY : v;
    red[tid] = vm; __syncthreads();
    for (int w = 256; w > 0; w >>= 1) { if (tid < w) red[tid] = fmaxf(red[tid], red[tid + w]); __syncthreads(); }
    float m = red[0]; __syncthreads();
    float ex = pad ? 0.f : __expf(vm - m);
    red[tid] = ex; __syncthreads();
    for (int w = 256; w > 0; w >>= 1) { if (tid < w) red[tid] += red[tid + w]; __syncthreads(); }
    float Z = red[0]; __syncthreads();
    float a = ex / Z;
    aw[tid] = a;
    int nt = tgt[b * T + t];
    red[tid] = (tok == nt) ? a : 0.f; __syncthreads();
    for (int w = 256; w > 0; w >>= 1) { if (tid < w) red[tid] += red[tid + w]; __syncthreads(); }
    if (tid == 0) copyp[bt] = red[0];
    __syncthreads();
    int d = tid;
    const float* hp = (d < H) ? (h1f + (size_t)b * H + d) : (h1b + (size_t)b * H + (d - H));
    float acc = 0.f;
#pragma unroll 4
    for (int s2 = 0; s2 < S; s2++) { acc += aw[s2] * hp[0]; hp += B * H; }
    ectx[(size_t)bt * D + d] = acc;
}

// ---------------- intra-decoder attention. grid B*T, 128 threads
__global__ void decattn(const float* __restrict__ qd, const float* __restrict__ h1d,
                        float* __restrict__ dctx) {
    int bt = blockIdx.x;
    int b = bt / T, t = bt - b * T;
    int tid = threadIdx.x;
    __shared__ float q[D];
    __shared__ float wl[T];
    __shared__ float red[128];
    for (int i = tid; i < D; i += 128) q[i] = qd[((size_t)(t * B + b)) * D + i];
    __syncthreads();
    float sc = -INFINITY;
    if (tid < t) {
        const float* hu = h1d + ((size_t)(tid * B + b)) * D;
        float a = 0.f;
#pragma unroll 4
        for (int k = 0; k < D; k++) a += q[k] * hu[k];
        sc = a;
    }
    red[tid] = sc; __syncthreads();
    for (int w = 64; w > 0; w >>= 1) { if (tid < w) red[tid] = fmaxf(red[tid], red[tid + w]); __syncthreads(); }
    float m = red[0]; __syncthreads();
    float ex = (tid < t) ? __expf(sc - m) : 0.f;
    red[tid] = ex; __syncthreads();
    for (int w = 64; w > 0; w >>= 1) { if (tid < w) red[tid] += red[tid + w]; __syncthreads(); }
    float Z = red[0]; __syncthreads();
    wl[tid] = (t > 0) ? (ex / Z) : 0.f;
    __syncthreads();
    for (int d = tid; d < D; d += 128) {
        float acc = 0.f;
        for (int u = 0; u < t; u++) acc += wl[u] * h1d[((size_t)(u * B + b)) * D + d];
        dctx[(size_t)bt * D + d] = acc;
    }
}

// ---------------- concat + p_gen; writes bf16 ccb16 [row][1536]. grid B*T, 512 thr
__global__ void concat_k(const float* __restrict__ h1d, const float* __restrict__ ectx,
                         const float* __restrict__ dctx, const float* __restrict__ sW,
                         const float* __restrict__ sb, ushort* __restrict__ ccb16,
                         float* __restrict__ pgen) {
    int bt = blockIdx.x;
    int b = bt / T, t = bt - b * T;
    int d = threadIdx.x;
    __shared__ float red[512];
    float v0 = h1d[((size_t)(t * B + b)) * D + d];
    float v1 = ectx[(size_t)bt * D + d];
    float v2 = dctx[(size_t)bt * D + d];
    ushort* c = ccb16 + (size_t)bt * C3;
    c[d] = (ushort)bf16s(v0); c[D + d] = (ushort)bf16s(v1); c[2 * D + d] = (ushort)bf16s(v2);
    red[d] = v0 * sW[d] + v1 * sW[D + d] + v2 * sW[2 * D + d];
    __syncthreads();
    for (int w = 256; w > 0; w >>= 1) { if (d < w) red[d] += red[d + w]; __syncthreads(); }
    if (d == 0) pgen[bt] = 1.f / (1.f + __expf(-(red[0] + sb[0])));
}

// ---------------- vocab GEMM: register-A (M=128/block), LDS dbuf B stream (passing).
__global__ void __launch_bounds__(512) vocab_mfma3(
        const __hip_bfloat16* __restrict__ outT2, const ushort* __restrict__ ccb16,
        const float* __restrict__ ob, const int* __restrict__ tgt,
        float* __restrict__ pbuf) {
    __shared__ __align__(16) ushort Bs[2][3072 * 8];   // 2 x 48 KB
    __shared__ int jstar_s[128];
    int bid = blockIdx.x;
    int rb = bid & 15, jg = bid >> 4;
    int row0 = rb * 128;
    int tid = threadIdx.x;
    int lane = tid & 63, w = tid >> 6;
    int cl = lane & 15, hi = lane >> 4;
    int j0base = jg * 2000;

    if (tid < 128) {
        int nt = tgt[row0 + tid];
        int ix = nt - 3;
        ix = ix < 0 ? 0 : (ix > VO - 1 ? VO - 1 : ix);
        jstar_s[tid] = ix;
    }
    short8 a[48];
    {
        const ushort* asrc = ccb16 + (size_t)(row0 + w * 16 + cl) * C3 + hi * 8;
#pragma unroll
        for (int kt = 0; kt < 48; kt++) a[kt] = *(const short8*)(asrc + kt * 32);
    }
    {
#pragma unroll
        for (int ii = 0; ii < 6; ii++) {
            int c = w * 384 + ii * 64 + lane;
            int o = c >> 4, jl = c & 15;
            const char* g = (const char*)outT2 + ((size_t)o * JS + (size_t)(j0base + jl)) * 16;
            gload_lds16(g, (char*)&Bs[0][0] + (size_t)(w * 384 + ii * 64) * 16);
        }
    }
    asm volatile("s_waitcnt vmcnt(0)" ::: "memory");
    __syncthreads();
    int jst[4];
    float m[4], sacc[4], gl[4];
#pragma unroll
    for (int i = 0; i < 4; i++) {
        jst[i] = jstar_s[w * 16 + hi * 4 + i];
        m[i] = -1e30f; sacc[i] = 0.f; gl[i] = -1e30f;
    }
    int buf = 0;
    for (int t = 0; t < 125; t++) {
        if (t + 1 < 125) {
            int j0 = j0base + (t + 1) * 16;
#pragma unroll
            for (int ii = 0; ii < 6; ii++) {
                int c = w * 384 + ii * 64 + lane;
                int o = c >> 4, jl = c & 15;
                const char* g = (const char*)outT2 + ((size_t)o * JS + (size_t)(j0 + jl)) * 16;
                gload_lds16(g, (char*)&Bs[buf ^ 1][0] + (size_t)(w * 384 + ii * 64) * 16);
            }
        }
        f32x4 acc = {0.f, 0.f, 0.f, 0.f};
        const ushort* bp = &Bs[buf][0] + (size_t)(hi * 16 + cl) * 8;
#pragma unroll
        for (int kt = 0; kt < 48; kt++) {
            short8 b = *(const short8*)(bp + (size_t)kt * 512);
            acc = __builtin_amdgcn_mfma_f32_16x16x32_bf16(a[kt], b, acc, 0, 0, 0);
        }
        int j = j0base + t * 16 + cl;
        bool valid = j < VO;
        float obj = valid ? ob[j] : 0.f;
#pragma unroll
        for (int i = 0; i < 4; i++) {
            float L = acc[i] + obj;
            if (valid) {
                if (j == jst[i]) gl[i] = L;
                float mn = fmaxf(m[i], L);
                sacc[i] = sacc[i] * __expf(m[i] - mn) + __expf(L - mn);
                m[i] = mn;
            }
        }
        asm volatile("s_waitcnt vmcnt(0)" ::: "memory");
        __syncthreads();
        buf ^= 1;
    }
#pragma unroll
    for (int i = 0; i < 4; i++) {
        for (int mask = 1; mask < 16; mask <<= 1) {
            float om = __shfl_xor(m[i], mask);
            float os = __shfl_xor(sacc[i], mask);
            float mn = fmaxf(m[i], om);
            sacc[i] = sacc[i] * __expf(m[i] - mn) + os * __expf(om - mn);
            m[i] = mn;
            gl[i] = fmaxf(gl[i], __shfl_xor(gl[i], mask));
        }
    }
    if (cl == 0) {
#pragma unroll
        for (int i = 0; i < 4; i++) {
            int rl = w * 16 + hi * 4 + i;
            float* o = pbuf + ((size_t)(jg * 16 + rb) * 128 + rl) * 4;
            o[0] = m[i]; o[1] = sacc[i]; o[2] = gl[i];
        }
    }
}

// ---------------- combine 16 jg-partials + pointer mix + NLL. grid B, 128 threads.
__global__ void combine_nll_k(const float* __restrict__ pbuf, const int* __restrict__ tgt,
                              const float* __restrict__ pgen, const float* __restrict__ copyp,
                              const int* __restrict__ tlen, float* __restrict__ out) {
    int b = blockIdx.x, t = threadIdx.x;
    int row = b * T + t;
    int rb = row >> 7, rl = row & 127;
    float M = -1e30f, SS = 0.f, GL = -1e30f;
#pragma unroll
    for (int q = 0; q < 16; q++) {
        const float* p = pbuf + ((size_t)(q * 16 + rb) * 128 + rl) * 4;
        float mq = p[0], sq = p[1], gq = p[2];
        float mn = fmaxf(M, mq);
        SS = SS * __expf(M - mn) + sq * __expf(mq - mn);
        M = mn;
        GL = fmaxf(GL, gq);
    }
    int nt = tgt[row];
    float genp = (nt >= 3 && nt < V) ? __expf(GL - M) / SS : 0.f;
    float pg = pgen[row];
    float p = pg * genp + (1.f - pg) * copyp[row];
    __shared__ float red[128];
    red[t] = (t < tlen[b]) ? -logf(p + 1e-9f) : 0.f;
    __syncthreads();
    for (int w = 64; w > 0; w >>= 1) { if (t < w) red[t] += red[t + w]; __syncthreads(); }
    if (t == 0) out[b] = red[0];
}

extern "C" void kernel_launch(void* const* d_in, const int* in_sizes, int n_in,
                              void* d_out, int out_size, void* d_ws, size_t ws_size,
                              hipStream_t stream) {
    const int* input_ids = (const int*)d_in[0];
    const int* target_ids = (const int*)d_in[1];
    const int* tlen = (const int*)d_in[3];
    const float* emb = (const float*)d_in[5];
    const float* eWih0f = (const float*)d_in[6],  *eWhh0f = (const float*)d_in[7],  *eb0f = (const float*)d_in[8];
    const float* eWih0b = (const float*)d_in[9],  *eWhh0b = (const float*)d_in[10], *eb0b = (const float*)d_in[11];
    const float* eWih1f = (const float*)d_in[12], *eWhh1f = (const float*)d_in[13], *eb1f = (const float*)d_in[14];
    const float* eWih1b = (const float*)d_in[15], *eWhh1b = (const float*)d_in[16], *eb1b = (const float*)d_in[17];
    const float* dWih0 = (const float*)d_in[18], *dWhh0 = (const float*)d_in[19], *db0 = (const float*)d_in[20];
    const float* dWih1 = (const float*)d_in[21], *dWhh1 = (const float*)d_in[22], *db1 = (const float*)d_in[23];
    const float* Wenc = (const float*)d_in[24], *Wdec = (const float*)d_in[25];
    const float* Wvoc = (const float*)d_in[26], *sW = (const float*)d_in[27], *sb = (const float*)d_in[28];
    const float* ob = (const float*)d_in[29];
    float* out = (float*)d_out;
    (void)ws_size; (void)n_in; (void)in_sizes; (void)out_size;

    // ============ workspace layout (~185 MB, phase-aliased) ============
    char* A = (char*)d_ws;                          // 98,304,000 B
    float4* pWih0f = (float4*)(A + 0);
    float4* pWih0b = (float4*)(A + 524288);
    ushort* PMW1f  = (ushort*)(A + 1048576);
    ushort* PMW1b  = (ushort*)(A + 2097152);
    float4* pdWih0 = (float4*)(A + 5242880);
    ushort* PMf0  = (ushort*)(A + 6291456);
    ushort* PMb0  = (ushort*)(A + 6815744);
    ushort* PMf1  = (ushort*)(A + 7340032);
    ushort* PMb1  = (ushort*)(A + 7864320);
    float* G0f = (float*)(A + 23068672);            // 33.5 MB (L0 then L1 gates)
    float* G0b = (float*)(A + 56623104);            // 33.5 MB
    __hip_bfloat16* outT2 = (__hip_bfloat16*)A;     // whole region, written in megaC

    char* Bh = A + 98304000;                        // 16,777,216 B
    float* h0f = (float*)(Bh + 0);
    float* h0b = (float*)(Bh + 8388608);
    float* h1d = (float*)(Bh + 0);                  // aliases h0f (dead after enc1 gates)
    ushort* qeb16 = (ushort*)(Bh + 4194304);        // 2 MB (bf16 q rows)
    float* qd  = (float*)(Bh + 8388608);            // aliases h0b (dead)
    float* ew  = (float*)(Bh + 12582912);           // 4 MB
    float* pbuf = (float*)(Bh + 12582912);          // aliases ew (dead after attnctx)

    char* Cr = Bh + 16777216;                       // ~30 MB
    float* h1f = (float*)(Cr + 0);
    float* h1b = (float*)(Cr + 8388608);
    ushort* ccb16 = (ushort*)(Cr + 16777216);
    float* dec_init = (float*)(Cr + 29360128);
    float* pgen  = (float*)(Cr + 29425664);
    float* copyp = (float*)(Cr + 29433856);
    uint* hpkE0  = (uint*)(Cr + 29769728);          // 64 KB packets
    uint* hpkE1  = (uint*)(Cr + 29835264);
    uint* h0pkD  = (uint*)(Cr + 29900800);
    uint* h1pkD  = (uint*)(Cr + 29966336);          // ends Cr+30,031,872

    char* X = Cr + 30031872;                        // 39.8 MB non-aliased region
    float*  Gd0x  = (float*)(X + 0);                // 16,777,216
    ushort* PM0x  = (ushort*)(X + 16777216);        // 2,097,152
    ushort* PM1x  = (ushort*)(X + 18874368);        // 4,194,304
    ushort* enchB = (ushort*)(X + 23068672);        // 8,388,608
    float*  ectx  = (float*)(X + 31457280);         // 4,194,304
    float*  dctx  = (float*)(X + 35651584);         // 4,194,304
    // total ≈ 98,304,000 + 16,777,216 + 30,031,872 + 39,845,888 = 184,958,976 B

    hipMemsetAsync(hpkE0, 0, 262144, stream);       // all four packet regions

    auto pack = [&](const float* W, float4* P, int Hn, int K) {
        int total = Hn * K;
        hipLaunchKernelGGL(pack4_kernel, dim3((total + 255) / 256), dim3(256), 0, stream, W, P, Hn, K);
    };
    pack(eWih0f, pWih0f, H, E);
    pack(eWih0b, pWih0b, H, E);
    pack(dWih0, pdWih0, D, E);
    hipLaunchKernelGGL(packencMK_k, dim3(4 * H * 256 / 256), dim3(256), 0, stream, eWhh0f, PMf0, 256);
    hipLaunchKernelGGL(packencMK_k, dim3(4 * H * 256 / 256), dim3(256), 0, stream, eWhh0b, PMb0, 256);
    hipLaunchKernelGGL(packencMK_k, dim3(4 * H * 256 / 256), dim3(256), 0, stream, eWhh1f, PMf1, 256);
    hipLaunchKernelGGL(packencMK_k, dim3(4 * H * 256 / 256), dim3(256), 0, stream, eWhh1b, PMb1, 256);
    hipLaunchKernelGGL(packencMK_k, dim3(4 * H * 512 / 256), dim3(256), 0, stream, eWih1f, PMW1f, 512);
    hipLaunchKernelGGL(packencMK_k, dim3(4 * H * 512 / 256), dim3(256), 0, stream, eWih1b, PMW1b, 512);
    hipLaunchKernelGGL(packdecM_k, dim3(4 * D * D / 256), dim3(256), 0, stream, dWhh0, PM0x);
    hipLaunchKernelGGL(packdecM2_k, dim3(8 * D * D / 256), dim3(256), 0, stream, dWih1, dWhh1, PM1x);

    hipLaunchKernelGGL(enc0_gates2, dim3(S * B / 8), dim3(256), 0, stream,
                       input_ids, emb, pWih0f, eb0f, pWih0b, eb0b, G0f, G0b);
    // megaA: enc L0 scan (16) + dec0 gates (256)
    hipLaunchKernelGGL(megaA, dim3(272), dim3(256), 0, stream,
                       G0f, G0b, PMf0, PMb0, h0f, h0b, dec_init, hpkE0,
                       target_ids, emb, pdWih0, db0, Gd0x);
    hipLaunchKernelGGL(enc1g_mfma, dim3(256), dim3(256), 0, stream,
                       h0f, h0b, PMW1f, PMW1b, eb1f, eb1b, G0f, G0b);
    hipLaunchKernelGGL(enc_pscan3, dim3(16), dim3(256), 0, stream,
                       G0f, G0b, PMf1, PMb1, h1f, h1b, dec_init + B * D, hpkE1);
    hipLaunchKernelGGL(dec_initpk, dim3(B * D / 256), dim3(256), 0, stream,
                       dec_init, h0pkD, h1pkD);
    // megaC: dec scan (32) + enchB pack (2048) + outproj (1000)
    hipLaunchKernelGGL(megaC, dim3(3080), dim3(256), 0, stream,
                       Gd0x, PM0x, PM1x, db1, h0pkD, h1pkD, h1d,
                       h1f, h1b, enchB, emb, Wvoc, outT2);
    hipLaunchKernelGGL(qproj, dim3(T * B), dim3(D), 0, stream, h1d, Wenc, Wdec, qeb16, qd);
    hipLaunchKernelGGL(escore_mfma, dim3(16), dim3(512), 0, stream, qeb16, enchB, ew);
    hipLaunchKernelGGL(temporal_k, dim3((B * S + 255) / 256), dim3(256), 0, stream, ew);
    hipLaunchKernelGGL(attnctx, dim3(B * T), dim3(S), 0, stream,
                       ew, input_ids, target_ids, h1f, h1b, ectx, copyp);
    hipLaunchKernelGGL(decattn, dim3(B * T), dim3(T), 0, stream, qd, h1d, dctx);
    hipLaunchKernelGGL(concat_k, dim3(B * T), dim3(D), 0, stream,
                       h1d, ectx, dctx, sW, sb, ccb16, pgen);
    hipLaunchKernelGGL(vocab_mfma3, dim3(256), dim3(512), 0, stream,
                       outT2, ccb16, ob, target_ids, pbuf);
    hipLaunchKernelGGL(combine_nll_k, dim3(B), dim3(T), 0, stream,
                       pbuf, target_ids, pgen, copyp, tlen, out);
}